// Round 9
// baseline (649.190 us; speedup 1.0000x reference)
//
#include <hip/hip_runtime.h>
#include <math.h>

constexpr int CC = 64, KK = 256, LL = 128;
constexpr int NN = KK * LL;          // 32768
constexpr int PR = 64;               // Linformer projection
constexpr int CPG = 16;              // channels per group (C / 4)
constexpr float EPSV = 1e-5f;
constexpr float SCL = 0.35355339059327373f;  // 1/sqrt(8)

typedef __attribute__((ext_vector_type(8))) short short8;      // 8 bf16 (4 VGPR)
typedef __attribute__((ext_vector_type(4))) float f32x4;       // MFMA 16x16 acc

__device__ __forceinline__ unsigned short f2bf(float x) {
  union { float f; unsigned int u; } v; v.f = x;
  unsigned int r = (v.u + 0x7FFFu + ((v.u >> 16) & 1u)) >> 16;
  return (unsigned short)r;
}
__device__ __forceinline__ float bf2f(unsigned short x) {
  union { unsigned int u; float f; } v; v.u = ((unsigned int)x) << 16;
  return v.f;
}
// unpack uint holding 2 bf16 (little-endian: low ushort = even elem)
__device__ __forceinline__ float2 unpbf2(unsigned int u) {
  union { unsigned int q; float f; } a, b;
  a.q = u << 16; b.q = u & 0xFFFF0000u;
  return make_float2(a.f, b.f);
}

// ---------------- adaptive adjacency: softmax(relu(nv1@nv2), axis=1) ----------------
__global__ __launch_bounds__(256) void k_adp(const float* __restrict__ nv1,
                                             const float* __restrict__ nv2,
                                             float* __restrict__ adp) {
  int w = blockIdx.x, v = threadIdx.x;
  float s = 0.f;
  for (int d = 0; d < 10; ++d) s += nv1[w * 10 + d] * nv2[d * KK + v];
  s = fmaxf(s, 0.f);
  __shared__ float red[256];
  red[v] = s; __syncthreads();
  for (int off = 128; off; off >>= 1) { if (v < off) red[v] = fmaxf(red[v], red[v + off]); __syncthreads(); }
  float m = red[0]; __syncthreads();
  float e = expf(s - m);
  red[v] = e; __syncthreads();
  for (int off = 128; off; off >>= 1) { if (v < off) red[v] += red[v + off]; __syncthreads(); }
  adp[w * KK + v] = e / red[0];
}

// ---------------- fp32 -> bf16 cast ----------------
__global__ __launch_bounds__(256) void k_cast(const float* __restrict__ src,
                                              unsigned short* __restrict__ dst) {
  int i = blockIdx.x * 256 + threadIdx.x;
  dst[i] = f2bf(src[i]);
}

// ---------------- channel-mix: U_s[(b,l,k), o] = xs[(b,l,k), c] @ W_s[c][o]  (MFMA, K=64) ----------------
__global__ __launch_bounds__(64) void k_mix(const unsigned short* __restrict__ Xbf,
                                            const unsigned short* __restrict__ Wbf,
                                            const float* __restrict__ bias,
                                            float* __restrict__ s0,
                                            unsigned short* __restrict__ U1, unsigned short* __restrict__ U2,
                                            unsigned short* __restrict__ U3, unsigned short* __restrict__ U4,
                                            unsigned short* __restrict__ U5, unsigned short* __restrict__ U6) {
  unsigned short* Us[6] = {U1, U2, U3, U4, U5, U6};
  int pb = blockIdx.x;
  int b = pb >> 9;
  int rem = pb & 511;
  int l = rem >> 2;
  int kq = (rem & 3) * 64;
  size_t posbase = ((size_t)(b * 128 + l)) * 256 + kq;
  int lane = threadIdx.x;
  int lr = lane & 15, g = lane >> 4;

  short8 af[4][2];
#pragma unroll
  for (int rt = 0; rt < 4; ++rt)
#pragma unroll
    for (int kc = 0; kc < 2; ++kc)
      af[rt][kc] = *(const short8*)(Xbf + (posbase + rt * 16 + lr) * 64 + kc * 32 + g * 8);

  for (int s = 0; s < 7; ++s) {
    short8 bf[4][2];
#pragma unroll
    for (int ct = 0; ct < 4; ++ct)
#pragma unroll
      for (int kc = 0; kc < 2; ++kc)
        bf[ct][kc] = *(const short8*)(Wbf + (size_t)(ct * 16 + lr) * 448 + s * 64 + kc * 32 + g * 8);
    f32x4 acc[4][4];
#pragma unroll
    for (int rt = 0; rt < 4; ++rt)
#pragma unroll
      for (int ct = 0; ct < 4; ++ct) acc[rt][ct] = f32x4{0.f, 0.f, 0.f, 0.f};
#pragma unroll
    for (int kc = 0; kc < 2; ++kc)
#pragma unroll
      for (int rt = 0; rt < 4; ++rt)
#pragma unroll
        for (int ct = 0; ct < 4; ++ct)
          acc[rt][ct] = __builtin_amdgcn_mfma_f32_16x16x32_bf16(af[rt][kc], bf[ct][kc], acc[rt][ct], 0, 0, 0);

    if (s == 0) {
#pragma unroll
      for (int rt = 0; rt < 4; ++rt)
#pragma unroll
        for (int ct = 0; ct < 4; ++ct) {
          int o = ct * 16 + lr;
          float bv = bias[o];
          int k = kq + rt * 16 + g * 4;
#pragma unroll
          for (int j = 0; j < 4; ++j)
            s0[(size_t)(b * 64 + o) * NN + (size_t)(k + j) * 128 + l] = acc[rt][ct][j] + bv;
        }
    } else {
      unsigned short* dst = Us[s - 1];
#pragma unroll
      for (int rt = 0; rt < 4; ++rt)
#pragma unroll
        for (int ct = 0; ct < 4; ++ct) {
          int o = ct * 16 + lr;
          int k = kq + rt * 16 + g * 4;
          ushort4 pk;
          pk.x = f2bf(acc[rt][ct][0]); pk.y = f2bf(acc[rt][ct][1]);
          pk.z = f2bf(acc[rt][ct][2]); pk.w = f2bf(acc[rt][ct][3]);
          *(ushort4*)&dst[((size_t)(b * 64 + o) * 128 + l) * 256 + k] = pk;
        }
    }
  }
}

// ---------------- out[bc, w, l] = sum_v A[w,v] * XT[bc, l, v]  (bf16 MFMA 16x16x32) ----------------
__global__ __launch_bounds__(256) void k_adjM(const unsigned short* __restrict__ Abf,
                                              const unsigned short* __restrict__ XT,
                                              float* __restrict__ out,
                                              unsigned short* __restrict__ outT,
                                              const unsigned short* __restrict__ addT) {
  int lq = blockIdx.x & 3, bc = blockIdx.x >> 2;
  int tid = threadIdx.x, wid = tid >> 6, lane = tid & 63;
  int lr = lane & 15, g = lane >> 4;
  int wbase = wid * 64;
  const unsigned short* aP = Abf + (size_t)(wbase + lr) * 256 + g * 8;
  const unsigned short* bP = XT + ((size_t)bc * 128 + lq * 32 + lr) * 256 + g * 8;
  f32x4 acc[4][2];
#pragma unroll
  for (int i = 0; i < 4; ++i)
#pragma unroll
    for (int j = 0; j < 2; ++j) acc[i][j] = f32x4{0.f, 0.f, 0.f, 0.f};
  for (int k0 = 0; k0 < 256; k0 += 32) {
    short8 af[4], bfv[2];
#pragma unroll
    for (int i = 0; i < 4; ++i) af[i] = *(const short8*)(aP + (size_t)i * 16 * 256 + k0);
#pragma unroll
    for (int i = 0; i < 2; ++i) bfv[i] = *(const short8*)(bP + (size_t)i * 16 * 256 + k0);
#pragma unroll
    for (int rm = 0; rm < 4; ++rm)
#pragma unroll
      for (int cn = 0; cn < 2; ++cn)
        acc[rm][cn] = __builtin_amdgcn_mfma_f32_16x16x32_bf16(af[rm], bfv[cn], acc[rm][cn], 0, 0, 0);
  }
  if (out) {
    float* dst = out + (size_t)bc * NN + lq * 32;
#pragma unroll
    for (int rm = 0; rm < 4; ++rm)
#pragma unroll
      for (int cn = 0; cn < 2; ++cn) {
        int col = cn * 16 + lr;
        int row = wbase + rm * 16 + g * 4;
#pragma unroll
        for (int j = 0; j < 4; ++j)
          dst[(size_t)(row + j) * 128 + col] = acc[rm][cn][j];
      }
  }
  if (outT) {
    unsigned short* dT = outT + (size_t)bc * NN + (size_t)(lq * 32) * 256;
    const unsigned short* aT = addT ? addT + (size_t)bc * NN + (size_t)(lq * 32) * 256 : nullptr;
#pragma unroll
    for (int rm = 0; rm < 4; ++rm)
#pragma unroll
      for (int cn = 0; cn < 2; ++cn) {
        int l = cn * 16 + lr;
        int v = wbase + rm * 16 + g * 4;
        float a0 = 0.f, a1 = 0.f, a2 = 0.f, a3 = 0.f;
        if (aT) {
          ushort4 av = *(const ushort4*)&aT[(size_t)l * 256 + v];
          a0 = bf2f(av.x); a1 = bf2f(av.y); a2 = bf2f(av.z); a3 = bf2f(av.w);
        }
        ushort4 pk;
        pk.x = f2bf(acc[rm][cn][0] + a0); pk.y = f2bf(acc[rm][cn][1] + a1);
        pk.z = f2bf(acc[rm][cn][2] + a2); pk.w = f2bf(acc[rm][cn][3] + a3);
        *(ushort4*)&dT[(size_t)l * 256 + v] = pk;
      }
  }
}

// ---------------- generic (c,l)-plane transpose per (b,k), optional add + bf16 side output ----------------
__global__ __launch_bounds__(256) void k_tr(const float* __restrict__ src, float* __restrict__ dst,
                                            const float* __restrict__ add,
                                            unsigned short* __restrict__ dstBf,
                                            long sb, long sk, long sc, long sl,
                                            long db, long dk, long dc, long dl, int nC, int nL) {
  int outer = blockIdx.x;
  int b = outer >> 8, k = outer & 255;
  int tilesL = nL >> 5;
  int tC = blockIdx.y / tilesL, tL = blockIdx.y % tilesL;
  int c0 = tC << 5, l0 = tL << 5;
  __shared__ float s[32][33];
  int tx = threadIdx.x & 31, ty = threadIdx.x >> 5;
  const float* sp = src + (long)b * sb + (long)k * sk;
#pragma unroll
  for (int j = 0; j < 4; ++j) {
    int cc = c0 + ty + j * 8;
    s[ty + j * 8][tx] = sp[(long)cc * sc + (long)(l0 + tx) * sl];
  }
  __syncthreads();
  long dbase = (long)b * db + (long)k * dk;
#pragma unroll
  for (int j = 0; j < 4; ++j) {
    int ll = l0 + ty + j * 8;
    long off = dbase + (long)(c0 + tx) * dc + (long)ll * dl;
    float val = s[tx][ty + j * 8];
    if (add) val += add[off];
    dst[off] = val;
    if (dstBf) dstBf[off] = f2bf(val);
  }
}

// ---------------- fused QKV row-matmul: (R,64) @ 3x(64,64) (+biases) ----------------
__global__ __launch_bounds__(256) void k_qkv(const float* __restrict__ in,
                                             const float* __restrict__ W0, const float* __restrict__ W1,
                                             const float* __restrict__ W2,
                                             const float* __restrict__ b0, const float* __restrict__ b1,
                                             const float* __restrict__ b2,
                                             float* __restrict__ o0, float* __restrict__ o1,
                                             float* __restrict__ o2) {
  int r0 = blockIdx.x * 64;
  __shared__ float sInT[64][68];
  __shared__ float sW[3][64][64];
  int t = threadIdx.x;
  for (int i = t; i < 4096; i += 256) {
    int c = i >> 6, o = i & 63;
    sW[0][c][o] = W0[i];
    sW[1][c][o] = W1[i];
    sW[2][c][o] = W2[i];
  }
  for (int i = t; i < 4096; i += 256) {
    int r = i >> 6, c = i & 63;
    sInT[c][r] = in[(size_t)(r0 + r) * 64 + c];
  }
  __syncthreads();
  int col = t & 63, rg = t >> 6;
  int rbase = rg * 16;
  float a0[16], a1[16], a2[16];
  float bv0 = b0 ? b0[col] : 0.f;
  float bv1 = b1 ? b1[col] : 0.f;
  float bv2 = b2 ? b2[col] : 0.f;
#pragma unroll
  for (int i = 0; i < 16; ++i) { a0[i] = bv0; a1[i] = bv1; a2[i] = bv2; }
  for (int c = 0; c < 64; ++c) {
    float w0 = sW[0][c][col], w1 = sW[1][c][col], w2 = sW[2][c][col];
#pragma unroll
    for (int rr = 0; rr < 16; rr += 4) {
      float4 xv = *(const float4*)&sInT[c][rbase + rr];
      a0[rr + 0] += xv.x * w0; a0[rr + 1] += xv.y * w0; a0[rr + 2] += xv.z * w0; a0[rr + 3] += xv.w * w0;
      a1[rr + 0] += xv.x * w1; a1[rr + 1] += xv.y * w1; a1[rr + 2] += xv.z * w1; a1[rr + 3] += xv.w * w1;
      a2[rr + 0] += xv.x * w2; a2[rr + 1] += xv.y * w2; a2[rr + 2] += xv.z * w2; a2[rr + 3] += xv.w * w2;
    }
  }
#pragma unroll
  for (int rr = 0; rr < 16; ++rr) {
    size_t idx = (size_t)(r0 + rbase + rr) * 64 + col;
    o0[idx] = a0[rr]; o1[idx] = a1[rr]; o2[idx] = a2[rr];
  }
}

// ---------------- row-major (R,CIN) @ (CIN,COUT) + bias, optional activation ----------------
template <int CIN, int COUT, int ACT, int ROWS>
__global__ __launch_bounds__(256) void k_rowmm(const float* __restrict__ in,
                                               const float* __restrict__ W,
                                               const float* __restrict__ bias,
                                               float* __restrict__ out) {
  int r0 = blockIdx.x * ROWS;
  __shared__ float sInT[CIN][ROWS + 4];
  __shared__ float sW[CIN][COUT];
  int t = threadIdx.x;
  for (int i = t; i < CIN * COUT; i += 256) ((float*)sW)[i] = W[i];
  for (int i = t; i < ROWS * CIN; i += 256) {
    int r = i / CIN, c = i % CIN;
    sInT[c][r] = in[(size_t)r0 * CIN + i];
  }
  __syncthreads();
  constexpr int NRG = 256 / COUT;
  constexpr int RPT = ROWS / NRG;
  int col = t % COUT, rg = t / COUT;
  int rbase = rg * RPT;
  float acc[RPT];
  float bv = bias ? bias[col] : 0.f;
#pragma unroll
  for (int r = 0; r < RPT; ++r) acc[r] = bv;
  for (int c = 0; c < CIN; ++c) {
    float wv = sW[c][col];
    if constexpr (RPT % 4 == 0) {
#pragma unroll
      for (int rr = 0; rr < RPT; rr += 4) {
        float4 xv = *(const float4*)&sInT[c][rbase + rr];
        acc[rr] += xv.x * wv; acc[rr + 1] += xv.y * wv;
        acc[rr + 2] += xv.z * wv; acc[rr + 3] += xv.w * wv;
      }
    } else {
#pragma unroll
      for (int rr = 0; rr < RPT; ++rr) acc[rr] += sInT[c][rbase + rr] * wv;
    }
  }
#pragma unroll
  for (int rr = 0; rr < RPT; ++rr) {
    float v = acc[rr];
    if (ACT == 1) v = fmaxf(v, 0.f);
    if (ACT == 2) v = 0.5f * v * (1.f + erff(v * 0.70710678118654752440f));
    out[(size_t)(r0 + rbase + rr) * COUT + col] = v;
  }
}

// ---------------- kp2[bl,p,c] = sum_n X[bl,n,c] * P[n,p] ----------------
__global__ __launch_bounds__(256) void k_sproj(const float* __restrict__ X,
                                               const float* __restrict__ P,
                                               float* __restrict__ out) {
  int bl = blockIdx.x;
  const float* src = X + (size_t)bl * KK * CC;
  float* dst = out + (size_t)bl * PR * CC;
  int t = threadIdx.x, c = t & 63, pg = t >> 6;
  __shared__ float sX[64][CC];
  __shared__ float sP[64][PR];
  float acc[16];
#pragma unroll
  for (int i = 0; i < 16; ++i) acc[i] = 0.f;
  for (int n0 = 0; n0 < KK; n0 += 64) {
    for (int i = t; i < 64 * CC; i += 256) ((float*)sX)[i] = src[(size_t)n0 * CC + i];
    for (int i = t; i < 64 * PR; i += 256) ((float*)sP)[i] = P[(size_t)n0 * PR + i];
    __syncthreads();
    for (int n = 0; n < 64; ++n) {
      float xv = sX[n][c];
#pragma unroll
      for (int q = 0; q < 4; ++q) {
        float4 pv = *(const float4*)&sP[n][pg * 16 + q * 4];
        acc[q * 4 + 0] += pv.x * xv; acc[q * 4 + 1] += pv.y * xv;
        acc[q * 4 + 2] += pv.z * xv; acc[q * 4 + 3] += pv.w * xv;
      }
    }
    __syncthreads();
  }
#pragma unroll
  for (int i = 0; i < 16; ++i) dst[(size_t)(pg * 16 + i) * CC + c] = acc[i];
}

// ---------------- spatial attention: block = (b,l,khalf), 8 waves = 8 heads; bf16 K/V in LDS ----------------
__global__ __launch_bounds__(512) void k_sattn(const float* __restrict__ Q, const float* __restrict__ KP,
                                               const float* __restrict__ VP, float* __restrict__ O) {
  int blk = blockIdx.x;
  int kh = blk & 1, bl = blk >> 1;
  int t = threadIdx.x;
  int h = t >> 6, lane = t & 63;
  __shared__ unsigned short sK[PR][64];   // 8 KB
  __shared__ unsigned short sV[PR][64];   // 8 KB
  {
    const float4* gK = (const float4*)(KP + (size_t)bl * PR * CC);
    const float4* gV = (const float4*)(VP + (size_t)bl * PR * CC);
    ushort4* lK = (ushort4*)sK;
    ushort4* lV = (ushort4*)sV;
    for (int i = t; i < 1024; i += 512) {
      float4 kx = gK[i], vx = gV[i];
      lK[i] = ushort4{f2bf(kx.x), f2bf(kx.y), f2bf(kx.z), f2bf(kx.w)};
      lV[i] = ushort4{f2bf(vx.x), f2bf(vx.y), f2bf(vx.z), f2bf(vx.w)};
    }
  }
  __syncthreads();
  float q[2][8], o[2][8], sum[2];
#pragma unroll
  for (int j = 0; j < 2; ++j) {
    int row = kh * 128 + j * 64 + lane;
    const float* qr = Q + ((size_t)bl * KK + row) * CC + h * 8;
    float4 qa = *(const float4*)qr, qb = *(const float4*)(qr + 4);
    q[j][0] = qa.x * SCL; q[j][1] = qa.y * SCL; q[j][2] = qa.z * SCL; q[j][3] = qa.w * SCL;
    q[j][4] = qb.x * SCL; q[j][5] = qb.y * SCL; q[j][6] = qb.z * SCL; q[j][7] = qb.w * SCL;
    sum[j] = 0.f;
#pragma unroll
    for (int d = 0; d < 8; ++d) o[j][d] = 0.f;
  }
  for (int p = 0; p < PR; ++p) {
    uint4 ku = *(const uint4*)&sK[p][h * 8];
    uint4 vu = *(const uint4*)&sV[p][h * 8];
    float k[8], v[8];
    { float2 e;
      e = unpbf2(ku.x); k[0] = e.x; k[1] = e.y;
      e = unpbf2(ku.y); k[2] = e.x; k[3] = e.y;
      e = unpbf2(ku.z); k[4] = e.x; k[5] = e.y;
      e = unpbf2(ku.w); k[6] = e.x; k[7] = e.y;
      e = unpbf2(vu.x); v[0] = e.x; v[1] = e.y;
      e = unpbf2(vu.y); v[2] = e.x; v[3] = e.y;
      e = unpbf2(vu.z); v[4] = e.x; v[5] = e.y;
      e = unpbf2(vu.w); v[6] = e.x; v[7] = e.y;
    }
#pragma unroll
    for (int j = 0; j < 2; ++j) {
      float s = 0.f;
#pragma unroll
      for (int d = 0; d < 8; ++d) s += q[j][d] * k[d];
      float e = __expf(s);
      sum[j] += e;
#pragma unroll
      for (int d = 0; d < 8; ++d) o[j][d] += e * v[d];
    }
  }
#pragma unroll
  for (int j = 0; j < 2; ++j) {
    float inv = 1.f / sum[j];
    int row = kh * 128 + j * 64 + lane;
    float* orow = O + ((size_t)bl * KK + row) * CC + h * 8;
    float4 ra = {o[j][0] * inv, o[j][1] * inv, o[j][2] * inv, o[j][3] * inv};
    float4 rb = {o[j][4] * inv, o[j][5] * inv, o[j][6] * inv, o[j][7] * inv};
    *(float4*)orow = ra; *(float4*)(orow + 4) = rb;
  }
}

// ---------------- temporal attention: block = (b,k), 8 waves = 8 heads; bf16 K/V in LDS ----------------
__global__ __launch_bounds__(512) void k_tattn(const float* __restrict__ Q, const float* __restrict__ Kt,
                                               const float* __restrict__ Vt, float* __restrict__ O) {
  int bk = blockIdx.x;
  int t = threadIdx.x;
  int h = t >> 6, lane = t & 63;
  __shared__ unsigned short sK[LL][64];   // 16 KB
  __shared__ unsigned short sV[LL][64];   // 16 KB
  {
    const float4* gK = (const float4*)(Kt + (size_t)bk * LL * CC);
    const float4* gV = (const float4*)(Vt + (size_t)bk * LL * CC);
    ushort4* lK = (ushort4*)sK;
    ushort4* lV = (ushort4*)sV;
    for (int i = t; i < 2048; i += 512) {
      float4 kx = gK[i], vx = gV[i];
      lK[i] = ushort4{f2bf(kx.x), f2bf(kx.y), f2bf(kx.z), f2bf(kx.w)};
      lV[i] = ushort4{f2bf(vx.x), f2bf(vx.y), f2bf(vx.z), f2bf(vx.w)};
    }
  }
  __syncthreads();
  float q[2][8], o[2][8], sum[2];
#pragma unroll
  for (int j = 0; j < 2; ++j) {
    int row = j * 64 + lane;
    const float* qr = Q + ((size_t)bk * LL + row) * CC + h * 8;
    float4 qa = *(const float4*)qr, qb = *(const float4*)(qr + 4);
    q[j][0] = qa.x * SCL; q[j][1] = qa.y * SCL; q[j][2] = qa.z * SCL; q[j][3] = qa.w * SCL;
    q[j][4] = qb.x * SCL; q[j][5] = qb.y * SCL; q[j][6] = qb.z * SCL; q[j][7] = qb.w * SCL;
    sum[j] = 0.f;
#pragma unroll
    for (int d = 0; d < 8; ++d) o[j][d] = 0.f;
  }
  for (int p = 0; p < LL; ++p) {
    uint4 ku = *(const uint4*)&sK[p][h * 8];
    uint4 vu = *(const uint4*)&sV[p][h * 8];
    float k[8], v[8];
    { float2 e;
      e = unpbf2(ku.x); k[0] = e.x; k[1] = e.y;
      e = unpbf2(ku.y); k[2] = e.x; k[3] = e.y;
      e = unpbf2(ku.z); k[4] = e.x; k[5] = e.y;
      e = unpbf2(ku.w); k[6] = e.x; k[7] = e.y;
      e = unpbf2(vu.x); v[0] = e.x; v[1] = e.y;
      e = unpbf2(vu.y); v[2] = e.x; v[3] = e.y;
      e = unpbf2(vu.z); v[4] = e.x; v[5] = e.y;
      e = unpbf2(vu.w); v[6] = e.x; v[7] = e.y;
    }
#pragma unroll
    for (int j = 0; j < 2; ++j) {
      float s = 0.f;
#pragma unroll
      for (int d = 0; d < 8; ++d) s += q[j][d] * k[d];
      float e = __expf(s);
      sum[j] += e;
#pragma unroll
      for (int d = 0; d < 8; ++d) o[j][d] += e * v[d];
    }
  }
#pragma unroll
  for (int j = 0; j < 2; ++j) {
    float inv = 1.f / sum[j];
    int row = j * 64 + lane;
    float* orow = O + ((size_t)bk * LL + row) * CC + h * 8;
    float4 ra = {o[j][0] * inv, o[j][1] * inv, o[j][2] * inv, o[j][3] * inv};
    float4 rb = {o[j][4] * inv, o[j][5] * inv, o[j][6] * inv, o[j][7] * inv};
    *(float4*)orow = ra; *(float4*)(orow + 4) = rb;
  }
}

// ---------------- LayerNorm over C=64 per row, input = A (+ optional Bp) ----------------
__global__ __launch_bounds__(256) void k_ln(const float* __restrict__ A, const float* __restrict__ Bp,
                                            const float* __restrict__ g, const float* __restrict__ be,
                                            float* __restrict__ out) {
  int row = blockIdx.x * 4 + (threadIdx.x >> 6);
  int c = threadIdx.x & 63;
  size_t idx = (size_t)row * CC + c;
  float x = A[idx] + (Bp ? Bp[idx] : 0.f);
  float s = x, ss = x * x;
#pragma unroll
  for (int off = 32; off; off >>= 1) { s += __shfl_xor(s, off); ss += __shfl_xor(ss, off); }
  float mu = s * (1.f / 64.f);
  float var = ss * (1.f / 64.f) - mu * mu;
  out[idx] = (x - mu) * rsqrtf(var + EPSV) * g[c] + be[c];
}

// ---------------- GroupNorm stats: up to 5 summed inputs, optional sum write-back ----------------
__global__ __launch_bounds__(256) void k_gn_part(const float* __restrict__ p0, const float* __restrict__ p1,
                                                 const float* __restrict__ p2, const float* __restrict__ p3,
                                                 const float* __restrict__ p4,
                                                 float* __restrict__ sumOut,
                                                 float* __restrict__ part) {
  int bg = blockIdx.y, blk = blockIdx.x, t = threadIdx.x;
  size_t start = (size_t)bg * ((size_t)CPG * NN) + (size_t)blk * 8192;
  const float4* q0 = (const float4*)(p0 + start);
  const float4* q1 = p1 ? (const float4*)(p1 + start) : nullptr;
  const float4* q2 = p2 ? (const float4*)(p2 + start) : nullptr;
  const float4* q3 = p3 ? (const float4*)(p3 + start) : nullptr;
  const float4* q4 = p4 ? (const float4*)(p4 + start) : nullptr;
  float4* so = sumOut ? (float4*)(sumOut + start) : nullptr;
  float s = 0.f, ss = 0.f;
  for (int i = t; i < 2048; i += 256) {
    float4 x = q0[i];
    if (q1) { float4 y4 = q1[i]; x.x += y4.x; x.y += y4.y; x.z += y4.z; x.w += y4.w; }
    if (q2) { float4 y4 = q2[i]; x.x += y4.x; x.y += y4.y; x.z += y4.z; x.w += y4.w; }
    if (q3) { float4 y4 = q3[i]; x.x += y4.x; x.y += y4.y; x.z += y4.z; x.w += y4.w; }
    if (q4) { float4 y4 = q4[i]; x.x += y4.x; x.y += y4.y; x.z += y4.z; x.w += y4.w; }
    if (so) so[i] = x;
    s += x.x + x.y + x.z + x.w;
    ss += x.x * x.x + x.y * x.y + x.z * x.z + x.w * x.w;
  }
  __shared__ float rs[256], rq[256];
  rs[t] = s; rq[t] = ss; __syncthreads();
  for (int off = 128; off; off >>= 1) { if (t < off) { rs[t] += rs[t + off]; rq[t] += rq[t + off]; } __syncthreads(); }
  if (t == 0) { part[(bg * 64 + blk) * 2] = rs[0]; part[(bg * 64 + blk) * 2 + 1] = rq[0]; }
}

__global__ __launch_bounds__(64) void k_gn_final(const float* __restrict__ part, float* __restrict__ stats) {
  int bg = blockIdx.x, t = threadIdx.x;
  float s = part[(bg * 64 + t) * 2], ss = part[(bg * 64 + t) * 2 + 1];
#pragma unroll
  for (int off = 32; off; off >>= 1) { s += __shfl_xor(s, off); ss += __shfl_xor(ss, off); }
  if (t == 0) {
    float inv = 1.f / (float)((size_t)CPG * NN);
    float mu = s * inv;
    float var = ss * inv - mu * mu;
    stats[bg * 2] = mu;
    stats[bg * 2 + 1] = rsqrtf(var + EPSV);
  }
}

// out = GN(p0[+p1]) (+ q0) (+ q1)   — float4, grid 4096
__global__ __launch_bounds__(256) void k_gn_apply(const float* __restrict__ p0, const float* __restrict__ p1,
                                                  const float* __restrict__ stats, const float* __restrict__ g,
                                                  const float* __restrict__ be,
                                                  const float* __restrict__ q0, const float* __restrict__ q1,
                                                  float* __restrict__ out) {
  size_t i4 = (size_t)blockIdx.x * 256 + threadIdx.x;
  size_t i = i4 * 4;
  int chan = (int)(i >> 15) & 63;
  int bg = (int)(i >> 19);
  float4 x = ((const float4*)p0)[i4];
  if (p1) { float4 y4 = ((const float4*)p1)[i4]; x.x += y4.x; x.y += y4.y; x.z += y4.z; x.w += y4.w; }
  float mu = stats[bg * 2], rr = stats[bg * 2 + 1];
  float gc = g[chan], bc = be[chan];
  float4 v;
  v.x = (x.x - mu) * rr * gc + bc;
  v.y = (x.y - mu) * rr * gc + bc;
  v.z = (x.z - mu) * rr * gc + bc;
  v.w = (x.w - mu) * rr * gc + bc;
  if (q0) { float4 y4 = ((const float4*)q0)[i4]; v.x += y4.x; v.y += y4.y; v.z += y4.z; v.w += y4.w; }
  if (q1) { float4 y4 = ((const float4*)q1)[i4]; v.x += y4.x; v.y += y4.y; v.z += y4.z; v.w += y4.w; }
  ((float4*)out)[i4] = v;
}

extern "C" void kernel_launch(void* const* d_in, const int* in_sizes, int n_in,
                              void* d_out, int out_size, void* d_ws, size_t ws_size,
                              hipStream_t stream) {
  (void)in_sizes; (void)n_in; (void)out_size; (void)ws_size;
  const float* y     = (const float*)d_in[0];
  const float* a1    = (const float*)d_in[1];
  const float* a2    = (const float*)d_in[2];
  const float* nv1   = (const float*)d_in[3];
  const float* nv2   = (const float*)d_in[4];
  const float* gcn_w = (const float*)d_in[5];
  const float* gcn_b = (const float*)d_in[6];
  const float* s_wq  = (const float*)d_in[7];
  const float* s_wk  = (const float*)d_in[8];
  const float* s_wv  = (const float*)d_in[9];
  const float* s_pk  = (const float*)d_in[10];
  const float* s_pv  = (const float*)d_in[11];
  const float* s_wo  = (const float*)d_in[12];
  const float* s_bo  = (const float*)d_in[13];
  const float* t_wq  = (const float*)d_in[14];
  const float* t_wk  = (const float*)d_in[15];
  const float* t_wv  = (const float*)d_in[16];
  const float* t_bq  = (const float*)d_in[17];
  const float* t_bk  = (const float*)d_in[18];
  const float* t_bv  = (const float*)d_in[19];
  const float* t_wo  = (const float*)d_in[20];
  const float* t_bo  = (const float*)d_in[21];
  const float* t_l1w = (const float*)d_in[22];
  const float* t_l1b = (const float*)d_in[23];
  const float* t_l2w = (const float*)d_in[24];
  const float* t_l2b = (const float*)d_in[25];
  const float* ln1g  = (const float*)d_in[26];
  const float* ln1b  = (const float*)d_in[27];
  const float* ln2g  = (const float*)d_in[28];
  const float* ln2b  = (const float*)d_in[29];
  const float* gnlg  = (const float*)d_in[30];
  const float* gnlb  = (const float*)d_in[31];
  const float* gnsg  = (const float*)d_in[32];
  const float* gnsb  = (const float*)d_in[33];
  const float* gntg  = (const float*)d_in[34];
  const float* gntb  = (const float*)d_in[35];
  const float* ff1w  = (const float*)d_in[36];
  const float* ff1b  = (const float*)d_in[37];
  const float* ff2w  = (const float*)d_in[38];
  const float* ff2b  = (const float*)d_in[39];
  const float* gn2g  = (const float*)d_in[40];
  const float* gn2b  = (const float*)d_in[41];

  float* ws = (float*)d_ws;
  float* adp   = ws;
  float* part  = ws + 65536;
  float* stats = ws + 66560;
  unsigned short* a1_bf   = (unsigned short*)(ws + 131072);
  unsigned short* a2_bf   = (unsigned short*)(ws + 163840);
  unsigned short* adp_bf  = (unsigned short*)(ws + 196608);
  unsigned short* gcnw_bf = (unsigned short*)(ws + 229376);
  unsigned short* xs_bf   = (unsigned short*)(ws + 262144);
  float* kp2 = ws + 131072;
  float* vp2 = ws + 131072 + 1048576;
  float* ffh = ws + 2228224;
  const size_t SLOT = 4194304;
  float* G0 = ws + SLOT * 1;
  float* G1 = ws + SLOT * 2;
  float* G2 = ws + SLOT * 3;
  float* G3 = ws + SLOT * 4;
  float* G4 = ws + SLOT * 5;
  float* G5 = ws + SLOT * 6;
  float* G6 = ws + SLOT * 7;
  unsigned short* U1 = (unsigned short*)G3;
  unsigned short* U2 = (unsigned short*)G3 + 4194304;
  unsigned short* U3 = (unsigned short*)G4;
  unsigned short* U4 = (unsigned short*)G4 + 4194304;
  unsigned short* U5 = (unsigned short*)G5;
  unsigned short* U6 = (unsigned short*)G5 + 4194304;
  unsigned short* PT = (unsigned short*)G6;
  float* out = (float*)d_out;

  const long BS = 2097152;

  // ---- adaptive adjacency + bf16 casts ----
  k_adp<<<256, 256, 0, stream>>>(nv1, nv2, adp);
  k_cast<<<256, 256, 0, stream>>>(a1, a1_bf);
  k_cast<<<256, 256, 0, stream>>>(a2, a2_bf);
  k_cast<<<256, 256, 0, stream>>>(adp, adp_bf);
  k_cast<<<112, 256, 0, stream>>>(gcn_w, gcnw_bf);

  // ---- xs (B,L,K,C) fp32 + bf16 ----
  k_tr<<<dim3(512, 8), 256, 0, stream>>>(y, G2, nullptr, xs_bf, BS, 128, 32768, 1, BS, 64, 1, 16384, 64, 128);

  // ---- AdaptiveGCN (reordered): U_s = W_s X; out = s0 + Sum_f A_f(U_odd + A_f U_even) ----
  k_mix<<<1024, 64, 0, stream>>>(xs_bf, gcnw_bf, gcn_b, G1, U1, U2, U3, U4, U5, U6);
  k_adjM<<<512, 256, 0, stream>>>(a1_bf, U2, nullptr, PT, U1);
  k_adjM<<<512, 256, 0, stream>>>(a1_bf, PT, G0, nullptr, nullptr);   // Q1
  k_adjM<<<512, 256, 0, stream>>>(a2_bf, U4, nullptr, PT, U3);
  k_adjM<<<512, 256, 0, stream>>>(a2_bf, PT, G4, nullptr, nullptr);   // Q2 (G4's U3/U4 dead now)
  k_adjM<<<512, 256, 0, stream>>>(adp_bf, U6, nullptr, PT, U5);
  k_adjM<<<512, 256, 0, stream>>>(adp_bf, PT, G5, nullptr, nullptr);  // Q3
  // sum y+G1+G0+G4+G5 -> G3 (U1/U2 dead), stats from it
  k_gn_part<<<dim3(64, 8), 256, 0, stream>>>(y, G1, G0, G4, G5, G3, part);
  k_gn_final<<<8, 64, 0, stream>>>(part, stats);
  k_gn_apply<<<4096, 256, 0, stream>>>(G3, nullptr, stats, gnlg, gnlb, nullptr, nullptr, G0);

  // ---- Linformer spatial attention (G2 = xs) ----
  k_qkv<<<1024, 256, 0, stream>>>(G2, s_wq, s_wk, s_wv, nullptr, nullptr, nullptr, G3, G4, G5);
  k_sproj<<<256, 256, 0, stream>>>(G4, s_pk, kp2);
  k_sproj<<<256, 256, 0, stream>>>(G5, s_pv, vp2);
  k_sattn<<<512, 512, 0, stream>>>(G3, kp2, vp2, G6);
  k_rowmm<64, 64, 0, 64><<<1024, 256, 0, stream>>>(G6, s_wo, s_bo, G4);
  k_tr<<<dim3(512, 8), 256, 0, stream>>>(G4, G1, nullptr, nullptr, BS, 64, 16384, 1, BS, 128, 1, 32768, 128, 64);
  k_gn_part<<<dim3(64, 8), 256, 0, stream>>>(y, G1, nullptr, nullptr, nullptr, G2, part);
  k_gn_final<<<8, 64, 0, stream>>>(part, stats);
  k_gn_apply<<<4096, 256, 0, stream>>>(G2, nullptr, stats, gnsg, gnsb, nullptr, nullptr, G1);

  // ---- temporal transformer layer ----
  k_tr<<<dim3(512, 8), 256, 0, stream>>>(y, G2, nullptr, nullptr, BS, 128, 32768, 1, BS, 8192, 1, 64, 64, 128);
  k_qkv<<<1024, 256, 0, stream>>>(G2, t_wq, t_wk, t_wv, t_bq, t_bk, t_bv, G3, G4, G5);
  k_tattn<<<512, 512, 0, stream>>>(G3, G4, G5, G6);
  k_rowmm<64, 64, 0, 64><<<1024, 256, 0, stream>>>(G6, t_wo, t_bo, G3);
  k_ln<<<16384, 256, 0, stream>>>(G2, G3, ln1g, ln1b, G4);
  k_rowmm<64, 8, 2, 64><<<1024, 256, 0, stream>>>(G4, t_l1w, t_l1b, ffh);
  k_rowmm<8, 64, 0, 64><<<1024, 256, 0, stream>>>(ffh, t_l2w, t_l2b, G5);
  k_ln<<<16384, 256, 0, stream>>>(G4, G5, ln2g, ln2b, G6);
  k_tr<<<dim3(512, 8), 256, 0, stream>>>(G6, G2, nullptr, nullptr, BS, 8192, 64, 1, BS, 128, 1, 32768, 128, 64);
  k_gn_part<<<dim3(64, 8), 256, 0, stream>>>(y, G2, nullptr, nullptr, nullptr, G5, part);
  k_gn_final<<<8, 64, 0, stream>>>(part, stats);
  // y_in2 = GN(sum G5) + G0 + G1 -> G3
  k_gn_apply<<<4096, 256, 0, stream>>>(G5, nullptr, stats, gntg, gntb, G0, G1, G3);

  // ---- fuse + channel FFN + final GroupNorm ----
  k_tr<<<dim3(512, 8), 256, 0, stream>>>(G3, G4, nullptr, nullptr, BS, 128, 32768, 1, BS, 8192, 1, 64, 64, 128);
  k_rowmm<64, 128, 1, 64><<<1024, 256, 0, stream>>>(G4, ff1w, ff1b, G5);
  k_rowmm<128, 64, 0, 32><<<2048, 256, 0, stream>>>(G5, ff2w, ff2b, G4);
  k_tr<<<dim3(512, 8), 256, 0, stream>>>(G4, out, G3, nullptr, BS, 8192, 64, 1, BS, 128, 1, 32768, 128, 64);
  k_gn_part<<<dim3(64, 8), 256, 0, stream>>>(out, nullptr, nullptr, nullptr, nullptr, nullptr, part);
  k_gn_final<<<8, 64, 0, stream>>>(part, stats);
  k_gn_apply<<<4096, 256, 0, stream>>>(out, nullptr, stats, gn2g, gn2b, nullptr, nullptr, out);
}

// Round 11
// 596.110 us; speedup vs baseline: 1.0890x; 1.0890x over previous
//
#include <hip/hip_runtime.h>
#include <math.h>

constexpr int CC = 64, KK = 256, LL = 128;
constexpr int NN = KK * LL;          // 32768
constexpr int PR = 64;               // Linformer projection
constexpr int CPG = 16;              // channels per group (C / 4)
constexpr float EPSV = 1e-5f;
constexpr float SCL = 0.35355339059327373f;  // 1/sqrt(8)

typedef __attribute__((ext_vector_type(8))) short short8;      // 8 bf16 (4 VGPR)
typedef __attribute__((ext_vector_type(4))) float f32x4;       // MFMA 16x16 acc

__device__ __forceinline__ unsigned short f2bf(float x) {
  union { float f; unsigned int u; } v; v.f = x;
  unsigned int r = (v.u + 0x7FFFu + ((v.u >> 16) & 1u)) >> 16;
  return (unsigned short)r;
}
__device__ __forceinline__ float bf2f(unsigned short x) {
  union { unsigned int u; float f; } v; v.u = ((unsigned int)x) << 16;
  return v.f;
}

// ---------------- adaptive adjacency: softmax(relu(nv1@nv2), axis=1) ----------------
__global__ __launch_bounds__(256) void k_adp(const float* __restrict__ nv1,
                                             const float* __restrict__ nv2,
                                             float* __restrict__ adp) {
  int w = blockIdx.x, v = threadIdx.x;
  float s = 0.f;
  for (int d = 0; d < 10; ++d) s += nv1[w * 10 + d] * nv2[d * KK + v];
  s = fmaxf(s, 0.f);
  __shared__ float red[256];
  red[v] = s; __syncthreads();
  for (int off = 128; off; off >>= 1) { if (v < off) red[v] = fmaxf(red[v], red[v + off]); __syncthreads(); }
  float m = red[0]; __syncthreads();
  float e = expf(s - m);
  red[v] = e; __syncthreads();
  for (int off = 128; off; off >>= 1) { if (v < off) red[v] += red[v + off]; __syncthreads(); }
  adp[w * KK + v] = e / red[0];
}

// ---------------- fp32 -> bf16 cast ----------------
__global__ __launch_bounds__(256) void k_cast(const float* __restrict__ src,
                                              unsigned short* __restrict__ dst) {
  int i = blockIdx.x * 256 + threadIdx.x;
  dst[i] = f2bf(src[i]);
}

// ---------------- channel-mix: U_s[(b,l,k), o] = xs[(b,l,k), c] @ W_s[c][o]  (MFMA, K=64) ----------------
__global__ __launch_bounds__(64) void k_mix(const unsigned short* __restrict__ Xbf,
                                            const unsigned short* __restrict__ Wbf,
                                            const float* __restrict__ bias,
                                            float* __restrict__ s0,
                                            unsigned short* __restrict__ U1, unsigned short* __restrict__ U2,
                                            unsigned short* __restrict__ U3, unsigned short* __restrict__ U4,
                                            unsigned short* __restrict__ U5, unsigned short* __restrict__ U6) {
  unsigned short* Us[6] = {U1, U2, U3, U4, U5, U6};
  int pb = blockIdx.x;
  int b = pb >> 9;
  int rem = pb & 511;
  int l = rem >> 2;
  int kq = (rem & 3) * 64;
  size_t posbase = ((size_t)(b * 128 + l)) * 256 + kq;
  int lane = threadIdx.x;
  int lr = lane & 15, g = lane >> 4;

  short8 af[4][2];
#pragma unroll
  for (int rt = 0; rt < 4; ++rt)
#pragma unroll
    for (int kc = 0; kc < 2; ++kc)
      af[rt][kc] = *(const short8*)(Xbf + (posbase + rt * 16 + lr) * 64 + kc * 32 + g * 8);

  for (int s = 0; s < 7; ++s) {
    short8 bf[4][2];
#pragma unroll
    for (int ct = 0; ct < 4; ++ct)
#pragma unroll
      for (int kc = 0; kc < 2; ++kc)
        bf[ct][kc] = *(const short8*)(Wbf + (size_t)(ct * 16 + lr) * 448 + s * 64 + kc * 32 + g * 8);
    f32x4 acc[4][4];
#pragma unroll
    for (int rt = 0; rt < 4; ++rt)
#pragma unroll
      for (int ct = 0; ct < 4; ++ct) acc[rt][ct] = f32x4{0.f, 0.f, 0.f, 0.f};
#pragma unroll
    for (int kc = 0; kc < 2; ++kc)
#pragma unroll
      for (int rt = 0; rt < 4; ++rt)
#pragma unroll
        for (int ct = 0; ct < 4; ++ct)
          acc[rt][ct] = __builtin_amdgcn_mfma_f32_16x16x32_bf16(af[rt][kc], bf[ct][kc], acc[rt][ct], 0, 0, 0);

    if (s == 0) {
#pragma unroll
      for (int rt = 0; rt < 4; ++rt)
#pragma unroll
        for (int ct = 0; ct < 4; ++ct) {
          int o = ct * 16 + lr;
          float bv = bias[o];
          int k = kq + rt * 16 + g * 4;
#pragma unroll
          for (int j = 0; j < 4; ++j)
            s0[(size_t)(b * 64 + o) * NN + (size_t)(k + j) * 128 + l] = acc[rt][ct][j] + bv;
        }
    } else {
      unsigned short* dst = Us[s - 1];
#pragma unroll
      for (int rt = 0; rt < 4; ++rt)
#pragma unroll
        for (int ct = 0; ct < 4; ++ct) {
          int o = ct * 16 + lr;
          int k = kq + rt * 16 + g * 4;
          ushort4 pk;
          pk.x = f2bf(acc[rt][ct][0]); pk.y = f2bf(acc[rt][ct][1]);
          pk.z = f2bf(acc[rt][ct][2]); pk.w = f2bf(acc[rt][ct][3]);
          *(ushort4*)&dst[((size_t)(b * 64 + o) * 128 + l) * 256 + k] = pk;
        }
    }
  }
}

// ---------------- out[bc, w, l] = sum_v A[w,v] * XT[bc, l, v]  (bf16 MFMA 16x16x32) ----------------
__global__ __launch_bounds__(256) void k_adjM(const unsigned short* __restrict__ Abf,
                                              const unsigned short* __restrict__ XT,
                                              float* __restrict__ out,
                                              unsigned short* __restrict__ outT,
                                              const unsigned short* __restrict__ addT) {
  int lq = blockIdx.x & 3, bc = blockIdx.x >> 2;
  int tid = threadIdx.x, wid = tid >> 6, lane = tid & 63;
  int lr = lane & 15, g = lane >> 4;
  int wbase = wid * 64;
  const unsigned short* aP = Abf + (size_t)(wbase + lr) * 256 + g * 8;
  const unsigned short* bP = XT + ((size_t)bc * 128 + lq * 32 + lr) * 256 + g * 8;
  f32x4 acc[4][2];
#pragma unroll
  for (int i = 0; i < 4; ++i)
#pragma unroll
    for (int j = 0; j < 2; ++j) acc[i][j] = f32x4{0.f, 0.f, 0.f, 0.f};
  for (int k0 = 0; k0 < 256; k0 += 32) {
    short8 af[4], bfv[2];
#pragma unroll
    for (int i = 0; i < 4; ++i) af[i] = *(const short8*)(aP + (size_t)i * 16 * 256 + k0);
#pragma unroll
    for (int i = 0; i < 2; ++i) bfv[i] = *(const short8*)(bP + (size_t)i * 16 * 256 + k0);
#pragma unroll
    for (int rm = 0; rm < 4; ++rm)
#pragma unroll
      for (int cn = 0; cn < 2; ++cn)
        acc[rm][cn] = __builtin_amdgcn_mfma_f32_16x16x32_bf16(af[rm], bfv[cn], acc[rm][cn], 0, 0, 0);
  }
  if (out) {
    float* dst = out + (size_t)bc * NN + lq * 32;
#pragma unroll
    for (int rm = 0; rm < 4; ++rm)
#pragma unroll
      for (int cn = 0; cn < 2; ++cn) {
        int col = cn * 16 + lr;
        int row = wbase + rm * 16 + g * 4;
#pragma unroll
        for (int j = 0; j < 4; ++j)
          dst[(size_t)(row + j) * 128 + col] = acc[rm][cn][j];
      }
  }
  if (outT) {
    unsigned short* dT = outT + (size_t)bc * NN + (size_t)(lq * 32) * 256;
    const unsigned short* aT = addT ? addT + (size_t)bc * NN + (size_t)(lq * 32) * 256 : nullptr;
#pragma unroll
    for (int rm = 0; rm < 4; ++rm)
#pragma unroll
      for (int cn = 0; cn < 2; ++cn) {
        int l = cn * 16 + lr;
        int v = wbase + rm * 16 + g * 4;
        float a0 = 0.f, a1 = 0.f, a2 = 0.f, a3 = 0.f;
        if (aT) {
          ushort4 av = *(const ushort4*)&aT[(size_t)l * 256 + v];
          a0 = bf2f(av.x); a1 = bf2f(av.y); a2 = bf2f(av.z); a3 = bf2f(av.w);
        }
        ushort4 pk;
        pk.x = f2bf(acc[rm][cn][0] + a0); pk.y = f2bf(acc[rm][cn][1] + a1);
        pk.z = f2bf(acc[rm][cn][2] + a2); pk.w = f2bf(acc[rm][cn][3] + a3);
        *(ushort4*)&dT[(size_t)l * 256 + v] = pk;
      }
  }
}

// ---------------- generic (c,l)-plane transpose per (b,k), optional add + bf16 side output ----------------
__global__ __launch_bounds__(256) void k_tr(const float* __restrict__ src, float* __restrict__ dst,
                                            const float* __restrict__ add,
                                            unsigned short* __restrict__ dstBf,
                                            long sb, long sk, long sc, long sl,
                                            long db, long dk, long dc, long dl, int nC, int nL) {
  int outer = blockIdx.x;
  int b = outer >> 8, k = outer & 255;
  int tilesL = nL >> 5;
  int tC = blockIdx.y / tilesL, tL = blockIdx.y % tilesL;
  int c0 = tC << 5, l0 = tL << 5;
  __shared__ float s[32][33];
  int tx = threadIdx.x & 31, ty = threadIdx.x >> 5;
  const float* sp = src + (long)b * sb + (long)k * sk;
#pragma unroll
  for (int j = 0; j < 4; ++j) {
    int cc = c0 + ty + j * 8;
    s[ty + j * 8][tx] = sp[(long)cc * sc + (long)(l0 + tx) * sl];
  }
  __syncthreads();
  long dbase = (long)b * db + (long)k * dk;
#pragma unroll
  for (int j = 0; j < 4; ++j) {
    int ll = l0 + ty + j * 8;
    long off = dbase + (long)(c0 + tx) * dc + (long)ll * dl;
    float val = s[tx][ty + j * 8];
    if (add) val += add[off];
    dst[off] = val;
    if (dstBf) dstBf[off] = f2bf(val);
  }
}

// ---------------- spatial QKV: Q -> bf16, K/V -> fp32 ----------------
__global__ __launch_bounds__(256) void k_qkv_s(const float* __restrict__ in,
                                               const float* __restrict__ W0, const float* __restrict__ W1,
                                               const float* __restrict__ W2,
                                               unsigned short* __restrict__ qb,
                                               float* __restrict__ o1, float* __restrict__ o2) {
  int r0 = blockIdx.x * 64;
  __shared__ float sInT[64][68];
  __shared__ float sW[3][64][64];
  int t = threadIdx.x;
  for (int i = t; i < 4096; i += 256) {
    int c = i >> 6, o = i & 63;
    sW[0][c][o] = W0[i];
    sW[1][c][o] = W1[i];
    sW[2][c][o] = W2[i];
  }
  for (int i = t; i < 4096; i += 256) {
    int r = i >> 6, c = i & 63;
    sInT[c][r] = in[(size_t)(r0 + r) * 64 + c];
  }
  __syncthreads();
  int col = t & 63, rg = t >> 6;
  int rbase = rg * 16;
  float a0[16], a1[16], a2[16];
#pragma unroll
  for (int i = 0; i < 16; ++i) { a0[i] = 0.f; a1[i] = 0.f; a2[i] = 0.f; }
  for (int c = 0; c < 64; ++c) {
    float w0 = sW[0][c][col], w1 = sW[1][c][col], w2 = sW[2][c][col];
#pragma unroll
    for (int rr = 0; rr < 16; rr += 4) {
      float4 xv = *(const float4*)&sInT[c][rbase + rr];
      a0[rr + 0] += xv.x * w0; a0[rr + 1] += xv.y * w0; a0[rr + 2] += xv.z * w0; a0[rr + 3] += xv.w * w0;
      a1[rr + 0] += xv.x * w1; a1[rr + 1] += xv.y * w1; a1[rr + 2] += xv.z * w1; a1[rr + 3] += xv.w * w1;
      a2[rr + 0] += xv.x * w2; a2[rr + 1] += xv.y * w2; a2[rr + 2] += xv.z * w2; a2[rr + 3] += xv.w * w2;
    }
  }
#pragma unroll
  for (int rr = 0; rr < 16; ++rr) {
    size_t idx = (size_t)(r0 + rbase + rr) * 64 + col;
    qb[idx] = f2bf(a0[rr]); o1[idx] = a1[rr]; o2[idx] = a2[rr];
  }
}

// ---------------- temporal QKV: Q,K -> bf16 row-major; V -> bf16 TRANSPOSED [bk][c][l] ----------------
__global__ __launch_bounds__(256) void k_qkv_t(const float* __restrict__ in,
                                               const float* __restrict__ W0, const float* __restrict__ W1,
                                               const float* __restrict__ W2,
                                               const float* __restrict__ b0, const float* __restrict__ b1,
                                               const float* __restrict__ b2,
                                               unsigned short* __restrict__ qb,
                                               unsigned short* __restrict__ kb,
                                               unsigned short* __restrict__ vt) {
  int r0 = blockIdx.x * 64;
  __shared__ float sInT[64][68];
  __shared__ float sW[3][64][64];
  int t = threadIdx.x;
  for (int i = t; i < 4096; i += 256) {
    int c = i >> 6, o = i & 63;
    sW[0][c][o] = W0[i];
    sW[1][c][o] = W1[i];
    sW[2][c][o] = W2[i];
  }
  for (int i = t; i < 4096; i += 256) {
    int r = i >> 6, c = i & 63;
    sInT[c][r] = in[(size_t)(r0 + r) * 64 + c];
  }
  __syncthreads();
  int col = t & 63, rg = t >> 6;
  int rbase = rg * 16;
  float a0[16], a1[16], a2[16];
  float bv0 = b0[col], bv1 = b1[col], bv2 = b2[col];
#pragma unroll
  for (int i = 0; i < 16; ++i) { a0[i] = bv0; a1[i] = bv1; a2[i] = bv2; }
  for (int c = 0; c < 64; ++c) {
    float w0 = sW[0][c][col], w1 = sW[1][c][col], w2 = sW[2][c][col];
#pragma unroll
    for (int rr = 0; rr < 16; rr += 4) {
      float4 xv = *(const float4*)&sInT[c][rbase + rr];
      a0[rr + 0] += xv.x * w0; a0[rr + 1] += xv.y * w0; a0[rr + 2] += xv.z * w0; a0[rr + 3] += xv.w * w0;
      a1[rr + 0] += xv.x * w1; a1[rr + 1] += xv.y * w1; a1[rr + 2] += xv.z * w1; a1[rr + 3] += xv.w * w1;
      a2[rr + 0] += xv.x * w2; a2[rr + 1] += xv.y * w2; a2[rr + 2] += xv.z * w2; a2[rr + 3] += xv.w * w2;
    }
  }
#pragma unroll
  for (int rr = 0; rr < 16; ++rr) {
    size_t idx = (size_t)(r0 + rbase + rr) * 64 + col;
    qb[idx] = f2bf(a0[rr]); kb[idx] = f2bf(a1[rr]);
  }
  int bk = r0 >> 7;
  int lbase = (r0 & 127) + rbase;
  unsigned short* vd = vt + (size_t)bk * 8192 + (size_t)col * 128 + lbase;
#pragma unroll
  for (int rr = 0; rr < 16; ++rr) vd[rr] = f2bf(a2[rr]);
}

// ---------------- row-major (R,CIN) @ (CIN,COUT) + bias, optional activation ----------------
template <int CIN, int COUT, int ACT, int ROWS>
__global__ __launch_bounds__(256) void k_rowmm(const float* __restrict__ in,
                                               const float* __restrict__ W,
                                               const float* __restrict__ bias,
                                               float* __restrict__ out) {
  int r0 = blockIdx.x * ROWS;
  __shared__ float sInT[CIN][ROWS + 4];
  __shared__ float sW[CIN][COUT];
  int t = threadIdx.x;
  for (int i = t; i < CIN * COUT; i += 256) ((float*)sW)[i] = W[i];
  for (int i = t; i < ROWS * CIN; i += 256) {
    int r = i / CIN, c = i % CIN;
    sInT[c][r] = in[(size_t)r0 * CIN + i];
  }
  __syncthreads();
  constexpr int NRG = 256 / COUT;
  constexpr int RPT = ROWS / NRG;
  int col = t % COUT, rg = t / COUT;
  int rbase = rg * RPT;
  float acc[RPT];
  float bv = bias ? bias[col] : 0.f;
#pragma unroll
  for (int r = 0; r < RPT; ++r) acc[r] = bv;
  for (int c = 0; c < CIN; ++c) {
    float wv = sW[c][col];
    if constexpr (RPT % 4 == 0) {
#pragma unroll
      for (int rr = 0; rr < RPT; rr += 4) {
        float4 xv = *(const float4*)&sInT[c][rbase + rr];
        acc[rr] += xv.x * wv; acc[rr + 1] += xv.y * wv;
        acc[rr + 2] += xv.z * wv; acc[rr + 3] += xv.w * wv;
      }
    } else {
#pragma unroll
      for (int rr = 0; rr < RPT; ++rr) acc[rr] += sInT[c][rbase + rr] * wv;
    }
  }
#pragma unroll
  for (int rr = 0; rr < RPT; ++rr) {
    float v = acc[rr];
    if (ACT == 1) v = fmaxf(v, 0.f);
    if (ACT == 2) v = 0.5f * v * (1.f + erff(v * 0.70710678118654752440f));
    out[(size_t)(r0 + rbase + rr) * COUT + col] = v;
  }
}

// ---------------- sproj: out[bl,p,c] = sum_n X[bl,n,c] * P[n,p]; bf16 outputs (RM and/or T) ----------------
__global__ __launch_bounds__(256) void k_sproj(const float* __restrict__ X,
                                               const float* __restrict__ P,
                                               unsigned short* __restrict__ outRM,
                                               unsigned short* __restrict__ outT) {
  int bl = blockIdx.x;
  const float* src = X + (size_t)bl * KK * CC;
  int t = threadIdx.x, c = t & 63, pg = t >> 6;
  __shared__ float sX[64][CC];
  __shared__ float sP[64][PR];
  float acc[16];
#pragma unroll
  for (int i = 0; i < 16; ++i) acc[i] = 0.f;
  for (int n0 = 0; n0 < KK; n0 += 64) {
    for (int i = t; i < 64 * CC; i += 256) ((float*)sX)[i] = src[(size_t)n0 * CC + i];
    for (int i = t; i < 64 * PR; i += 256) ((float*)sP)[i] = P[(size_t)n0 * PR + i];
    __syncthreads();
    for (int n = 0; n < 64; ++n) {
      float xv = sX[n][c];
#pragma unroll
      for (int q = 0; q < 4; ++q) {
        float4 pv = *(const float4*)&sP[n][pg * 16 + q * 4];
        acc[q * 4 + 0] += pv.x * xv; acc[q * 4 + 1] += pv.y * xv;
        acc[q * 4 + 2] += pv.z * xv; acc[q * 4 + 3] += pv.w * xv;
      }
    }
    __syncthreads();
  }
  if (outRM) {
    unsigned short* d = outRM + (size_t)bl * PR * CC;
#pragma unroll
    for (int i = 0; i < 16; ++i) d[(size_t)(pg * 16 + i) * CC + c] = f2bf(acc[i]);
  }
  if (outT) {
    unsigned short* d = outT + (size_t)bl * PR * CC + (size_t)c * PR + pg * 16;
#pragma unroll
    for (int i = 0; i < 16; ++i) d[i] = f2bf(acc[i]);
  }
}

// ---------------- per-head MFMA attention: block = 128 q-rows, 8 waves = 8 heads ----------------
// Qb: bf16 [blk][128][64]; Kb: bf16 [blk>>KVSHIFT][NKV][64]; VTb: bf16 [blk>>KVSHIFT][64][NKV].
// O: fp32 [blk][128][64]. Head h dims = [h*8, h*8+8). A-fragment zero-padded K=32 (g==0 lanes real).
template <int NKV, int KVSHIFT>
__global__ __launch_bounds__(512) void k_attnH(const unsigned short* __restrict__ Qb,
                                               const unsigned short* __restrict__ Kb,
                                               const unsigned short* __restrict__ VTb,
                                               float* __restrict__ O) {
  constexpr int NCT = NKV / 16;   // S col tiles
  constexpr int NKS = NKV / 32;   // PV k steps
  int blk = blockIdx.x;
  const unsigned short* Qp = Qb + (size_t)blk * 128 * 64;
  float* Op = O + (size_t)blk * 128 * 64;
  const unsigned short* Kp = Kb + (size_t)(blk >> KVSHIFT) * NKV * 64;
  const unsigned short* VTp = VTb + (size_t)(blk >> KVSHIFT) * 64 * NKV;
  int t = threadIdx.x;
  int h = t >> 6, lane = t & 63, lr = lane & 15, g = lane >> 4;
  __shared__ unsigned short sP[8][16 * NKV];
  unsigned short* myP = sP[h];

  // B fragments for S: column n = kv pos ct*16+lr; only k<8 (g==0 of A) contributes.
  short8 kbf[NCT];
#pragma unroll
  for (int ct = 0; ct < NCT; ++ct)
    kbf[ct] = *(const short8*)(Kp + (size_t)(ct * 16 + lr) * 64 + h * 8);

  // B fragments for PV: column n = head-dim lr (valid lr<8); k contiguous along kv.
  int vr = h * 8 + lr; if (vr > 63) vr = 63;
  short8 vbf[NKS];
#pragma unroll
  for (int ks = 0; ks < NKS; ++ks)
    vbf[ks] = *(const short8*)(VTp + (size_t)vr * NKV + ks * 32 + g * 8);

  for (int mt = 0; mt < 8; ++mt) {
    // A fragment: row lr of Q tile, k = g*8+i; only g==0 holds the head's 8 real dims.
    short8 qa = short8{0, 0, 0, 0, 0, 0, 0, 0};
    if (g == 0) qa = *(const short8*)(Qp + (size_t)(mt * 16 + lr) * 64 + h * 8);

    f32x4 sacc[NCT];
#pragma unroll
    for (int ct = 0; ct < NCT; ++ct) sacc[ct] = f32x4{0.f, 0.f, 0.f, 0.f};
#pragma unroll
    for (int ct = 0; ct < NCT; ++ct)
      sacc[ct] = __builtin_amdgcn_mfma_f32_16x16x32_bf16(qa, kbf[ct], sacc[ct], 0, 0, 0);

    // softmax (no max-sub; scores small — identical semantics to passing rounds)
    float inv4[4];
#pragma unroll
    for (int reg = 0; reg < 4; ++reg) {
      float s = 0.f;
#pragma unroll
      for (int ct = 0; ct < NCT; ++ct) {
        float e = __expf(sacc[ct][reg] * SCL);
        sacc[ct][reg] = e;
        s += e;
      }
      s += __shfl_xor(s, 1); s += __shfl_xor(s, 2); s += __shfl_xor(s, 4); s += __shfl_xor(s, 8);
      inv4[reg] = 1.f / s;
    }

    // P -> bf16 into XOR-swizzled per-wave LDS tile [16][NKV]
#pragma unroll
    for (int ct = 0; ct < NCT; ++ct)
#pragma unroll
      for (int reg = 0; reg < 4; ++reg) {
        int row = g * 4 + reg;
        int bo = ((row * NKV + ct * 16 + lr) * 2) ^ ((row & 7) << 4);
        *(unsigned short*)((char*)myP + bo) = f2bf(sacc[ct][reg]);
      }
    __syncthreads();

    // O tile = P @ V
    f32x4 oacc = f32x4{0.f, 0.f, 0.f, 0.f};
#pragma unroll
    for (int ks = 0; ks < NKS; ++ks) {
      int bo = ((lr * NKV + ks * 32 + g * 8) * 2) ^ ((lr & 7) << 4);
      short8 pa = *(const short8*)((char*)myP + bo);
      oacc = __builtin_amdgcn_mfma_f32_16x16x32_bf16(pa, vbf[ks], oacc, 0, 0, 0);
    }
    if (lr < 8) {
#pragma unroll
      for (int reg = 0; reg < 4; ++reg) {
        int row = mt * 16 + g * 4 + reg;
        Op[(size_t)row * 64 + h * 8 + lr] = oacc[reg] * inv4[reg];
      }
    }
    __syncthreads();
  }
}

// ---------------- LayerNorm over C=64 per row, input = A (+ optional Bp) ----------------
__global__ __launch_bounds__(256) void k_ln(const float* __restrict__ A, const float* __restrict__ Bp,
                                            const float* __restrict__ g, const float* __restrict__ be,
                                            float* __restrict__ out) {
  int row = blockIdx.x * 4 + (threadIdx.x >> 6);
  int c = threadIdx.x & 63;
  size_t idx = (size_t)row * CC + c;
  float x = A[idx] + (Bp ? Bp[idx] : 0.f);
  float s = x, ss = x * x;
#pragma unroll
  for (int off = 32; off; off >>= 1) { s += __shfl_xor(s, off); ss += __shfl_xor(ss, off); }
  float mu = s * (1.f / 64.f);
  float var = ss * (1.f / 64.f) - mu * mu;
  out[idx] = (x - mu) * rsqrtf(var + EPSV) * g[c] + be[c];
}

// ---------------- GroupNorm stats: up to 5 summed inputs, optional sum write-back ----------------
__global__ __launch_bounds__(256) void k_gn_part(const float* __restrict__ p0, const float* __restrict__ p1,
                                                 const float* __restrict__ p2, const float* __restrict__ p3,
                                                 const float* __restrict__ p4,
                                                 float* __restrict__ sumOut,
                                                 float* __restrict__ part) {
  int bg = blockIdx.y, blk = blockIdx.x, t = threadIdx.x;
  size_t start = (size_t)bg * ((size_t)CPG * NN) + (size_t)blk * 8192;
  const float4* q0 = (const float4*)(p0 + start);
  const float4* q1 = p1 ? (const float4*)(p1 + start) : nullptr;
  const float4* q2 = p2 ? (const float4*)(p2 + start) : nullptr;
  const float4* q3 = p3 ? (const float4*)(p3 + start) : nullptr;
  const float4* q4 = p4 ? (const float4*)(p4 + start) : nullptr;
  float4* so = sumOut ? (float4*)(sumOut + start) : nullptr;
  float s = 0.f, ss = 0.f;
  for (int i = t; i < 2048; i += 256) {
    float4 x = q0[i];
    if (q1) { float4 y4 = q1[i]; x.x += y4.x; x.y += y4.y; x.z += y4.z; x.w += y4.w; }
    if (q2) { float4 y4 = q2[i]; x.x += y4.x; x.y += y4.y; x.z += y4.z; x.w += y4.w; }
    if (q3) { float4 y4 = q3[i]; x.x += y4.x; x.y += y4.y; x.z += y4.z; x.w += y4.w; }
    if (q4) { float4 y4 = q4[i]; x.x += y4.x; x.y += y4.y; x.z += y4.z; x.w += y4.w; }
    if (so) so[i] = x;
    s += x.x + x.y + x.z + x.w;
    ss += x.x * x.x + x.y * x.y + x.z * x.z + x.w * x.w;
  }
  __shared__ float rs[256], rq[256];
  rs[t] = s; rq[t] = ss; __syncthreads();
  for (int off = 128; off; off >>= 1) { if (t < off) { rs[t] += rs[t + off]; rq[t] += rq[t + off]; } __syncthreads(); }
  if (t == 0) { part[(bg * 64 + blk) * 2] = rs[0]; part[(bg * 64 + blk) * 2 + 1] = rq[0]; }
}

__global__ __launch_bounds__(64) void k_gn_final(const float* __restrict__ part, float* __restrict__ stats) {
  int bg = blockIdx.x, t = threadIdx.x;
  float s = part[(bg * 64 + t) * 2], ss = part[(bg * 64 + t) * 2 + 1];
#pragma unroll
  for (int off = 32; off; off >>= 1) { s += __shfl_xor(s, off); ss += __shfl_xor(ss, off); }
  if (t == 0) {
    float inv = 1.f / (float)((size_t)CPG * NN);
    float mu = s * inv;
    float var = ss * inv - mu * mu;
    stats[bg * 2] = mu;
    stats[bg * 2 + 1] = rsqrtf(var + EPSV);
  }
}

// out = GN(p0[+p1]) (+ q0) (+ q1)   — float4, grid 4096
__global__ __launch_bounds__(256) void k_gn_apply(const float* __restrict__ p0, const float* __restrict__ p1,
                                                  const float* __restrict__ stats, const float* __restrict__ g,
                                                  const float* __restrict__ be,
                                                  const float* __restrict__ q0, const float* __restrict__ q1,
                                                  float* __restrict__ out) {
  size_t i4 = (size_t)blockIdx.x * 256 + threadIdx.x;
  size_t i = i4 * 4;
  int chan = (int)(i >> 15) & 63;
  int bg = (int)(i >> 19);
  float4 x = ((const float4*)p0)[i4];
  if (p1) { float4 y4 = ((const float4*)p1)[i4]; x.x += y4.x; x.y += y4.y; x.z += y4.z; x.w += y4.w; }
  float mu = stats[bg * 2], rr = stats[bg * 2 + 1];
  float gc = g[chan], bc = be[chan];
  float4 v;
  v.x = (x.x - mu) * rr * gc + bc;
  v.y = (x.y - mu) * rr * gc + bc;
  v.z = (x.z - mu) * rr * gc + bc;
  v.w = (x.w - mu) * rr * gc + bc;
  if (q0) { float4 y4 = ((const float4*)q0)[i4]; v.x += y4.x; v.y += y4.y; v.z += y4.z; v.w += y4.w; }
  if (q1) { float4 y4 = ((const float4*)q1)[i4]; v.x += y4.x; v.y += y4.y; v.z += y4.z; v.w += y4.w; }
  ((float4*)out)[i4] = v;
}

extern "C" void kernel_launch(void* const* d_in, const int* in_sizes, int n_in,
                              void* d_out, int out_size, void* d_ws, size_t ws_size,
                              hipStream_t stream) {
  (void)in_sizes; (void)n_in; (void)out_size; (void)ws_size;
  const float* y     = (const float*)d_in[0];
  const float* a1    = (const float*)d_in[1];
  const float* a2    = (const float*)d_in[2];
  const float* nv1   = (const float*)d_in[3];
  const float* nv2   = (const float*)d_in[4];
  const float* gcn_w = (const float*)d_in[5];
  const float* gcn_b = (const float*)d_in[6];
  const float* s_wq  = (const float*)d_in[7];
  const float* s_wk  = (const float*)d_in[8];
  const float* s_wv  = (const float*)d_in[9];
  const float* s_pk  = (const float*)d_in[10];
  const float* s_pv  = (const float*)d_in[11];
  const float* s_wo  = (const float*)d_in[12];
  const float* s_bo  = (const float*)d_in[13];
  const float* t_wq  = (const float*)d_in[14];
  const float* t_wk  = (const float*)d_in[15];
  const float* t_wv  = (const float*)d_in[16];
  const float* t_bq  = (const float*)d_in[17];
  const float* t_bk  = (const float*)d_in[18];
  const float* t_bv  = (const float*)d_in[19];
  const float* t_wo  = (const float*)d_in[20];
  const float* t_bo  = (const float*)d_in[21];
  const float* t_l1w = (const float*)d_in[22];
  const float* t_l1b = (const float*)d_in[23];
  const float* t_l2w = (const float*)d_in[24];
  const float* t_l2b = (const float*)d_in[25];
  const float* ln1g  = (const float*)d_in[26];
  const float* ln1b  = (const float*)d_in[27];
  const float* ln2g  = (const float*)d_in[28];
  const float* ln2b  = (const float*)d_in[29];
  const float* gnlg  = (const float*)d_in[30];
  const float* gnlb  = (const float*)d_in[31];
  const float* gnsg  = (const float*)d_in[32];
  const float* gnsb  = (const float*)d_in[33];
  const float* gntg  = (const float*)d_in[34];
  const float* gntb  = (const float*)d_in[35];
  const float* ff1w  = (const float*)d_in[36];
  const float* ff1b  = (const float*)d_in[37];
  const float* ff2w  = (const float*)d_in[38];
  const float* ff2b  = (const float*)d_in[39];
  const float* gn2g  = (const float*)d_in[40];
  const float* gn2b  = (const float*)d_in[41];

  float* ws = (float*)d_ws;
  float* adp   = ws;
  float* part  = ws + 65536;
  float* stats = ws + 66560;
  unsigned short* a1_bf   = (unsigned short*)(ws + 131072);
  unsigned short* a2_bf   = (unsigned short*)(ws + 163840);
  unsigned short* adp_bf  = (unsigned short*)(ws + 196608);
  unsigned short* gcnw_bf = (unsigned short*)(ws + 229376);
  unsigned short* xs_bf   = (unsigned short*)(ws + 262144);
  float* kp2 = ws + 131072;                 // reused post-GCN
  float* vp2 = ws + 131072 + 1048576;
  unsigned short* kpb  = (unsigned short*)kp2;
  unsigned short* vptb = (unsigned short*)vp2;
  float* ffh = ws + 2228224;
  const size_t SLOT = 4194304;
  float* G0 = ws + SLOT * 1;
  float* G1 = ws + SLOT * 2;
  float* G2 = ws + SLOT * 3;
  float* G3 = ws + SLOT * 4;
  float* G4 = ws + SLOT * 5;
  float* G5 = ws + SLOT * 6;
  float* G6 = ws + SLOT * 7;
  unsigned short* U1 = (unsigned short*)G3;
  unsigned short* U2 = (unsigned short*)G3 + 4194304;
  unsigned short* U3 = (unsigned short*)G4;
  unsigned short* U4 = (unsigned short*)G4 + 4194304;
  unsigned short* U5 = (unsigned short*)G5;
  unsigned short* U6 = (unsigned short*)G5 + 4194304;
  unsigned short* PT = (unsigned short*)G6;
  float* out = (float*)d_out;

  const long BS = 2097152;

  // ---- adaptive adjacency + bf16 casts ----
  k_adp<<<256, 256, 0, stream>>>(nv1, nv2, adp);
  k_cast<<<256, 256, 0, stream>>>(a1, a1_bf);
  k_cast<<<256, 256, 0, stream>>>(a2, a2_bf);
  k_cast<<<256, 256, 0, stream>>>(adp, adp_bf);
  k_cast<<<112, 256, 0, stream>>>(gcn_w, gcnw_bf);

  // ---- xs (B,L,K,C) fp32 + bf16 ----
  k_tr<<<dim3(512, 8), 256, 0, stream>>>(y, G2, nullptr, xs_bf, BS, 128, 32768, 1, BS, 64, 1, 16384, 64, 128);

  // ---- AdaptiveGCN: U_s = W_s X; out = s0 + Sum_f A_f(U_odd + A_f U_even) ----
  k_mix<<<1024, 64, 0, stream>>>(xs_bf, gcnw_bf, gcn_b, G1, U1, U2, U3, U4, U5, U6);
  k_adjM<<<512, 256, 0, stream>>>(a1_bf, U2, nullptr, PT, U1);
  k_adjM<<<512, 256, 0, stream>>>(a1_bf, PT, G0, nullptr, nullptr);   // Q1
  k_adjM<<<512, 256, 0, stream>>>(a2_bf, U4, nullptr, PT, U3);
  k_adjM<<<512, 256, 0, stream>>>(a2_bf, PT, G4, nullptr, nullptr);   // Q2
  k_adjM<<<512, 256, 0, stream>>>(adp_bf, U6, nullptr, PT, U5);
  k_adjM<<<512, 256, 0, stream>>>(adp_bf, PT, G5, nullptr, nullptr);  // Q3
  k_gn_part<<<dim3(64, 8), 256, 0, stream>>>(y, G1, G0, G4, G5, G3, part);
  k_gn_final<<<8, 64, 0, stream>>>(part, stats);
  k_gn_apply<<<4096, 256, 0, stream>>>(G3, nullptr, stats, gnlg, gnlb, nullptr, nullptr, G0);

  // ---- Linformer spatial attention (G2 = xs) ----
  k_qkv_s<<<1024, 256, 0, stream>>>(G2, s_wq, s_wk, s_wv, (unsigned short*)G3, G4, G5);
  k_sproj<<<256, 256, 0, stream>>>(G4, s_pk, kpb, nullptr);
  k_sproj<<<256, 256, 0, stream>>>(G5, s_pv, nullptr, vptb);
  k_attnH<64, 1><<<512, 512, 0, stream>>>((unsigned short*)G3, kpb, vptb, G6);
  k_rowmm<64, 64, 0, 64><<<1024, 256, 0, stream>>>(G6, s_wo, s_bo, G4);
  k_tr<<<dim3(512, 8), 256, 0, stream>>>(G4, G1, nullptr, nullptr, BS, 64, 16384, 1, BS, 128, 1, 32768, 128, 64);
  k_gn_part<<<dim3(64, 8), 256, 0, stream>>>(y, G1, nullptr, nullptr, nullptr, G2, part);
  k_gn_final<<<8, 64, 0, stream>>>(part, stats);
  k_gn_apply<<<4096, 256, 0, stream>>>(G2, nullptr, stats, gnsg, gnsb, nullptr, nullptr, G1);

  // ---- temporal transformer layer ----
  k_tr<<<dim3(512, 8), 256, 0, stream>>>(y, G2, nullptr, nullptr, BS, 128, 32768, 1, BS, 8192, 1, 64, 64, 128);
  k_qkv_t<<<1024, 256, 0, stream>>>(G2, t_wq, t_wk, t_wv, t_bq, t_bk, t_bv,
                                    (unsigned short*)G3, (unsigned short*)G4, (unsigned short*)G5);
  k_attnH<128, 0><<<512, 512, 0, stream>>>((unsigned short*)G3, (unsigned short*)G4, (unsigned short*)G5, G6);
  k_rowmm<64, 64, 0, 64><<<1024, 256, 0, stream>>>(G6, t_wo, t_bo, G3);
  k_ln<<<16384, 256, 0, stream>>>(G2, G3, ln1g, ln1b, G4);
  k_rowmm<64, 8, 2, 64><<<1024, 256, 0, stream>>>(G4, t_l1w, t_l1b, ffh);
  k_rowmm<8, 64, 0, 64><<<1024, 256, 0, stream>>>(ffh, t_l2w, t_l2b, G5);
  k_ln<<<16384, 256, 0, stream>>>(G4, G5, ln2g, ln2b, G6);
  k_tr<<<dim3(512, 8), 256, 0, stream>>>(G6, G2, nullptr, nullptr, BS, 8192, 64, 1, BS, 128, 1, 32768, 128, 64);
  k_gn_part<<<dim3(64, 8), 256, 0, stream>>>(y, G2, nullptr, nullptr, nullptr, G5, part);
  k_gn_final<<<8, 64, 0, stream>>>(part, stats);
  k_gn_apply<<<4096, 256, 0, stream>>>(G5, nullptr, stats, gntg, gntb, G0, G1, G3);

  // ---- fuse + channel FFN + final GroupNorm ----
  k_tr<<<dim3(512, 8), 256, 0, stream>>>(G3, G4, nullptr, nullptr, BS, 128, 32768, 1, BS, 8192, 1, 64, 64, 128);
  k_rowmm<64, 128, 1, 64><<<1024, 256, 0, stream>>>(G4, ff1w, ff1b, G5);
  k_rowmm<128, 64, 0, 32><<<2048, 256, 0, stream>>>(G5, ff2w, ff2b, G4);
  k_tr<<<dim3(512, 8), 256, 0, stream>>>(G4, out, G3, nullptr, BS, 8192, 64, 1, BS, 128, 1, 32768, 128, 64);
  k_gn_part<<<dim3(64, 8), 256, 0, stream>>>(out, nullptr, nullptr, nullptr, nullptr, nullptr, part);
  k_gn_final<<<8, 64, 0, stream>>>(part, stats);
  k_gn_apply<<<4096, 256, 0, stream>>>(out, nullptr, stats, gn2g, gn2b, nullptr, nullptr, out);
}

// Round 12
// 585.474 us; speedup vs baseline: 1.1088x; 1.0182x over previous
//
#include <hip/hip_runtime.h>
#include <math.h>

constexpr int CC = 64, KK = 256, LL = 128;
constexpr int NN = KK * LL;          // 32768
constexpr int PR = 64;               // Linformer projection
constexpr int CPG = 16;              // channels per group (C / 4)
constexpr float EPSV = 1e-5f;
constexpr float SCL = 0.35355339059327373f;  // 1/sqrt(8)

typedef __attribute__((ext_vector_type(8))) short short8;      // 8 bf16 (4 VGPR)
typedef __attribute__((ext_vector_type(4))) float f32x4;       // MFMA 16x16 acc

__device__ __forceinline__ unsigned short f2bf(float x) {
  union { float f; unsigned int u; } v; v.f = x;
  unsigned int r = (v.u + 0x7FFFu + ((v.u >> 16) & 1u)) >> 16;
  return (unsigned short)r;
}
__device__ __forceinline__ float bf2f(unsigned short x) {
  union { unsigned int u; float f; } v; v.u = ((unsigned int)x) << 16;
  return v.f;
}

// ---------------- adaptive adjacency: softmax(relu(nv1@nv2), axis=1) ----------------
__global__ __launch_bounds__(256) void k_adp(const float* __restrict__ nv1,
                                             const float* __restrict__ nv2,
                                             float* __restrict__ adp) {
  int w = blockIdx.x, v = threadIdx.x;
  float s = 0.f;
  for (int d = 0; d < 10; ++d) s += nv1[w * 10 + d] * nv2[d * KK + v];
  s = fmaxf(s, 0.f);
  __shared__ float red[256];
  red[v] = s; __syncthreads();
  for (int off = 128; off; off >>= 1) { if (v < off) red[v] = fmaxf(red[v], red[v + off]); __syncthreads(); }
  float m = red[0]; __syncthreads();
  float e = expf(s - m);
  red[v] = e; __syncthreads();
  for (int off = 128; off; off >>= 1) { if (v < off) red[v] += red[v + off]; __syncthreads(); }
  adp[w * KK + v] = e / red[0];
}

// ---------------- fp32 -> bf16 cast ----------------
__global__ __launch_bounds__(256) void k_cast(const float* __restrict__ src,
                                              unsigned short* __restrict__ dst) {
  int i = blockIdx.x * 256 + threadIdx.x;
  dst[i] = f2bf(src[i]);
}

// ---------------- s0 term: s0[b,o,k,l] = bias[o] + sum_c W0[o][c]*xs[(b,l,k)][c]  (A=W,B=X; coalesced l) ----------------
__global__ __launch_bounds__(64) void k_mix0(const unsigned short* __restrict__ Xbf,
                                             const unsigned short* __restrict__ Wbf,
                                             const float* __restrict__ bias,
                                             float* __restrict__ s0) {
  int pb = blockIdx.x;
  int lh = pb & 1;
  int k = (pb >> 1) & 255;
  int b = pb >> 9;
  int lane = threadIdx.x;
  int lr = lane & 15, g = lane >> 4;
  short8 af[4][2], bfv[4][2];
#pragma unroll
  for (int ot = 0; ot < 4; ++ot)
#pragma unroll
    for (int kc = 0; kc < 2; ++kc)
      af[ot][kc] = *(const short8*)(Wbf + (size_t)(ot * 16 + lr) * 448 + kc * 32 + g * 8);
#pragma unroll
  for (int ct = 0; ct < 4; ++ct)
#pragma unroll
    for (int kc = 0; kc < 2; ++kc)
      bfv[ct][kc] = *(const short8*)(Xbf + ((size_t)(b * 128 + lh * 64 + ct * 16 + lr) * 256 + k) * 64 + kc * 32 + g * 8);
  f32x4 acc[4][4];
#pragma unroll
  for (int ot = 0; ot < 4; ++ot)
#pragma unroll
    for (int ct = 0; ct < 4; ++ct) acc[ot][ct] = f32x4{0.f, 0.f, 0.f, 0.f};
#pragma unroll
  for (int kc = 0; kc < 2; ++kc)
#pragma unroll
    for (int ot = 0; ot < 4; ++ot)
#pragma unroll
      for (int ct = 0; ct < 4; ++ct)
        acc[ot][ct] = __builtin_amdgcn_mfma_f32_16x16x32_bf16(af[ot][kc], bfv[ct][kc], acc[ot][ct], 0, 0, 0);
#pragma unroll
  for (int ot = 0; ot < 4; ++ot)
#pragma unroll
    for (int ct = 0; ct < 4; ++ct) {
      // D: row = o (ot*16 + g*4 + reg), col = l (ct*16 + lr) -> contiguous in l
#pragma unroll
      for (int reg = 0; reg < 4; ++reg) {
        int o = ot * 16 + g * 4 + reg;
        s0[(size_t)(b * 64 + o) * NN + (size_t)k * 128 + lh * 64 + ct * 16 + lr] = acc[ot][ct][reg] + bias[o];
      }
    }
}

// ---------------- U terms: U_s[(b*64+o)][l][k] bf16; blockIdx.y picks s-pair {1,2},{3,4},{5,6} ----------------
__global__ __launch_bounds__(64) void k_mix6(const unsigned short* __restrict__ Xbf,
                                             const unsigned short* __restrict__ Wbf,
                                             unsigned short* __restrict__ U1, unsigned short* __restrict__ U2,
                                             unsigned short* __restrict__ U3, unsigned short* __restrict__ U4,
                                             unsigned short* __restrict__ U5, unsigned short* __restrict__ U6) {
  unsigned short* Us[6] = {U1, U2, U3, U4, U5, U6};
  int pb = blockIdx.x;
  int sy = blockIdx.y;               // 0,1,2
  int b = pb >> 9;
  int rem = pb & 511;
  int l = rem >> 2;
  int kq = (rem & 3) * 64;
  size_t posbase = ((size_t)(b * 128 + l)) * 256 + kq;
  int lane = threadIdx.x;
  int lr = lane & 15, g = lane >> 4;

  short8 af[4][2];
#pragma unroll
  for (int rt = 0; rt < 4; ++rt)
#pragma unroll
    for (int kc = 0; kc < 2; ++kc)
      af[rt][kc] = *(const short8*)(Xbf + (posbase + rt * 16 + lr) * 64 + kc * 32 + g * 8);

  for (int si = 0; si < 2; ++si) {
    int s = sy * 2 + 1 + si;
    short8 bfv[4][2];
#pragma unroll
    for (int ct = 0; ct < 4; ++ct)
#pragma unroll
      for (int kc = 0; kc < 2; ++kc)
        bfv[ct][kc] = *(const short8*)(Wbf + (size_t)(ct * 16 + lr) * 448 + s * 64 + kc * 32 + g * 8);
    f32x4 acc[4][4];
#pragma unroll
    for (int rt = 0; rt < 4; ++rt)
#pragma unroll
      for (int ct = 0; ct < 4; ++ct) acc[rt][ct] = f32x4{0.f, 0.f, 0.f, 0.f};
#pragma unroll
    for (int kc = 0; kc < 2; ++kc)
#pragma unroll
      for (int rt = 0; rt < 4; ++rt)
#pragma unroll
        for (int ct = 0; ct < 4; ++ct)
          acc[rt][ct] = __builtin_amdgcn_mfma_f32_16x16x32_bf16(af[rt][kc], bfv[ct][kc], acc[rt][ct], 0, 0, 0);
    unsigned short* dst = Us[s - 1];
#pragma unroll
    for (int rt = 0; rt < 4; ++rt)
#pragma unroll
      for (int ct = 0; ct < 4; ++ct) {
        int o = ct * 16 + lr;
        int k = kq + rt * 16 + g * 4;
        ushort4 pk;
        pk.x = f2bf(acc[rt][ct][0]); pk.y = f2bf(acc[rt][ct][1]);
        pk.z = f2bf(acc[rt][ct][2]); pk.w = f2bf(acc[rt][ct][3]);
        *(ushort4*)&dst[((size_t)(b * 64 + o) * 128 + l) * 256 + k] = pk;
      }
  }
}

// ---------------- out[bc, w, l] = sum_v A[w,v] * XT[bc, l, v]  (bf16 MFMA 16x16x32) ----------------
__global__ __launch_bounds__(256) void k_adjM(const unsigned short* __restrict__ Abf,
                                              const unsigned short* __restrict__ XT,
                                              float* __restrict__ out,
                                              unsigned short* __restrict__ outT,
                                              const unsigned short* __restrict__ addT) {
  int lq = blockIdx.x & 3, bc = blockIdx.x >> 2;
  int tid = threadIdx.x, wid = tid >> 6, lane = tid & 63;
  int lr = lane & 15, g = lane >> 4;
  int wbase = wid * 64;
  const unsigned short* aP = Abf + (size_t)(wbase + lr) * 256 + g * 8;
  const unsigned short* bP = XT + ((size_t)bc * 128 + lq * 32 + lr) * 256 + g * 8;
  f32x4 acc[4][2];
#pragma unroll
  for (int i = 0; i < 4; ++i)
#pragma unroll
    for (int j = 0; j < 2; ++j) acc[i][j] = f32x4{0.f, 0.f, 0.f, 0.f};
  for (int k0 = 0; k0 < 256; k0 += 32) {
    short8 af[4], bfv[2];
#pragma unroll
    for (int i = 0; i < 4; ++i) af[i] = *(const short8*)(aP + (size_t)i * 16 * 256 + k0);
#pragma unroll
    for (int i = 0; i < 2; ++i) bfv[i] = *(const short8*)(bP + (size_t)i * 16 * 256 + k0);
#pragma unroll
    for (int rm = 0; rm < 4; ++rm)
#pragma unroll
      for (int cn = 0; cn < 2; ++cn)
        acc[rm][cn] = __builtin_amdgcn_mfma_f32_16x16x32_bf16(af[rm], bfv[cn], acc[rm][cn], 0, 0, 0);
  }
  if (out) {
    float* dst = out + (size_t)bc * NN + lq * 32;
#pragma unroll
    for (int rm = 0; rm < 4; ++rm)
#pragma unroll
      for (int cn = 0; cn < 2; ++cn) {
        int col = cn * 16 + lr;
        int row = wbase + rm * 16 + g * 4;
#pragma unroll
        for (int j = 0; j < 4; ++j)
          dst[(size_t)(row + j) * 128 + col] = acc[rm][cn][j];
      }
  }
  if (outT) {
    unsigned short* dT = outT + (size_t)bc * NN + (size_t)(lq * 32) * 256;
    const unsigned short* aT = addT ? addT + (size_t)bc * NN + (size_t)(lq * 32) * 256 : nullptr;
#pragma unroll
    for (int rm = 0; rm < 4; ++rm)
#pragma unroll
      for (int cn = 0; cn < 2; ++cn) {
        int l = cn * 16 + lr;
        int v = wbase + rm * 16 + g * 4;
        float a0 = 0.f, a1 = 0.f, a2 = 0.f, a3 = 0.f;
        if (aT) {
          ushort4 av = *(const ushort4*)&aT[(size_t)l * 256 + v];
          a0 = bf2f(av.x); a1 = bf2f(av.y); a2 = bf2f(av.z); a3 = bf2f(av.w);
        }
        ushort4 pk;
        pk.x = f2bf(acc[rm][cn][0] + a0); pk.y = f2bf(acc[rm][cn][1] + a1);
        pk.z = f2bf(acc[rm][cn][2] + a2); pk.w = f2bf(acc[rm][cn][3] + a3);
        *(ushort4*)&dT[(size_t)l * 256 + v] = pk;
      }
  }
}

// ---------------- generic (c,l)-plane transpose per (b,k), optional add + bf16 side output ----------------
__global__ __launch_bounds__(256) void k_tr(const float* __restrict__ src, float* __restrict__ dst,
                                            const float* __restrict__ add,
                                            unsigned short* __restrict__ dstBf,
                                            long sb, long sk, long sc, long sl,
                                            long db, long dk, long dc, long dl, int nC, int nL) {
  int outer = blockIdx.x;
  int b = outer >> 8, k = outer & 255;
  int tilesL = nL >> 5;
  int tC = blockIdx.y / tilesL, tL = blockIdx.y % tilesL;
  int c0 = tC << 5, l0 = tL << 5;
  __shared__ float s[32][33];
  int tx = threadIdx.x & 31, ty = threadIdx.x >> 5;
  const float* sp = src + (long)b * sb + (long)k * sk;
#pragma unroll
  for (int j = 0; j < 4; ++j) {
    int cc = c0 + ty + j * 8;
    s[ty + j * 8][tx] = sp[(long)cc * sc + (long)(l0 + tx) * sl];
  }
  __syncthreads();
  long dbase = (long)b * db + (long)k * dk;
#pragma unroll
  for (int j = 0; j < 4; ++j) {
    int ll = l0 + ty + j * 8;
    long off = dbase + (long)(c0 + tx) * dc + (long)ll * dl;
    float val = s[tx][ty + j * 8];
    if (add) val += add[off];
    dst[off] = val;
    if (dstBf) dstBf[off] = f2bf(val);
  }
}

// ---------------- spatial QKV: Q -> bf16, K/V -> fp32 ----------------
__global__ __launch_bounds__(256) void k_qkv_s(const float* __restrict__ in,
                                               const float* __restrict__ W0, const float* __restrict__ W1,
                                               const float* __restrict__ W2,
                                               unsigned short* __restrict__ qb,
                                               float* __restrict__ o1, float* __restrict__ o2) {
  int r0 = blockIdx.x * 64;
  __shared__ float sInT[64][68];
  __shared__ float sW[3][64][64];
  int t = threadIdx.x;
  for (int i = t; i < 4096; i += 256) {
    int c = i >> 6, o = i & 63;
    sW[0][c][o] = W0[i];
    sW[1][c][o] = W1[i];
    sW[2][c][o] = W2[i];
  }
  for (int i = t; i < 4096; i += 256) {
    int r = i >> 6, c = i & 63;
    sInT[c][r] = in[(size_t)(r0 + r) * 64 + c];
  }
  __syncthreads();
  int col = t & 63, rg = t >> 6;
  int rbase = rg * 16;
  float a0[16], a1[16], a2[16];
#pragma unroll
  for (int i = 0; i < 16; ++i) { a0[i] = 0.f; a1[i] = 0.f; a2[i] = 0.f; }
  for (int c = 0; c < 64; ++c) {
    float w0 = sW[0][c][col], w1 = sW[1][c][col], w2 = sW[2][c][col];
#pragma unroll
    for (int rr = 0; rr < 16; rr += 4) {
      float4 xv = *(const float4*)&sInT[c][rbase + rr];
      a0[rr + 0] += xv.x * w0; a0[rr + 1] += xv.y * w0; a0[rr + 2] += xv.z * w0; a0[rr + 3] += xv.w * w0;
      a1[rr + 0] += xv.x * w1; a1[rr + 1] += xv.y * w1; a1[rr + 2] += xv.z * w1; a1[rr + 3] += xv.w * w1;
      a2[rr + 0] += xv.x * w2; a2[rr + 1] += xv.y * w2; a2[rr + 2] += xv.z * w2; a2[rr + 3] += xv.w * w2;
    }
  }
#pragma unroll
  for (int rr = 0; rr < 16; ++rr) {
    size_t idx = (size_t)(r0 + rbase + rr) * 64 + col;
    qb[idx] = f2bf(a0[rr]); o1[idx] = a1[rr]; o2[idx] = a2[rr];
  }
}

// ---------------- temporal QKV: Q,K -> bf16 row-major; V -> bf16 TRANSPOSED [bk][c][l] ----------------
__global__ __launch_bounds__(256) void k_qkv_t(const float* __restrict__ in,
                                               const float* __restrict__ W0, const float* __restrict__ W1,
                                               const float* __restrict__ W2,
                                               const float* __restrict__ b0, const float* __restrict__ b1,
                                               const float* __restrict__ b2,
                                               unsigned short* __restrict__ qb,
                                               unsigned short* __restrict__ kb,
                                               unsigned short* __restrict__ vt) {
  int r0 = blockIdx.x * 64;
  __shared__ float sInT[64][68];
  __shared__ float sW[3][64][64];
  int t = threadIdx.x;
  for (int i = t; i < 4096; i += 256) {
    int c = i >> 6, o = i & 63;
    sW[0][c][o] = W0[i];
    sW[1][c][o] = W1[i];
    sW[2][c][o] = W2[i];
  }
  for (int i = t; i < 4096; i += 256) {
    int r = i >> 6, c = i & 63;
    sInT[c][r] = in[(size_t)(r0 + r) * 64 + c];
  }
  __syncthreads();
  int col = t & 63, rg = t >> 6;
  int rbase = rg * 16;
  float a0[16], a1[16], a2[16];
  float bv0 = b0[col], bv1 = b1[col], bv2 = b2[col];
#pragma unroll
  for (int i = 0; i < 16; ++i) { a0[i] = bv0; a1[i] = bv1; a2[i] = bv2; }
  for (int c = 0; c < 64; ++c) {
    float w0 = sW[0][c][col], w1 = sW[1][c][col], w2 = sW[2][c][col];
#pragma unroll
    for (int rr = 0; rr < 16; rr += 4) {
      float4 xv = *(const float4*)&sInT[c][rbase + rr];
      a0[rr + 0] += xv.x * w0; a0[rr + 1] += xv.y * w0; a0[rr + 2] += xv.z * w0; a0[rr + 3] += xv.w * w0;
      a1[rr + 0] += xv.x * w1; a1[rr + 1] += xv.y * w1; a1[rr + 2] += xv.z * w1; a1[rr + 3] += xv.w * w1;
      a2[rr + 0] += xv.x * w2; a2[rr + 1] += xv.y * w2; a2[rr + 2] += xv.z * w2; a2[rr + 3] += xv.w * w2;
    }
  }
#pragma unroll
  for (int rr = 0; rr < 16; ++rr) {
    size_t idx = (size_t)(r0 + rbase + rr) * 64 + col;
    qb[idx] = f2bf(a0[rr]); kb[idx] = f2bf(a1[rr]);
  }
  int bk = r0 >> 7;
  int lbase = (r0 & 127) + rbase;
  unsigned short* vd = vt + (size_t)bk * 8192 + (size_t)col * 128 + lbase;
#pragma unroll
  for (int rr = 0; rr < 16; ++rr) vd[rr] = f2bf(a2[rr]);
}

// ---------------- row-major (R,CIN) @ (CIN,COUT) + bias, optional activation ----------------
template <int CIN, int COUT, int ACT, int ROWS>
__global__ __launch_bounds__(256) void k_rowmm(const float* __restrict__ in,
                                               const float* __restrict__ W,
                                               const float* __restrict__ bias,
                                               float* __restrict__ out) {
  int r0 = blockIdx.x * ROWS;
  __shared__ float sInT[CIN][ROWS + 4];
  __shared__ float sW[CIN][COUT];
  int t = threadIdx.x;
  for (int i = t; i < CIN * COUT; i += 256) ((float*)sW)[i] = W[i];
  for (int i = t; i < ROWS * CIN; i += 256) {
    int r = i / CIN, c = i % CIN;
    sInT[c][r] = in[(size_t)r0 * CIN + i];
  }
  __syncthreads();
  constexpr int NRG = 256 / COUT;
  constexpr int RPT = ROWS / NRG;
  int col = t % COUT, rg = t / COUT;
  int rbase = rg * RPT;
  float acc[RPT];
  float bv = bias ? bias[col] : 0.f;
#pragma unroll
  for (int r = 0; r < RPT; ++r) acc[r] = bv;
  for (int c = 0; c < CIN; ++c) {
    float wv = sW[c][col];
    if constexpr (RPT % 4 == 0) {
#pragma unroll
      for (int rr = 0; rr < RPT; rr += 4) {
        float4 xv = *(const float4*)&sInT[c][rbase + rr];
        acc[rr] += xv.x * wv; acc[rr + 1] += xv.y * wv;
        acc[rr + 2] += xv.z * wv; acc[rr + 3] += xv.w * wv;
      }
    } else {
#pragma unroll
      for (int rr = 0; rr < RPT; ++rr) acc[rr] += sInT[c][rbase + rr] * wv;
    }
  }
#pragma unroll
  for (int rr = 0; rr < RPT; ++rr) {
    float v = acc[rr];
    if (ACT == 1) v = fmaxf(v, 0.f);
    if (ACT == 2) v = 0.5f * v * (1.f + erff(v * 0.70710678118654752440f));
    out[(size_t)(r0 + rbase + rr) * COUT + col] = v;
  }
}

// ---------------- sproj: out[bl,p,c] = sum_n X[bl,n,c] * P[n,p]; bf16 outputs (RM and/or T) ----------------
__global__ __launch_bounds__(256) void k_sproj(const float* __restrict__ X,
                                               const float* __restrict__ P,
                                               unsigned short* __restrict__ outRM,
                                               unsigned short* __restrict__ outT) {
  int bl = blockIdx.x;
  const float* src = X + (size_t)bl * KK * CC;
  int t = threadIdx.x, c = t & 63, pg = t >> 6;
  __shared__ float sX[64][CC];
  __shared__ float sP[64][PR];
  float acc[16];
#pragma unroll
  for (int i = 0; i < 16; ++i) acc[i] = 0.f;
  for (int n0 = 0; n0 < KK; n0 += 64) {
    for (int i = t; i < 64 * CC; i += 256) ((float*)sX)[i] = src[(size_t)n0 * CC + i];
    for (int i = t; i < 64 * PR; i += 256) ((float*)sP)[i] = P[(size_t)n0 * PR + i];
    __syncthreads();
    for (int n = 0; n < 64; ++n) {
      float xv = sX[n][c];
#pragma unroll
      for (int q = 0; q < 4; ++q) {
        float4 pv = *(const float4*)&sP[n][pg * 16 + q * 4];
        acc[q * 4 + 0] += pv.x * xv; acc[q * 4 + 1] += pv.y * xv;
        acc[q * 4 + 2] += pv.z * xv; acc[q * 4 + 3] += pv.w * xv;
      }
    }
    __syncthreads();
  }
  if (outRM) {
    unsigned short* d = outRM + (size_t)bl * PR * CC;
#pragma unroll
    for (int i = 0; i < 16; ++i) d[(size_t)(pg * 16 + i) * CC + c] = f2bf(acc[i]);
  }
  if (outT) {
    unsigned short* d = outT + (size_t)bl * PR * CC + (size_t)c * PR + pg * 16;
#pragma unroll
    for (int i = 0; i < 16; ++i) d[i] = f2bf(acc[i]);
  }
}

// ---------------- per-head MFMA attention: block = 128 q-rows, 8 waves = 8 heads ----------------
template <int NKV, int KVSHIFT>
__global__ __launch_bounds__(512) void k_attnH(const unsigned short* __restrict__ Qb,
                                               const unsigned short* __restrict__ Kb,
                                               const unsigned short* __restrict__ VTb,
                                               float* __restrict__ O) {
  constexpr int NCT = NKV / 16;
  constexpr int NKS = NKV / 32;
  int blk = blockIdx.x;
  const unsigned short* Qp = Qb + (size_t)blk * 128 * 64;
  float* Op = O + (size_t)blk * 128 * 64;
  const unsigned short* Kp = Kb + (size_t)(blk >> KVSHIFT) * NKV * 64;
  const unsigned short* VTp = VTb + (size_t)(blk >> KVSHIFT) * 64 * NKV;
  int t = threadIdx.x;
  int h = t >> 6, lane = t & 63, lr = lane & 15, g = lane >> 4;
  __shared__ unsigned short sP[8][16 * NKV];
  unsigned short* myP = sP[h];

  short8 kbf[NCT];
#pragma unroll
  for (int ct = 0; ct < NCT; ++ct)
    kbf[ct] = *(const short8*)(Kp + (size_t)(ct * 16 + lr) * 64 + h * 8);

  int vr = h * 8 + lr; if (vr > 63) vr = 63;
  short8 vbf[NKS];
#pragma unroll
  for (int ks = 0; ks < NKS; ++ks)
    vbf[ks] = *(const short8*)(VTp + (size_t)vr * NKV + ks * 32 + g * 8);

  for (int mt = 0; mt < 8; ++mt) {
    short8 qa = short8{0, 0, 0, 0, 0, 0, 0, 0};
    if (g == 0) qa = *(const short8*)(Qp + (size_t)(mt * 16 + lr) * 64 + h * 8);

    f32x4 sacc[NCT];
#pragma unroll
    for (int ct = 0; ct < NCT; ++ct) sacc[ct] = f32x4{0.f, 0.f, 0.f, 0.f};
#pragma unroll
    for (int ct = 0; ct < NCT; ++ct)
      sacc[ct] = __builtin_amdgcn_mfma_f32_16x16x32_bf16(qa, kbf[ct], sacc[ct], 0, 0, 0);

    float inv4[4];
#pragma unroll
    for (int reg = 0; reg < 4; ++reg) {
      float s = 0.f;
#pragma unroll
      for (int ct = 0; ct < NCT; ++ct) {
        float e = __expf(sacc[ct][reg] * SCL);
        sacc[ct][reg] = e;
        s += e;
      }
      s += __shfl_xor(s, 1); s += __shfl_xor(s, 2); s += __shfl_xor(s, 4); s += __shfl_xor(s, 8);
      inv4[reg] = 1.f / s;
    }

#pragma unroll
    for (int ct = 0; ct < NCT; ++ct)
#pragma unroll
      for (int reg = 0; reg < 4; ++reg) {
        int row = g * 4 + reg;
        int bo = ((row * NKV + ct * 16 + lr) * 2) ^ ((row & 7) << 4);
        *(unsigned short*)((char*)myP + bo) = f2bf(sacc[ct][reg]);
      }
    __syncthreads();

    f32x4 oacc = f32x4{0.f, 0.f, 0.f, 0.f};
#pragma unroll
    for (int ks = 0; ks < NKS; ++ks) {
      int bo = ((lr * NKV + ks * 32 + g * 8) * 2) ^ ((lr & 7) << 4);
      short8 pa = *(const short8*)((char*)myP + bo);
      oacc = __builtin_amdgcn_mfma_f32_16x16x32_bf16(pa, vbf[ks], oacc, 0, 0, 0);
    }
    if (lr < 8) {
#pragma unroll
      for (int reg = 0; reg < 4; ++reg) {
        int row = mt * 16 + g * 4 + reg;
        Op[(size_t)row * 64 + h * 8 + lr] = oacc[reg] * inv4[reg];
      }
    }
    __syncthreads();
  }
}

// ---------------- LayerNorm over C=64 per row, input = A (+ optional Bp) ----------------
__global__ __launch_bounds__(256) void k_ln(const float* __restrict__ A, const float* __restrict__ Bp,
                                            const float* __restrict__ g, const float* __restrict__ be,
                                            float* __restrict__ out) {
  int row = blockIdx.x * 4 + (threadIdx.x >> 6);
  int c = threadIdx.x & 63;
  size_t idx = (size_t)row * CC + c;
  float x = A[idx] + (Bp ? Bp[idx] : 0.f);
  float s = x, ss = x * x;
#pragma unroll
  for (int off = 32; off; off >>= 1) { s += __shfl_xor(s, off); ss += __shfl_xor(ss, off); }
  float mu = s * (1.f / 64.f);
  float var = ss * (1.f / 64.f) - mu * mu;
  out[idx] = (x - mu) * rsqrtf(var + EPSV) * g[c] + be[c];
}

// ---------------- GroupNorm stats: up to 5 summed inputs, optional sum write-back ----------------
__global__ __launch_bounds__(256) void k_gn_part(const float* __restrict__ p0, const float* __restrict__ p1,
                                                 const float* __restrict__ p2, const float* __restrict__ p3,
                                                 const float* __restrict__ p4,
                                                 float* __restrict__ sumOut,
                                                 float* __restrict__ part) {
  int bg = blockIdx.y, blk = blockIdx.x, t = threadIdx.x;
  size_t start = (size_t)bg * ((size_t)CPG * NN) + (size_t)blk * 8192;
  const float4* q0 = (const float4*)(p0 + start);
  const float4* q1 = p1 ? (const float4*)(p1 + start) : nullptr;
  const float4* q2 = p2 ? (const float4*)(p2 + start) : nullptr;
  const float4* q3 = p3 ? (const float4*)(p3 + start) : nullptr;
  const float4* q4 = p4 ? (const float4*)(p4 + start) : nullptr;
  float4* so = sumOut ? (float4*)(sumOut + start) : nullptr;
  float s = 0.f, ss = 0.f;
  for (int i = t; i < 2048; i += 256) {
    float4 x = q0[i];
    if (q1) { float4 y4 = q1[i]; x.x += y4.x; x.y += y4.y; x.z += y4.z; x.w += y4.w; }
    if (q2) { float4 y4 = q2[i]; x.x += y4.x; x.y += y4.y; x.z += y4.z; x.w += y4.w; }
    if (q3) { float4 y4 = q3[i]; x.x += y4.x; x.y += y4.y; x.z += y4.z; x.w += y4.w; }
    if (q4) { float4 y4 = q4[i]; x.x += y4.x; x.y += y4.y; x.z += y4.z; x.w += y4.w; }
    if (so) so[i] = x;
    s += x.x + x.y + x.z + x.w;
    ss += x.x * x.x + x.y * x.y + x.z * x.z + x.w * x.w;
  }
  __shared__ float rs[256], rq[256];
  rs[t] = s; rq[t] = ss; __syncthreads();
  for (int off = 128; off; off >>= 1) { if (t < off) { rs[t] += rs[t + off]; rq[t] += rq[t + off]; } __syncthreads(); }
  if (t == 0) { part[(bg * 64 + blk) * 2] = rs[0]; part[(bg * 64 + blk) * 2 + 1] = rq[0]; }
}

__global__ __launch_bounds__(64) void k_gn_final(const float* __restrict__ part, float* __restrict__ stats) {
  int bg = blockIdx.x, t = threadIdx.x;
  float s = part[(bg * 64 + t) * 2], ss = part[(bg * 64 + t) * 2 + 1];
#pragma unroll
  for (int off = 32; off; off >>= 1) { s += __shfl_xor(s, off); ss += __shfl_xor(ss, off); }
  if (t == 0) {
    float inv = 1.f / (float)((size_t)CPG * NN);
    float mu = s * inv;
    float var = ss * inv - mu * mu;
    stats[bg * 2] = mu;
    stats[bg * 2 + 1] = rsqrtf(var + EPSV);
  }
}

// out = GN(p0[+p1]) (+ q0) (+ q1)   — float4, grid 4096
__global__ __launch_bounds__(256) void k_gn_apply(const float* __restrict__ p0, const float* __restrict__ p1,
                                                  const float* __restrict__ stats, const float* __restrict__ g,
                                                  const float* __restrict__ be,
                                                  const float* __restrict__ q0, const float* __restrict__ q1,
                                                  float* __restrict__ out) {
  size_t i4 = (size_t)blockIdx.x * 256 + threadIdx.x;
  size_t i = i4 * 4;
  int chan = (int)(i >> 15) & 63;
  int bg = (int)(i >> 19);
  float4 x = ((const float4*)p0)[i4];
  if (p1) { float4 y4 = ((const float4*)p1)[i4]; x.x += y4.x; x.y += y4.y; x.z += y4.z; x.w += y4.w; }
  float mu = stats[bg * 2], rr = stats[bg * 2 + 1];
  float gc = g[chan], bc = be[chan];
  float4 v;
  v.x = (x.x - mu) * rr * gc + bc;
  v.y = (x.y - mu) * rr * gc + bc;
  v.z = (x.z - mu) * rr * gc + bc;
  v.w = (x.w - mu) * rr * gc + bc;
  if (q0) { float4 y4 = ((const float4*)q0)[i4]; v.x += y4.x; v.y += y4.y; v.z += y4.z; v.w += y4.w; }
  if (q1) { float4 y4 = ((const float4*)q1)[i4]; v.x += y4.x; v.y += y4.y; v.z += y4.z; v.w += y4.w; }
  ((float4*)out)[i4] = v;
}

extern "C" void kernel_launch(void* const* d_in, const int* in_sizes, int n_in,
                              void* d_out, int out_size, void* d_ws, size_t ws_size,
                              hipStream_t stream) {
  (void)in_sizes; (void)n_in; (void)out_size; (void)ws_size;
  const float* y     = (const float*)d_in[0];
  const float* a1    = (const float*)d_in[1];
  const float* a2    = (const float*)d_in[2];
  const float* nv1   = (const float*)d_in[3];
  const float* nv2   = (const float*)d_in[4];
  const float* gcn_w = (const float*)d_in[5];
  const float* gcn_b = (const float*)d_in[6];
  const float* s_wq  = (const float*)d_in[7];
  const float* s_wk  = (const float*)d_in[8];
  const float* s_wv  = (const float*)d_in[9];
  const float* s_pk  = (const float*)d_in[10];
  const float* s_pv  = (const float*)d_in[11];
  const float* s_wo  = (const float*)d_in[12];
  const float* s_bo  = (const float*)d_in[13];
  const float* t_wq  = (const float*)d_in[14];
  const float* t_wk  = (const float*)d_in[15];
  const float* t_wv  = (const float*)d_in[16];
  const float* t_bq  = (const float*)d_in[17];
  const float* t_bk  = (const float*)d_in[18];
  const float* t_bv  = (const float*)d_in[19];
  const float* t_wo  = (const float*)d_in[20];
  const float* t_bo  = (const float*)d_in[21];
  const float* t_l1w = (const float*)d_in[22];
  const float* t_l1b = (const float*)d_in[23];
  const float* t_l2w = (const float*)d_in[24];
  const float* t_l2b = (const float*)d_in[25];
  const float* ln1g  = (const float*)d_in[26];
  const float* ln1b  = (const float*)d_in[27];
  const float* ln2g  = (const float*)d_in[28];
  const float* ln2b  = (const float*)d_in[29];
  const float* gnlg  = (const float*)d_in[30];
  const float* gnlb  = (const float*)d_in[31];
  const float* gnsg  = (const float*)d_in[32];
  const float* gnsb  = (const float*)d_in[33];
  const float* gntg  = (const float*)d_in[34];
  const float* gntb  = (const float*)d_in[35];
  const float* ff1w  = (const float*)d_in[36];
  const float* ff1b  = (const float*)d_in[37];
  const float* ff2w  = (const float*)d_in[38];
  const float* ff2b  = (const float*)d_in[39];
  const float* gn2g  = (const float*)d_in[40];
  const float* gn2b  = (const float*)d_in[41];

  float* ws = (float*)d_ws;
  float* adp   = ws;
  float* part  = ws + 65536;
  float* stats = ws + 66560;
  unsigned short* a1_bf   = (unsigned short*)(ws + 131072);
  unsigned short* a2_bf   = (unsigned short*)(ws + 163840);
  unsigned short* adp_bf  = (unsigned short*)(ws + 196608);
  unsigned short* gcnw_bf = (unsigned short*)(ws + 229376);
  unsigned short* xs_bf   = (unsigned short*)(ws + 262144);
  float* kp2 = ws + 131072;                 // reused post-GCN
  float* vp2 = ws + 131072 + 1048576;
  unsigned short* kpb  = (unsigned short*)kp2;
  unsigned short* vptb = (unsigned short*)vp2;
  float* ffh = ws + 2228224;
  const size_t SLOT = 4194304;
  float* G0 = ws + SLOT * 1;
  float* G1 = ws + SLOT * 2;
  float* G2 = ws + SLOT * 3;
  float* G3 = ws + SLOT * 4;
  float* G4 = ws + SLOT * 5;
  float* G5 = ws + SLOT * 6;
  float* G6 = ws + SLOT * 7;
  unsigned short* U1 = (unsigned short*)G3;
  unsigned short* U2 = (unsigned short*)G3 + 4194304;
  unsigned short* U3 = (unsigned short*)G4;
  unsigned short* U4 = (unsigned short*)G4 + 4194304;
  unsigned short* U5 = (unsigned short*)G5;
  unsigned short* U6 = (unsigned short*)G5 + 4194304;
  unsigned short* PT = (unsigned short*)G6;
  float* out = (float*)d_out;

  const long BS = 2097152;

  // ---- adaptive adjacency + bf16 casts ----
  k_adp<<<256, 256, 0, stream>>>(nv1, nv2, adp);
  k_cast<<<256, 256, 0, stream>>>(a1, a1_bf);
  k_cast<<<256, 256, 0, stream>>>(a2, a2_bf);
  k_cast<<<256, 256, 0, stream>>>(adp, adp_bf);
  k_cast<<<112, 256, 0, stream>>>(gcn_w, gcnw_bf);

  // ---- xs (B,L,K,C) fp32 + bf16 ----
  k_tr<<<dim3(512, 8), 256, 0, stream>>>(y, G2, nullptr, xs_bf, BS, 128, 32768, 1, BS, 64, 1, 16384, 64, 128);

  // ---- AdaptiveGCN: U_s = W_s X; out = s0 + Sum_f A_f(U_odd + A_f U_even) ----
  k_mix0<<<1024, 64, 0, stream>>>(xs_bf, gcnw_bf, gcn_b, G1);
  k_mix6<<<dim3(1024, 3), 64, 0, stream>>>(xs_bf, gcnw_bf, U1, U2, U3, U4, U5, U6);
  k_adjM<<<512, 256, 0, stream>>>(a1_bf, U2, nullptr, PT, U1);
  k_adjM<<<512, 256, 0, stream>>>(a1_bf, PT, G0, nullptr, nullptr);   // Q1
  k_adjM<<<512, 256, 0, stream>>>(a2_bf, U4, nullptr, PT, U3);
  k_adjM<<<512, 256, 0, stream>>>(a2_bf, PT, G4, nullptr, nullptr);   // Q2
  k_adjM<<<512, 256, 0, stream>>>(adp_bf, U6, nullptr, PT, U5);
  k_adjM<<<512, 256, 0, stream>>>(adp_bf, PT, G5, nullptr, nullptr);  // Q3
  k_gn_part<<<dim3(64, 8), 256, 0, stream>>>(y, G1, G0, G4, G5, G3, part);
  k_gn_final<<<8, 64, 0, stream>>>(part, stats);
  k_gn_apply<<<4096, 256, 0, stream>>>(G3, nullptr, stats, gnlg, gnlb, nullptr, nullptr, G0);

  // ---- Linformer spatial attention (G2 = xs) ----
  k_qkv_s<<<1024, 256, 0, stream>>>(G2, s_wq, s_wk, s_wv, (unsigned short*)G3, G4, G5);
  k_sproj<<<256, 256, 0, stream>>>(G4, s_pk, kpb, nullptr);
  k_sproj<<<256, 256, 0, stream>>>(G5, s_pv, nullptr, vptb);
  k_attnH<64, 1><<<512, 512, 0, stream>>>((unsigned short*)G3, kpb, vptb, G6);
  k_rowmm<64, 64, 0, 64><<<1024, 256, 0, stream>>>(G6, s_wo, s_bo, G4);
  k_tr<<<dim3(512, 8), 256, 0, stream>>>(G4, G1, nullptr, nullptr, BS, 64, 16384, 1, BS, 128, 1, 32768, 128, 64);
  k_gn_part<<<dim3(64, 8), 256, 0, stream>>>(y, G1, nullptr, nullptr, nullptr, G2, part);
  k_gn_final<<<8, 64, 0, stream>>>(part, stats);
  k_gn_apply<<<4096, 256, 0, stream>>>(G2, nullptr, stats, gnsg, gnsb, nullptr, nullptr, G1);

  // ---- temporal transformer layer ----
  k_tr<<<dim3(512, 8), 256, 0, stream>>>(y, G2, nullptr, nullptr, BS, 128, 32768, 1, BS, 8192, 1, 64, 64, 128);
  k_qkv_t<<<1024, 256, 0, stream>>>(G2, t_wq, t_wk, t_wv, t_bq, t_bk, t_bv,
                                    (unsigned short*)G3, (unsigned short*)G4, (unsigned short*)G5);
  k_attnH<128, 0><<<512, 512, 0, stream>>>((unsigned short*)G3, (unsigned short*)G4, (unsigned short*)G5, G6);
  k_rowmm<64, 64, 0, 64><<<1024, 256, 0, stream>>>(G6, t_wo, t_bo, G3);
  k_ln<<<16384, 256, 0, stream>>>(G2, G3, ln1g, ln1b, G4);
  k_rowmm<64, 8, 2, 64><<<1024, 256, 0, stream>>>(G4, t_l1w, t_l1b, ffh);
  k_rowmm<8, 64, 0, 64><<<1024, 256, 0, stream>>>(ffh, t_l2w, t_l2b, G5);
  k_ln<<<16384, 256, 0, stream>>>(G4, G5, ln2g, ln2b, G6);
  k_tr<<<dim3(512, 8), 256, 0, stream>>>(G6, G2, nullptr, nullptr, BS, 8192, 64, 1, BS, 128, 1, 32768, 128, 64);
  k_gn_part<<<dim3(64, 8), 256, 0, stream>>>(y, G2, nullptr, nullptr, nullptr, G5, part);
  k_gn_final<<<8, 64, 0, stream>>>(part, stats);
  k_gn_apply<<<4096, 256, 0, stream>>>(G5, nullptr, stats, gntg, gntb, G0, G1, G3);

  // ---- fuse + channel FFN + final GroupNorm ----
  k_tr<<<dim3(512, 8), 256, 0, stream>>>(G3, G4, nullptr, nullptr, BS, 128, 32768, 1, BS, 8192, 1, 64, 64, 128);
  k_rowmm<64, 128, 1, 64><<<1024, 256, 0, stream>>>(G4, ff1w, ff1b, G5);
  k_rowmm<128, 64, 0, 32><<<2048, 256, 0, stream>>>(G5, ff2w, ff2b, G4);
  k_tr<<<dim3(512, 8), 256, 0, stream>>>(G4, out, G3, nullptr, BS, 8192, 64, 1, BS, 128, 1, 32768, 128, 64);
  k_gn_part<<<dim3(64, 8), 256, 0, stream>>>(out, nullptr, nullptr, nullptr, nullptr, nullptr, part);
  k_gn_final<<<8, 64, 0, stream>>>(part, stats);
  k_gn_apply<<<4096, 256, 0, stream>>>(out, nullptr, stats, gn2g, gn2b, nullptr, nullptr, out);
}

// Round 13
// 537.136 us; speedup vs baseline: 1.2086x; 1.0900x over previous
//
#include <hip/hip_runtime.h>
#include <math.h>

constexpr int CC = 64, KK = 256, LL = 128;
constexpr int NN = KK * LL;          // 32768
constexpr int PR = 64;               // Linformer projection
constexpr int CPG = 16;              // channels per group (C / 4)
constexpr float EPSV = 1e-5f;
constexpr float SCL = 0.35355339059327373f;  // 1/sqrt(8)

typedef __attribute__((ext_vector_type(8))) short short8;      // 8 bf16 (4 VGPR)
typedef __attribute__((ext_vector_type(4))) float f32x4;       // MFMA 16x16 acc

__device__ __forceinline__ unsigned short f2bf(float x) {
  union { float f; unsigned int u; } v; v.f = x;
  unsigned int r = (v.u + 0x7FFFu + ((v.u >> 16) & 1u)) >> 16;
  return (unsigned short)r;
}
__device__ __forceinline__ float bf2f(unsigned short x) {
  union { unsigned int u; float f; } v; v.u = ((unsigned int)x) << 16;
  return v.f;
}

// ---------------- adaptive adjacency: softmax(relu(nv1@nv2), axis=1) ----------------
__global__ __launch_bounds__(256) void k_adp(const float* __restrict__ nv1,
                                             const float* __restrict__ nv2,
                                             float* __restrict__ adp) {
  int w = blockIdx.x, v = threadIdx.x;
  float s = 0.f;
  for (int d = 0; d < 10; ++d) s += nv1[w * 10 + d] * nv2[d * KK + v];
  s = fmaxf(s, 0.f);
  __shared__ float red[256];
  red[v] = s; __syncthreads();
  for (int off = 128; off; off >>= 1) { if (v < off) red[v] = fmaxf(red[v], red[v + off]); __syncthreads(); }
  float m = red[0]; __syncthreads();
  float e = expf(s - m);
  red[v] = e; __syncthreads();
  for (int off = 128; off; off >>= 1) { if (v < off) red[v] += red[v + off]; __syncthreads(); }
  adp[w * KK + v] = e / red[0];
}

// ---------------- fp32 -> bf16 cast (single range) ----------------
__global__ __launch_bounds__(256) void k_cast(const float* __restrict__ src,
                                              unsigned short* __restrict__ dst) {
  int i = blockIdx.x * 256 + threadIdx.x;
  dst[i] = f2bf(src[i]);
}

// ---------------- fused cast of a1 (65536) + a2 (65536) + gcn_w (28672); grid 640 ----------------
__global__ __launch_bounds__(256) void k_cast3(const float* __restrict__ s0, const float* __restrict__ s1,
                                               const float* __restrict__ s2,
                                               unsigned short* __restrict__ d0, unsigned short* __restrict__ d1,
                                               unsigned short* __restrict__ d2) {
  int i = blockIdx.x * 256 + threadIdx.x;
  if (i < 65536) d0[i] = f2bf(s0[i]);
  else if (i < 131072) d1[i - 65536] = f2bf(s1[i - 65536]);
  else if (i < 159744) d2[i - 131072] = f2bf(s2[i - 131072]);
}

// ---------------- s0 term: s0[b,o,k,l] = bias[o] + sum_c W0[o][c]*xs[(b,l,k)][c] ----------------
__global__ __launch_bounds__(64) void k_mix0(const unsigned short* __restrict__ Xbf,
                                             const unsigned short* __restrict__ Wbf,
                                             const float* __restrict__ bias,
                                             float* __restrict__ s0) {
  int pb = blockIdx.x;
  int lh = pb & 1;
  int k = (pb >> 1) & 255;
  int b = pb >> 9;
  int lane = threadIdx.x;
  int lr = lane & 15, g = lane >> 4;
  short8 af[4][2], bfv[4][2];
#pragma unroll
  for (int ot = 0; ot < 4; ++ot)
#pragma unroll
    for (int kc = 0; kc < 2; ++kc)
      af[ot][kc] = *(const short8*)(Wbf + (size_t)(ot * 16 + lr) * 448 + kc * 32 + g * 8);
#pragma unroll
  for (int ct = 0; ct < 4; ++ct)
#pragma unroll
    for (int kc = 0; kc < 2; ++kc)
      bfv[ct][kc] = *(const short8*)(Xbf + ((size_t)(b * 128 + lh * 64 + ct * 16 + lr) * 256 + k) * 64 + kc * 32 + g * 8);
  f32x4 acc[4][4];
#pragma unroll
  for (int ot = 0; ot < 4; ++ot)
#pragma unroll
    for (int ct = 0; ct < 4; ++ct) acc[ot][ct] = f32x4{0.f, 0.f, 0.f, 0.f};
#pragma unroll
  for (int kc = 0; kc < 2; ++kc)
#pragma unroll
    for (int ot = 0; ot < 4; ++ot)
#pragma unroll
      for (int ct = 0; ct < 4; ++ct)
        acc[ot][ct] = __builtin_amdgcn_mfma_f32_16x16x32_bf16(af[ot][kc], bfv[ct][kc], acc[ot][ct], 0, 0, 0);
#pragma unroll
  for (int ot = 0; ot < 4; ++ot)
#pragma unroll
    for (int ct = 0; ct < 4; ++ct) {
#pragma unroll
      for (int reg = 0; reg < 4; ++reg) {
        int o = ot * 16 + g * 4 + reg;
        s0[(size_t)(b * 64 + o) * NN + (size_t)k * 128 + lh * 64 + ct * 16 + lr] = acc[ot][ct][reg] + bias[o];
      }
    }
}

// ---------------- U terms: U_s[(b*64+o)][l][k] bf16; blockIdx.y picks s-pair ----------------
__global__ __launch_bounds__(64) void k_mix6(const unsigned short* __restrict__ Xbf,
                                             const unsigned short* __restrict__ Wbf,
                                             unsigned short* __restrict__ U1, unsigned short* __restrict__ U2,
                                             unsigned short* __restrict__ U3, unsigned short* __restrict__ U4,
                                             unsigned short* __restrict__ U5, unsigned short* __restrict__ U6) {
  unsigned short* Us[6] = {U1, U2, U3, U4, U5, U6};
  int pb = blockIdx.x;
  int sy = blockIdx.y;
  int b = pb >> 9;
  int rem = pb & 511;
  int l = rem >> 2;
  int kq = (rem & 3) * 64;
  size_t posbase = ((size_t)(b * 128 + l)) * 256 + kq;
  int lane = threadIdx.x;
  int lr = lane & 15, g = lane >> 4;

  short8 af[4][2];
#pragma unroll
  for (int rt = 0; rt < 4; ++rt)
#pragma unroll
    for (int kc = 0; kc < 2; ++kc)
      af[rt][kc] = *(const short8*)(Xbf + (posbase + rt * 16 + lr) * 64 + kc * 32 + g * 8);

  for (int si = 0; si < 2; ++si) {
    int s = sy * 2 + 1 + si;
    short8 bfv[4][2];
#pragma unroll
    for (int ct = 0; ct < 4; ++ct)
#pragma unroll
      for (int kc = 0; kc < 2; ++kc)
        bfv[ct][kc] = *(const short8*)(Wbf + (size_t)(ct * 16 + lr) * 448 + s * 64 + kc * 32 + g * 8);
    f32x4 acc[4][4];
#pragma unroll
    for (int rt = 0; rt < 4; ++rt)
#pragma unroll
      for (int ct = 0; ct < 4; ++ct) acc[rt][ct] = f32x4{0.f, 0.f, 0.f, 0.f};
#pragma unroll
    for (int kc = 0; kc < 2; ++kc)
#pragma unroll
      for (int rt = 0; rt < 4; ++rt)
#pragma unroll
        for (int ct = 0; ct < 4; ++ct)
          acc[rt][ct] = __builtin_amdgcn_mfma_f32_16x16x32_bf16(af[rt][kc], bfv[ct][kc], acc[rt][ct], 0, 0, 0);
    unsigned short* dst = Us[s - 1];
#pragma unroll
    for (int rt = 0; rt < 4; ++rt)
#pragma unroll
      for (int ct = 0; ct < 4; ++ct) {
        int o = ct * 16 + lr;
        int k = kq + rt * 16 + g * 4;
        ushort4 pk;
        pk.x = f2bf(acc[rt][ct][0]); pk.y = f2bf(acc[rt][ct][1]);
        pk.z = f2bf(acc[rt][ct][2]); pk.w = f2bf(acc[rt][ct][3]);
        *(ushort4*)&dst[((size_t)(b * 64 + o) * 128 + l) * 256 + k] = pk;
      }
  }
}

// ---------------- out[bc, w, l] = sum_v A[w,v] * XT[bc, l, v]  (bf16 MFMA 16x16x32) ----------------
__global__ __launch_bounds__(256) void k_adjM(const unsigned short* __restrict__ Abf,
                                              const unsigned short* __restrict__ XT,
                                              float* __restrict__ out,
                                              unsigned short* __restrict__ outT,
                                              const unsigned short* __restrict__ addT) {
  int lq = blockIdx.x & 3, bc = blockIdx.x >> 2;
  int tid = threadIdx.x, wid = tid >> 6, lane = tid & 63;
  int lr = lane & 15, g = lane >> 4;
  int wbase = wid * 64;
  const unsigned short* aP = Abf + (size_t)(wbase + lr) * 256 + g * 8;
  const unsigned short* bP = XT + ((size_t)bc * 128 + lq * 32 + lr) * 256 + g * 8;
  f32x4 acc[4][2];
#pragma unroll
  for (int i = 0; i < 4; ++i)
#pragma unroll
    for (int j = 0; j < 2; ++j) acc[i][j] = f32x4{0.f, 0.f, 0.f, 0.f};
  for (int k0 = 0; k0 < 256; k0 += 32) {
    short8 af[4], bfv[2];
#pragma unroll
    for (int i = 0; i < 4; ++i) af[i] = *(const short8*)(aP + (size_t)i * 16 * 256 + k0);
#pragma unroll
    for (int i = 0; i < 2; ++i) bfv[i] = *(const short8*)(bP + (size_t)i * 16 * 256 + k0);
#pragma unroll
    for (int rm = 0; rm < 4; ++rm)
#pragma unroll
      for (int cn = 0; cn < 2; ++cn)
        acc[rm][cn] = __builtin_amdgcn_mfma_f32_16x16x32_bf16(af[rm], bfv[cn], acc[rm][cn], 0, 0, 0);
  }
  if (out) {
    float* dst = out + (size_t)bc * NN + lq * 32;
#pragma unroll
    for (int rm = 0; rm < 4; ++rm)
#pragma unroll
      for (int cn = 0; cn < 2; ++cn) {
        int col = cn * 16 + lr;
        int row = wbase + rm * 16 + g * 4;
#pragma unroll
        for (int j = 0; j < 4; ++j)
          dst[(size_t)(row + j) * 128 + col] = acc[rm][cn][j];
      }
  }
  if (outT) {
    unsigned short* dT = outT + (size_t)bc * NN + (size_t)(lq * 32) * 256;
    const unsigned short* aT = addT ? addT + (size_t)bc * NN + (size_t)(lq * 32) * 256 : nullptr;
#pragma unroll
    for (int rm = 0; rm < 4; ++rm)
#pragma unroll
      for (int cn = 0; cn < 2; ++cn) {
        int l = cn * 16 + lr;
        int v = wbase + rm * 16 + g * 4;
        float a0 = 0.f, a1 = 0.f, a2 = 0.f, a3 = 0.f;
        if (aT) {
          ushort4 av = *(const ushort4*)&aT[(size_t)l * 256 + v];
          a0 = bf2f(av.x); a1 = bf2f(av.y); a2 = bf2f(av.z); a3 = bf2f(av.w);
        }
        ushort4 pk;
        pk.x = f2bf(acc[rm][cn][0] + a0); pk.y = f2bf(acc[rm][cn][1] + a1);
        pk.z = f2bf(acc[rm][cn][2] + a2); pk.w = f2bf(acc[rm][cn][3] + a3);
        *(ushort4*)&dT[(size_t)l * 256 + v] = pk;
      }
  }
}

// ---------------- generic (c,l)-plane transpose per (b,k), optional add + bf16 side output ----------------
__global__ __launch_bounds__(256) void k_tr(const float* __restrict__ src, float* __restrict__ dst,
                                            const float* __restrict__ add,
                                            unsigned short* __restrict__ dstBf,
                                            long sb, long sk, long sc, long sl,
                                            long db, long dk, long dc, long dl, int nC, int nL) {
  int outer = blockIdx.x;
  int b = outer >> 8, k = outer & 255;
  int tilesL = nL >> 5;
  int tC = blockIdx.y / tilesL, tL = blockIdx.y % tilesL;
  int c0 = tC << 5, l0 = tL << 5;
  __shared__ float s[32][33];
  int tx = threadIdx.x & 31, ty = threadIdx.x >> 5;
  const float* sp = src + (long)b * sb + (long)k * sk;
#pragma unroll
  for (int j = 0; j < 4; ++j) {
    int cc = c0 + ty + j * 8;
    s[ty + j * 8][tx] = sp[(long)cc * sc + (long)(l0 + tx) * sl];
  }
  __syncthreads();
  long dbase = (long)b * db + (long)k * dk;
#pragma unroll
  for (int j = 0; j < 4; ++j) {
    int ll = l0 + ty + j * 8;
    long off = dbase + (long)(c0 + tx) * dc + (long)ll * dl;
    float val = s[tx][ty + j * 8];
    if (add) val += add[off];
    dst[off] = val;
    if (dstBf) dstBf[off] = f2bf(val);
  }
}

// ---------------- spatial QKV: Q -> bf16, K/V -> fp32 ----------------
__global__ __launch_bounds__(256) void k_qkv_s(const float* __restrict__ in,
                                               const float* __restrict__ W0, const float* __restrict__ W1,
                                               const float* __restrict__ W2,
                                               unsigned short* __restrict__ qb,
                                               float* __restrict__ o1, float* __restrict__ o2) {
  int r0 = blockIdx.x * 64;
  __shared__ float sInT[64][68];
  __shared__ float sW[3][64][64];
  int t = threadIdx.x;
  for (int i = t; i < 4096; i += 256) {
    int c = i >> 6, o = i & 63;
    sW[0][c][o] = W0[i];
    sW[1][c][o] = W1[i];
    sW[2][c][o] = W2[i];
  }
  for (int i = t; i < 4096; i += 256) {
    int r = i >> 6, c = i & 63;
    sInT[c][r] = in[(size_t)(r0 + r) * 64 + c];
  }
  __syncthreads();
  int col = t & 63, rg = t >> 6;
  int rbase = rg * 16;
  float a0[16], a1[16], a2[16];
#pragma unroll
  for (int i = 0; i < 16; ++i) { a0[i] = 0.f; a1[i] = 0.f; a2[i] = 0.f; }
  for (int c = 0; c < 64; ++c) {
    float w0 = sW[0][c][col], w1 = sW[1][c][col], w2 = sW[2][c][col];
#pragma unroll
    for (int rr = 0; rr < 16; rr += 4) {
      float4 xv = *(const float4*)&sInT[c][rbase + rr];
      a0[rr + 0] += xv.x * w0; a0[rr + 1] += xv.y * w0; a0[rr + 2] += xv.z * w0; a0[rr + 3] += xv.w * w0;
      a1[rr + 0] += xv.x * w1; a1[rr + 1] += xv.y * w1; a1[rr + 2] += xv.z * w1; a1[rr + 3] += xv.w * w1;
      a2[rr + 0] += xv.x * w2; a2[rr + 1] += xv.y * w2; a2[rr + 2] += xv.z * w2; a2[rr + 3] += xv.w * w2;
    }
  }
#pragma unroll
  for (int rr = 0; rr < 16; ++rr) {
    size_t idx = (size_t)(r0 + rbase + rr) * 64 + col;
    qb[idx] = f2bf(a0[rr]); o1[idx] = a1[rr]; o2[idx] = a2[rr];
  }
}

// ---------------- temporal QKV: Q,K -> bf16 row-major; V -> bf16 TRANSPOSED [bk][c][l] ----------------
__global__ __launch_bounds__(256) void k_qkv_t(const float* __restrict__ in,
                                               const float* __restrict__ W0, const float* __restrict__ W1,
                                               const float* __restrict__ W2,
                                               const float* __restrict__ b0, const float* __restrict__ b1,
                                               const float* __restrict__ b2,
                                               unsigned short* __restrict__ qb,
                                               unsigned short* __restrict__ kb,
                                               unsigned short* __restrict__ vt) {
  int r0 = blockIdx.x * 64;
  __shared__ float sInT[64][68];
  __shared__ float sW[3][64][64];
  int t = threadIdx.x;
  for (int i = t; i < 4096; i += 256) {
    int c = i >> 6, o = i & 63;
    sW[0][c][o] = W0[i];
    sW[1][c][o] = W1[i];
    sW[2][c][o] = W2[i];
  }
  for (int i = t; i < 4096; i += 256) {
    int r = i >> 6, c = i & 63;
    sInT[c][r] = in[(size_t)(r0 + r) * 64 + c];
  }
  __syncthreads();
  int col = t & 63, rg = t >> 6;
  int rbase = rg * 16;
  float a0[16], a1[16], a2[16];
  float bv0 = b0[col], bv1 = b1[col], bv2 = b2[col];
#pragma unroll
  for (int i = 0; i < 16; ++i) { a0[i] = bv0; a1[i] = bv1; a2[i] = bv2; }
  for (int c = 0; c < 64; ++c) {
    float w0 = sW[0][c][col], w1 = sW[1][c][col], w2 = sW[2][c][col];
#pragma unroll
    for (int rr = 0; rr < 16; rr += 4) {
      float4 xv = *(const float4*)&sInT[c][rbase + rr];
      a0[rr + 0] += xv.x * w0; a0[rr + 1] += xv.y * w0; a0[rr + 2] += xv.z * w0; a0[rr + 3] += xv.w * w0;
      a1[rr + 0] += xv.x * w1; a1[rr + 1] += xv.y * w1; a1[rr + 2] += xv.z * w1; a1[rr + 3] += xv.w * w1;
      a2[rr + 0] += xv.x * w2; a2[rr + 1] += xv.y * w2; a2[rr + 2] += xv.z * w2; a2[rr + 3] += xv.w * w2;
    }
  }
#pragma unroll
  for (int rr = 0; rr < 16; ++rr) {
    size_t idx = (size_t)(r0 + rbase + rr) * 64 + col;
    qb[idx] = f2bf(a0[rr]); kb[idx] = f2bf(a1[rr]);
  }
  int bk = r0 >> 7;
  int lbase = (r0 & 127) + rbase;
  unsigned short* vd = vt + (size_t)bk * 8192 + (size_t)col * 128 + lbase;
#pragma unroll
  for (int rr = 0; rr < 16; ++rr) vd[rr] = f2bf(a2[rr]);
}

// ---------------- row-major (R,CIN) @ (CIN,COUT) + bias, optional activation ----------------
template <int CIN, int COUT, int ACT, int ROWS>
__global__ __launch_bounds__(256) void k_rowmm(const float* __restrict__ in,
                                               const float* __restrict__ W,
                                               const float* __restrict__ bias,
                                               float* __restrict__ out) {
  int r0 = blockIdx.x * ROWS;
  __shared__ float sInT[CIN][ROWS + 4];
  __shared__ float sW[CIN][COUT];
  int t = threadIdx.x;
  for (int i = t; i < CIN * COUT; i += 256) ((float*)sW)[i] = W[i];
  for (int i = t; i < ROWS * CIN; i += 256) {
    int r = i / CIN, c = i % CIN;
    sInT[c][r] = in[(size_t)r0 * CIN + i];
  }
  __syncthreads();
  constexpr int NRG = 256 / COUT;
  constexpr int RPT = ROWS / NRG;
  int col = t % COUT, rg = t / COUT;
  int rbase = rg * RPT;
  float acc[RPT];
  float bv = bias ? bias[col] : 0.f;
#pragma unroll
  for (int r = 0; r < RPT; ++r) acc[r] = bv;
  for (int c = 0; c < CIN; ++c) {
    float wv = sW[c][col];
#pragma unroll
    for (int rr = 0; rr < RPT; rr += 4) {
      float4 xv = *(const float4*)&sInT[c][rbase + rr];
      acc[rr] += xv.x * wv; acc[rr + 1] += xv.y * wv;
      acc[rr + 2] += xv.z * wv; acc[rr + 3] += xv.w * wv;
    }
  }
#pragma unroll
  for (int rr = 0; rr < RPT; ++rr) {
    float v = acc[rr];
    if (ACT == 1) v = fmaxf(v, 0.f);
    out[(size_t)(r0 + rbase + rr) * COUT + col] = v;
  }
}

// ---------------- fused LN1 -> FFN(64->8 gelu ->64) -> LN2, row-local; block = 64 rows ----------------
__global__ __launch_bounds__(256) void k_tffn(const float* __restrict__ A, const float* __restrict__ Bz,
                                              const float* __restrict__ l1w, const float* __restrict__ l1b,
                                              const float* __restrict__ l2w, const float* __restrict__ l2b,
                                              const float* __restrict__ ln1g, const float* __restrict__ ln1b,
                                              const float* __restrict__ ln2g, const float* __restrict__ ln2b,
                                              float* __restrict__ outp) {
  int r0 = blockIdx.x * 64;
  __shared__ float sSrc[64][65];
  __shared__ float sH[64][8];
  __shared__ float sW1[64][8];
  __shared__ float sW2[8][64];
  int t = threadIdx.x;
  for (int i = t; i < 512; i += 256) { ((float*)sW1)[i] = l1w[i]; ((float*)sW2)[i] = l2w[i]; }
  int c = t & 63, rg = t >> 6;
  float g1 = ln1g[c], be1 = ln1b[c];
  for (int it = 0; it < 16; ++it) {
    int r = it * 4 + rg;
    size_t idx = (size_t)(r0 + r) * 64 + c;
    float x = A[idx] + Bz[idx];
    float s = x, ss = x * x;
#pragma unroll
    for (int off = 32; off; off >>= 1) { s += __shfl_xor(s, off); ss += __shfl_xor(ss, off); }
    float mu = s * (1.f / 64.f);
    float var = ss * (1.f / 64.f) - mu * mu;
    sSrc[r][c] = (x - mu) * rsqrtf(var + EPSV) * g1 + be1;
  }
  __syncthreads();
#pragma unroll
  for (int p = 0; p < 2; ++p) {
    int idx = t + 256 * p;
    int row = idx >> 3, j = idx & 7;
    float acc = l1b[j];
    for (int cc = 0; cc < 64; ++cc) acc += sSrc[row][cc] * sW1[cc][j];
    acc = 0.5f * acc * (1.f + erff(acc * 0.70710678118654752440f));
    sH[row][j] = acc;
  }
  __syncthreads();
  float g2 = ln2g[c], be2 = ln2b[c];
  float l2bc = l2b[c];
  for (int it = 0; it < 16; ++it) {
    int r = it * 4 + rg;
    float o = l2bc;
#pragma unroll
    for (int j = 0; j < 8; ++j) o += sH[r][j] * sW2[j][c];
    float x = sSrc[r][c] + o;
    float s = x, ss = x * x;
#pragma unroll
    for (int off = 32; off; off >>= 1) { s += __shfl_xor(s, off); ss += __shfl_xor(ss, off); }
    float mu = s * (1.f / 64.f);
    float var = ss * (1.f / 64.f) - mu * mu;
    outp[(size_t)(r0 + r) * 64 + c] = (x - mu) * rsqrtf(var + EPSV) * g2 + be2;
  }
}

// ---------------- sproj dual: y==0: K path (X0@P0 -> RM bf16); y==1: V path (X1@P1 -> T bf16) ----------------
__global__ __launch_bounds__(256) void k_sproj2(const float* __restrict__ X0, const float* __restrict__ X1,
                                                const float* __restrict__ P0, const float* __restrict__ P1,
                                                unsigned short* __restrict__ outRM,
                                                unsigned short* __restrict__ outT) {
  int bl = blockIdx.x;
  int which = blockIdx.y;
  const float* X = which ? X1 : X0;
  const float* P = which ? P1 : P0;
  const float* src = X + (size_t)bl * KK * CC;
  int t = threadIdx.x, c = t & 63, pg = t >> 6;
  __shared__ float sX[64][CC];
  __shared__ float sP[64][PR];
  float acc[16];
#pragma unroll
  for (int i = 0; i < 16; ++i) acc[i] = 0.f;
  for (int n0 = 0; n0 < KK; n0 += 64) {
    for (int i = t; i < 64 * CC; i += 256) ((float*)sX)[i] = src[(size_t)n0 * CC + i];
    for (int i = t; i < 64 * PR; i += 256) ((float*)sP)[i] = P[(size_t)n0 * PR + i];
    __syncthreads();
    for (int n = 0; n < 64; ++n) {
      float xv = sX[n][c];
#pragma unroll
      for (int q = 0; q < 4; ++q) {
        float4 pv = *(const float4*)&sP[n][pg * 16 + q * 4];
        acc[q * 4 + 0] += pv.x * xv; acc[q * 4 + 1] += pv.y * xv;
        acc[q * 4 + 2] += pv.z * xv; acc[q * 4 + 3] += pv.w * xv;
      }
    }
    __syncthreads();
  }
  if (!which) {
    unsigned short* d = outRM + (size_t)bl * PR * CC;
#pragma unroll
    for (int i = 0; i < 16; ++i) d[(size_t)(pg * 16 + i) * CC + c] = f2bf(acc[i]);
  } else {
    unsigned short* d = outT + (size_t)bl * PR * CC + (size_t)c * PR + pg * 16;
#pragma unroll
    for (int i = 0; i < 16; ++i) d[i] = f2bf(acc[i]);
  }
}

// ---------------- per-head MFMA attention: block = 128 q-rows, 8 waves = 8 heads ----------------
template <int NKV, int KVSHIFT>
__global__ __launch_bounds__(512) void k_attnH(const unsigned short* __restrict__ Qb,
                                               const unsigned short* __restrict__ Kb,
                                               const unsigned short* __restrict__ VTb,
                                               float* __restrict__ O) {
  constexpr int NCT = NKV / 16;
  constexpr int NKS = NKV / 32;
  int blk = blockIdx.x;
  const unsigned short* Qp = Qb + (size_t)blk * 128 * 64;
  float* Op = O + (size_t)blk * 128 * 64;
  const unsigned short* Kp = Kb + (size_t)(blk >> KVSHIFT) * NKV * 64;
  const unsigned short* VTp = VTb + (size_t)(blk >> KVSHIFT) * 64 * NKV;
  int t = threadIdx.x;
  int h = t >> 6, lane = t & 63, lr = lane & 15, g = lane >> 4;
  __shared__ unsigned short sP[8][16 * NKV];
  unsigned short* myP = sP[h];

  short8 kbf[NCT];
#pragma unroll
  for (int ct = 0; ct < NCT; ++ct)
    kbf[ct] = *(const short8*)(Kp + (size_t)(ct * 16 + lr) * 64 + h * 8);

  int vr = h * 8 + lr; if (vr > 63) vr = 63;
  short8 vbf[NKS];
#pragma unroll
  for (int ks = 0; ks < NKS; ++ks)
    vbf[ks] = *(const short8*)(VTp + (size_t)vr * NKV + ks * 32 + g * 8);

  for (int mt = 0; mt < 8; ++mt) {
    short8 qa = short8{0, 0, 0, 0, 0, 0, 0, 0};
    if (g == 0) qa = *(const short8*)(Qp + (size_t)(mt * 16 + lr) * 64 + h * 8);

    f32x4 sacc[NCT];
#pragma unroll
    for (int ct = 0; ct < NCT; ++ct) sacc[ct] = f32x4{0.f, 0.f, 0.f, 0.f};
#pragma unroll
    for (int ct = 0; ct < NCT; ++ct)
      sacc[ct] = __builtin_amdgcn_mfma_f32_16x16x32_bf16(qa, kbf[ct], sacc[ct], 0, 0, 0);

    float inv4[4];
#pragma unroll
    for (int reg = 0; reg < 4; ++reg) {
      float s = 0.f;
#pragma unroll
      for (int ct = 0; ct < NCT; ++ct) {
        float e = __expf(sacc[ct][reg] * SCL);
        sacc[ct][reg] = e;
        s += e;
      }
      s += __shfl_xor(s, 1); s += __shfl_xor(s, 2); s += __shfl_xor(s, 4); s += __shfl_xor(s, 8);
      inv4[reg] = 1.f / s;
    }

#pragma unroll
    for (int ct = 0; ct < NCT; ++ct)
#pragma unroll
      for (int reg = 0; reg < 4; ++reg) {
        int row = g * 4 + reg;
        int bo = ((row * NKV + ct * 16 + lr) * 2) ^ ((row & 7) << 4);
        *(unsigned short*)((char*)myP + bo) = f2bf(sacc[ct][reg]);
      }
    __syncthreads();

    f32x4 oacc = f32x4{0.f, 0.f, 0.f, 0.f};
#pragma unroll
    for (int ks = 0; ks < NKS; ++ks) {
      int bo = ((lr * NKV + ks * 32 + g * 8) * 2) ^ ((lr & 7) << 4);
      short8 pa = *(const short8*)((char*)myP + bo);
      oacc = __builtin_amdgcn_mfma_f32_16x16x32_bf16(pa, vbf[ks], oacc, 0, 0, 0);
    }
    if (lr < 8) {
#pragma unroll
      for (int reg = 0; reg < 4; ++reg) {
        int row = mt * 16 + g * 4 + reg;
        Op[(size_t)row * 64 + h * 8 + lr] = oacc[reg] * inv4[reg];
      }
    }
    __syncthreads();
  }
}

// ---------------- LayerNorm over C=64 per row, input = A (+ optional Bp) ----------------
__global__ __launch_bounds__(256) void k_ln(const float* __restrict__ A, const float* __restrict__ Bp,
                                            const float* __restrict__ g, const float* __restrict__ be,
                                            float* __restrict__ out) {
  int row = blockIdx.x * 4 + (threadIdx.x >> 6);
  int c = threadIdx.x & 63;
  size_t idx = (size_t)row * CC + c;
  float x = A[idx] + (Bp ? Bp[idx] : 0.f);
  float s = x, ss = x * x;
#pragma unroll
  for (int off = 32; off; off >>= 1) { s += __shfl_xor(s, off); ss += __shfl_xor(ss, off); }
  float mu = s * (1.f / 64.f);
  float var = ss * (1.f / 64.f) - mu * mu;
  out[idx] = (x - mu) * rsqrtf(var + EPSV) * g[c] + be[c];
}

// ---------------- GroupNorm stats: up to 5 summed inputs, optional sum write-back ----------------
__global__ __launch_bounds__(256) void k_gn_part(const float* __restrict__ p0, const float* __restrict__ p1,
                                                 const float* __restrict__ p2, const float* __restrict__ p3,
                                                 const float* __restrict__ p4,
                                                 float* __restrict__ sumOut,
                                                 float* __restrict__ part) {
  int bg = blockIdx.y, blk = blockIdx.x, t = threadIdx.x;
  size_t start = (size_t)bg * ((size_t)CPG * NN) + (size_t)blk * 8192;
  const float4* q0 = (const float4*)(p0 + start);
  const float4* q1 = p1 ? (const float4*)(p1 + start) : nullptr;
  const float4* q2 = p2 ? (const float4*)(p2 + start) : nullptr;
  const float4* q3 = p3 ? (const float4*)(p3 + start) : nullptr;
  const float4* q4 = p4 ? (const float4*)(p4 + start) : nullptr;
  float4* so = sumOut ? (float4*)(sumOut + start) : nullptr;
  float s = 0.f, ss = 0.f;
  for (int i = t; i < 2048; i += 256) {
    float4 x = q0[i];
    if (q1) { float4 y4 = q1[i]; x.x += y4.x; x.y += y4.y; x.z += y4.z; x.w += y4.w; }
    if (q2) { float4 y4 = q2[i]; x.x += y4.x; x.y += y4.y; x.z += y4.z; x.w += y4.w; }
    if (q3) { float4 y4 = q3[i]; x.x += y4.x; x.y += y4.y; x.z += y4.z; x.w += y4.w; }
    if (q4) { float4 y4 = q4[i]; x.x += y4.x; x.y += y4.y; x.z += y4.z; x.w += y4.w; }
    if (so) so[i] = x;
    s += x.x + x.y + x.z + x.w;
    ss += x.x * x.x + x.y * x.y + x.z * x.z + x.w * x.w;
  }
  __shared__ float rs[256], rq[256];
  rs[t] = s; rq[t] = ss; __syncthreads();
  for (int off = 128; off; off >>= 1) { if (t < off) { rs[t] += rs[t + off]; rq[t] += rq[t + off]; } __syncthreads(); }
  if (t == 0) { part[(bg * 64 + blk) * 2] = rs[0]; part[(bg * 64 + blk) * 2 + 1] = rq[0]; }
}

// out = GN(p0[+p1]) (+ q0) (+ q1) — reduces 64 partials per block (gn_final folded in)
__global__ __launch_bounds__(256) void k_gn_apply(const float* __restrict__ p0, const float* __restrict__ p1,
                                                  const float* __restrict__ part, const float* __restrict__ g,
                                                  const float* __restrict__ be,
                                                  const float* __restrict__ q0, const float* __restrict__ q1,
                                                  float* __restrict__ out) {
  size_t i4 = (size_t)blockIdx.x * 256 + threadIdx.x;
  size_t i = i4 * 4;
  int chan = (int)(i >> 15) & 63;
  int bg = (int)(i >> 19);
  __shared__ float smu, srr;
  int t = threadIdx.x;
  if (t < 64) {
    float s = part[(bg * 64 + t) * 2], ss = part[(bg * 64 + t) * 2 + 1];
#pragma unroll
    for (int off = 32; off; off >>= 1) { s += __shfl_xor(s, off); ss += __shfl_xor(ss, off); }
    if (t == 0) {
      float inv = 1.f / (float)((size_t)CPG * NN);
      float mu = s * inv;
      float var = ss * inv - mu * mu;
      smu = mu; srr = rsqrtf(var + EPSV);
    }
  }
  __syncthreads();
  float mu = smu, rr = srr;
  float4 x = ((const float4*)p0)[i4];
  if (p1) { float4 y4 = ((const float4*)p1)[i4]; x.x += y4.x; x.y += y4.y; x.z += y4.z; x.w += y4.w; }
  float gc = g[chan], bc = be[chan];
  float4 v;
  v.x = (x.x - mu) * rr * gc + bc;
  v.y = (x.y - mu) * rr * gc + bc;
  v.z = (x.z - mu) * rr * gc + bc;
  v.w = (x.w - mu) * rr * gc + bc;
  if (q0) { float4 y4 = ((const float4*)q0)[i4]; v.x += y4.x; v.y += y4.y; v.z += y4.z; v.w += y4.w; }
  if (q1) { float4 y4 = ((const float4*)q1)[i4]; v.x += y4.x; v.y += y4.y; v.z += y4.z; v.w += y4.w; }
  ((float4*)out)[i4] = v;
}

extern "C" void kernel_launch(void* const* d_in, const int* in_sizes, int n_in,
                              void* d_out, int out_size, void* d_ws, size_t ws_size,
                              hipStream_t stream) {
  (void)in_sizes; (void)n_in; (void)out_size; (void)ws_size;
  const float* y     = (const float*)d_in[0];
  const float* a1    = (const float*)d_in[1];
  const float* a2    = (const float*)d_in[2];
  const float* nv1   = (const float*)d_in[3];
  const float* nv2   = (const float*)d_in[4];
  const float* gcn_w = (const float*)d_in[5];
  const float* gcn_b = (const float*)d_in[6];
  const float* s_wq  = (const float*)d_in[7];
  const float* s_wk  = (const float*)d_in[8];
  const float* s_wv  = (const float*)d_in[9];
  const float* s_pk  = (const float*)d_in[10];
  const float* s_pv  = (const float*)d_in[11];
  const float* s_wo  = (const float*)d_in[12];
  const float* s_bo  = (const float*)d_in[13];
  const float* t_wq  = (const float*)d_in[14];
  const float* t_wk  = (const float*)d_in[15];
  const float* t_wv  = (const float*)d_in[16];
  const float* t_bq  = (const float*)d_in[17];
  const float* t_bk  = (const float*)d_in[18];
  const float* t_bv  = (const float*)d_in[19];
  const float* t_wo  = (const float*)d_in[20];
  const float* t_bo  = (const float*)d_in[21];
  const float* t_l1w = (const float*)d_in[22];
  const float* t_l1b = (const float*)d_in[23];
  const float* t_l2w = (const float*)d_in[24];
  const float* t_l2b = (const float*)d_in[25];
  const float* ln1g  = (const float*)d_in[26];
  const float* ln1b  = (const float*)d_in[27];
  const float* ln2g  = (const float*)d_in[28];
  const float* ln2b  = (const float*)d_in[29];
  const float* gnlg  = (const float*)d_in[30];
  const float* gnlb  = (const float*)d_in[31];
  const float* gnsg  = (const float*)d_in[32];
  const float* gnsb  = (const float*)d_in[33];
  const float* gntg  = (const float*)d_in[34];
  const float* gntb  = (const float*)d_in[35];
  const float* ff1w  = (const float*)d_in[36];
  const float* ff1b  = (const float*)d_in[37];
  const float* ff2w  = (const float*)d_in[38];
  const float* ff2b  = (const float*)d_in[39];
  const float* gn2g  = (const float*)d_in[40];
  const float* gn2b  = (const float*)d_in[41];

  float* ws = (float*)d_ws;
  float* adp   = ws;
  float* part  = ws + 65536;
  unsigned short* a1_bf   = (unsigned short*)(ws + 131072);
  unsigned short* a2_bf   = (unsigned short*)(ws + 163840);
  unsigned short* adp_bf  = (unsigned short*)(ws + 196608);
  unsigned short* gcnw_bf = (unsigned short*)(ws + 229376);
  unsigned short* xs_bf   = (unsigned short*)(ws + 262144);
  float* kp2 = ws + 131072;                 // reused post-GCN
  float* vp2 = ws + 131072 + 1048576;
  unsigned short* kpb  = (unsigned short*)kp2;
  unsigned short* vptb = (unsigned short*)vp2;
  const size_t SLOT = 4194304;
  float* G0 = ws + SLOT * 1;
  float* G1 = ws + SLOT * 2;
  float* G2 = ws + SLOT * 3;
  float* G3 = ws + SLOT * 4;
  float* G4 = ws + SLOT * 5;
  float* G5 = ws + SLOT * 6;
  float* G6 = ws + SLOT * 7;
  unsigned short* U1 = (unsigned short*)G3;
  unsigned short* U2 = (unsigned short*)G3 + 4194304;
  unsigned short* U3 = (unsigned short*)G4;
  unsigned short* U4 = (unsigned short*)G4 + 4194304;
  unsigned short* U5 = (unsigned short*)G5;
  unsigned short* U6 = (unsigned short*)G5 + 4194304;
  unsigned short* PT = (unsigned short*)G6;
  float* out = (float*)d_out;

  const long BS = 2097152;

  // ---- adaptive adjacency + bf16 casts ----
  k_adp<<<256, 256, 0, stream>>>(nv1, nv2, adp);
  k_cast3<<<640, 256, 0, stream>>>(a1, a2, gcn_w, a1_bf, a2_bf, gcnw_bf);
  k_cast<<<256, 256, 0, stream>>>(adp, adp_bf);

  // ---- xs (B,L,K,C) fp32 + bf16 ----
  k_tr<<<dim3(512, 8), 256, 0, stream>>>(y, G2, nullptr, xs_bf, BS, 128, 32768, 1, BS, 64, 1, 16384, 64, 128);

  // ---- AdaptiveGCN ----
  k_mix0<<<1024, 64, 0, stream>>>(xs_bf, gcnw_bf, gcn_b, G1);
  k_mix6<<<dim3(1024, 3), 64, 0, stream>>>(xs_bf, gcnw_bf, U1, U2, U3, U4, U5, U6);
  k_adjM<<<512, 256, 0, stream>>>(a1_bf, U2, nullptr, PT, U1);
  k_adjM<<<512, 256, 0, stream>>>(a1_bf, PT, G0, nullptr, nullptr);   // Q1
  k_adjM<<<512, 256, 0, stream>>>(a2_bf, U4, nullptr, PT, U3);
  k_adjM<<<512, 256, 0, stream>>>(a2_bf, PT, G4, nullptr, nullptr);   // Q2
  k_adjM<<<512, 256, 0, stream>>>(adp_bf, U6, nullptr, PT, U5);
  k_adjM<<<512, 256, 0, stream>>>(adp_bf, PT, G5, nullptr, nullptr);  // Q3
  k_gn_part<<<dim3(64, 8), 256, 0, stream>>>(y, G1, G0, G4, G5, G3, part);
  k_gn_apply<<<4096, 256, 0, stream>>>(G3, nullptr, part, gnlg, gnlb, nullptr, nullptr, G0);

  // ---- Linformer spatial attention (G2 = xs) ----
  k_qkv_s<<<1024, 256, 0, stream>>>(G2, s_wq, s_wk, s_wv, (unsigned short*)G3, G4, G5);
  k_sproj2<<<dim3(256, 2), 256, 0, stream>>>(G4, G5, s_pk, s_pv, kpb, vptb);
  k_attnH<64, 1><<<512, 512, 0, stream>>>((unsigned short*)G3, kpb, vptb, G6);
  k_rowmm<64, 64, 0, 64><<<1024, 256, 0, stream>>>(G6, s_wo, s_bo, G4);
  k_tr<<<dim3(512, 8), 256, 0, stream>>>(G4, G1, nullptr, nullptr, BS, 64, 16384, 1, BS, 128, 1, 32768, 128, 64);
  k_gn_part<<<dim3(64, 8), 256, 0, stream>>>(y, G1, nullptr, nullptr, nullptr, G2, part);
  k_gn_apply<<<4096, 256, 0, stream>>>(G2, nullptr, part, gnsg, gnsb, nullptr, nullptr, G1);

  // ---- temporal transformer layer ----
  k_tr<<<dim3(512, 8), 256, 0, stream>>>(y, G2, nullptr, nullptr, BS, 128, 32768, 1, BS, 8192, 1, 64, 64, 128);
  k_qkv_t<<<1024, 256, 0, stream>>>(G2, t_wq, t_wk, t_wv, t_bq, t_bk, t_bv,
                                    (unsigned short*)G3, (unsigned short*)G4, (unsigned short*)G5);
  k_attnH<128, 0><<<512, 512, 0, stream>>>((unsigned short*)G3, (unsigned short*)G4, (unsigned short*)G5, G6);
  k_rowmm<64, 64, 0, 64><<<1024, 256, 0, stream>>>(G6, t_wo, t_bo, G3);
  k_tffn<<<1024, 256, 0, stream>>>(G2, G3, t_l1w, t_l1b, t_l2w, t_l2b,
                                   ln1g, ln1b, ln2g, ln2b, G6);
  k_tr<<<dim3(512, 8), 256, 0, stream>>>(G6, G2, nullptr, nullptr, BS, 8192, 64, 1, BS, 128, 1, 32768, 128, 64);
  k_gn_part<<<dim3(64, 8), 256, 0, stream>>>(y, G2, nullptr, nullptr, nullptr, G5, part);
  k_gn_apply<<<4096, 256, 0, stream>>>(G5, nullptr, part, gntg, gntb, G0, G1, G3);

  // ---- fuse + channel FFN + final GroupNorm ----
  k_tr<<<dim3(512, 8), 256, 0, stream>>>(G3, G4, nullptr, nullptr, BS, 128, 32768, 1, BS, 8192, 1, 64, 64, 128);
  k_rowmm<64, 128, 1, 64><<<1024, 256, 0, stream>>>(G4, ff1w, ff1b, G5);
  k_rowmm<128, 64, 0, 32><<<2048, 256, 0, stream>>>(G5, ff2w, ff2b, G4);
  k_tr<<<dim3(512, 8), 256, 0, stream>>>(G4, out, G3, nullptr, BS, 8192, 64, 1, BS, 128, 1, 32768, 128, 64);
  k_gn_part<<<dim3(64, 8), 256, 0, stream>>>(out, nullptr, nullptr, nullptr, nullptr, nullptr, part);
  k_gn_apply<<<4096, 256, 0, stream>>>(out, nullptr, part, gn2g, gn2b, nullptr, nullptr, out);
}

// Round 14
// 516.071 us; speedup vs baseline: 1.2579x; 1.0408x over previous
//
#include <hip/hip_runtime.h>
#include <math.h>

constexpr int CC = 64, KK = 256, LL = 128;
constexpr int NN = KK * LL;          // 32768
constexpr int PR = 64;               // Linformer projection
constexpr int CPG = 16;              // channels per group (C / 4)
constexpr float EPSV = 1e-5f;
constexpr float SCL = 0.35355339059327373f;  // 1/sqrt(8)

typedef __attribute__((ext_vector_type(8))) short short8;      // 8 bf16 (4 VGPR)
typedef __attribute__((ext_vector_type(4))) float f32x4;       // MFMA 16x16 acc

__device__ __forceinline__ unsigned short f2bf(float x) {
  union { float f; unsigned int u; } v; v.f = x;
  unsigned int r = (v.u + 0x7FFFu + ((v.u >> 16) & 1u)) >> 16;
  return (unsigned short)r;
}
__device__ __forceinline__ float bf2f(unsigned short x) {
  union { unsigned int u; float f; } v; v.u = ((unsigned int)x) << 16;
  return v.f;
}

// ---------------- adaptive adjacency: softmax(relu(nv1@nv2), axis=1) ----------------
__global__ __launch_bounds__(256) void k_adp(const float* __restrict__ nv1,
                                             const float* __restrict__ nv2,
                                             float* __restrict__ adp) {
  int w = blockIdx.x, v = threadIdx.x;
  float s = 0.f;
  for (int d = 0; d < 10; ++d) s += nv1[w * 10 + d] * nv2[d * KK + v];
  s = fmaxf(s, 0.f);
  __shared__ float red[256];
  red[v] = s; __syncthreads();
  for (int off = 128; off; off >>= 1) { if (v < off) red[v] = fmaxf(red[v], red[v + off]); __syncthreads(); }
  float m = red[0]; __syncthreads();
  float e = expf(s - m);
  red[v] = e; __syncthreads();
  for (int off = 128; off; off >>= 1) { if (v < off) red[v] += red[v + off]; __syncthreads(); }
  adp[w * KK + v] = e / red[0];
}

// ---------------- fp32 -> bf16 cast (single range) ----------------
__global__ __launch_bounds__(256) void k_cast(const float* __restrict__ src,
                                              unsigned short* __restrict__ dst) {
  int i = blockIdx.x * 256 + threadIdx.x;
  dst[i] = f2bf(src[i]);
}

// ---------------- fused cast of a1 + a2 + gcn_w ----------------
__global__ __launch_bounds__(256) void k_cast3(const float* __restrict__ s0, const float* __restrict__ s1,
                                               const float* __restrict__ s2,
                                               unsigned short* __restrict__ d0, unsigned short* __restrict__ d1,
                                               unsigned short* __restrict__ d2) {
  int i = blockIdx.x * 256 + threadIdx.x;
  if (i < 65536) d0[i] = f2bf(s0[i]);
  else if (i < 131072) d1[i - 65536] = f2bf(s1[i - 65536]);
  else if (i < 159744) d2[i - 131072] = f2bf(s2[i - 131072]);
}

// ---------------- transpose-cast P (256 x 64) -> PT bf16 (64 x 256); grid (16, 2) ----------------
__global__ __launch_bounds__(256) void k_castP(const float* __restrict__ P0, const float* __restrict__ P1,
                                               unsigned short* __restrict__ T0, unsigned short* __restrict__ T1) {
  const float* P = blockIdx.y ? P1 : P0;
  unsigned short* T = blockIdx.y ? T1 : T0;
  int tv = blockIdx.x >> 1, tc = blockIdx.x & 1;   // n-tile (8), c-tile (2)
  int n0 = tv * 32, c0 = tc * 32;
  __shared__ float s[32][33];
  int tx = threadIdx.x & 31, ty = threadIdx.x >> 5;
#pragma unroll
  for (int j = 0; j < 4; ++j)
    s[ty + j * 8][tx] = P[(size_t)(n0 + ty + j * 8) * 64 + c0 + tx];
  __syncthreads();
#pragma unroll
  for (int j = 0; j < 4; ++j)
    T[(size_t)(c0 + ty + j * 8) * 256 + n0 + tx] = f2bf(s[tx][ty + j * 8]);
}

// ---------------- s0 term: s0[b,o,k,l] = bias[o] + sum_c W0[o][c]*xs[(b,l,k)][c] ----------------
__global__ __launch_bounds__(64) void k_mix0(const unsigned short* __restrict__ Xbf,
                                             const unsigned short* __restrict__ Wbf,
                                             const float* __restrict__ bias,
                                             float* __restrict__ s0) {
  int pb = blockIdx.x;
  int lh = pb & 1;
  int k = (pb >> 1) & 255;
  int b = pb >> 9;
  int lane = threadIdx.x;
  int lr = lane & 15, g = lane >> 4;
  short8 af[4][2], bfv[4][2];
#pragma unroll
  for (int ot = 0; ot < 4; ++ot)
#pragma unroll
    for (int kc = 0; kc < 2; ++kc)
      af[ot][kc] = *(const short8*)(Wbf + (size_t)(ot * 16 + lr) * 448 + kc * 32 + g * 8);
#pragma unroll
  for (int ct = 0; ct < 4; ++ct)
#pragma unroll
    for (int kc = 0; kc < 2; ++kc)
      bfv[ct][kc] = *(const short8*)(Xbf + ((size_t)(b * 128 + lh * 64 + ct * 16 + lr) * 256 + k) * 64 + kc * 32 + g * 8);
  f32x4 acc[4][4];
#pragma unroll
  for (int ot = 0; ot < 4; ++ot)
#pragma unroll
    for (int ct = 0; ct < 4; ++ct) acc[ot][ct] = f32x4{0.f, 0.f, 0.f, 0.f};
#pragma unroll
  for (int kc = 0; kc < 2; ++kc)
#pragma unroll
    for (int ot = 0; ot < 4; ++ot)
#pragma unroll
      for (int ct = 0; ct < 4; ++ct)
        acc[ot][ct] = __builtin_amdgcn_mfma_f32_16x16x32_bf16(af[ot][kc], bfv[ct][kc], acc[ot][ct], 0, 0, 0);
#pragma unroll
  for (int ot = 0; ot < 4; ++ot)
#pragma unroll
    for (int ct = 0; ct < 4; ++ct) {
#pragma unroll
      for (int reg = 0; reg < 4; ++reg) {
        int o = ot * 16 + g * 4 + reg;
        s0[(size_t)(b * 64 + o) * NN + (size_t)k * 128 + lh * 64 + ct * 16 + lr] = acc[ot][ct][reg] + bias[o];
      }
    }
}

// ---------------- U terms: U_s[(b*64+o)][l][k] bf16; blockIdx.y picks s-pair ----------------
__global__ __launch_bounds__(64) void k_mix6(const unsigned short* __restrict__ Xbf,
                                             const unsigned short* __restrict__ Wbf,
                                             unsigned short* __restrict__ U1, unsigned short* __restrict__ U2,
                                             unsigned short* __restrict__ U3, unsigned short* __restrict__ U4,
                                             unsigned short* __restrict__ U5, unsigned short* __restrict__ U6) {
  unsigned short* Us[6] = {U1, U2, U3, U4, U5, U6};
  int pb = blockIdx.x;
  int sy = blockIdx.y;
  int b = pb >> 9;
  int rem = pb & 511;
  int l = rem >> 2;
  int kq = (rem & 3) * 64;
  size_t posbase = ((size_t)(b * 128 + l)) * 256 + kq;
  int lane = threadIdx.x;
  int lr = lane & 15, g = lane >> 4;

  short8 af[4][2];
#pragma unroll
  for (int rt = 0; rt < 4; ++rt)
#pragma unroll
    for (int kc = 0; kc < 2; ++kc)
      af[rt][kc] = *(const short8*)(Xbf + (posbase + rt * 16 + lr) * 64 + kc * 32 + g * 8);

  for (int si = 0; si < 2; ++si) {
    int s = sy * 2 + 1 + si;
    short8 bfv[4][2];
#pragma unroll
    for (int ct = 0; ct < 4; ++ct)
#pragma unroll
      for (int kc = 0; kc < 2; ++kc)
        bfv[ct][kc] = *(const short8*)(Wbf + (size_t)(ct * 16 + lr) * 448 + s * 64 + kc * 32 + g * 8);
    f32x4 acc[4][4];
#pragma unroll
    for (int rt = 0; rt < 4; ++rt)
#pragma unroll
      for (int ct = 0; ct < 4; ++ct) acc[rt][ct] = f32x4{0.f, 0.f, 0.f, 0.f};
#pragma unroll
    for (int kc = 0; kc < 2; ++kc)
#pragma unroll
      for (int rt = 0; rt < 4; ++rt)
#pragma unroll
        for (int ct = 0; ct < 4; ++ct)
          acc[rt][ct] = __builtin_amdgcn_mfma_f32_16x16x32_bf16(af[rt][kc], bfv[ct][kc], acc[rt][ct], 0, 0, 0);
    unsigned short* dst = Us[s - 1];
#pragma unroll
    for (int rt = 0; rt < 4; ++rt)
#pragma unroll
      for (int ct = 0; ct < 4; ++ct) {
        int o = ct * 16 + lr;
        int k = kq + rt * 16 + g * 4;
        ushort4 pk;
        pk.x = f2bf(acc[rt][ct][0]); pk.y = f2bf(acc[rt][ct][1]);
        pk.z = f2bf(acc[rt][ct][2]); pk.w = f2bf(acc[rt][ct][3]);
        *(ushort4*)&dst[((size_t)(b * 64 + o) * 128 + l) * 256 + k] = pk;
      }
  }
}

// ---------------- out[bc, w, l] = sum_v A[w,v] * XT[bc, l, v]  (bf16 MFMA 16x16x32) ----------------
__global__ __launch_bounds__(256) void k_adjM(const unsigned short* __restrict__ Abf,
                                              const unsigned short* __restrict__ XT,
                                              float* __restrict__ out,
                                              unsigned short* __restrict__ outT,
                                              const unsigned short* __restrict__ addT) {
  int lq = blockIdx.x & 3, bc = blockIdx.x >> 2;
  int tid = threadIdx.x, wid = tid >> 6, lane = tid & 63;
  int lr = lane & 15, g = lane >> 4;
  int wbase = wid * 64;
  const unsigned short* aP = Abf + (size_t)(wbase + lr) * 256 + g * 8;
  const unsigned short* bP = XT + ((size_t)bc * 128 + lq * 32 + lr) * 256 + g * 8;
  f32x4 acc[4][2];
#pragma unroll
  for (int i = 0; i < 4; ++i)
#pragma unroll
    for (int j = 0; j < 2; ++j) acc[i][j] = f32x4{0.f, 0.f, 0.f, 0.f};
  for (int k0 = 0; k0 < 256; k0 += 32) {
    short8 af[4], bfv[2];
#pragma unroll
    for (int i = 0; i < 4; ++i) af[i] = *(const short8*)(aP + (size_t)i * 16 * 256 + k0);
#pragma unroll
    for (int i = 0; i < 2; ++i) bfv[i] = *(const short8*)(bP + (size_t)i * 16 * 256 + k0);
#pragma unroll
    for (int rm = 0; rm < 4; ++rm)
#pragma unroll
      for (int cn = 0; cn < 2; ++cn)
        acc[rm][cn] = __builtin_amdgcn_mfma_f32_16x16x32_bf16(af[rm], bfv[cn], acc[rm][cn], 0, 0, 0);
  }
  if (out) {
    float* dst = out + (size_t)bc * NN + lq * 32;
#pragma unroll
    for (int rm = 0; rm < 4; ++rm)
#pragma unroll
      for (int cn = 0; cn < 2; ++cn) {
        int col = cn * 16 + lr;
        int row = wbase + rm * 16 + g * 4;
#pragma unroll
        for (int j = 0; j < 4; ++j)
          dst[(size_t)(row + j) * 128 + col] = acc[rm][cn][j];
      }
  }
  if (outT) {
    unsigned short* dT = outT + (size_t)bc * NN + (size_t)(lq * 32) * 256;
    const unsigned short* aT = addT ? addT + (size_t)bc * NN + (size_t)(lq * 32) * 256 : nullptr;
#pragma unroll
    for (int rm = 0; rm < 4; ++rm)
#pragma unroll
      for (int cn = 0; cn < 2; ++cn) {
        int l = cn * 16 + lr;
        int v = wbase + rm * 16 + g * 4;
        float a0 = 0.f, a1 = 0.f, a2 = 0.f, a3 = 0.f;
        if (aT) {
          ushort4 av = *(const ushort4*)&aT[(size_t)l * 256 + v];
          a0 = bf2f(av.x); a1 = bf2f(av.y); a2 = bf2f(av.z); a3 = bf2f(av.w);
        }
        ushort4 pk;
        pk.x = f2bf(acc[rm][cn][0] + a0); pk.y = f2bf(acc[rm][cn][1] + a1);
        pk.z = f2bf(acc[rm][cn][2] + a2); pk.w = f2bf(acc[rm][cn][3] + a3);
        *(ushort4*)&dT[(size_t)l * 256 + v] = pk;
      }
  }
}

// ---------------- generic (c,l)-plane transpose per (b,k), optional add + bf16 side output ----------------
__global__ __launch_bounds__(256) void k_tr(const float* __restrict__ src, float* __restrict__ dst,
                                            const float* __restrict__ add,
                                            unsigned short* __restrict__ dstBf,
                                            long sb, long sk, long sc, long sl,
                                            long db, long dk, long dc, long dl, int nC, int nL) {
  int outer = blockIdx.x;
  int b = outer >> 8, k = outer & 255;
  int tilesL = nL >> 5;
  int tC = blockIdx.y / tilesL, tL = blockIdx.y % tilesL;
  int c0 = tC << 5, l0 = tL << 5;
  __shared__ float s[32][33];
  int tx = threadIdx.x & 31, ty = threadIdx.x >> 5;
  const float* sp = src + (long)b * sb + (long)k * sk;
#pragma unroll
  for (int j = 0; j < 4; ++j) {
    int cc = c0 + ty + j * 8;
    s[ty + j * 8][tx] = sp[(long)cc * sc + (long)(l0 + tx) * sl];
  }
  __syncthreads();
  long dbase = (long)b * db + (long)k * dk;
#pragma unroll
  for (int j = 0; j < 4; ++j) {
    int ll = l0 + ty + j * 8;
    long off = dbase + (long)(c0 + tx) * dc + (long)ll * dl;
    float val = s[tx][ty + j * 8];
    if (add) val += add[off];
    dst[off] = val;
    if (dstBf) dstBf[off] = f2bf(val);
  }
}

// ---------------- spatial QKV: Q -> bf16 RM; K,V -> bf16 TRANSPOSED [bl][c][n] ----------------
__global__ __launch_bounds__(256) void k_qkv_s(const float* __restrict__ in,
                                               const float* __restrict__ W0, const float* __restrict__ W1,
                                               const float* __restrict__ W2,
                                               unsigned short* __restrict__ qb,
                                               unsigned short* __restrict__ xkT,
                                               unsigned short* __restrict__ xvT) {
  int r0 = blockIdx.x * 64;
  __shared__ float sInT[64][68];
  __shared__ float sW[3][64][64];
  int t = threadIdx.x;
  for (int i = t; i < 4096; i += 256) {
    int c = i >> 6, o = i & 63;
    sW[0][c][o] = W0[i];
    sW[1][c][o] = W1[i];
    sW[2][c][o] = W2[i];
  }
  for (int i = t; i < 4096; i += 256) {
    int r = i >> 6, c = i & 63;
    sInT[c][r] = in[(size_t)(r0 + r) * 64 + c];
  }
  __syncthreads();
  int col = t & 63, rg = t >> 6;
  int rbase = rg * 16;
  float a0[16], a1[16], a2[16];
#pragma unroll
  for (int i = 0; i < 16; ++i) { a0[i] = 0.f; a1[i] = 0.f; a2[i] = 0.f; }
  for (int c = 0; c < 64; ++c) {
    float w0 = sW[0][c][col], w1 = sW[1][c][col], w2 = sW[2][c][col];
#pragma unroll
    for (int rr = 0; rr < 16; rr += 4) {
      float4 xv = *(const float4*)&sInT[c][rbase + rr];
      a0[rr + 0] += xv.x * w0; a0[rr + 1] += xv.y * w0; a0[rr + 2] += xv.z * w0; a0[rr + 3] += xv.w * w0;
      a1[rr + 0] += xv.x * w1; a1[rr + 1] += xv.y * w1; a1[rr + 2] += xv.z * w1; a1[rr + 3] += xv.w * w1;
      a2[rr + 0] += xv.x * w2; a2[rr + 1] += xv.y * w2; a2[rr + 2] += xv.z * w2; a2[rr + 3] += xv.w * w2;
    }
  }
#pragma unroll
  for (int rr = 0; rr < 16; ++rr)
    qb[(size_t)(r0 + rbase + rr) * 64 + col] = f2bf(a0[rr]);
  int bl = r0 >> 8;
  int nb = (r0 & 255) + rbase;
  unsigned short* kd = xkT + (size_t)bl * 16384 + (size_t)col * 256 + nb;
  unsigned short* vd = xvT + (size_t)bl * 16384 + (size_t)col * 256 + nb;
#pragma unroll
  for (int rr = 0; rr < 16; ++rr) { kd[rr] = f2bf(a1[rr]); vd[rr] = f2bf(a2[rr]); }
}

// ---------------- MFMA sproj: which=0: kpb[bl][p][c] = (X_k @ P_k); which=1: vptb[bl][c][p] ----------------
// XkT/XvT: bf16 [bl][c][n=256]; PkT/PvT: bf16 [p][n=256]. grid (256, 2), 256 threads (4 waves).
__global__ __launch_bounds__(256) void k_sprojM(const unsigned short* __restrict__ XkT,
                                                const unsigned short* __restrict__ XvT,
                                                const unsigned short* __restrict__ PkT,
                                                const unsigned short* __restrict__ PvT,
                                                unsigned short* __restrict__ kpb,
                                                unsigned short* __restrict__ vptb) {
  int bl = blockIdx.x;
  int which = blockIdx.y;
  int t = threadIdx.x, w = t >> 6, lane = t & 63;
  int lr = lane & 15, g = lane >> 4;
  // which==0 (K): A = XkT rows c (wave tile), B = PkT cols p -> D[c][p]
  // which==1 (V): A = PvT rows p (wave tile), B = XvT cols c -> D[p][c]
  const unsigned short* Abase = which ? PvT : XkT + (size_t)bl * 16384;
  const unsigned short* Bbase = which ? XvT + (size_t)bl * 16384 : PkT;
  const unsigned short* aP = Abase + (size_t)(w * 16 + lr) * 256 + g * 8;
  f32x4 acc[4];
#pragma unroll
  for (int ct = 0; ct < 4; ++ct) acc[ct] = f32x4{0.f, 0.f, 0.f, 0.f};
  for (int k0 = 0; k0 < 256; k0 += 32) {
    short8 af = *(const short8*)(aP + k0);
#pragma unroll
    for (int ct = 0; ct < 4; ++ct) {
      short8 bf = *(const short8*)(Bbase + (size_t)(ct * 16 + lr) * 256 + k0 + g * 8);
      acc[ct] = __builtin_amdgcn_mfma_f32_16x16x32_bf16(af, bf, acc[ct], 0, 0, 0);
    }
  }
  if (!which) {
    // D row = c (w*16+g*4+reg), col = p (ct*16+lr); store kpb[p][c], 4 consecutive c
    unsigned short* dst = kpb + (size_t)bl * 4096;
#pragma unroll
    for (int ct = 0; ct < 4; ++ct) {
      int p = ct * 16 + lr;
      int c0 = w * 16 + g * 4;
      ushort4 pk;
      pk.x = f2bf(acc[ct][0]); pk.y = f2bf(acc[ct][1]);
      pk.z = f2bf(acc[ct][2]); pk.w = f2bf(acc[ct][3]);
      *(ushort4*)&dst[(size_t)p * 64 + c0] = pk;
    }
  } else {
    // D row = p (w*16+g*4+reg), col = c (ct*16+lr); store vptb[c][p], 4 consecutive p
    unsigned short* dst = vptb + (size_t)bl * 4096;
#pragma unroll
    for (int ct = 0; ct < 4; ++ct) {
      int c = ct * 16 + lr;
      int p0 = w * 16 + g * 4;
      ushort4 pk;
      pk.x = f2bf(acc[ct][0]); pk.y = f2bf(acc[ct][1]);
      pk.z = f2bf(acc[ct][2]); pk.w = f2bf(acc[ct][3]);
      *(ushort4*)&dst[(size_t)c * 64 + p0] = pk;
    }
  }
}

// ---------------- temporal QKV: Q,K -> bf16 row-major; V -> bf16 TRANSPOSED [bk][c][l] ----------------
__global__ __launch_bounds__(256) void k_qkv_t(const float* __restrict__ in,
                                               const float* __restrict__ W0, const float* __restrict__ W1,
                                               const float* __restrict__ W2,
                                               const float* __restrict__ b0, const float* __restrict__ b1,
                                               const float* __restrict__ b2,
                                               unsigned short* __restrict__ qb,
                                               unsigned short* __restrict__ kb,
                                               unsigned short* __restrict__ vt) {
  int r0 = blockIdx.x * 64;
  __shared__ float sInT[64][68];
  __shared__ float sW[3][64][64];
  int t = threadIdx.x;
  for (int i = t; i < 4096; i += 256) {
    int c = i >> 6, o = i & 63;
    sW[0][c][o] = W0[i];
    sW[1][c][o] = W1[i];
    sW[2][c][o] = W2[i];
  }
  for (int i = t; i < 4096; i += 256) {
    int r = i >> 6, c = i & 63;
    sInT[c][r] = in[(size_t)(r0 + r) * 64 + c];
  }
  __syncthreads();
  int col = t & 63, rg = t >> 6;
  int rbase = rg * 16;
  float a0[16], a1[16], a2[16];
  float bv0 = b0[col], bv1 = b1[col], bv2 = b2[col];
#pragma unroll
  for (int i = 0; i < 16; ++i) { a0[i] = bv0; a1[i] = bv1; a2[i] = bv2; }
  for (int c = 0; c < 64; ++c) {
    float w0 = sW[0][c][col], w1 = sW[1][c][col], w2 = sW[2][c][col];
#pragma unroll
    for (int rr = 0; rr < 16; rr += 4) {
      float4 xv = *(const float4*)&sInT[c][rbase + rr];
      a0[rr + 0] += xv.x * w0; a0[rr + 1] += xv.y * w0; a0[rr + 2] += xv.z * w0; a0[rr + 3] += xv.w * w0;
      a1[rr + 0] += xv.x * w1; a1[rr + 1] += xv.y * w1; a1[rr + 2] += xv.z * w1; a1[rr + 3] += xv.w * w1;
      a2[rr + 0] += xv.x * w2; a2[rr + 1] += xv.y * w2; a2[rr + 2] += xv.z * w2; a2[rr + 3] += xv.w * w2;
    }
  }
#pragma unroll
  for (int rr = 0; rr < 16; ++rr) {
    size_t idx = (size_t)(r0 + rbase + rr) * 64 + col;
    qb[idx] = f2bf(a0[rr]); kb[idx] = f2bf(a1[rr]);
  }
  int bk = r0 >> 7;
  int lbase = (r0 & 127) + rbase;
  unsigned short* vd = vt + (size_t)bk * 8192 + (size_t)col * 128 + lbase;
#pragma unroll
  for (int rr = 0; rr < 16; ++rr) vd[rr] = f2bf(a2[rr]);
}

// ---------------- row-major (R,CIN) @ (CIN,COUT) + bias, optional activation ----------------
template <int CIN, int COUT, int ACT, int ROWS>
__global__ __launch_bounds__(256) void k_rowmm(const float* __restrict__ in,
                                               const float* __restrict__ W,
                                               const float* __restrict__ bias,
                                               float* __restrict__ out) {
  int r0 = blockIdx.x * ROWS;
  __shared__ float sInT[CIN][ROWS + 4];
  __shared__ float sW[CIN][COUT];
  int t = threadIdx.x;
  for (int i = t; i < CIN * COUT; i += 256) ((float*)sW)[i] = W[i];
  for (int i = t; i < ROWS * CIN; i += 256) {
    int r = i / CIN, c = i % CIN;
    sInT[c][r] = in[(size_t)r0 * CIN + i];
  }
  __syncthreads();
  constexpr int NRG = 256 / COUT;
  constexpr int RPT = ROWS / NRG;
  int col = t % COUT, rg = t / COUT;
  int rbase = rg * RPT;
  float acc[RPT];
  float bv = bias ? bias[col] : 0.f;
#pragma unroll
  for (int r = 0; r < RPT; ++r) acc[r] = bv;
  for (int c = 0; c < CIN; ++c) {
    float wv = sW[c][col];
#pragma unroll
    for (int rr = 0; rr < RPT; rr += 4) {
      float4 xv = *(const float4*)&sInT[c][rbase + rr];
      acc[rr] += xv.x * wv; acc[rr + 1] += xv.y * wv;
      acc[rr + 2] += xv.z * wv; acc[rr + 3] += xv.w * wv;
    }
  }
#pragma unroll
  for (int rr = 0; rr < RPT; ++rr) {
    float v = acc[rr];
    if (ACT == 1) v = fmaxf(v, 0.f);
    out[(size_t)(r0 + rbase + rr) * COUT + col] = v;
  }
}

// ---------------- fused LN1 -> FFN(64->8 gelu ->64) -> LN2, row-local; block = 64 rows ----------------
__global__ __launch_bounds__(256) void k_tffn(const float* __restrict__ A, const float* __restrict__ Bz,
                                              const float* __restrict__ l1w, const float* __restrict__ l1b,
                                              const float* __restrict__ l2w, const float* __restrict__ l2b,
                                              const float* __restrict__ ln1g, const float* __restrict__ ln1b,
                                              const float* __restrict__ ln2g, const float* __restrict__ ln2b,
                                              float* __restrict__ outp) {
  int r0 = blockIdx.x * 64;
  __shared__ float sSrc[64][65];
  __shared__ float sH[64][8];
  __shared__ float sW1[64][8];
  __shared__ float sW2[8][64];
  int t = threadIdx.x;
  for (int i = t; i < 512; i += 256) { ((float*)sW1)[i] = l1w[i]; ((float*)sW2)[i] = l2w[i]; }
  int c = t & 63, rg = t >> 6;
  float g1 = ln1g[c], be1 = ln1b[c];
  for (int it = 0; it < 16; ++it) {
    int r = it * 4 + rg;
    size_t idx = (size_t)(r0 + r) * 64 + c;
    float x = A[idx] + Bz[idx];
    float s = x, ss = x * x;
#pragma unroll
    for (int off = 32; off; off >>= 1) { s += __shfl_xor(s, off); ss += __shfl_xor(ss, off); }
    float mu = s * (1.f / 64.f);
    float var = ss * (1.f / 64.f) - mu * mu;
    sSrc[r][c] = (x - mu) * rsqrtf(var + EPSV) * g1 + be1;
  }
  __syncthreads();
#pragma unroll
  for (int p = 0; p < 2; ++p) {
    int idx = t + 256 * p;
    int row = idx >> 3, j = idx & 7;
    float acc = l1b[j];
    for (int cc = 0; cc < 64; ++cc) acc += sSrc[row][cc] * sW1[cc][j];
    acc = 0.5f * acc * (1.f + erff(acc * 0.70710678118654752440f));
    sH[row][j] = acc;
  }
  __syncthreads();
  float g2 = ln2g[c], be2 = ln2b[c];
  float l2bc = l2b[c];
  for (int it = 0; it < 16; ++it) {
    int r = it * 4 + rg;
    float o = l2bc;
#pragma unroll
    for (int j = 0; j < 8; ++j) o += sH[r][j] * sW2[j][c];
    float x = sSrc[r][c] + o;
    float s = x, ss = x * x;
#pragma unroll
    for (int off = 32; off; off >>= 1) { s += __shfl_xor(s, off); ss += __shfl_xor(ss, off); }
    float mu = s * (1.f / 64.f);
    float var = ss * (1.f / 64.f) - mu * mu;
    outp[(size_t)(r0 + r) * 64 + c] = (x - mu) * rsqrtf(var + EPSV) * g2 + be2;
  }
}

// ---------------- per-head MFMA attention: block = 128 q-rows, 8 waves = 8 heads ----------------
template <int NKV, int KVSHIFT>
__global__ __launch_bounds__(512) void k_attnH(const unsigned short* __restrict__ Qb,
                                               const unsigned short* __restrict__ Kb,
                                               const unsigned short* __restrict__ VTb,
                                               float* __restrict__ O) {
  constexpr int NCT = NKV / 16;
  constexpr int NKS = NKV / 32;
  int blk = blockIdx.x;
  const unsigned short* Qp = Qb + (size_t)blk * 128 * 64;
  float* Op = O + (size_t)blk * 128 * 64;
  const unsigned short* Kp = Kb + (size_t)(blk >> KVSHIFT) * NKV * 64;
  const unsigned short* VTp = VTb + (size_t)(blk >> KVSHIFT) * 64 * NKV;
  int t = threadIdx.x;
  int h = t >> 6, lane = t & 63, lr = lane & 15, g = lane >> 4;
  __shared__ unsigned short sP[8][16 * NKV];
  unsigned short* myP = sP[h];

  short8 kbf[NCT];
#pragma unroll
  for (int ct = 0; ct < NCT; ++ct)
    kbf[ct] = *(const short8*)(Kp + (size_t)(ct * 16 + lr) * 64 + h * 8);

  int vr = h * 8 + lr; if (vr > 63) vr = 63;
  short8 vbf[NKS];
#pragma unroll
  for (int ks = 0; ks < NKS; ++ks)
    vbf[ks] = *(const short8*)(VTp + (size_t)vr * NKV + ks * 32 + g * 8);

  for (int mt = 0; mt < 8; ++mt) {
    short8 qa = short8{0, 0, 0, 0, 0, 0, 0, 0};
    if (g == 0) qa = *(const short8*)(Qp + (size_t)(mt * 16 + lr) * 64 + h * 8);

    f32x4 sacc[NCT];
#pragma unroll
    for (int ct = 0; ct < NCT; ++ct) sacc[ct] = f32x4{0.f, 0.f, 0.f, 0.f};
#pragma unroll
    for (int ct = 0; ct < NCT; ++ct)
      sacc[ct] = __builtin_amdgcn_mfma_f32_16x16x32_bf16(qa, kbf[ct], sacc[ct], 0, 0, 0);

    float inv4[4];
#pragma unroll
    for (int reg = 0; reg < 4; ++reg) {
      float s = 0.f;
#pragma unroll
      for (int ct = 0; ct < NCT; ++ct) {
        float e = __expf(sacc[ct][reg] * SCL);
        sacc[ct][reg] = e;
        s += e;
      }
      s += __shfl_xor(s, 1); s += __shfl_xor(s, 2); s += __shfl_xor(s, 4); s += __shfl_xor(s, 8);
      inv4[reg] = 1.f / s;
    }

#pragma unroll
    for (int ct = 0; ct < NCT; ++ct)
#pragma unroll
      for (int reg = 0; reg < 4; ++reg) {
        int row = g * 4 + reg;
        int bo = ((row * NKV + ct * 16 + lr) * 2) ^ ((row & 7) << 4);
        *(unsigned short*)((char*)myP + bo) = f2bf(sacc[ct][reg]);
      }
    __syncthreads();

    f32x4 oacc = f32x4{0.f, 0.f, 0.f, 0.f};
#pragma unroll
    for (int ks = 0; ks < NKS; ++ks) {
      int bo = ((lr * NKV + ks * 32 + g * 8) * 2) ^ ((lr & 7) << 4);
      short8 pa = *(const short8*)((char*)myP + bo);
      oacc = __builtin_amdgcn_mfma_f32_16x16x32_bf16(pa, vbf[ks], oacc, 0, 0, 0);
    }
    if (lr < 8) {
#pragma unroll
      for (int reg = 0; reg < 4; ++reg) {
        int row = mt * 16 + g * 4 + reg;
        Op[(size_t)row * 64 + h * 8 + lr] = oacc[reg] * inv4[reg];
      }
    }
    __syncthreads();
  }
}

// ---------------- GroupNorm stats: up to 5 summed inputs, optional sum write-back ----------------
__global__ __launch_bounds__(256) void k_gn_part(const float* __restrict__ p0, const float* __restrict__ p1,
                                                 const float* __restrict__ p2, const float* __restrict__ p3,
                                                 const float* __restrict__ p4,
                                                 float* __restrict__ sumOut,
                                                 float* __restrict__ part) {
  int bg = blockIdx.y, blk = blockIdx.x, t = threadIdx.x;
  size_t start = (size_t)bg * ((size_t)CPG * NN) + (size_t)blk * 8192;
  const float4* q0 = (const float4*)(p0 + start);
  const float4* q1 = p1 ? (const float4*)(p1 + start) : nullptr;
  const float4* q2 = p2 ? (const float4*)(p2 + start) : nullptr;
  const float4* q3 = p3 ? (const float4*)(p3 + start) : nullptr;
  const float4* q4 = p4 ? (const float4*)(p4 + start) : nullptr;
  float4* so = sumOut ? (float4*)(sumOut + start) : nullptr;
  float s = 0.f, ss = 0.f;
  for (int i = t; i < 2048; i += 256) {
    float4 x = q0[i];
    if (q1) { float4 y4 = q1[i]; x.x += y4.x; x.y += y4.y; x.z += y4.z; x.w += y4.w; }
    if (q2) { float4 y4 = q2[i]; x.x += y4.x; x.y += y4.y; x.z += y4.z; x.w += y4.w; }
    if (q3) { float4 y4 = q3[i]; x.x += y4.x; x.y += y4.y; x.z += y4.z; x.w += y4.w; }
    if (q4) { float4 y4 = q4[i]; x.x += y4.x; x.y += y4.y; x.z += y4.z; x.w += y4.w; }
    if (so) so[i] = x;
    s += x.x + x.y + x.z + x.w;
    ss += x.x * x.x + x.y * x.y + x.z * x.z + x.w * x.w;
  }
  __shared__ float rs[256], rq[256];
  rs[t] = s; rq[t] = ss; __syncthreads();
  for (int off = 128; off; off >>= 1) { if (t < off) { rs[t] += rs[t + off]; rq[t] += rq[t + off]; } __syncthreads(); }
  if (t == 0) { part[(bg * 64 + blk) * 2] = rs[0]; part[(bg * 64 + blk) * 2 + 1] = rq[0]; }
}

// out = GN(p0[+p1]) (+ q0) (+ q1) — reduces 64 partials per block (gn_final folded in)
__global__ __launch_bounds__(256) void k_gn_apply(const float* __restrict__ p0, const float* __restrict__ p1,
                                                  const float* __restrict__ part, const float* __restrict__ g,
                                                  const float* __restrict__ be,
                                                  const float* __restrict__ q0, const float* __restrict__ q1,
                                                  float* __restrict__ out) {
  size_t i4 = (size_t)blockIdx.x * 256 + threadIdx.x;
  size_t i = i4 * 4;
  int chan = (int)(i >> 15) & 63;
  int bg = (int)(i >> 19);
  __shared__ float smu, srr;
  int t = threadIdx.x;
  if (t < 64) {
    float s = part[(bg * 64 + t) * 2], ss = part[(bg * 64 + t) * 2 + 1];
#pragma unroll
    for (int off = 32; off; off >>= 1) { s += __shfl_xor(s, off); ss += __shfl_xor(ss, off); }
    if (t == 0) {
      float inv = 1.f / (float)((size_t)CPG * NN);
      float mu = s * inv;
      float var = ss * inv - mu * mu;
      smu = mu; srr = rsqrtf(var + EPSV);
    }
  }
  __syncthreads();
  float mu = smu, rr = srr;
  float4 x = ((const float4*)p0)[i4];
  if (p1) { float4 y4 = ((const float4*)p1)[i4]; x.x += y4.x; x.y += y4.y; x.z += y4.z; x.w += y4.w; }
  float gc = g[chan], bc = be[chan];
  float4 v;
  v.x = (x.x - mu) * rr * gc + bc;
  v.y = (x.y - mu) * rr * gc + bc;
  v.z = (x.z - mu) * rr * gc + bc;
  v.w = (x.w - mu) * rr * gc + bc;
  if (q0) { float4 y4 = ((const float4*)q0)[i4]; v.x += y4.x; v.y += y4.y; v.z += y4.z; v.w += y4.w; }
  if (q1) { float4 y4 = ((const float4*)q1)[i4]; v.x += y4.x; v.y += y4.y; v.z += y4.z; v.w += y4.w; }
  ((float4*)out)[i4] = v;
}

extern "C" void kernel_launch(void* const* d_in, const int* in_sizes, int n_in,
                              void* d_out, int out_size, void* d_ws, size_t ws_size,
                              hipStream_t stream) {
  (void)in_sizes; (void)n_in; (void)out_size; (void)ws_size;
  const float* y     = (const float*)d_in[0];
  const float* a1    = (const float*)d_in[1];
  const float* a2    = (const float*)d_in[2];
  const float* nv1   = (const float*)d_in[3];
  const float* nv2   = (const float*)d_in[4];
  const float* gcn_w = (const float*)d_in[5];
  const float* gcn_b = (const float*)d_in[6];
  const float* s_wq  = (const float*)d_in[7];
  const float* s_wk  = (const float*)d_in[8];
  const float* s_wv  = (const float*)d_in[9];
  const float* s_pk  = (const float*)d_in[10];
  const float* s_pv  = (const float*)d_in[11];
  const float* s_wo  = (const float*)d_in[12];
  const float* s_bo  = (const float*)d_in[13];
  const float* t_wq  = (const float*)d_in[14];
  const float* t_wk  = (const float*)d_in[15];
  const float* t_wv  = (const float*)d_in[16];
  const float* t_bq  = (const float*)d_in[17];
  const float* t_bk  = (const float*)d_in[18];
  const float* t_bv  = (const float*)d_in[19];
  const float* t_wo  = (const float*)d_in[20];
  const float* t_bo  = (const float*)d_in[21];
  const float* t_l1w = (const float*)d_in[22];
  const float* t_l1b = (const float*)d_in[23];
  const float* t_l2w = (const float*)d_in[24];
  const float* t_l2b = (const float*)d_in[25];
  const float* ln1g  = (const float*)d_in[26];
  const float* ln1b  = (const float*)d_in[27];
  const float* ln2g  = (const float*)d_in[28];
  const float* ln2b  = (const float*)d_in[29];
  const float* gnlg  = (const float*)d_in[30];
  const float* gnlb  = (const float*)d_in[31];
  const float* gnsg  = (const float*)d_in[32];
  const float* gnsb  = (const float*)d_in[33];
  const float* gntg  = (const float*)d_in[34];
  const float* gntb  = (const float*)d_in[35];
  const float* ff1w  = (const float*)d_in[36];
  const float* ff1b  = (const float*)d_in[37];
  const float* ff2w  = (const float*)d_in[38];
  const float* ff2b  = (const float*)d_in[39];
  const float* gn2g  = (const float*)d_in[40];
  const float* gn2b  = (const float*)d_in[41];

  float* ws = (float*)d_ws;
  float* adp   = ws;
  float* part  = ws + 65536;
  unsigned short* a1_bf   = (unsigned short*)(ws + 131072);
  unsigned short* a2_bf   = (unsigned short*)(ws + 163840);
  unsigned short* adp_bf  = (unsigned short*)(ws + 196608);
  unsigned short* gcnw_bf = (unsigned short*)(ws + 229376);
  unsigned short* xs_bf   = (unsigned short*)(ws + 262144);
  // spatial attn scratch (post-GCN; a*_bf etc dead):
  unsigned short* kpb  = (unsigned short*)(ws + 131072);     // 1M ushort (512K floats) -> ends 655360
  unsigned short* PkT  = (unsigned short*)(ws + 720896);     // 16K ushort
  unsigned short* PvT  = (unsigned short*)(ws + 729088);
  unsigned short* vptb = (unsigned short*)(ws + 1179648);    // 1M ushort -> ends 1703936
  const size_t SLOT = 4194304;
  float* G0 = ws + SLOT * 1;
  float* G1 = ws + SLOT * 2;
  float* G2 = ws + SLOT * 3;
  float* G3 = ws + SLOT * 4;
  float* G4 = ws + SLOT * 5;
  float* G5 = ws + SLOT * 6;
  float* G6 = ws + SLOT * 7;
  unsigned short* U1 = (unsigned short*)G3;
  unsigned short* U2 = (unsigned short*)G3 + 4194304;
  unsigned short* U3 = (unsigned short*)G4;
  unsigned short* U4 = (unsigned short*)G4 + 4194304;
  unsigned short* U5 = (unsigned short*)G5;
  unsigned short* U6 = (unsigned short*)G5 + 4194304;
  unsigned short* PT = (unsigned short*)G6;
  unsigned short* xkT = (unsigned short*)G4;   // spatial K^T bf16 [bl][c][n]
  unsigned short* xvT = (unsigned short*)G5;   // spatial V^T bf16
  float* out = (float*)d_out;

  const long BS = 2097152;

  // ---- adaptive adjacency + bf16 casts ----
  k_adp<<<256, 256, 0, stream>>>(nv1, nv2, adp);
  k_cast3<<<640, 256, 0, stream>>>(a1, a2, gcn_w, a1_bf, a2_bf, gcnw_bf);
  k_cast<<<256, 256, 0, stream>>>(adp, adp_bf);

  // ---- xs (B,L,K,C) fp32 + bf16 ----
  k_tr<<<dim3(512, 8), 256, 0, stream>>>(y, G2, nullptr, xs_bf, BS, 128, 32768, 1, BS, 64, 1, 16384, 64, 128);

  // ---- AdaptiveGCN ----
  k_mix0<<<1024, 64, 0, stream>>>(xs_bf, gcnw_bf, gcn_b, G1);
  k_mix6<<<dim3(1024, 3), 64, 0, stream>>>(xs_bf, gcnw_bf, U1, U2, U3, U4, U5, U6);
  k_adjM<<<512, 256, 0, stream>>>(a1_bf, U2, nullptr, PT, U1);
  k_adjM<<<512, 256, 0, stream>>>(a1_bf, PT, G0, nullptr, nullptr);   // Q1
  k_adjM<<<512, 256, 0, stream>>>(a2_bf, U4, nullptr, PT, U3);
  k_adjM<<<512, 256, 0, stream>>>(a2_bf, PT, G4, nullptr, nullptr);   // Q2
  k_adjM<<<512, 256, 0, stream>>>(adp_bf, U6, nullptr, PT, U5);
  k_adjM<<<512, 256, 0, stream>>>(adp_bf, PT, G5, nullptr, nullptr);  // Q3
  k_gn_part<<<dim3(64, 8), 256, 0, stream>>>(y, G1, G0, G4, G5, G3, part);
  k_gn_apply<<<4096, 256, 0, stream>>>(G3, nullptr, part, gnlg, gnlb, nullptr, nullptr, G0);

  // ---- Linformer spatial attention (G2 = xs) ----
  k_castP<<<dim3(16, 2), 256, 0, stream>>>(s_pk, s_pv, PkT, PvT);
  k_qkv_s<<<1024, 256, 0, stream>>>(G2, s_wq, s_wk, s_wv, (unsigned short*)G3, xkT, xvT);
  k_sprojM<<<dim3(256, 2), 256, 0, stream>>>(xkT, xvT, PkT, PvT, kpb, vptb);
  k_attnH<64, 1><<<512, 512, 0, stream>>>((unsigned short*)G3, kpb, vptb, G6);
  k_rowmm<64, 64, 0, 64><<<1024, 256, 0, stream>>>(G6, s_wo, s_bo, G4);
  k_tr<<<dim3(512, 8), 256, 0, stream>>>(G4, G1, nullptr, nullptr, BS, 64, 16384, 1, BS, 128, 1, 32768, 128, 64);
  k_gn_part<<<dim3(64, 8), 256, 0, stream>>>(y, G1, nullptr, nullptr, nullptr, G2, part);
  k_gn_apply<<<4096, 256, 0, stream>>>(G2, nullptr, part, gnsg, gnsb, nullptr, nullptr, G1);

  // ---- temporal transformer layer ----
  k_tr<<<dim3(512, 8), 256, 0, stream>>>(y, G2, nullptr, nullptr, BS, 128, 32768, 1, BS, 8192, 1, 64, 64, 128);
  k_qkv_t<<<1024, 256, 0, stream>>>(G2, t_wq, t_wk, t_wv, t_bq, t_bk, t_bv,
                                    (unsigned short*)G3, (unsigned short*)G4, (unsigned short*)G5);
  k_attnH<128, 0><<<512, 512, 0, stream>>>((unsigned short*)G3, (unsigned short*)G4, (unsigned short*)G5, G6);
  k_rowmm<64, 64, 0, 64><<<1024, 256, 0, stream>>>(G6, t_wo, t_bo, G3);
  k_tffn<<<1024, 256, 0, stream>>>(G2, G3, t_l1w, t_l1b, t_l2w, t_l2b,
                                   ln1g, ln1b, ln2g, ln2b, G6);
  k_tr<<<dim3(512, 8), 256, 0, stream>>>(G6, G2, nullptr, nullptr, BS, 8192, 64, 1, BS, 128, 1, 32768, 128, 64);
  k_gn_part<<<dim3(64, 8), 256, 0, stream>>>(y, G2, nullptr, nullptr, nullptr, G5, part);
  k_gn_apply<<<4096, 256, 0, stream>>>(G5, nullptr, part, gntg, gntb, G0, G1, G3);

  // ---- fuse + channel FFN + final GroupNorm ----
  k_tr<<<dim3(512, 8), 256, 0, stream>>>(G3, G4, nullptr, nullptr, BS, 128, 32768, 1, BS, 8192, 1, 64, 64, 128);
  k_rowmm<64, 128, 1, 64><<<1024, 256, 0, stream>>>(G4, ff1w, ff1b, G5);
  k_rowmm<128, 64, 0, 32><<<2048, 256, 0, stream>>>(G5, ff2w, ff2b, G4);
  k_tr<<<dim3(512, 8), 256, 0, stream>>>(G4, out, G3, nullptr, BS, 8192, 64, 1, BS, 128, 1, 32768, 128, 64);
  k_gn_part<<<dim3(64, 8), 256, 0, stream>>>(out, nullptr, nullptr, nullptr, nullptr, nullptr, part);
  k_gn_apply<<<4096, 256, 0, stream>>>(out, nullptr, part, gn2g, gn2b, nullptr, nullptr, out);
}

// Round 15
// 485.177 us; speedup vs baseline: 1.3380x; 1.0637x over previous
//
#include <hip/hip_runtime.h>
#include <math.h>

constexpr int CC = 64, KK = 256, LL = 128;
constexpr int NN = KK * LL;          // 32768
constexpr int PR = 64;               // Linformer projection
constexpr int CPG = 16;              // channels per group (C / 4)
constexpr float EPSV = 1e-5f;
constexpr float SCL = 0.35355339059327373f;  // 1/sqrt(8)

typedef __attribute__((ext_vector_type(8))) short short8;      // 8 bf16 (4 VGPR)
typedef __attribute__((ext_vector_type(4))) float f32x4;       // MFMA 16x16 acc

__device__ __forceinline__ unsigned short f2bf(float x) {
  union { float f; unsigned int u; } v; v.f = x;
  unsigned int r = (v.u + 0x7FFFu + ((v.u >> 16) & 1u)) >> 16;
  return (unsigned short)r;
}
__device__ __forceinline__ float bf2f(unsigned short x) {
  union { unsigned int u; float f; } v; v.u = ((unsigned int)x) << 16;
  return v.f;
}

// ---------------- adaptive adjacency: softmax(relu(nv1@nv2), axis=1) ----------------
__global__ __launch_bounds__(256) void k_adp(const float* __restrict__ nv1,
                                             const float* __restrict__ nv2,
                                             float* __restrict__ adp) {
  int w = blockIdx.x, v = threadIdx.x;
  float s = 0.f;
  for (int d = 0; d < 10; ++d) s += nv1[w * 10 + d] * nv2[d * KK + v];
  s = fmaxf(s, 0.f);
  __shared__ float red[256];
  red[v] = s; __syncthreads();
  for (int off = 128; off; off >>= 1) { if (v < off) red[v] = fmaxf(red[v], red[v + off]); __syncthreads(); }
  float m = red[0]; __syncthreads();
  float e = expf(s - m);
  red[v] = e; __syncthreads();
  for (int off = 128; off; off >>= 1) { if (v < off) red[v] += red[v + off]; __syncthreads(); }
  adp[w * KK + v] = e / red[0];
}

// ---------------- fp32 -> bf16 cast (single range) ----------------
__global__ __launch_bounds__(256) void k_cast(const float* __restrict__ src,
                                              unsigned short* __restrict__ dst) {
  int i = blockIdx.x * 256 + threadIdx.x;
  dst[i] = f2bf(src[i]);
}

// ---------------- fused cast of a1 + a2 + gcn_w ----------------
__global__ __launch_bounds__(256) void k_cast3(const float* __restrict__ s0, const float* __restrict__ s1,
                                               const float* __restrict__ s2,
                                               unsigned short* __restrict__ d0, unsigned short* __restrict__ d1,
                                               unsigned short* __restrict__ d2) {
  int i = blockIdx.x * 256 + threadIdx.x;
  if (i < 65536) d0[i] = f2bf(s0[i]);
  else if (i < 131072) d1[i - 65536] = f2bf(s1[i - 65536]);
  else if (i < 159744) d2[i - 131072] = f2bf(s2[i - 131072]);
}

// ---------------- transpose-cast P (256 x 64) -> PT bf16 (64 x 256); grid (16, 2) ----------------
__global__ __launch_bounds__(256) void k_castP(const float* __restrict__ P0, const float* __restrict__ P1,
                                               unsigned short* __restrict__ T0, unsigned short* __restrict__ T1) {
  const float* P = blockIdx.y ? P1 : P0;
  unsigned short* T = blockIdx.y ? T1 : T0;
  int tv = blockIdx.x >> 1, tc = blockIdx.x & 1;
  int n0 = tv * 32, c0 = tc * 32;
  __shared__ float s[32][33];
  int tx = threadIdx.x & 31, ty = threadIdx.x >> 5;
#pragma unroll
  for (int j = 0; j < 4; ++j)
    s[ty + j * 8][tx] = P[(size_t)(n0 + ty + j * 8) * 64 + c0 + tx];
  __syncthreads();
#pragma unroll
  for (int j = 0; j < 4; ++j)
    T[(size_t)(c0 + ty + j * 8) * 256 + n0 + tx] = f2bf(s[tx][ty + j * 8]);
}

// ---------------- s0 term: s0[b,o,k,l] = bias[o] + sum_c W0[o][c]*xs[(b,l,k)][c] ----------------
__global__ __launch_bounds__(64) void k_mix0(const unsigned short* __restrict__ Xbf,
                                             const unsigned short* __restrict__ Wbf,
                                             const float* __restrict__ bias,
                                             float* __restrict__ s0) {
  int pb = blockIdx.x;
  int lh = pb & 1;
  int k = (pb >> 1) & 255;
  int b = pb >> 9;
  int lane = threadIdx.x;
  int lr = lane & 15, g = lane >> 4;
  short8 af[4][2], bfv[4][2];
#pragma unroll
  for (int ot = 0; ot < 4; ++ot)
#pragma unroll
    for (int kc = 0; kc < 2; ++kc)
      af[ot][kc] = *(const short8*)(Wbf + (size_t)(ot * 16 + lr) * 448 + kc * 32 + g * 8);
#pragma unroll
  for (int ct = 0; ct < 4; ++ct)
#pragma unroll
    for (int kc = 0; kc < 2; ++kc)
      bfv[ct][kc] = *(const short8*)(Xbf + ((size_t)(b * 128 + lh * 64 + ct * 16 + lr) * 256 + k) * 64 + kc * 32 + g * 8);
  f32x4 acc[4][4];
#pragma unroll
  for (int ot = 0; ot < 4; ++ot)
#pragma unroll
    for (int ct = 0; ct < 4; ++ct) acc[ot][ct] = f32x4{0.f, 0.f, 0.f, 0.f};
#pragma unroll
  for (int kc = 0; kc < 2; ++kc)
#pragma unroll
    for (int ot = 0; ot < 4; ++ot)
#pragma unroll
      for (int ct = 0; ct < 4; ++ct)
        acc[ot][ct] = __builtin_amdgcn_mfma_f32_16x16x32_bf16(af[ot][kc], bfv[ct][kc], acc[ot][ct], 0, 0, 0);
#pragma unroll
  for (int ot = 0; ot < 4; ++ot)
#pragma unroll
    for (int ct = 0; ct < 4; ++ct) {
#pragma unroll
      for (int reg = 0; reg < 4; ++reg) {
        int o = ot * 16 + g * 4 + reg;
        s0[(size_t)(b * 64 + o) * NN + (size_t)k * 128 + lh * 64 + ct * 16 + lr] = acc[ot][ct][reg] + bias[o];
      }
    }
}

// ---------------- U terms: U_s[(b*64+o)][l][k] bf16; blockIdx.y picks s-pair ----------------
__global__ __launch_bounds__(64) void k_mix6(const unsigned short* __restrict__ Xbf,
                                             const unsigned short* __restrict__ Wbf,
                                             unsigned short* __restrict__ U1, unsigned short* __restrict__ U2,
                                             unsigned short* __restrict__ U3, unsigned short* __restrict__ U4,
                                             unsigned short* __restrict__ U5, unsigned short* __restrict__ U6) {
  unsigned short* Us[6] = {U1, U2, U3, U4, U5, U6};
  int pb = blockIdx.x;
  int sy = blockIdx.y;
  int b = pb >> 9;
  int rem = pb & 511;
  int l = rem >> 2;
  int kq = (rem & 3) * 64;
  size_t posbase = ((size_t)(b * 128 + l)) * 256 + kq;
  int lane = threadIdx.x;
  int lr = lane & 15, g = lane >> 4;

  short8 af[4][2];
#pragma unroll
  for (int rt = 0; rt < 4; ++rt)
#pragma unroll
    for (int kc = 0; kc < 2; ++kc)
      af[rt][kc] = *(const short8*)(Xbf + (posbase + rt * 16 + lr) * 64 + kc * 32 + g * 8);

  for (int si = 0; si < 2; ++si) {
    int s = sy * 2 + 1 + si;
    short8 bfv[4][2];
#pragma unroll
    for (int ct = 0; ct < 4; ++ct)
#pragma unroll
      for (int kc = 0; kc < 2; ++kc)
        bfv[ct][kc] = *(const short8*)(Wbf + (size_t)(ct * 16 + lr) * 448 + s * 64 + kc * 32 + g * 8);
    f32x4 acc[4][4];
#pragma unroll
    for (int rt = 0; rt < 4; ++rt)
#pragma unroll
      for (int ct = 0; ct < 4; ++ct) acc[rt][ct] = f32x4{0.f, 0.f, 0.f, 0.f};
#pragma unroll
    for (int kc = 0; kc < 2; ++kc)
#pragma unroll
      for (int rt = 0; rt < 4; ++rt)
#pragma unroll
        for (int ct = 0; ct < 4; ++ct)
          acc[rt][ct] = __builtin_amdgcn_mfma_f32_16x16x32_bf16(af[rt][kc], bfv[ct][kc], acc[rt][ct], 0, 0, 0);
    unsigned short* dst = Us[s - 1];
#pragma unroll
    for (int rt = 0; rt < 4; ++rt)
#pragma unroll
      for (int ct = 0; ct < 4; ++ct) {
        int o = ct * 16 + lr;
        int k = kq + rt * 16 + g * 4;
        ushort4 pk;
        pk.x = f2bf(acc[rt][ct][0]); pk.y = f2bf(acc[rt][ct][1]);
        pk.z = f2bf(acc[rt][ct][2]); pk.w = f2bf(acc[rt][ct][3]);
        *(ushort4*)&dst[((size_t)(b * 64 + o) * 128 + l) * 256 + k] = pk;
      }
  }
}

// ---------------- fused 2-hop: out = A @ bf16(A @ Ueven + Uodd); LDS-staged middle ----------------
// grid 512 = (bc=128) x (lq=4); 256 threads = 4 waves; wave owns 64 v'-rows of both hops.
__global__ __launch_bounds__(256) void k_adj2M(const unsigned short* __restrict__ Abf,
                                               const unsigned short* __restrict__ Ueven,
                                               const unsigned short* __restrict__ Uodd,
                                               float* __restrict__ out) {
  __shared__ unsigned short sH[32 * 256];   // [l][v] bf16, byte ^ ((l&7)<<4)
  int lq = blockIdx.x & 3, bc = blockIdx.x >> 2;
  int tid = threadIdx.x, wid = tid >> 6, lane = tid & 63;
  int lr = lane & 15, g = lane >> 4;
  int wbase = wid * 64;
  const unsigned short* aP = Abf + (size_t)(wbase + lr) * 256 + g * 8;
  const unsigned short* bP = Ueven + ((size_t)bc * 128 + lq * 32 + lr) * 256 + g * 8;

  f32x4 acc[4][2];
#pragma unroll
  for (int i = 0; i < 4; ++i)
#pragma unroll
    for (int j = 0; j < 2; ++j) acc[i][j] = f32x4{0.f, 0.f, 0.f, 0.f};
  for (int k0 = 0; k0 < 256; k0 += 32) {
    short8 af[4], bfv[2];
#pragma unroll
    for (int i = 0; i < 4; ++i) af[i] = *(const short8*)(aP + (size_t)i * 16 * 256 + k0);
#pragma unroll
    for (int i = 0; i < 2; ++i) bfv[i] = *(const short8*)(bP + (size_t)i * 16 * 256 + k0);
#pragma unroll
    for (int rm = 0; rm < 4; ++rm)
#pragma unroll
      for (int cn = 0; cn < 2; ++cn)
        acc[rm][cn] = __builtin_amdgcn_mfma_f32_16x16x32_bf16(af[rm], bfv[cn], acc[rm][cn], 0, 0, 0);
  }
  // add Uodd, pack bf16 into swizzled LDS [l][v]
  {
    const unsigned short* aT = Uodd + (size_t)bc * NN + (size_t)(lq * 32) * 256;
#pragma unroll
    for (int rm = 0; rm < 4; ++rm)
#pragma unroll
      for (int cn = 0; cn < 2; ++cn) {
        int l = cn * 16 + lr;
        int v = wbase + rm * 16 + g * 4;
        ushort4 av = *(const ushort4*)&aT[(size_t)l * 256 + v];
        ushort4 pk;
        pk.x = f2bf(acc[rm][cn][0] + bf2f(av.x));
        pk.y = f2bf(acc[rm][cn][1] + bf2f(av.y));
        pk.z = f2bf(acc[rm][cn][2] + bf2f(av.z));
        pk.w = f2bf(acc[rm][cn][3] + bf2f(av.w));
        int bo = ((l * 256 + v) * 2) ^ ((l & 7) << 4);
        *(ushort4*)((char*)sH + bo) = pk;
      }
  }
  __syncthreads();

  f32x4 c2[4][2];
#pragma unroll
  for (int i = 0; i < 4; ++i)
#pragma unroll
    for (int j = 0; j < 2; ++j) c2[i][j] = f32x4{0.f, 0.f, 0.f, 0.f};
  for (int k0 = 0; k0 < 256; k0 += 32) {
    short8 af[4], bfv[2];
#pragma unroll
    for (int i = 0; i < 4; ++i) af[i] = *(const short8*)(aP + (size_t)i * 16 * 256 + k0);
#pragma unroll
    for (int cn = 0; cn < 2; ++cn) {
      int l = cn * 16 + lr;
      int bo = ((l * 256 + k0 + g * 8) * 2) ^ ((l & 7) << 4);
      bfv[cn] = *(const short8*)((char*)sH + bo);
    }
#pragma unroll
    for (int rm = 0; rm < 4; ++rm)
#pragma unroll
      for (int cn = 0; cn < 2; ++cn)
        c2[rm][cn] = __builtin_amdgcn_mfma_f32_16x16x32_bf16(af[rm], bfv[cn], c2[rm][cn], 0, 0, 0);
  }
  float* dst = out + (size_t)bc * NN + lq * 32;
#pragma unroll
  for (int rm = 0; rm < 4; ++rm)
#pragma unroll
    for (int cn = 0; cn < 2; ++cn) {
      int col = cn * 16 + lr;
      int row = wbase + rm * 16 + g * 4;
#pragma unroll
      for (int j = 0; j < 4; ++j)
        dst[(size_t)(row + j) * 128 + col] = c2[rm][cn][j];
    }
}

// ---------------- generic (c,l)-plane transpose per (b,k), optional add + bf16 side output ----------------
__global__ __launch_bounds__(256) void k_tr(const float* __restrict__ src, float* __restrict__ dst,
                                            const float* __restrict__ add,
                                            unsigned short* __restrict__ dstBf,
                                            long sb, long sk, long sc, long sl,
                                            long db, long dk, long dc, long dl, int nC, int nL) {
  int outer = blockIdx.x;
  int b = outer >> 8, k = outer & 255;
  int tilesL = nL >> 5;
  int tC = blockIdx.y / tilesL, tL = blockIdx.y % tilesL;
  int c0 = tC << 5, l0 = tL << 5;
  __shared__ float s[32][33];
  int tx = threadIdx.x & 31, ty = threadIdx.x >> 5;
  const float* sp = src + (long)b * sb + (long)k * sk;
#pragma unroll
  for (int j = 0; j < 4; ++j) {
    int cc = c0 + ty + j * 8;
    s[ty + j * 8][tx] = sp[(long)cc * sc + (long)(l0 + tx) * sl];
  }
  __syncthreads();
  long dbase = (long)b * db + (long)k * dk;
#pragma unroll
  for (int j = 0; j < 4; ++j) {
    int ll = l0 + ty + j * 8;
    long off = dbase + (long)(c0 + tx) * dc + (long)ll * dl;
    float val = s[tx][ty + j * 8];
    if (add) val += add[off];
    dst[off] = val;
    if (dstBf) dstBf[off] = f2bf(val);
  }
}

// ---------------- spatial QKV: Q -> bf16 RM; K,V -> bf16 TRANSPOSED [bl][c][n] ----------------
__global__ __launch_bounds__(256) void k_qkv_s(const float* __restrict__ in,
                                               const float* __restrict__ W0, const float* __restrict__ W1,
                                               const float* __restrict__ W2,
                                               unsigned short* __restrict__ qb,
                                               unsigned short* __restrict__ xkT,
                                               unsigned short* __restrict__ xvT) {
  int r0 = blockIdx.x * 64;
  __shared__ float sInT[64][68];
  __shared__ float sW[3][64][64];
  int t = threadIdx.x;
  for (int i = t; i < 4096; i += 256) {
    int c = i >> 6, o = i & 63;
    sW[0][c][o] = W0[i];
    sW[1][c][o] = W1[i];
    sW[2][c][o] = W2[i];
  }
  for (int i = t; i < 4096; i += 256) {
    int r = i >> 6, c = i & 63;
    sInT[c][r] = in[(size_t)(r0 + r) * 64 + c];
  }
  __syncthreads();
  int col = t & 63, rg = t >> 6;
  int rbase = rg * 16;
  float a0[16], a1[16], a2[16];
#pragma unroll
  for (int i = 0; i < 16; ++i) { a0[i] = 0.f; a1[i] = 0.f; a2[i] = 0.f; }
  for (int c = 0; c < 64; ++c) {
    float w0 = sW[0][c][col], w1 = sW[1][c][col], w2 = sW[2][c][col];
#pragma unroll
    for (int rr = 0; rr < 16; rr += 4) {
      float4 xv = *(const float4*)&sInT[c][rbase + rr];
      a0[rr + 0] += xv.x * w0; a0[rr + 1] += xv.y * w0; a0[rr + 2] += xv.z * w0; a0[rr + 3] += xv.w * w0;
      a1[rr + 0] += xv.x * w1; a1[rr + 1] += xv.y * w1; a1[rr + 2] += xv.z * w1; a1[rr + 3] += xv.w * w1;
      a2[rr + 0] += xv.x * w2; a2[rr + 1] += xv.y * w2; a2[rr + 2] += xv.z * w2; a2[rr + 3] += xv.w * w2;
    }
  }
#pragma unroll
  for (int rr = 0; rr < 16; ++rr)
    qb[(size_t)(r0 + rbase + rr) * 64 + col] = f2bf(a0[rr]);
  int bl = r0 >> 8;
  int nb = (r0 & 255) + rbase;
  unsigned short* kd = xkT + (size_t)bl * 16384 + (size_t)col * 256 + nb;
  unsigned short* vd = xvT + (size_t)bl * 16384 + (size_t)col * 256 + nb;
#pragma unroll
  for (int rr = 0; rr < 16; ++rr) { kd[rr] = f2bf(a1[rr]); vd[rr] = f2bf(a2[rr]); }
}

// ---------------- MFMA sproj ----------------
__global__ __launch_bounds__(256) void k_sprojM(const unsigned short* __restrict__ XkT,
                                                const unsigned short* __restrict__ XvT,
                                                const unsigned short* __restrict__ PkT,
                                                const unsigned short* __restrict__ PvT,
                                                unsigned short* __restrict__ kpb,
                                                unsigned short* __restrict__ vptb) {
  int bl = blockIdx.x;
  int which = blockIdx.y;
  int t = threadIdx.x, w = t >> 6, lane = t & 63;
  int lr = lane & 15, g = lane >> 4;
  const unsigned short* Abase = which ? PvT : XkT + (size_t)bl * 16384;
  const unsigned short* Bbase = which ? XvT + (size_t)bl * 16384 : PkT;
  const unsigned short* aP = Abase + (size_t)(w * 16 + lr) * 256 + g * 8;
  f32x4 acc[4];
#pragma unroll
  for (int ct = 0; ct < 4; ++ct) acc[ct] = f32x4{0.f, 0.f, 0.f, 0.f};
  for (int k0 = 0; k0 < 256; k0 += 32) {
    short8 af = *(const short8*)(aP + k0);
#pragma unroll
    for (int ct = 0; ct < 4; ++ct) {
      short8 bf = *(const short8*)(Bbase + (size_t)(ct * 16 + lr) * 256 + k0 + g * 8);
      acc[ct] = __builtin_amdgcn_mfma_f32_16x16x32_bf16(af, bf, acc[ct], 0, 0, 0);
    }
  }
  if (!which) {
    unsigned short* dst = kpb + (size_t)bl * 4096;
#pragma unroll
    for (int ct = 0; ct < 4; ++ct) {
      int p = ct * 16 + lr;
      int c0 = w * 16 + g * 4;
      ushort4 pk;
      pk.x = f2bf(acc[ct][0]); pk.y = f2bf(acc[ct][1]);
      pk.z = f2bf(acc[ct][2]); pk.w = f2bf(acc[ct][3]);
      *(ushort4*)&dst[(size_t)p * 64 + c0] = pk;
    }
  } else {
    unsigned short* dst = vptb + (size_t)bl * 4096;
#pragma unroll
    for (int ct = 0; ct < 4; ++ct) {
      int c = ct * 16 + lr;
      int p0 = w * 16 + g * 4;
      ushort4 pk;
      pk.x = f2bf(acc[ct][0]); pk.y = f2bf(acc[ct][1]);
      pk.z = f2bf(acc[ct][2]); pk.w = f2bf(acc[ct][3]);
      *(ushort4*)&dst[(size_t)c * 64 + p0] = pk;
    }
  }
}

// ---------------- temporal QKV: Q,K -> bf16 row-major; V -> bf16 TRANSPOSED [bk][c][l] ----------------
__global__ __launch_bounds__(256) void k_qkv_t(const float* __restrict__ in,
                                               const float* __restrict__ W0, const float* __restrict__ W1,
                                               const float* __restrict__ W2,
                                               const float* __restrict__ b0, const float* __restrict__ b1,
                                               const float* __restrict__ b2,
                                               unsigned short* __restrict__ qb,
                                               unsigned short* __restrict__ kb,
                                               unsigned short* __restrict__ vt) {
  int r0 = blockIdx.x * 64;
  __shared__ float sInT[64][68];
  __shared__ float sW[3][64][64];
  int t = threadIdx.x;
  for (int i = t; i < 4096; i += 256) {
    int c = i >> 6, o = i & 63;
    sW[0][c][o] = W0[i];
    sW[1][c][o] = W1[i];
    sW[2][c][o] = W2[i];
  }
  for (int i = t; i < 4096; i += 256) {
    int r = i >> 6, c = i & 63;
    sInT[c][r] = in[(size_t)(r0 + r) * 64 + c];
  }
  __syncthreads();
  int col = t & 63, rg = t >> 6;
  int rbase = rg * 16;
  float a0[16], a1[16], a2[16];
  float bv0 = b0[col], bv1 = b1[col], bv2 = b2[col];
#pragma unroll
  for (int i = 0; i < 16; ++i) { a0[i] = bv0; a1[i] = bv1; a2[i] = bv2; }
  for (int c = 0; c < 64; ++c) {
    float w0 = sW[0][c][col], w1 = sW[1][c][col], w2 = sW[2][c][col];
#pragma unroll
    for (int rr = 0; rr < 16; rr += 4) {
      float4 xv = *(const float4*)&sInT[c][rbase + rr];
      a0[rr + 0] += xv.x * w0; a0[rr + 1] += xv.y * w0; a0[rr + 2] += xv.z * w0; a0[rr + 3] += xv.w * w0;
      a1[rr + 0] += xv.x * w1; a1[rr + 1] += xv.y * w1; a1[rr + 2] += xv.z * w1; a1[rr + 3] += xv.w * w1;
      a2[rr + 0] += xv.x * w2; a2[rr + 1] += xv.y * w2; a2[rr + 2] += xv.z * w2; a2[rr + 3] += xv.w * w2;
    }
  }
#pragma unroll
  for (int rr = 0; rr < 16; ++rr) {
    size_t idx = (size_t)(r0 + rbase + rr) * 64 + col;
    qb[idx] = f2bf(a0[rr]); kb[idx] = f2bf(a1[rr]);
  }
  int bk = r0 >> 7;
  int lbase = (r0 & 127) + rbase;
  unsigned short* vd = vt + (size_t)bk * 8192 + (size_t)col * 128 + lbase;
#pragma unroll
  for (int rr = 0; rr < 16; ++rr) vd[rr] = f2bf(a2[rr]);
}

// ---------------- row-major (R,CIN) @ (CIN,COUT) + bias, optional activation ----------------
template <int CIN, int COUT, int ACT, int ROWS>
__global__ __launch_bounds__(256) void k_rowmm(const float* __restrict__ in,
                                               const float* __restrict__ W,
                                               const float* __restrict__ bias,
                                               float* __restrict__ out) {
  int r0 = blockIdx.x * ROWS;
  __shared__ float sInT[CIN][ROWS + 4];
  __shared__ float sW[CIN][COUT];
  int t = threadIdx.x;
  for (int i = t; i < CIN * COUT; i += 256) ((float*)sW)[i] = W[i];
  for (int i = t; i < ROWS * CIN; i += 256) {
    int r = i / CIN, c = i % CIN;
    sInT[c][r] = in[(size_t)r0 * CIN + i];
  }
  __syncthreads();
  constexpr int NRG = 256 / COUT;
  constexpr int RPT = ROWS / NRG;
  int col = t % COUT, rg = t / COUT;
  int rbase = rg * RPT;
  float acc[RPT];
  float bv = bias ? bias[col] : 0.f;
#pragma unroll
  for (int r = 0; r < RPT; ++r) acc[r] = bv;
  for (int c = 0; c < CIN; ++c) {
    float wv = sW[c][col];
#pragma unroll
    for (int rr = 0; rr < RPT; rr += 4) {
      float4 xv = *(const float4*)&sInT[c][rbase + rr];
      acc[rr] += xv.x * wv; acc[rr + 1] += xv.y * wv;
      acc[rr + 2] += xv.z * wv; acc[rr + 3] += xv.w * wv;
    }
  }
#pragma unroll
  for (int rr = 0; rr < RPT; ++rr) {
    float v = acc[rr];
    if (ACT == 1) v = fmaxf(v, 0.f);
    out[(size_t)(r0 + rbase + rr) * COUT + col] = v;
  }
}

// ---------------- fused LN1 -> FFN(64->8 gelu ->64) -> LN2, row-local; block = 64 rows ----------------
__global__ __launch_bounds__(256) void k_tffn(const float* __restrict__ A, const float* __restrict__ Bz,
                                              const float* __restrict__ l1w, const float* __restrict__ l1b,
                                              const float* __restrict__ l2w, const float* __restrict__ l2b,
                                              const float* __restrict__ ln1g, const float* __restrict__ ln1b,
                                              const float* __restrict__ ln2g, const float* __restrict__ ln2b,
                                              float* __restrict__ outp) {
  int r0 = blockIdx.x * 64;
  __shared__ float sSrc[64][65];
  __shared__ float sH[64][8];
  __shared__ float sW1[64][8];
  __shared__ float sW2[8][64];
  int t = threadIdx.x;
  for (int i = t; i < 512; i += 256) { ((float*)sW1)[i] = l1w[i]; ((float*)sW2)[i] = l2w[i]; }
  int c = t & 63, rg = t >> 6;
  float g1 = ln1g[c], be1 = ln1b[c];
  for (int it = 0; it < 16; ++it) {
    int r = it * 4 + rg;
    size_t idx = (size_t)(r0 + r) * 64 + c;
    float x = A[idx] + Bz[idx];
    float s = x, ss = x * x;
#pragma unroll
    for (int off = 32; off; off >>= 1) { s += __shfl_xor(s, off); ss += __shfl_xor(ss, off); }
    float mu = s * (1.f / 64.f);
    float var = ss * (1.f / 64.f) - mu * mu;
    sSrc[r][c] = (x - mu) * rsqrtf(var + EPSV) * g1 + be1;
  }
  __syncthreads();
#pragma unroll
  for (int p = 0; p < 2; ++p) {
    int idx = t + 256 * p;
    int row = idx >> 3, j = idx & 7;
    float acc = l1b[j];
    for (int cc = 0; cc < 64; ++cc) acc += sSrc[row][cc] * sW1[cc][j];
    acc = 0.5f * acc * (1.f + erff(acc * 0.70710678118654752440f));
    sH[row][j] = acc;
  }
  __syncthreads();
  float g2 = ln2g[c], be2 = ln2b[c];
  float l2bc = l2b[c];
  for (int it = 0; it < 16; ++it) {
    int r = it * 4 + rg;
    float o = l2bc;
#pragma unroll
    for (int j = 0; j < 8; ++j) o += sH[r][j] * sW2[j][c];
    float x = sSrc[r][c] + o;
    float s = x, ss = x * x;
#pragma unroll
    for (int off = 32; off; off >>= 1) { s += __shfl_xor(s, off); ss += __shfl_xor(ss, off); }
    float mu = s * (1.f / 64.f);
    float var = ss * (1.f / 64.f) - mu * mu;
    outp[(size_t)(r0 + r) * 64 + c] = (x - mu) * rsqrtf(var + EPSV) * g2 + be2;
  }
}

// ---------------- per-head MFMA attention: block = 128 q-rows, 8 waves = 8 heads ----------------
template <int NKV, int KVSHIFT>
__global__ __launch_bounds__(512) void k_attnH(const unsigned short* __restrict__ Qb,
                                               const unsigned short* __restrict__ Kb,
                                               const unsigned short* __restrict__ VTb,
                                               float* __restrict__ O) {
  constexpr int NCT = NKV / 16;
  constexpr int NKS = NKV / 32;
  int blk = blockIdx.x;
  const unsigned short* Qp = Qb + (size_t)blk * 128 * 64;
  float* Op = O + (size_t)blk * 128 * 64;
  const unsigned short* Kp = Kb + (size_t)(blk >> KVSHIFT) * NKV * 64;
  const unsigned short* VTp = VTb + (size_t)(blk >> KVSHIFT) * 64 * NKV;
  int t = threadIdx.x;
  int h = t >> 6, lane = t & 63, lr = lane & 15, g = lane >> 4;
  __shared__ unsigned short sP[8][16 * NKV];
  unsigned short* myP = sP[h];

  short8 kbf[NCT];
#pragma unroll
  for (int ct = 0; ct < NCT; ++ct)
    kbf[ct] = *(const short8*)(Kp + (size_t)(ct * 16 + lr) * 64 + h * 8);

  int vr = h * 8 + lr; if (vr > 63) vr = 63;
  short8 vbf[NKS];
#pragma unroll
  for (int ks = 0; ks < NKS; ++ks)
    vbf[ks] = *(const short8*)(VTp + (size_t)vr * NKV + ks * 32 + g * 8);

  for (int mt = 0; mt < 8; ++mt) {
    short8 qa = short8{0, 0, 0, 0, 0, 0, 0, 0};
    if (g == 0) qa = *(const short8*)(Qp + (size_t)(mt * 16 + lr) * 64 + h * 8);

    f32x4 sacc[NCT];
#pragma unroll
    for (int ct = 0; ct < NCT; ++ct) sacc[ct] = f32x4{0.f, 0.f, 0.f, 0.f};
#pragma unroll
    for (int ct = 0; ct < NCT; ++ct)
      sacc[ct] = __builtin_amdgcn_mfma_f32_16x16x32_bf16(qa, kbf[ct], sacc[ct], 0, 0, 0);

    float inv4[4];
#pragma unroll
    for (int reg = 0; reg < 4; ++reg) {
      float s = 0.f;
#pragma unroll
      for (int ct = 0; ct < NCT; ++ct) {
        float e = __expf(sacc[ct][reg] * SCL);
        sacc[ct][reg] = e;
        s += e;
      }
      s += __shfl_xor(s, 1); s += __shfl_xor(s, 2); s += __shfl_xor(s, 4); s += __shfl_xor(s, 8);
      inv4[reg] = 1.f / s;
    }

#pragma unroll
    for (int ct = 0; ct < NCT; ++ct)
#pragma unroll
      for (int reg = 0; reg < 4; ++reg) {
        int row = g * 4 + reg;
        int bo = ((row * NKV + ct * 16 + lr) * 2) ^ ((row & 7) << 4);
        *(unsigned short*)((char*)myP + bo) = f2bf(sacc[ct][reg]);
      }
    __syncthreads();

    f32x4 oacc = f32x4{0.f, 0.f, 0.f, 0.f};
#pragma unroll
    for (int ks = 0; ks < NKS; ++ks) {
      int bo = ((lr * NKV + ks * 32 + g * 8) * 2) ^ ((lr & 7) << 4);
      short8 pa = *(const short8*)((char*)myP + bo);
      oacc = __builtin_amdgcn_mfma_f32_16x16x32_bf16(pa, vbf[ks], oacc, 0, 0, 0);
    }
    if (lr < 8) {
#pragma unroll
      for (int reg = 0; reg < 4; ++reg) {
        int row = mt * 16 + g * 4 + reg;
        Op[(size_t)row * 64 + h * 8 + lr] = oacc[reg] * inv4[reg];
      }
    }
    __syncthreads();
  }
}

// ---------------- GroupNorm stats: up to 5 summed inputs, optional sum write-back ----------------
__global__ __launch_bounds__(256) void k_gn_part(const float* __restrict__ p0, const float* __restrict__ p1,
                                                 const float* __restrict__ p2, const float* __restrict__ p3,
                                                 const float* __restrict__ p4,
                                                 float* __restrict__ sumOut,
                                                 float* __restrict__ part) {
  int bg = blockIdx.y, blk = blockIdx.x, t = threadIdx.x;
  size_t start = (size_t)bg * ((size_t)CPG * NN) + (size_t)blk * 8192;
  const float4* q0 = (const float4*)(p0 + start);
  const float4* q1 = p1 ? (const float4*)(p1 + start) : nullptr;
  const float4* q2 = p2 ? (const float4*)(p2 + start) : nullptr;
  const float4* q3 = p3 ? (const float4*)(p3 + start) : nullptr;
  const float4* q4 = p4 ? (const float4*)(p4 + start) : nullptr;
  float4* so = sumOut ? (float4*)(sumOut + start) : nullptr;
  float s = 0.f, ss = 0.f;
  for (int i = t; i < 2048; i += 256) {
    float4 x = q0[i];
    if (q1) { float4 y4 = q1[i]; x.x += y4.x; x.y += y4.y; x.z += y4.z; x.w += y4.w; }
    if (q2) { float4 y4 = q2[i]; x.x += y4.x; x.y += y4.y; x.z += y4.z; x.w += y4.w; }
    if (q3) { float4 y4 = q3[i]; x.x += y4.x; x.y += y4.y; x.z += y4.z; x.w += y4.w; }
    if (q4) { float4 y4 = q4[i]; x.x += y4.x; x.y += y4.y; x.z += y4.z; x.w += y4.w; }
    if (so) so[i] = x;
    s += x.x + x.y + x.z + x.w;
    ss += x.x * x.x + x.y * x.y + x.z * x.z + x.w * x.w;
  }
  __shared__ float rs[256], rq[256];
  rs[t] = s; rq[t] = ss; __syncthreads();
  for (int off = 128; off; off >>= 1) { if (t < off) { rs[t] += rs[t + off]; rq[t] += rq[t + off]; } __syncthreads(); }
  if (t == 0) { part[(bg * 64 + blk) * 2] = rs[0]; part[(bg * 64 + blk) * 2 + 1] = rq[0]; }
}

// out = GN(p0[+p1]) (+ q0) (+ q1) — reduces 64 partials per block (gn_final folded in)
__global__ __launch_bounds__(256) void k_gn_apply(const float* __restrict__ p0, const float* __restrict__ p1,
                                                  const float* __restrict__ part, const float* __restrict__ g,
                                                  const float* __restrict__ be,
                                                  const float* __restrict__ q0, const float* __restrict__ q1,
                                                  float* __restrict__ out) {
  size_t i4 = (size_t)blockIdx.x * 256 + threadIdx.x;
  size_t i = i4 * 4;
  int chan = (int)(i >> 15) & 63;
  int bg = (int)(i >> 19);
  __shared__ float smu, srr;
  int t = threadIdx.x;
  if (t < 64) {
    float s = part[(bg * 64 + t) * 2], ss = part[(bg * 64 + t) * 2 + 1];
#pragma unroll
    for (int off = 32; off; off >>= 1) { s += __shfl_xor(s, off); ss += __shfl_xor(ss, off); }
    if (t == 0) {
      float inv = 1.f / (float)((size_t)CPG * NN);
      float mu = s * inv;
      float var = ss * inv - mu * mu;
      smu = mu; srr = rsqrtf(var + EPSV);
    }
  }
  __syncthreads();
  float mu = smu, rr = srr;
  float4 x = ((const float4*)p0)[i4];
  if (p1) { float4 y4 = ((const float4*)p1)[i4]; x.x += y4.x; x.y += y4.y; x.z += y4.z; x.w += y4.w; }
  float gc = g[chan], bc = be[chan];
  float4 v;
  v.x = (x.x - mu) * rr * gc + bc;
  v.y = (x.y - mu) * rr * gc + bc;
  v.z = (x.z - mu) * rr * gc + bc;
  v.w = (x.w - mu) * rr * gc + bc;
  if (q0) { float4 y4 = ((const float4*)q0)[i4]; v.x += y4.x; v.y += y4.y; v.z += y4.z; v.w += y4.w; }
  if (q1) { float4 y4 = ((const float4*)q1)[i4]; v.x += y4.x; v.y += y4.y; v.z += y4.z; v.w += y4.w; }
  ((float4*)out)[i4] = v;
}

extern "C" void kernel_launch(void* const* d_in, const int* in_sizes, int n_in,
                              void* d_out, int out_size, void* d_ws, size_t ws_size,
                              hipStream_t stream) {
  (void)in_sizes; (void)n_in; (void)out_size; (void)ws_size;
  const float* y     = (const float*)d_in[0];
  const float* a1    = (const float*)d_in[1];
  const float* a2    = (const float*)d_in[2];
  const float* nv1   = (const float*)d_in[3];
  const float* nv2   = (const float*)d_in[4];
  const float* gcn_w = (const float*)d_in[5];
  const float* gcn_b = (const float*)d_in[6];
  const float* s_wq  = (const float*)d_in[7];
  const float* s_wk  = (const float*)d_in[8];
  const float* s_wv  = (const float*)d_in[9];
  const float* s_pk  = (const float*)d_in[10];
  const float* s_pv  = (const float*)d_in[11];
  const float* s_wo  = (const float*)d_in[12];
  const float* s_bo  = (const float*)d_in[13];
  const float* t_wq  = (const float*)d_in[14];
  const float* t_wk  = (const float*)d_in[15];
  const float* t_wv  = (const float*)d_in[16];
  const float* t_bq  = (const float*)d_in[17];
  const float* t_bk  = (const float*)d_in[18];
  const float* t_bv  = (const float*)d_in[19];
  const float* t_wo  = (const float*)d_in[20];
  const float* t_bo  = (const float*)d_in[21];
  const float* t_l1w = (const float*)d_in[22];
  const float* t_l1b = (const float*)d_in[23];
  const float* t_l2w = (const float*)d_in[24];
  const float* t_l2b = (const float*)d_in[25];
  const float* ln1g  = (const float*)d_in[26];
  const float* ln1b  = (const float*)d_in[27];
  const float* ln2g  = (const float*)d_in[28];
  const float* ln2b  = (const float*)d_in[29];
  const float* gnlg  = (const float*)d_in[30];
  const float* gnlb  = (const float*)d_in[31];
  const float* gnsg  = (const float*)d_in[32];
  const float* gnsb  = (const float*)d_in[33];
  const float* gntg  = (const float*)d_in[34];
  const float* gntb  = (const float*)d_in[35];
  const float* ff1w  = (const float*)d_in[36];
  const float* ff1b  = (const float*)d_in[37];
  const float* ff2w  = (const float*)d_in[38];
  const float* ff2b  = (const float*)d_in[39];
  const float* gn2g  = (const float*)d_in[40];
  const float* gn2b  = (const float*)d_in[41];

  float* ws = (float*)d_ws;
  float* adp   = ws;
  float* part  = ws + 65536;
  unsigned short* a1_bf   = (unsigned short*)(ws + 131072);
  unsigned short* a2_bf   = (unsigned short*)(ws + 163840);
  unsigned short* adp_bf  = (unsigned short*)(ws + 196608);
  unsigned short* gcnw_bf = (unsigned short*)(ws + 229376);
  unsigned short* xs_bf   = (unsigned short*)(ws + 262144);
  // spatial attn scratch (post-GCN):
  unsigned short* kpb  = (unsigned short*)(ws + 131072);
  unsigned short* PkT  = (unsigned short*)(ws + 720896);
  unsigned short* PvT  = (unsigned short*)(ws + 729088);
  unsigned short* vptb = (unsigned short*)(ws + 1179648);
  const size_t SLOT = 4194304;
  float* G0 = ws + SLOT * 1;
  float* G1 = ws + SLOT * 2;
  float* G2 = ws + SLOT * 3;
  float* G3 = ws + SLOT * 4;
  float* G4 = ws + SLOT * 5;
  float* G5 = ws + SLOT * 6;
  float* G6 = ws + SLOT * 7;
  unsigned short* U1 = (unsigned short*)G3;
  unsigned short* U2 = (unsigned short*)G3 + 4194304;
  unsigned short* U3 = (unsigned short*)G4;
  unsigned short* U4 = (unsigned short*)G4 + 4194304;
  unsigned short* U5 = (unsigned short*)G5;
  unsigned short* U6 = (unsigned short*)G5 + 4194304;
  unsigned short* xkT = (unsigned short*)G4;   // spatial K^T bf16 [bl][c][n]
  unsigned short* xvT = (unsigned short*)G5;   // spatial V^T bf16
  float* out = (float*)d_out;

  const long BS = 2097152;

  // ---- adaptive adjacency + bf16 casts ----
  k_adp<<<256, 256, 0, stream>>>(nv1, nv2, adp);
  k_cast3<<<640, 256, 0, stream>>>(a1, a2, gcn_w, a1_bf, a2_bf, gcnw_bf);
  k_cast<<<256, 256, 0, stream>>>(adp, adp_bf);

  // ---- xs (B,L,K,C) fp32 + bf16 ----
  k_tr<<<dim3(512, 8), 256, 0, stream>>>(y, G2, nullptr, xs_bf, BS, 128, 32768, 1, BS, 64, 1, 16384, 64, 128);

  // ---- AdaptiveGCN: U_s = W_s X; Q_f = A_f(A_f U_even + U_odd) fused in one kernel each ----
  k_mix0<<<1024, 64, 0, stream>>>(xs_bf, gcnw_bf, gcn_b, G1);
  k_mix6<<<dim3(1024, 3), 64, 0, stream>>>(xs_bf, gcnw_bf, U1, U2, U3, U4, U5, U6);
  k_adj2M<<<512, 256, 0, stream>>>(a1_bf, U2, U1, G0);   // Q1
  k_adj2M<<<512, 256, 0, stream>>>(a2_bf, U4, U3, G6);   // Q2
  k_adj2M<<<512, 256, 0, stream>>>(adp_bf, U6, U5, G5);  // Q3 (overwrites U5/U6 after read... G5 holds U5/U6!)
  k_gn_part<<<dim3(64, 8), 256, 0, stream>>>(y, G1, G0, G6, G5, G3, part);
  k_gn_apply<<<4096, 256, 0, stream>>>(G3, nullptr, part, gnlg, gnlb, nullptr, nullptr, G0);

  // ---- Linformer spatial attention (G2 = xs) ----
  k_castP<<<dim3(16, 2), 256, 0, stream>>>(s_pk, s_pv, PkT, PvT);
  k_qkv_s<<<1024, 256, 0, stream>>>(G2, s_wq, s_wk, s_wv, (unsigned short*)G3, xkT, xvT);
  k_sprojM<<<dim3(256, 2), 256, 0, stream>>>(xkT, xvT, PkT, PvT, kpb, vptb);
  k_attnH<64, 1><<<512, 512, 0, stream>>>((unsigned short*)G3, kpb, vptb, G6);
  k_rowmm<64, 64, 0, 64><<<1024, 256, 0, stream>>>(G6, s_wo, s_bo, G4);
  k_tr<<<dim3(512, 8), 256, 0, stream>>>(G4, G1, y, nullptr, BS, 64, 16384, 1, BS, 128, 1, 32768, 128, 64);
  k_gn_part<<<dim3(64, 8), 256, 0, stream>>>(G1, nullptr, nullptr, nullptr, nullptr, nullptr, part);
  k_gn_apply<<<4096, 256, 0, stream>>>(G1, nullptr, part, gnsg, gnsb, nullptr, nullptr, G1);

  // ---- temporal transformer layer ----
  k_tr<<<dim3(512, 8), 256, 0, stream>>>(y, G2, nullptr, nullptr, BS, 128, 32768, 1, BS, 8192, 1, 64, 64, 128);
  k_qkv_t<<<1024, 256, 0, stream>>>(G2, t_wq, t_wk, t_wv, t_bq, t_bk, t_bv,
                                    (unsigned short*)G3, (unsigned short*)G4, (unsigned short*)G5);
  k_attnH<128, 0><<<512, 512, 0, stream>>>((unsigned short*)G3, (unsigned short*)G4, (unsigned short*)G5, G6);
  k_rowmm<64, 64, 0, 64><<<1024, 256, 0, stream>>>(G6, t_wo, t_bo, G3);
  k_tffn<<<1024, 256, 0, stream>>>(G2, G3, t_l1w, t_l1b, t_l2w, t_l2b,
                                   ln1g, ln1b, ln2g, ln2b, G6);
  k_tr<<<dim3(512, 8), 256, 0, stream>>>(G6, G2, y, nullptr, BS, 8192, 64, 1, BS, 128, 1, 32768, 128, 64);
  k_gn_part<<<dim3(64, 8), 256, 0, stream>>>(G2, nullptr, nullptr, nullptr, nullptr, nullptr, part);
  k_gn_apply<<<4096, 256, 0, stream>>>(G2, nullptr, part, gntg, gntb, G0, G1, G3);

  // ---- fuse + channel FFN + final GroupNorm ----
  k_tr<<<dim3(512, 8), 256, 0, stream>>>(G3, G4, nullptr, nullptr, BS, 128, 32768, 1, BS, 8192, 1, 64, 64, 128);
  k_rowmm<64, 128, 1, 64><<<1024, 256, 0, stream>>>(G4, ff1w, ff1b, G5);
  k_rowmm<128, 64, 0, 32><<<2048, 256, 0, stream>>>(G5, ff2w, ff2b, G4);
  k_tr<<<dim3(512, 8), 256, 0, stream>>>(G4, out, G3, nullptr, BS, 8192, 64, 1, BS, 128, 1, 32768, 128, 64);
  k_gn_part<<<dim3(64, 8), 256, 0, stream>>>(out, nullptr, nullptr, nullptr, nullptr, nullptr, part);
  k_gn_apply<<<4096, 256, 0, stream>>>(out, nullptr, part, gn2g, gn2b, nullptr, nullptr, out);
}

// Round 16
// 434.451 us; speedup vs baseline: 1.4943x; 1.1168x over previous
//
#include <hip/hip_runtime.h>
#include <math.h>

constexpr int CC = 64, KK = 256, LL = 128;
constexpr int NN = KK * LL;          // 32768
constexpr int PR = 64;               // Linformer projection
constexpr int CPG = 16;              // channels per group (C / 4)
constexpr float EPSV = 1e-5f;
constexpr float SCL = 0.35355339059327373f;  // 1/sqrt(8)

typedef __attribute__((ext_vector_type(8))) short short8;      // 8 bf16 (4 VGPR)
typedef __attribute__((ext_vector_type(4))) float f32x4;       // MFMA 16x16 acc

__device__ __forceinline__ unsigned short f2bf(float x) {
  union { float f; unsigned int u; } v; v.f = x;
  unsigned int r = (v.u + 0x7FFFu + ((v.u >> 16) & 1u)) >> 16;
  return (unsigned short)r;
}
__device__ __forceinline__ float bf2f(unsigned short x) {
  union { unsigned int u; float f; } v; v.u = ((unsigned int)x) << 16;
  return v.f;
}

// ---------------- adaptive adjacency: softmax(relu(nv1@nv2), axis=1) ----------------
__global__ __launch_bounds__(256) void k_adp(const float* __restrict__ nv1,
                                             const float* __restrict__ nv2,
                                             float* __restrict__ adp) {
  int w = blockIdx.x, v = threadIdx.x;
  float s = 0.f;
  for (int d = 0; d < 10; ++d) s += nv1[w * 10 + d] * nv2[d * KK + v];
  s = fmaxf(s, 0.f);
  __shared__ float red[256];
  red[v] = s; __syncthreads();
  for (int off = 128; off; off >>= 1) { if (v < off) red[v] = fmaxf(red[v], red[v + off]); __syncthreads(); }
  float m = red[0]; __syncthreads();
  float e = expf(s - m);
  red[v] = e; __syncthreads();
  for (int off = 128; off; off >>= 1) { if (v < off) red[v] += red[v + off]; __syncthreads(); }
  adp[w * KK + v] = e / red[0];
}

// ---------------- fp32 -> bf16 cast (single range) ----------------
__global__ __launch_bounds__(256) void k_cast(const float* __restrict__ src,
                                              unsigned short* __restrict__ dst) {
  int i = blockIdx.x * 256 + threadIdx.x;
  dst[i] = f2bf(src[i]);
}

// ---------------- fused cast of a1 + a2 + gcn_w ----------------
__global__ __launch_bounds__(256) void k_cast3(const float* __restrict__ s0, const float* __restrict__ s1,
                                               const float* __restrict__ s2,
                                               unsigned short* __restrict__ d0, unsigned short* __restrict__ d1,
                                               unsigned short* __restrict__ d2) {
  int i = blockIdx.x * 256 + threadIdx.x;
  if (i < 65536) d0[i] = f2bf(s0[i]);
  else if (i < 131072) d1[i - 65536] = f2bf(s1[i - 65536]);
  else if (i < 159744) d2[i - 131072] = f2bf(s2[i - 131072]);
}

// ---------------- transpose-cast of s_wo(64x64), t_wo(64x64), ff1w(64x128), ff2w(128x64) -> [out][in] bf16 ----------------
__global__ __launch_bounds__(256) void k_castWT(const float* __restrict__ swo, const float* __restrict__ two,
                                                const float* __restrict__ f1, const float* __restrict__ f2,
                                                unsigned short* __restrict__ swoT, unsigned short* __restrict__ twoT,
                                                unsigned short* __restrict__ ff1T, unsigned short* __restrict__ ff2T) {
  int i = blockIdx.x * 256 + threadIdx.x;
  if (i < 4096) { int r = i >> 6, c = i & 63; swoT[c * 64 + r] = f2bf(swo[i]); }
  else if (i < 8192) { int j = i - 4096; int r = j >> 6, c = j & 63; twoT[c * 64 + r] = f2bf(two[j]); }
  else if (i < 16384) { int j = i - 8192; int r = j >> 7, c = j & 127; ff1T[c * 64 + r] = f2bf(f1[j]); }
  else if (i < 24576) { int j = i - 16384; int r = j >> 6, c = j & 63; ff2T[c * 128 + r] = f2bf(f2[j]); }
}

// ---------------- transpose-cast P (256 x 64) -> PT bf16 (64 x 256); grid (16, 2) ----------------
__global__ __launch_bounds__(256) void k_castP(const float* __restrict__ P0, const float* __restrict__ P1,
                                               unsigned short* __restrict__ T0, unsigned short* __restrict__ T1) {
  const float* P = blockIdx.y ? P1 : P0;
  unsigned short* T = blockIdx.y ? T1 : T0;
  int tv = blockIdx.x >> 1, tc = blockIdx.x & 1;
  int n0 = tv * 32, c0 = tc * 32;
  __shared__ float s[32][33];
  int tx = threadIdx.x & 31, ty = threadIdx.x >> 5;
#pragma unroll
  for (int j = 0; j < 4; ++j)
    s[ty + j * 8][tx] = P[(size_t)(n0 + ty + j * 8) * 64 + c0 + tx];
  __syncthreads();
#pragma unroll
  for (int j = 0; j < 4; ++j)
    T[(size_t)(c0 + ty + j * 8) * 256 + n0 + tx] = f2bf(s[tx][ty + j * 8]);
}

// ---------------- s0 term: s0[b,o,k,l] = bias[o] + sum_c W0[o][c]*xs[(b,l,k)][c] ----------------
__global__ __launch_bounds__(64) void k_mix0(const unsigned short* __restrict__ Xbf,
                                             const unsigned short* __restrict__ Wbf,
                                             const float* __restrict__ bias,
                                             float* __restrict__ s0) {
  int pb = blockIdx.x;
  int lh = pb & 1;
  int k = (pb >> 1) & 255;
  int b = pb >> 9;
  int lane = threadIdx.x;
  int lr = lane & 15, g = lane >> 4;
  short8 af[4][2], bfv[4][2];
#pragma unroll
  for (int ot = 0; ot < 4; ++ot)
#pragma unroll
    for (int kc = 0; kc < 2; ++kc)
      af[ot][kc] = *(const short8*)(Wbf + (size_t)(ot * 16 + lr) * 448 + kc * 32 + g * 8);
#pragma unroll
  for (int ct = 0; ct < 4; ++ct)
#pragma unroll
    for (int kc = 0; kc < 2; ++kc)
      bfv[ct][kc] = *(const short8*)(Xbf + ((size_t)(b * 128 + lh * 64 + ct * 16 + lr) * 256 + k) * 64 + kc * 32 + g * 8);
  f32x4 acc[4][4];
#pragma unroll
  for (int ot = 0; ot < 4; ++ot)
#pragma unroll
    for (int ct = 0; ct < 4; ++ct) acc[ot][ct] = f32x4{0.f, 0.f, 0.f, 0.f};
#pragma unroll
  for (int kc = 0; kc < 2; ++kc)
#pragma unroll
    for (int ot = 0; ot < 4; ++ot)
#pragma unroll
      for (int ct = 0; ct < 4; ++ct)
        acc[ot][ct] = __builtin_amdgcn_mfma_f32_16x16x32_bf16(af[ot][kc], bfv[ct][kc], acc[ot][ct], 0, 0, 0);
#pragma unroll
  for (int ot = 0; ot < 4; ++ot)
#pragma unroll
    for (int ct = 0; ct < 4; ++ct) {
#pragma unroll
      for (int reg = 0; reg < 4; ++reg) {
        int o = ot * 16 + g * 4 + reg;
        s0[(size_t)(b * 64 + o) * NN + (size_t)k * 128 + lh * 64 + ct * 16 + lr] = acc[ot][ct][reg] + bias[o];
      }
    }
}

// ---------------- U terms: U_s[(b*64+o)][l][k] bf16; blockIdx.y picks s-pair ----------------
__global__ __launch_bounds__(64) void k_mix6(const unsigned short* __restrict__ Xbf,
                                             const unsigned short* __restrict__ Wbf,
                                             unsigned short* __restrict__ U1, unsigned short* __restrict__ U2,
                                             unsigned short* __restrict__ U3, unsigned short* __restrict__ U4,
                                             unsigned short* __restrict__ U5, unsigned short* __restrict__ U6) {
  unsigned short* Us[6] = {U1, U2, U3, U4, U5, U6};
  int pb = blockIdx.x;
  int sy = blockIdx.y;
  int b = pb >> 9;
  int rem = pb & 511;
  int l = rem >> 2;
  int kq = (rem & 3) * 64;
  size_t posbase = ((size_t)(b * 128 + l)) * 256 + kq;
  int lane = threadIdx.x;
  int lr = lane & 15, g = lane >> 4;

  short8 af[4][2];
#pragma unroll
  for (int rt = 0; rt < 4; ++rt)
#pragma unroll
    for (int kc = 0; kc < 2; ++kc)
      af[rt][kc] = *(const short8*)(Xbf + (posbase + rt * 16 + lr) * 64 + kc * 32 + g * 8);

  for (int si = 0; si < 2; ++si) {
    int s = sy * 2 + 1 + si;
    short8 bfv[4][2];
#pragma unroll
    for (int ct = 0; ct < 4; ++ct)
#pragma unroll
      for (int kc = 0; kc < 2; ++kc)
        bfv[ct][kc] = *(const short8*)(Wbf + (size_t)(ct * 16 + lr) * 448 + s * 64 + kc * 32 + g * 8);
    f32x4 acc[4][4];
#pragma unroll
    for (int rt = 0; rt < 4; ++rt)
#pragma unroll
      for (int ct = 0; ct < 4; ++ct) acc[rt][ct] = f32x4{0.f, 0.f, 0.f, 0.f};
#pragma unroll
    for (int kc = 0; kc < 2; ++kc)
#pragma unroll
      for (int rt = 0; rt < 4; ++rt)
#pragma unroll
        for (int ct = 0; ct < 4; ++ct)
          acc[rt][ct] = __builtin_amdgcn_mfma_f32_16x16x32_bf16(af[rt][kc], bfv[ct][kc], acc[rt][ct], 0, 0, 0);
    unsigned short* dst = Us[s - 1];
#pragma unroll
    for (int rt = 0; rt < 4; ++rt)
#pragma unroll
      for (int ct = 0; ct < 4; ++ct) {
        int o = ct * 16 + lr;
        int k = kq + rt * 16 + g * 4;
        ushort4 pk;
        pk.x = f2bf(acc[rt][ct][0]); pk.y = f2bf(acc[rt][ct][1]);
        pk.z = f2bf(acc[rt][ct][2]); pk.w = f2bf(acc[rt][ct][3]);
        *(ushort4*)&dst[((size_t)(b * 64 + o) * 128 + l) * 256 + k] = pk;
      }
  }
}

// ---------------- fused 2-hop: out = A @ bf16(A @ Ueven + Uodd); LDS-staged middle ----------------
__global__ __launch_bounds__(256) void k_adj2M(const unsigned short* __restrict__ Abf,
                                               const unsigned short* __restrict__ Ueven,
                                               const unsigned short* __restrict__ Uodd,
                                               float* __restrict__ out) {
  __shared__ unsigned short sH[32 * 256];
  int lq = blockIdx.x & 3, bc = blockIdx.x >> 2;
  int tid = threadIdx.x, wid = tid >> 6, lane = tid & 63;
  int lr = lane & 15, g = lane >> 4;
  int wbase = wid * 64;
  const unsigned short* aP = Abf + (size_t)(wbase + lr) * 256 + g * 8;
  const unsigned short* bP = Ueven + ((size_t)bc * 128 + lq * 32 + lr) * 256 + g * 8;

  f32x4 acc[4][2];
#pragma unroll
  for (int i = 0; i < 4; ++i)
#pragma unroll
    for (int j = 0; j < 2; ++j) acc[i][j] = f32x4{0.f, 0.f, 0.f, 0.f};
  for (int k0 = 0; k0 < 256; k0 += 32) {
    short8 af[4], bfv[2];
#pragma unroll
    for (int i = 0; i < 4; ++i) af[i] = *(const short8*)(aP + (size_t)i * 16 * 256 + k0);
#pragma unroll
    for (int i = 0; i < 2; ++i) bfv[i] = *(const short8*)(bP + (size_t)i * 16 * 256 + k0);
#pragma unroll
    for (int rm = 0; rm < 4; ++rm)
#pragma unroll
      for (int cn = 0; cn < 2; ++cn)
        acc[rm][cn] = __builtin_amdgcn_mfma_f32_16x16x32_bf16(af[rm], bfv[cn], acc[rm][cn], 0, 0, 0);
  }
  {
    const unsigned short* aT = Uodd + (size_t)bc * NN + (size_t)(lq * 32) * 256;
#pragma unroll
    for (int rm = 0; rm < 4; ++rm)
#pragma unroll
      for (int cn = 0; cn < 2; ++cn) {
        int l = cn * 16 + lr;
        int v = wbase + rm * 16 + g * 4;
        ushort4 av = *(const ushort4*)&aT[(size_t)l * 256 + v];
        ushort4 pk;
        pk.x = f2bf(acc[rm][cn][0] + bf2f(av.x));
        pk.y = f2bf(acc[rm][cn][1] + bf2f(av.y));
        pk.z = f2bf(acc[rm][cn][2] + bf2f(av.z));
        pk.w = f2bf(acc[rm][cn][3] + bf2f(av.w));
        int bo = ((l * 256 + v) * 2) ^ ((l & 7) << 4);
        *(ushort4*)((char*)sH + bo) = pk;
      }
  }
  __syncthreads();

  f32x4 c2[4][2];
#pragma unroll
  for (int i = 0; i < 4; ++i)
#pragma unroll
    for (int j = 0; j < 2; ++j) c2[i][j] = f32x4{0.f, 0.f, 0.f, 0.f};
  for (int k0 = 0; k0 < 256; k0 += 32) {
    short8 af[4], bfv[2];
#pragma unroll
    for (int i = 0; i < 4; ++i) af[i] = *(const short8*)(aP + (size_t)i * 16 * 256 + k0);
#pragma unroll
    for (int cn = 0; cn < 2; ++cn) {
      int l = cn * 16 + lr;
      int bo = ((l * 256 + k0 + g * 8) * 2) ^ ((l & 7) << 4);
      bfv[cn] = *(const short8*)((char*)sH + bo);
    }
#pragma unroll
    for (int rm = 0; rm < 4; ++rm)
#pragma unroll
      for (int cn = 0; cn < 2; ++cn)
        c2[rm][cn] = __builtin_amdgcn_mfma_f32_16x16x32_bf16(af[rm], bfv[cn], c2[rm][cn], 0, 0, 0);
  }
  float* dst = out + (size_t)bc * NN + lq * 32;
#pragma unroll
  for (int rm = 0; rm < 4; ++rm)
#pragma unroll
    for (int cn = 0; cn < 2; ++cn) {
      int col = cn * 16 + lr;
      int row = wbase + rm * 16 + g * 4;
#pragma unroll
      for (int j = 0; j < 4; ++j)
        dst[(size_t)(row + j) * 128 + col] = c2[rm][cn][j];
    }
}

// ---------------- generic (c,l)-plane transpose per (b,k); optional dst/add/bf16 outputs ----------------
__global__ __launch_bounds__(256) void k_tr(const float* __restrict__ src, float* __restrict__ dst,
                                            const float* __restrict__ add,
                                            unsigned short* __restrict__ dstBf,
                                            long sb, long sk, long sc, long sl,
                                            long db, long dk, long dc, long dl, int nC, int nL) {
  int outer = blockIdx.x;
  int b = outer >> 8, k = outer & 255;
  int tilesL = nL >> 5;
  int tC = blockIdx.y / tilesL, tL = blockIdx.y % tilesL;
  int c0 = tC << 5, l0 = tL << 5;
  __shared__ float s[32][33];
  int tx = threadIdx.x & 31, ty = threadIdx.x >> 5;
  const float* sp = src + (long)b * sb + (long)k * sk;
#pragma unroll
  for (int j = 0; j < 4; ++j) {
    int cc = c0 + ty + j * 8;
    s[ty + j * 8][tx] = sp[(long)cc * sc + (long)(l0 + tx) * sl];
  }
  __syncthreads();
  long dbase = (long)b * db + (long)k * dk;
#pragma unroll
  for (int j = 0; j < 4; ++j) {
    int ll = l0 + ty + j * 8;
    long off = dbase + (long)(c0 + tx) * dc + (long)ll * dl;
    float val = s[tx][ty + j * 8];
    if (add) val += add[off];
    if (dst) dst[off] = val;
    if (dstBf) dstBf[off] = f2bf(val);
  }
}

// ---------------- spatial QKV: Q -> bf16 RM; K,V -> bf16 TRANSPOSED [bl][c][n] ----------------
__global__ __launch_bounds__(256) void k_qkv_s(const float* __restrict__ in,
                                               const float* __restrict__ W0, const float* __restrict__ W1,
                                               const float* __restrict__ W2,
                                               unsigned short* __restrict__ qb,
                                               unsigned short* __restrict__ xkT,
                                               unsigned short* __restrict__ xvT) {
  int r0 = blockIdx.x * 64;
  __shared__ float sInT[64][68];
  __shared__ float sW[3][64][64];
  int t = threadIdx.x;
  for (int i = t; i < 4096; i += 256) {
    int c = i >> 6, o = i & 63;
    sW[0][c][o] = W0[i];
    sW[1][c][o] = W1[i];
    sW[2][c][o] = W2[i];
  }
  for (int i = t; i < 4096; i += 256) {
    int r = i >> 6, c = i & 63;
    sInT[c][r] = in[(size_t)(r0 + r) * 64 + c];
  }
  __syncthreads();
  int col = t & 63, rg = t >> 6;
  int rbase = rg * 16;
  float a0[16], a1[16], a2[16];
#pragma unroll
  for (int i = 0; i < 16; ++i) { a0[i] = 0.f; a1[i] = 0.f; a2[i] = 0.f; }
  for (int c = 0; c < 64; ++c) {
    float w0 = sW[0][c][col], w1 = sW[1][c][col], w2 = sW[2][c][col];
#pragma unroll
    for (int rr = 0; rr < 16; rr += 4) {
      float4 xv = *(const float4*)&sInT[c][rbase + rr];
      a0[rr + 0] += xv.x * w0; a0[rr + 1] += xv.y * w0; a0[rr + 2] += xv.z * w0; a0[rr + 3] += xv.w * w0;
      a1[rr + 0] += xv.x * w1; a1[rr + 1] += xv.y * w1; a1[rr + 2] += xv.z * w1; a1[rr + 3] += xv.w * w1;
      a2[rr + 0] += xv.x * w2; a2[rr + 1] += xv.y * w2; a2[rr + 2] += xv.z * w2; a2[rr + 3] += xv.w * w2;
    }
  }
#pragma unroll
  for (int rr = 0; rr < 16; ++rr)
    qb[(size_t)(r0 + rbase + rr) * 64 + col] = f2bf(a0[rr]);
  int bl = r0 >> 8;
  int nb = (r0 & 255) + rbase;
  unsigned short* kd = xkT + (size_t)bl * 16384 + (size_t)col * 256 + nb;
  unsigned short* vd = xvT + (size_t)bl * 16384 + (size_t)col * 256 + nb;
#pragma unroll
  for (int rr = 0; rr < 16; ++rr) { kd[rr] = f2bf(a1[rr]); vd[rr] = f2bf(a2[rr]); }
}

// ---------------- MFMA sproj ----------------
__global__ __launch_bounds__(256) void k_sprojM(const unsigned short* __restrict__ XkT,
                                                const unsigned short* __restrict__ XvT,
                                                const unsigned short* __restrict__ PkT,
                                                const unsigned short* __restrict__ PvT,
                                                unsigned short* __restrict__ kpb,
                                                unsigned short* __restrict__ vptb) {
  int bl = blockIdx.x;
  int which = blockIdx.y;
  int t = threadIdx.x, w = t >> 6, lane = t & 63;
  int lr = lane & 15, g = lane >> 4;
  const unsigned short* Abase = which ? PvT : XkT + (size_t)bl * 16384;
  const unsigned short* Bbase = which ? XvT + (size_t)bl * 16384 : PkT;
  const unsigned short* aP = Abase + (size_t)(w * 16 + lr) * 256 + g * 8;
  f32x4 acc[4];
#pragma unroll
  for (int ct = 0; ct < 4; ++ct) acc[ct] = f32x4{0.f, 0.f, 0.f, 0.f};
  for (int k0 = 0; k0 < 256; k0 += 32) {
    short8 af = *(const short8*)(aP + k0);
#pragma unroll
    for (int ct = 0; ct < 4; ++ct) {
      short8 bf = *(const short8*)(Bbase + (size_t)(ct * 16 + lr) * 256 + k0 + g * 8);
      acc[ct] = __builtin_amdgcn_mfma_f32_16x16x32_bf16(af, bf, acc[ct], 0, 0, 0);
    }
  }
  if (!which) {
    unsigned short* dst = kpb + (size_t)bl * 4096;
#pragma unroll
    for (int ct = 0; ct < 4; ++ct) {
      int p = ct * 16 + lr;
      int c0 = w * 16 + g * 4;
      ushort4 pk;
      pk.x = f2bf(acc[ct][0]); pk.y = f2bf(acc[ct][1]);
      pk.z = f2bf(acc[ct][2]); pk.w = f2bf(acc[ct][3]);
      *(ushort4*)&dst[(size_t)p * 64 + c0] = pk;
    }
  } else {
    unsigned short* dst = vptb + (size_t)bl * 4096;
#pragma unroll
    for (int ct = 0; ct < 4; ++ct) {
      int c = ct * 16 + lr;
      int p0 = w * 16 + g * 4;
      ushort4 pk;
      pk.x = f2bf(acc[ct][0]); pk.y = f2bf(acc[ct][1]);
      pk.z = f2bf(acc[ct][2]); pk.w = f2bf(acc[ct][3]);
      *(ushort4*)&dst[(size_t)c * 64 + p0] = pk;
    }
  }
}

// ---------------- temporal QKV: Q,K -> bf16 row-major; V -> bf16 TRANSPOSED [bk][c][l] ----------------
__global__ __launch_bounds__(256) void k_qkv_t(const float* __restrict__ in,
                                               const float* __restrict__ W0, const float* __restrict__ W1,
                                               const float* __restrict__ W2,
                                               const float* __restrict__ b0, const float* __restrict__ b1,
                                               const float* __restrict__ b2,
                                               unsigned short* __restrict__ qb,
                                               unsigned short* __restrict__ kb,
                                               unsigned short* __restrict__ vt) {
  int r0 = blockIdx.x * 64;
  __shared__ float sInT[64][68];
  __shared__ float sW[3][64][64];
  int t = threadIdx.x;
  for (int i = t; i < 4096; i += 256) {
    int c = i >> 6, o = i & 63;
    sW[0][c][o] = W0[i];
    sW[1][c][o] = W1[i];
    sW[2][c][o] = W2[i];
  }
  for (int i = t; i < 4096; i += 256) {
    int r = i >> 6, c = i & 63;
    sInT[c][r] = in[(size_t)(r0 + r) * 64 + c];
  }
  __syncthreads();
  int col = t & 63, rg = t >> 6;
  int rbase = rg * 16;
  float a0[16], a1[16], a2[16];
  float bv0 = b0[col], bv1 = b1[col], bv2 = b2[col];
#pragma unroll
  for (int i = 0; i < 16; ++i) { a0[i] = bv0; a1[i] = bv1; a2[i] = bv2; }
  for (int c = 0; c < 64; ++c) {
    float w0 = sW[0][c][col], w1 = sW[1][c][col], w2 = sW[2][c][col];
#pragma unroll
    for (int rr = 0; rr < 16; rr += 4) {
      float4 xv = *(const float4*)&sInT[c][rbase + rr];
      a0[rr + 0] += xv.x * w0; a0[rr + 1] += xv.y * w0; a0[rr + 2] += xv.z * w0; a0[rr + 3] += xv.w * w0;
      a1[rr + 0] += xv.x * w1; a1[rr + 1] += xv.y * w1; a1[rr + 2] += xv.z * w1; a1[rr + 3] += xv.w * w1;
      a2[rr + 0] += xv.x * w2; a2[rr + 1] += xv.y * w2; a2[rr + 2] += xv.z * w2; a2[rr + 3] += xv.w * w2;
    }
  }
#pragma unroll
  for (int rr = 0; rr < 16; ++rr) {
    size_t idx = (size_t)(r0 + rbase + rr) * 64 + col;
    qb[idx] = f2bf(a0[rr]); kb[idx] = f2bf(a1[rr]);
  }
  int bk = r0 >> 7;
  int lbase = (r0 & 127) + rbase;
  unsigned short* vd = vt + (size_t)bk * 8192 + (size_t)col * 128 + lbase;
#pragma unroll
  for (int rr = 0; rr < 16; ++rr) vd[rr] = f2bf(a2[rr]);
}

// ---------------- MFMA 64x64 projection: out = in(bf16 [R][64]) @ W^T + bias -> fp32 ----------------
__global__ __launch_bounds__(256) void k_lin64(const unsigned short* __restrict__ in,
                                               const unsigned short* __restrict__ WT,
                                               const float* __restrict__ bias,
                                               float* __restrict__ out) {
  int r0 = blockIdx.x * 64;
  int t = threadIdx.x, w = t >> 6, lane = t & 63;
  int lr = lane & 15, g = lane >> 4;
  const unsigned short* aP = in + (size_t)(r0 + w * 16 + lr) * 64 + g * 8;
  short8 af0 = *(const short8*)aP;
  short8 af1 = *(const short8*)(aP + 32);
  f32x4 acc[4];
#pragma unroll
  for (int ct = 0; ct < 4; ++ct) acc[ct] = f32x4{0.f, 0.f, 0.f, 0.f};
#pragma unroll
  for (int ct = 0; ct < 4; ++ct) {
    short8 b0 = *(const short8*)(WT + (size_t)(ct * 16 + lr) * 64 + g * 8);
    short8 b1 = *(const short8*)(WT + (size_t)(ct * 16 + lr) * 64 + 32 + g * 8);
    acc[ct] = __builtin_amdgcn_mfma_f32_16x16x32_bf16(af0, b0, acc[ct], 0, 0, 0);
    acc[ct] = __builtin_amdgcn_mfma_f32_16x16x32_bf16(af1, b1, acc[ct], 0, 0, 0);
  }
#pragma unroll
  for (int ct = 0; ct < 4; ++ct) {
    int o = ct * 16 + lr;
    float bv = bias[o];
#pragma unroll
    for (int reg = 0; reg < 4; ++reg)
      out[(size_t)(r0 + w * 16 + g * 4 + reg) * 64 + o] = acc[ct][reg] + bv;
  }
}

// ---------------- fused channel FFN (MFMA): relu(X@ff1+b1)@ff2+b2; X bf16 [R][64] -> fp32 ----------------
__global__ __launch_bounds__(256) void k_cffn(const unsigned short* __restrict__ in,
                                              const unsigned short* __restrict__ ff1T,
                                              const unsigned short* __restrict__ ff2T,
                                              const float* __restrict__ b1,
                                              const float* __restrict__ b2,
                                              float* __restrict__ out) {
  __shared__ unsigned short sH[4][16 * 128];
  int r0 = blockIdx.x * 64;
  int t = threadIdx.x, w = t >> 6, lane = t & 63;
  int lr = lane & 15, g = lane >> 4;
  unsigned short* myH = sH[w];
  const unsigned short* aP = in + (size_t)(r0 + w * 16 + lr) * 64 + g * 8;
  short8 af0 = *(const short8*)aP;
  short8 af1 = *(const short8*)(aP + 32);
  f32x4 acc1[8];
#pragma unroll
  for (int ct = 0; ct < 8; ++ct) acc1[ct] = f32x4{0.f, 0.f, 0.f, 0.f};
#pragma unroll
  for (int ct = 0; ct < 8; ++ct) {
    short8 b0 = *(const short8*)(ff1T + (size_t)(ct * 16 + lr) * 64 + g * 8);
    short8 bx = *(const short8*)(ff1T + (size_t)(ct * 16 + lr) * 64 + 32 + g * 8);
    acc1[ct] = __builtin_amdgcn_mfma_f32_16x16x32_bf16(af0, b0, acc1[ct], 0, 0, 0);
    acc1[ct] = __builtin_amdgcn_mfma_f32_16x16x32_bf16(af1, bx, acc1[ct], 0, 0, 0);
  }
  // H[m][o] = relu(acc + b1[o]); m = g*4+reg, o = ct*16+lr -> swizzled LDS
#pragma unroll
  for (int ct = 0; ct < 8; ++ct) {
    int o = ct * 16 + lr;
    float bv = b1[o];
#pragma unroll
    for (int reg = 0; reg < 4; ++reg) {
      int m = g * 4 + reg;
      float h = fmaxf(acc1[ct][reg] + bv, 0.f);
      int bo = ((m * 128 + o) * 2) ^ ((m & 7) << 4);
      *(unsigned short*)((char*)myH + bo) = f2bf(h);
    }
  }
  __syncthreads();
  // O = H @ ff2 (K = 128)
  short8 ha[4];
#pragma unroll
  for (int ks = 0; ks < 4; ++ks) {
    int bo = ((lr * 128 + ks * 32 + g * 8) * 2) ^ ((lr & 7) << 4);
    ha[ks] = *(const short8*)((char*)myH + bo);
  }
  f32x4 acc2[4];
#pragma unroll
  for (int ct = 0; ct < 4; ++ct) acc2[ct] = f32x4{0.f, 0.f, 0.f, 0.f};
#pragma unroll
  for (int ct = 0; ct < 4; ++ct)
#pragma unroll
    for (int ks = 0; ks < 4; ++ks) {
      short8 b0 = *(const short8*)(ff2T + (size_t)(ct * 16 + lr) * 128 + ks * 32 + g * 8);
      acc2[ct] = __builtin_amdgcn_mfma_f32_16x16x32_bf16(ha[ks], b0, acc2[ct], 0, 0, 0);
    }
#pragma unroll
  for (int ct = 0; ct < 4; ++ct) {
    int o = ct * 16 + lr;
    float bv = b2[o];
#pragma unroll
    for (int reg = 0; reg < 4; ++reg)
      out[(size_t)(r0 + w * 16 + g * 4 + reg) * 64 + o] = acc2[ct][reg] + bv;
  }
}

// ---------------- fused LN1 -> FFN(64->8 gelu ->64) -> LN2, row-local; block = 64 rows ----------------
__global__ __launch_bounds__(256) void k_tffn(const float* __restrict__ A, const float* __restrict__ Bz,
                                              const float* __restrict__ l1w, const float* __restrict__ l1b,
                                              const float* __restrict__ l2w, const float* __restrict__ l2b,
                                              const float* __restrict__ ln1g, const float* __restrict__ ln1b,
                                              const float* __restrict__ ln2g, const float* __restrict__ ln2b,
                                              float* __restrict__ outp) {
  int r0 = blockIdx.x * 64;
  __shared__ float sSrc[64][65];
  __shared__ float sH[64][8];
  __shared__ float sW1[64][8];
  __shared__ float sW2[8][64];
  int t = threadIdx.x;
  for (int i = t; i < 512; i += 256) { ((float*)sW1)[i] = l1w[i]; ((float*)sW2)[i] = l2w[i]; }
  int c = t & 63, rg = t >> 6;
  float g1 = ln1g[c], be1 = ln1b[c];
  for (int it = 0; it < 16; ++it) {
    int r = it * 4 + rg;
    size_t idx = (size_t)(r0 + r) * 64 + c;
    float x = A[idx] + Bz[idx];
    float s = x, ss = x * x;
#pragma unroll
    for (int off = 32; off; off >>= 1) { s += __shfl_xor(s, off); ss += __shfl_xor(ss, off); }
    float mu = s * (1.f / 64.f);
    float var = ss * (1.f / 64.f) - mu * mu;
    sSrc[r][c] = (x - mu) * rsqrtf(var + EPSV) * g1 + be1;
  }
  __syncthreads();
#pragma unroll
  for (int p = 0; p < 2; ++p) {
    int idx = t + 256 * p;
    int row = idx >> 3, j = idx & 7;
    float acc = l1b[j];
    for (int cc = 0; cc < 64; ++cc) acc += sSrc[row][cc] * sW1[cc][j];
    acc = 0.5f * acc * (1.f + erff(acc * 0.70710678118654752440f));
    sH[row][j] = acc;
  }
  __syncthreads();
  float g2 = ln2g[c], be2 = ln2b[c];
  float l2bc = l2b[c];
  for (int it = 0; it < 16; ++it) {
    int r = it * 4 + rg;
    float o = l2bc;
#pragma unroll
    for (int j = 0; j < 8; ++j) o += sH[r][j] * sW2[j][c];
    float x = sSrc[r][c] + o;
    float s = x, ss = x * x;
#pragma unroll
    for (int off = 32; off; off >>= 1) { s += __shfl_xor(s, off); ss += __shfl_xor(ss, off); }
    float mu = s * (1.f / 64.f);
    float var = ss * (1.f / 64.f) - mu * mu;
    outp[(size_t)(r0 + r) * 64 + c] = (x - mu) * rsqrtf(var + EPSV) * g2 + be2;
  }
}

// ---------------- per-head MFMA attention: block = 128 q-rows, 8 waves = 8 heads; bf16 out ----------------
template <int NKV, int KVSHIFT>
__global__ __launch_bounds__(512) void k_attnH(const unsigned short* __restrict__ Qb,
                                               const unsigned short* __restrict__ Kb,
                                               const unsigned short* __restrict__ VTb,
                                               unsigned short* __restrict__ O) {
  constexpr int NCT = NKV / 16;
  constexpr int NKS = NKV / 32;
  int blk = blockIdx.x;
  const unsigned short* Qp = Qb + (size_t)blk * 128 * 64;
  unsigned short* Op = O + (size_t)blk * 128 * 64;
  const unsigned short* Kp = Kb + (size_t)(blk >> KVSHIFT) * NKV * 64;
  const unsigned short* VTp = VTb + (size_t)(blk >> KVSHIFT) * 64 * NKV;
  int t = threadIdx.x;
  int h = t >> 6, lane = t & 63, lr = lane & 15, g = lane >> 4;
  __shared__ unsigned short sP[8][16 * NKV];
  unsigned short* myP = sP[h];

  short8 kbf[NCT];
#pragma unroll
  for (int ct = 0; ct < NCT; ++ct)
    kbf[ct] = *(const short8*)(Kp + (size_t)(ct * 16 + lr) * 64 + h * 8);

  int vr = h * 8 + lr; if (vr > 63) vr = 63;
  short8 vbf[NKS];
#pragma unroll
  for (int ks = 0; ks < NKS; ++ks)
    vbf[ks] = *(const short8*)(VTp + (size_t)vr * NKV + ks * 32 + g * 8);

  for (int mt = 0; mt < 8; ++mt) {
    short8 qa = short8{0, 0, 0, 0, 0, 0, 0, 0};
    if (g == 0) qa = *(const short8*)(Qp + (size_t)(mt * 16 + lr) * 64 + h * 8);

    f32x4 sacc[NCT];
#pragma unroll
    for (int ct = 0; ct < NCT; ++ct) sacc[ct] = f32x4{0.f, 0.f, 0.f, 0.f};
#pragma unroll
    for (int ct = 0; ct < NCT; ++ct)
      sacc[ct] = __builtin_amdgcn_mfma_f32_16x16x32_bf16(qa, kbf[ct], sacc[ct], 0, 0, 0);

    float inv4[4];
#pragma unroll
    for (int reg = 0; reg < 4; ++reg) {
      float s = 0.f;
#pragma unroll
      for (int ct = 0; ct < NCT; ++ct) {
        float e = __expf(sacc[ct][reg] * SCL);
        sacc[ct][reg] = e;
        s += e;
      }
      s += __shfl_xor(s, 1); s += __shfl_xor(s, 2); s += __shfl_xor(s, 4); s += __shfl_xor(s, 8);
      inv4[reg] = 1.f / s;
    }

#pragma unroll
    for (int ct = 0; ct < NCT; ++ct)
#pragma unroll
      for (int reg = 0; reg < 4; ++reg) {
        int row = g * 4 + reg;
        int bo = ((row * NKV + ct * 16 + lr) * 2) ^ ((row & 7) << 4);
        *(unsigned short*)((char*)myP + bo) = f2bf(sacc[ct][reg]);
      }
    __syncthreads();

    f32x4 oacc = f32x4{0.f, 0.f, 0.f, 0.f};
#pragma unroll
    for (int ks = 0; ks < NKS; ++ks) {
      int bo = ((lr * NKV + ks * 32 + g * 8) * 2) ^ ((lr & 7) << 4);
      short8 pa = *(const short8*)((char*)myP + bo);
      oacc = __builtin_amdgcn_mfma_f32_16x16x32_bf16(pa, vbf[ks], oacc, 0, 0, 0);
    }
    if (lr < 8) {
#pragma unroll
      for (int reg = 0; reg < 4; ++reg) {
        int row = mt * 16 + g * 4 + reg;
        Op[(size_t)row * 64 + h * 8 + lr] = f2bf(oacc[reg] * inv4[reg]);
      }
    }
    __syncthreads();
  }
}

// ---------------- GroupNorm stats: up to 5 summed inputs, optional sum write-back ----------------
__global__ __launch_bounds__(256) void k_gn_part(const float* __restrict__ p0, const float* __restrict__ p1,
                                                 const float* __restrict__ p2, const float* __restrict__ p3,
                                                 const float* __restrict__ p4,
                                                 float* __restrict__ sumOut,
                                                 float* __restrict__ part) {
  int bg = blockIdx.y, blk = blockIdx.x, t = threadIdx.x;
  size_t start = (size_t)bg * ((size_t)CPG * NN) + (size_t)blk * 8192;
  const float4* q0 = (const float4*)(p0 + start);
  const float4* q1 = p1 ? (const float4*)(p1 + start) : nullptr;
  const float4* q2 = p2 ? (const float4*)(p2 + start) : nullptr;
  const float4* q3 = p3 ? (const float4*)(p3 + start) : nullptr;
  const float4* q4 = p4 ? (const float4*)(p4 + start) : nullptr;
  float4* so = sumOut ? (float4*)(sumOut + start) : nullptr;
  float s = 0.f, ss = 0.f;
  for (int i = t; i < 2048; i += 256) {
    float4 x = q0[i];
    if (q1) { float4 y4 = q1[i]; x.x += y4.x; x.y += y4.y; x.z += y4.z; x.w += y4.w; }
    if (q2) { float4 y4 = q2[i]; x.x += y4.x; x.y += y4.y; x.z += y4.z; x.w += y4.w; }
    if (q3) { float4 y4 = q3[i]; x.x += y4.x; x.y += y4.y; x.z += y4.z; x.w += y4.w; }
    if (q4) { float4 y4 = q4[i]; x.x += y4.x; x.y += y4.y; x.z += y4.z; x.w += y4.w; }
    if (so) so[i] = x;
    s += x.x + x.y + x.z + x.w;
    ss += x.x * x.x + x.y * x.y + x.z * x.z + x.w * x.w;
  }
  __shared__ float rs[256], rq[256];
  rs[t] = s; rq[t] = ss; __syncthreads();
  for (int off = 128; off; off >>= 1) { if (t < off) { rs[t] += rs[t + off]; rq[t] += rq[t + off]; } __syncthreads(); }
  if (t == 0) { part[(bg * 64 + blk) * 2] = rs[0]; part[(bg * 64 + blk) * 2 + 1] = rq[0]; }
}

// out = GN(p0[+p1]) (+ q0) (+ q1) — reduces 64 partials per block
__global__ __launch_bounds__(256) void k_gn_apply(const float* __restrict__ p0, const float* __restrict__ p1,
                                                  const float* __restrict__ part, const float* __restrict__ g,
                                                  const float* __restrict__ be,
                                                  const float* __restrict__ q0, const float* __restrict__ q1,
                                                  float* __restrict__ out) {
  size_t i4 = (size_t)blockIdx.x * 256 + threadIdx.x;
  size_t i = i4 * 4;
  int chan = (int)(i >> 15) & 63;
  int bg = (int)(i >> 19);
  __shared__ float smu, srr;
  int t = threadIdx.x;
  if (t < 64) {
    float s = part[(bg * 64 + t) * 2], ss = part[(bg * 64 + t) * 2 + 1];
#pragma unroll
    for (int off = 32; off; off >>= 1) { s += __shfl_xor(s, off); ss += __shfl_xor(ss, off); }
    if (t == 0) {
      float inv = 1.f / (float)((size_t)CPG * NN);
      float mu = s * inv;
      float var = ss * inv - mu * mu;
      smu = mu; srr = rsqrtf(var + EPSV);
    }
  }
  __syncthreads();
  float mu = smu, rr = srr;
  float4 x = ((const float4*)p0)[i4];
  if (p1) { float4 y4 = ((const float4*)p1)[i4]; x.x += y4.x; x.y += y4.y; x.z += y4.z; x.w += y4.w; }
  float gc = g[chan], bc = be[chan];
  float4 v;
  v.x = (x.x - mu) * rr * gc + bc;
  v.y = (x.y - mu) * rr * gc + bc;
  v.z = (x.z - mu) * rr * gc + bc;
  v.w = (x.w - mu) * rr * gc + bc;
  if (q0) { float4 y4 = ((const float4*)q0)[i4]; v.x += y4.x; v.y += y4.y; v.z += y4.z; v.w += y4.w; }
  if (q1) { float4 y4 = ((const float4*)q1)[i4]; v.x += y4.x; v.y += y4.y; v.z += y4.z; v.w += y4.w; }
  ((float4*)out)[i4] = v;
}

extern "C" void kernel_launch(void* const* d_in, const int* in_sizes, int n_in,
                              void* d_out, int out_size, void* d_ws, size_t ws_size,
                              hipStream_t stream) {
  (void)in_sizes; (void)n_in; (void)out_size; (void)ws_size;
  const float* y     = (const float*)d_in[0];
  const float* a1    = (const float*)d_in[1];
  const float* a2    = (const float*)d_in[2];
  const float* nv1   = (const float*)d_in[3];
  const float* nv2   = (const float*)d_in[4];
  const float* gcn_w = (const float*)d_in[5];
  const float* gcn_b = (const float*)d_in[6];
  const float* s_wq  = (const float*)d_in[7];
  const float* s_wk  = (const float*)d_in[8];
  const float* s_wv  = (const float*)d_in[9];
  const float* s_pk  = (const float*)d_in[10];
  const float* s_pv  = (const float*)d_in[11];
  const float* s_wo  = (const float*)d_in[12];
  const float* s_bo  = (const float*)d_in[13];
  const float* t_wq  = (const float*)d_in[14];
  const float* t_wk  = (const float*)d_in[15];
  const float* t_wv  = (const float*)d_in[16];
  const float* t_bq  = (const float*)d_in[17];
  const float* t_bk  = (const float*)d_in[18];
  const float* t_bv  = (const float*)d_in[19];
  const float* t_wo  = (const float*)d_in[20];
  const float* t_bo  = (const float*)d_in[21];
  const float* t_l1w = (const float*)d_in[22];
  const float* t_l1b = (const float*)d_in[23];
  const float* t_l2w = (const float*)d_in[24];
  const float* t_l2b = (const float*)d_in[25];
  const float* ln1g  = (const float*)d_in[26];
  const float* ln1b  = (const float*)d_in[27];
  const float* ln2g  = (const float*)d_in[28];
  const float* ln2b  = (const float*)d_in[29];
  const float* gnlg  = (const float*)d_in[30];
  const float* gnlb  = (const float*)d_in[31];
  const float* gnsg  = (const float*)d_in[32];
  const float* gnsb  = (const float*)d_in[33];
  const float* gntg  = (const float*)d_in[34];
  const float* gntb  = (const float*)d_in[35];
  const float* ff1w  = (const float*)d_in[36];
  const float* ff1b  = (const float*)d_in[37];
  const float* ff2w  = (const float*)d_in[38];
  const float* ff2b  = (const float*)d_in[39];
  const float* gn2g  = (const float*)d_in[40];
  const float* gn2b  = (const float*)d_in[41];

  float* ws = (float*)d_ws;
  float* adp   = ws;
  float* part  = ws + 65536;
  unsigned short* a1_bf   = (unsigned short*)(ws + 131072);
  unsigned short* a2_bf   = (unsigned short*)(ws + 163840);
  unsigned short* adp_bf  = (unsigned short*)(ws + 196608);
  unsigned short* gcnw_bf = (unsigned short*)(ws + 229376);
  unsigned short* xs_bf   = (unsigned short*)(ws + 262144);   // ends 2359296
  // persistent weight-T bf16 (region never otherwise used):
  unsigned short* swoT = (unsigned short*)(ws + 2359296);
  unsigned short* twoT = (unsigned short*)(ws + 2361344);
  unsigned short* ff1T = (unsigned short*)(ws + 2363392);
  unsigned short* ff2T = (unsigned short*)(ws + 2367488);
  // spatial attn scratch (post-GCN):
  unsigned short* kpb  = (unsigned short*)(ws + 131072);
  unsigned short* PkT  = (unsigned short*)(ws + 720896);
  unsigned short* PvT  = (unsigned short*)(ws + 729088);
  unsigned short* vptb = (unsigned short*)(ws + 1179648);
  const size_t SLOT = 4194304;
  float* G0 = ws + SLOT * 1;
  float* G1 = ws + SLOT * 2;
  float* G2 = ws + SLOT * 3;
  float* G3 = ws + SLOT * 4;
  float* G4 = ws + SLOT * 5;
  float* G5 = ws + SLOT * 6;
  float* G6 = ws + SLOT * 7;
  unsigned short* U1 = (unsigned short*)G3;
  unsigned short* U2 = (unsigned short*)G3 + 4194304;
  unsigned short* U3 = (unsigned short*)G4;
  unsigned short* U4 = (unsigned short*)G4 + 4194304;
  unsigned short* U5 = (unsigned short*)G5;
  unsigned short* U6 = (unsigned short*)G5 + 4194304;
  unsigned short* xkT = (unsigned short*)G4;
  unsigned short* xvT = (unsigned short*)G5;
  float* out = (float*)d_out;

  const long BS = 2097152;

  // ---- adaptive adjacency + bf16 casts ----
  k_adp<<<256, 256, 0, stream>>>(nv1, nv2, adp);
  k_cast3<<<640, 256, 0, stream>>>(a1, a2, gcn_w, a1_bf, a2_bf, gcnw_bf);
  k_cast<<<256, 256, 0, stream>>>(adp, adp_bf);
  k_castWT<<<96, 256, 0, stream>>>(s_wo, t_wo, ff1w, ff2w, swoT, twoT, ff1T, ff2T);

  // ---- xs (B,L,K,C) fp32 + bf16 ----
  k_tr<<<dim3(512, 8), 256, 0, stream>>>(y, G2, nullptr, xs_bf, BS, 128, 32768, 1, BS, 64, 1, 16384, 64, 128);

  // ---- AdaptiveGCN ----
  k_mix0<<<1024, 64, 0, stream>>>(xs_bf, gcnw_bf, gcn_b, G1);
  k_mix6<<<dim3(1024, 3), 64, 0, stream>>>(xs_bf, gcnw_bf, U1, U2, U3, U4, U5, U6);
  k_adj2M<<<512, 256, 0, stream>>>(a1_bf, U2, U1, G0);   // Q1
  k_adj2M<<<512, 256, 0, stream>>>(a2_bf, U4, U3, G6);   // Q2
  k_adj2M<<<512, 256, 0, stream>>>(adp_bf, U6, U5, G5);  // Q3
  k_gn_part<<<dim3(64, 8), 256, 0, stream>>>(y, G1, G0, G6, G5, G3, part);
  k_gn_apply<<<4096, 256, 0, stream>>>(G3, nullptr, part, gnlg, gnlb, nullptr, nullptr, G0);

  // ---- Linformer spatial attention (G2 = xs) ----
  k_castP<<<dim3(16, 2), 256, 0, stream>>>(s_pk, s_pv, PkT, PvT);
  k_qkv_s<<<1024, 256, 0, stream>>>(G2, s_wq, s_wk, s_wv, (unsigned short*)G3, xkT, xvT);
  k_sprojM<<<dim3(256, 2), 256, 0, stream>>>(xkT, xvT, PkT, PvT, kpb, vptb);
  k_attnH<64, 1><<<512, 512, 0, stream>>>((unsigned short*)G3, kpb, vptb, (unsigned short*)G6);
  k_lin64<<<1024, 256, 0, stream>>>((unsigned short*)G6, swoT, s_bo, G4);
  k_tr<<<dim3(512, 8), 256, 0, stream>>>(G4, G1, y, nullptr, BS, 64, 16384, 1, BS, 128, 1, 32768, 128, 64);
  k_gn_part<<<dim3(64, 8), 256, 0, stream>>>(G1, nullptr, nullptr, nullptr, nullptr, nullptr, part);
  k_gn_apply<<<4096, 256, 0, stream>>>(G1, nullptr, part, gnsg, gnsb, nullptr, nullptr, G1);

  // ---- temporal transformer layer ----
  k_tr<<<dim3(512, 8), 256, 0, stream>>>(y, G2, nullptr, nullptr, BS, 128, 32768, 1, BS, 8192, 1, 64, 64, 128);
  k_qkv_t<<<1024, 256, 0, stream>>>(G2, t_wq, t_wk, t_wv, t_bq, t_bk, t_bv,
                                    (unsigned short*)G3, (unsigned short*)G4, (unsigned short*)G5);
  k_attnH<128, 0><<<512, 512, 0, stream>>>((unsigned short*)G3, (unsigned short*)G4, (unsigned short*)G5,
                                           (unsigned short*)G6);
  k_lin64<<<1024, 256, 0, stream>>>((unsigned short*)G6, twoT, t_bo, G3);
  k_tffn<<<1024, 256, 0, stream>>>(G2, G3, t_l1w, t_l1b, t_l2w, t_l2b,
                                   ln1g, ln1b, ln2g, ln2b, G6);
  k_tr<<<dim3(512, 8), 256, 0, stream>>>(G6, G2, y, nullptr, BS, 8192, 64, 1, BS, 128, 1, 32768, 128, 64);
  k_gn_part<<<dim3(64, 8), 256, 0, stream>>>(G2, nullptr, nullptr, nullptr, nullptr, nullptr, part);
  k_gn_apply<<<4096, 256, 0, stream>>>(G2, nullptr, part, gntg, gntb, G0, G1, G3);

  // ---- fuse + channel FFN + final GroupNorm ----
  k_tr<<<dim3(512, 8), 256, 0, stream>>>(G3, nullptr, nullptr, (unsigned short*)G4,
                                         BS, 128, 32768, 1, BS, 8192, 1, 64, 64, 128);
  k_cffn<<<1024, 256, 0, stream>>>((unsigned short*)G4, ff1T, ff2T, ff1b, ff2b, G5);
  k_tr<<<dim3(512, 8), 256, 0, stream>>>(G5, out, G3, nullptr, BS, 8192, 64, 1, BS, 128, 1, 32768, 128, 64);
  k_gn_part<<<dim3(64, 8), 256, 0, stream>>>(out, nullptr, nullptr, nullptr, nullptr, nullptr, part);
  k_gn_apply<<<4096, 256, 0, stream>>>(out, nullptr, part, gn2g, gn2b, nullptr, nullptr, out);
}

// Round 17
// 421.232 us; speedup vs baseline: 1.5412x; 1.0314x over previous
//
#include <hip/hip_runtime.h>
#include <math.h>

constexpr int CC = 64, KK = 256, LL = 128;
constexpr int NN = KK * LL;          // 32768
constexpr int PR = 64;               // Linformer projection
constexpr int CPG = 16;              // channels per group (C / 4)
constexpr float EPSV = 1e-5f;
constexpr float SCL = 0.35355339059327373f;  // 1/sqrt(8)

typedef __attribute__((ext_vector_type(8))) short short8;      // 8 bf16 (4 VGPR)
typedef __attribute__((ext_vector_type(4))) float f32x4;       // MFMA 16x16 acc

__device__ __forceinline__ unsigned short f2bf(float x) {
  union { float f; unsigned int u; } v; v.f = x;
  unsigned int r = (v.u + 0x7FFFu + ((v.u >> 16) & 1u)) >> 16;
  return (unsigned short)r;
}
__device__ __forceinline__ float bf2f(unsigned short x) {
  union { unsigned int u; float f; } v; v.u = ((unsigned int)x) << 16;
  return v.f;
}

// ---------------- adaptive adjacency: softmax(relu(nv1@nv2), axis=1) ----------------
__global__ __launch_bounds__(256) void k_adp(const float* __restrict__ nv1,
                                             const float* __restrict__ nv2,
                                             float* __restrict__ adp) {
  int w = blockIdx.x, v = threadIdx.x;
  float s = 0.f;
  for (int d = 0; d < 10; ++d) s += nv1[w * 10 + d] * nv2[d * KK + v];
  s = fmaxf(s, 0.f);
  __shared__ float red[256];
  red[v] = s; __syncthreads();
  for (int off = 128; off; off >>= 1) { if (v < off) red[v] = fmaxf(red[v], red[v + off]); __syncthreads(); }
  float m = red[0]; __syncthreads();
  float e = expf(s - m);
  red[v] = e; __syncthreads();
  for (int off = 128; off; off >>= 1) { if (v < off) red[v] += red[v + off]; __syncthreads(); }
  adp[w * KK + v] = e / red[0];
}

// ---------------- fp32 -> bf16 cast (single range) ----------------
__global__ __launch_bounds__(256) void k_cast(const float* __restrict__ src,
                                              unsigned short* __restrict__ dst) {
  int i = blockIdx.x * 256 + threadIdx.x;
  dst[i] = f2bf(src[i]);
}

// ---------------- fused cast: a1, a2, gcn_w (plain) + s_wo/t_wo/ff1/ff2 transposed; grid 736 ----------------
__global__ __launch_bounds__(256) void k_castW(const float* __restrict__ s0, const float* __restrict__ s1,
                                               const float* __restrict__ s2,
                                               const float* __restrict__ swo, const float* __restrict__ two,
                                               const float* __restrict__ f1, const float* __restrict__ f2,
                                               unsigned short* __restrict__ d0, unsigned short* __restrict__ d1,
                                               unsigned short* __restrict__ d2,
                                               unsigned short* __restrict__ swoT, unsigned short* __restrict__ twoT,
                                               unsigned short* __restrict__ ff1T, unsigned short* __restrict__ ff2T) {
  int i = blockIdx.x * 256 + threadIdx.x;
  if (i < 65536) d0[i] = f2bf(s0[i]);
  else if (i < 131072) d1[i - 65536] = f2bf(s1[i - 65536]);
  else if (i < 159744) d2[i - 131072] = f2bf(s2[i - 131072]);
  else if (i >= 163840) {
    int j = i - 163840;
    if (j < 4096) { int r = j >> 6, c = j & 63; swoT[c * 64 + r] = f2bf(swo[j]); }
    else if (j < 8192) { int q = j - 4096; int r = q >> 6, c = q & 63; twoT[c * 64 + r] = f2bf(two[q]); }
    else if (j < 16384) { int q = j - 8192; int r = q >> 7, c = q & 127; ff1T[c * 64 + r] = f2bf(f1[q]); }
    else if (j < 24576) { int q = j - 16384; int r = q >> 6, c = q & 63; ff2T[c * 128 + r] = f2bf(f2[q]); }
  }
}

// ---------------- transpose-cast P (256 x 64) -> PT bf16 (64 x 256); grid (16, 2) ----------------
__global__ __launch_bounds__(256) void k_castP(const float* __restrict__ P0, const float* __restrict__ P1,
                                               unsigned short* __restrict__ T0, unsigned short* __restrict__ T1) {
  const float* P = blockIdx.y ? P1 : P0;
  unsigned short* T = blockIdx.y ? T1 : T0;
  int tv = blockIdx.x >> 1, tc = blockIdx.x & 1;
  int n0 = tv * 32, c0 = tc * 32;
  __shared__ float s[32][33];
  int tx = threadIdx.x & 31, ty = threadIdx.x >> 5;
#pragma unroll
  for (int j = 0; j < 4; ++j)
    s[ty + j * 8][tx] = P[(size_t)(n0 + ty + j * 8) * 64 + c0 + tx];
  __syncthreads();
#pragma unroll
  for (int j = 0; j < 4; ++j)
    T[(size_t)(c0 + ty + j * 8) * 256 + n0 + tx] = f2bf(s[tx][ty + j * 8]);
}

// ---------------- s0 term (bf16 out): s0[b,o,k,l] = bias[o] + sum_c W0[o][c]*xs[(b,l,k)][c] ----------------
__global__ __launch_bounds__(64) void k_mix0(const unsigned short* __restrict__ Xbf,
                                             const unsigned short* __restrict__ Wbf,
                                             const float* __restrict__ bias,
                                             unsigned short* __restrict__ s0) {
  int pb = blockIdx.x;
  int lh = pb & 1;
  int k = (pb >> 1) & 255;
  int b = pb >> 9;
  int lane = threadIdx.x;
  int lr = lane & 15, g = lane >> 4;
  short8 af[4][2], bfv[4][2];
#pragma unroll
  for (int ot = 0; ot < 4; ++ot)
#pragma unroll
    for (int kc = 0; kc < 2; ++kc)
      af[ot][kc] = *(const short8*)(Wbf + (size_t)(ot * 16 + lr) * 448 + kc * 32 + g * 8);
#pragma unroll
  for (int ct = 0; ct < 4; ++ct)
#pragma unroll
    for (int kc = 0; kc < 2; ++kc)
      bfv[ct][kc] = *(const short8*)(Xbf + ((size_t)(b * 128 + lh * 64 + ct * 16 + lr) * 256 + k) * 64 + kc * 32 + g * 8);
  f32x4 acc[4][4];
#pragma unroll
  for (int ot = 0; ot < 4; ++ot)
#pragma unroll
    for (int ct = 0; ct < 4; ++ct) acc[ot][ct] = f32x4{0.f, 0.f, 0.f, 0.f};
#pragma unroll
  for (int kc = 0; kc < 2; ++kc)
#pragma unroll
    for (int ot = 0; ot < 4; ++ot)
#pragma unroll
      for (int ct = 0; ct < 4; ++ct)
        acc[ot][ct] = __builtin_amdgcn_mfma_f32_16x16x32_bf16(af[ot][kc], bfv[ct][kc], acc[ot][ct], 0, 0, 0);
#pragma unroll
  for (int ot = 0; ot < 4; ++ot)
#pragma unroll
    for (int ct = 0; ct < 4; ++ct) {
#pragma unroll
      for (int reg = 0; reg < 4; ++reg) {
        int o = ot * 16 + g * 4 + reg;
        s0[(size_t)(b * 64 + o) * NN + (size_t)k * 128 + lh * 64 + ct * 16 + lr] = f2bf(acc[ot][ct][reg] + bias[o]);
      }
    }
}

// ---------------- U terms: U_s[(b*64+o)][l][k] bf16; blockIdx.y picks s-pair ----------------
__global__ __launch_bounds__(64) void k_mix6(const unsigned short* __restrict__ Xbf,
                                             const unsigned short* __restrict__ Wbf,
                                             unsigned short* __restrict__ U1, unsigned short* __restrict__ U2,
                                             unsigned short* __restrict__ U3, unsigned short* __restrict__ U4,
                                             unsigned short* __restrict__ U5, unsigned short* __restrict__ U6) {
  unsigned short* Us[6] = {U1, U2, U3, U4, U5, U6};
  int pb = blockIdx.x;
  int sy = blockIdx.y;
  int b = pb >> 9;
  int rem = pb & 511;
  int l = rem >> 2;
  int kq = (rem & 3) * 64;
  size_t posbase = ((size_t)(b * 128 + l)) * 256 + kq;
  int lane = threadIdx.x;
  int lr = lane & 15, g = lane >> 4;

  short8 af[4][2];
#pragma unroll
  for (int rt = 0; rt < 4; ++rt)
#pragma unroll
    for (int kc = 0; kc < 2; ++kc)
      af[rt][kc] = *(const short8*)(Xbf + (posbase + rt * 16 + lr) * 64 + kc * 32 + g * 8);

  for (int si = 0; si < 2; ++si) {
    int s = sy * 2 + 1 + si;
    short8 bfv[4][2];
#pragma unroll
    for (int ct = 0; ct < 4; ++ct)
#pragma unroll
      for (int kc = 0; kc < 2; ++kc)
        bfv[ct][kc] = *(const short8*)(Wbf + (size_t)(ct * 16 + lr) * 448 + s * 64 + kc * 32 + g * 8);
    f32x4 acc[4][4];
#pragma unroll
    for (int rt = 0; rt < 4; ++rt)
#pragma unroll
      for (int ct = 0; ct < 4; ++ct) acc[rt][ct] = f32x4{0.f, 0.f, 0.f, 0.f};
#pragma unroll
    for (int kc = 0; kc < 2; ++kc)
#pragma unroll
      for (int rt = 0; rt < 4; ++rt)
#pragma unroll
        for (int ct = 0; ct < 4; ++ct)
          acc[rt][ct] = __builtin_amdgcn_mfma_f32_16x16x32_bf16(af[rt][kc], bfv[ct][kc], acc[rt][ct], 0, 0, 0);
    unsigned short* dst = Us[s - 1];
#pragma unroll
    for (int rt = 0; rt < 4; ++rt)
#pragma unroll
      for (int ct = 0; ct < 4; ++ct) {
        int o = ct * 16 + lr;
        int k = kq + rt * 16 + g * 4;
        ushort4 pk;
        pk.x = f2bf(acc[rt][ct][0]); pk.y = f2bf(acc[rt][ct][1]);
        pk.z = f2bf(acc[rt][ct][2]); pk.w = f2bf(acc[rt][ct][3]);
        *(ushort4*)&dst[((size_t)(b * 64 + o) * 128 + l) * 256 + k] = pk;
      }
  }
}

// ---------------- fused 2-hop (bf16 out): out = A @ bf16(A @ Ueven + Uodd) ----------------
__global__ __launch_bounds__(256) void k_adj2M(const unsigned short* __restrict__ Abf,
                                               const unsigned short* __restrict__ Ueven,
                                               const unsigned short* __restrict__ Uodd,
                                               unsigned short* __restrict__ out) {
  __shared__ unsigned short sH[32 * 256];
  int lq = blockIdx.x & 3, bc = blockIdx.x >> 2;
  int tid = threadIdx.x, wid = tid >> 6, lane = tid & 63;
  int lr = lane & 15, g = lane >> 4;
  int wbase = wid * 64;
  const unsigned short* aP = Abf + (size_t)(wbase + lr) * 256 + g * 8;
  const unsigned short* bP = Ueven + ((size_t)bc * 128 + lq * 32 + lr) * 256 + g * 8;

  f32x4 acc[4][2];
#pragma unroll
  for (int i = 0; i < 4; ++i)
#pragma unroll
    for (int j = 0; j < 2; ++j) acc[i][j] = f32x4{0.f, 0.f, 0.f, 0.f};
  for (int k0 = 0; k0 < 256; k0 += 32) {
    short8 af[4], bfv[2];
#pragma unroll
    for (int i = 0; i < 4; ++i) af[i] = *(const short8*)(aP + (size_t)i * 16 * 256 + k0);
#pragma unroll
    for (int i = 0; i < 2; ++i) bfv[i] = *(const short8*)(bP + (size_t)i * 16 * 256 + k0);
#pragma unroll
    for (int rm = 0; rm < 4; ++rm)
#pragma unroll
      for (int cn = 0; cn < 2; ++cn)
        acc[rm][cn] = __builtin_amdgcn_mfma_f32_16x16x32_bf16(af[rm], bfv[cn], acc[rm][cn], 0, 0, 0);
  }
  {
    const unsigned short* aT = Uodd + (size_t)bc * NN + (size_t)(lq * 32) * 256;
#pragma unroll
    for (int rm = 0; rm < 4; ++rm)
#pragma unroll
      for (int cn = 0; cn < 2; ++cn) {
        int l = cn * 16 + lr;
        int v = wbase + rm * 16 + g * 4;
        ushort4 av = *(const ushort4*)&aT[(size_t)l * 256 + v];
        ushort4 pk;
        pk.x = f2bf(acc[rm][cn][0] + bf2f(av.x));
        pk.y = f2bf(acc[rm][cn][1] + bf2f(av.y));
        pk.z = f2bf(acc[rm][cn][2] + bf2f(av.z));
        pk.w = f2bf(acc[rm][cn][3] + bf2f(av.w));
        int bo = ((l * 256 + v) * 2) ^ ((l & 7) << 4);
        *(ushort4*)((char*)sH + bo) = pk;
      }
  }
  __syncthreads();

  f32x4 c2[4][2];
#pragma unroll
  for (int i = 0; i < 4; ++i)
#pragma unroll
    for (int j = 0; j < 2; ++j) c2[i][j] = f32x4{0.f, 0.f, 0.f, 0.f};
  for (int k0 = 0; k0 < 256; k0 += 32) {
    short8 af[4], bfv[2];
#pragma unroll
    for (int i = 0; i < 4; ++i) af[i] = *(const short8*)(aP + (size_t)i * 16 * 256 + k0);
#pragma unroll
    for (int cn = 0; cn < 2; ++cn) {
      int l = cn * 16 + lr;
      int bo = ((l * 256 + k0 + g * 8) * 2) ^ ((l & 7) << 4);
      bfv[cn] = *(const short8*)((char*)sH + bo);
    }
#pragma unroll
    for (int rm = 0; rm < 4; ++rm)
#pragma unroll
      for (int cn = 0; cn < 2; ++cn)
        c2[rm][cn] = __builtin_amdgcn_mfma_f32_16x16x32_bf16(af[rm], bfv[cn], c2[rm][cn], 0, 0, 0);
  }
  unsigned short* dst = out + (size_t)bc * NN + lq * 32;
#pragma unroll
  for (int rm = 0; rm < 4; ++rm)
#pragma unroll
    for (int cn = 0; cn < 2; ++cn) {
      int col = cn * 16 + lr;
      int row = wbase + rm * 16 + g * 4;
#pragma unroll
      for (int j = 0; j < 4; ++j)
        dst[(size_t)(row + j) * 128 + col] = f2bf(c2[rm][cn][j]);
    }
}

// ---------------- generic (c,l)-plane transpose per (b,k); optional dst/add/bf16 outputs ----------------
__global__ __launch_bounds__(256) void k_tr(const float* __restrict__ src, float* __restrict__ dst,
                                            const float* __restrict__ add,
                                            unsigned short* __restrict__ dstBf,
                                            long sb, long sk, long sc, long sl,
                                            long db, long dk, long dc, long dl, int nC, int nL) {
  int outer = blockIdx.x;
  int b = outer >> 8, k = outer & 255;
  int tilesL = nL >> 5;
  int tC = blockIdx.y / tilesL, tL = blockIdx.y % tilesL;
  int c0 = tC << 5, l0 = tL << 5;
  __shared__ float s[32][33];
  int tx = threadIdx.x & 31, ty = threadIdx.x >> 5;
  const float* sp = src + (long)b * sb + (long)k * sk;
#pragma unroll
  for (int j = 0; j < 4; ++j) {
    int cc = c0 + ty + j * 8;
    s[ty + j * 8][tx] = sp[(long)cc * sc + (long)(l0 + tx) * sl];
  }
  __syncthreads();
  long dbase = (long)b * db + (long)k * dk;
#pragma unroll
  for (int j = 0; j < 4; ++j) {
    int ll = l0 + ty + j * 8;
    long off = dbase + (long)(c0 + tx) * dc + (long)ll * dl;
    float val = s[tx][ty + j * 8];
    if (add) val += add[off];
    if (dst) dst[off] = val;
    if (dstBf) dstBf[off] = f2bf(val);
  }
}

// ---------------- spatial QKV: Q -> bf16 RM; K,V -> bf16 TRANSPOSED [bl][c][n] ----------------
__global__ __launch_bounds__(256) void k_qkv_s(const float* __restrict__ in,
                                               const float* __restrict__ W0, const float* __restrict__ W1,
                                               const float* __restrict__ W2,
                                               unsigned short* __restrict__ qb,
                                               unsigned short* __restrict__ xkT,
                                               unsigned short* __restrict__ xvT) {
  int r0 = blockIdx.x * 64;
  __shared__ float sInT[64][68];
  __shared__ float sW[3][64][64];
  int t = threadIdx.x;
  for (int i = t; i < 4096; i += 256) {
    int c = i >> 6, o = i & 63;
    sW[0][c][o] = W0[i];
    sW[1][c][o] = W1[i];
    sW[2][c][o] = W2[i];
  }
  for (int i = t; i < 4096; i += 256) {
    int r = i >> 6, c = i & 63;
    sInT[c][r] = in[(size_t)(r0 + r) * 64 + c];
  }
  __syncthreads();
  int col = t & 63, rg = t >> 6;
  int rbase = rg * 16;
  float a0[16], a1[16], a2[16];
#pragma unroll
  for (int i = 0; i < 16; ++i) { a0[i] = 0.f; a1[i] = 0.f; a2[i] = 0.f; }
  for (int c = 0; c < 64; ++c) {
    float w0 = sW[0][c][col], w1 = sW[1][c][col], w2 = sW[2][c][col];
#pragma unroll
    for (int rr = 0; rr < 16; rr += 4) {
      float4 xv = *(const float4*)&sInT[c][rbase + rr];
      a0[rr + 0] += xv.x * w0; a0[rr + 1] += xv.y * w0; a0[rr + 2] += xv.z * w0; a0[rr + 3] += xv.w * w0;
      a1[rr + 0] += xv.x * w1; a1[rr + 1] += xv.y * w1; a1[rr + 2] += xv.z * w1; a1[rr + 3] += xv.w * w1;
      a2[rr + 0] += xv.x * w2; a2[rr + 1] += xv.y * w2; a2[rr + 2] += xv.z * w2; a2[rr + 3] += xv.w * w2;
    }
  }
#pragma unroll
  for (int rr = 0; rr < 16; ++rr)
    qb[(size_t)(r0 + rbase + rr) * 64 + col] = f2bf(a0[rr]);
  int bl = r0 >> 8;
  int nb = (r0 & 255) + rbase;
  unsigned short* kd = xkT + (size_t)bl * 16384 + (size_t)col * 256 + nb;
  unsigned short* vd = xvT + (size_t)bl * 16384 + (size_t)col * 256 + nb;
#pragma unroll
  for (int rr = 0; rr < 16; ++rr) { kd[rr] = f2bf(a1[rr]); vd[rr] = f2bf(a2[rr]); }
}

// ---------------- MFMA sproj ----------------
__global__ __launch_bounds__(256) void k_sprojM(const unsigned short* __restrict__ XkT,
                                                const unsigned short* __restrict__ XvT,
                                                const unsigned short* __restrict__ PkT,
                                                const unsigned short* __restrict__ PvT,
                                                unsigned short* __restrict__ kpb,
                                                unsigned short* __restrict__ vptb) {
  int bl = blockIdx.x;
  int which = blockIdx.y;
  int t = threadIdx.x, w = t >> 6, lane = t & 63;
  int lr = lane & 15, g = lane >> 4;
  const unsigned short* Abase = which ? PvT : XkT + (size_t)bl * 16384;
  const unsigned short* Bbase = which ? XvT + (size_t)bl * 16384 : PkT;
  const unsigned short* aP = Abase + (size_t)(w * 16 + lr) * 256 + g * 8;
  f32x4 acc[4];
#pragma unroll
  for (int ct = 0; ct < 4; ++ct) acc[ct] = f32x4{0.f, 0.f, 0.f, 0.f};
  for (int k0 = 0; k0 < 256; k0 += 32) {
    short8 af = *(const short8*)(aP + k0);
#pragma unroll
    for (int ct = 0; ct < 4; ++ct) {
      short8 bf = *(const short8*)(Bbase + (size_t)(ct * 16 + lr) * 256 + k0 + g * 8);
      acc[ct] = __builtin_amdgcn_mfma_f32_16x16x32_bf16(af, bf, acc[ct], 0, 0, 0);
    }
  }
  if (!which) {
    unsigned short* dst = kpb + (size_t)bl * 4096;
#pragma unroll
    for (int ct = 0; ct < 4; ++ct) {
      int p = ct * 16 + lr;
      int c0 = w * 16 + g * 4;
      ushort4 pk;
      pk.x = f2bf(acc[ct][0]); pk.y = f2bf(acc[ct][1]);
      pk.z = f2bf(acc[ct][2]); pk.w = f2bf(acc[ct][3]);
      *(ushort4*)&dst[(size_t)p * 64 + c0] = pk;
    }
  } else {
    unsigned short* dst = vptb + (size_t)bl * 4096;
#pragma unroll
    for (int ct = 0; ct < 4; ++ct) {
      int c = ct * 16 + lr;
      int p0 = w * 16 + g * 4;
      ushort4 pk;
      pk.x = f2bf(acc[ct][0]); pk.y = f2bf(acc[ct][1]);
      pk.z = f2bf(acc[ct][2]); pk.w = f2bf(acc[ct][3]);
      *(ushort4*)&dst[(size_t)c * 64 + p0] = pk;
    }
  }
}

// ---------------- temporal QKV: Q,K -> bf16 row-major; V -> bf16 TRANSPOSED [bk][c][l] ----------------
__global__ __launch_bounds__(256) void k_qkv_t(const float* __restrict__ in,
                                               const float* __restrict__ W0, const float* __restrict__ W1,
                                               const float* __restrict__ W2,
                                               const float* __restrict__ b0, const float* __restrict__ b1,
                                               const float* __restrict__ b2,
                                               unsigned short* __restrict__ qb,
                                               unsigned short* __restrict__ kb,
                                               unsigned short* __restrict__ vt) {
  int r0 = blockIdx.x * 64;
  __shared__ float sInT[64][68];
  __shared__ float sW[3][64][64];
  int t = threadIdx.x;
  for (int i = t; i < 4096; i += 256) {
    int c = i >> 6, o = i & 63;
    sW[0][c][o] = W0[i];
    sW[1][c][o] = W1[i];
    sW[2][c][o] = W2[i];
  }
  for (int i = t; i < 4096; i += 256) {
    int r = i >> 6, c = i & 63;
    sInT[c][r] = in[(size_t)(r0 + r) * 64 + c];
  }
  __syncthreads();
  int col = t & 63, rg = t >> 6;
  int rbase = rg * 16;
  float a0[16], a1[16], a2[16];
  float bv0 = b0[col], bv1 = b1[col], bv2 = b2[col];
#pragma unroll
  for (int i = 0; i < 16; ++i) { a0[i] = bv0; a1[i] = bv1; a2[i] = bv2; }
  for (int c = 0; c < 64; ++c) {
    float w0 = sW[0][c][col], w1 = sW[1][c][col], w2 = sW[2][c][col];
#pragma unroll
    for (int rr = 0; rr < 16; rr += 4) {
      float4 xv = *(const float4*)&sInT[c][rbase + rr];
      a0[rr + 0] += xv.x * w0; a0[rr + 1] += xv.y * w0; a0[rr + 2] += xv.z * w0; a0[rr + 3] += xv.w * w0;
      a1[rr + 0] += xv.x * w1; a1[rr + 1] += xv.y * w1; a1[rr + 2] += xv.z * w1; a1[rr + 3] += xv.w * w1;
      a2[rr + 0] += xv.x * w2; a2[rr + 1] += xv.y * w2; a2[rr + 2] += xv.z * w2; a2[rr + 3] += xv.w * w2;
    }
  }
#pragma unroll
  for (int rr = 0; rr < 16; ++rr) {
    size_t idx = (size_t)(r0 + rbase + rr) * 64 + col;
    qb[idx] = f2bf(a0[rr]); kb[idx] = f2bf(a1[rr]);
  }
  int bk = r0 >> 7;
  int lbase = (r0 & 127) + rbase;
  unsigned short* vd = vt + (size_t)bk * 8192 + (size_t)col * 128 + lbase;
#pragma unroll
  for (int rr = 0; rr < 16; ++rr) vd[rr] = f2bf(a2[rr]);
}

// ---------------- MFMA 64x64 projection: out = in(bf16 [R][64]) @ W^T + bias -> fp32 ----------------
__global__ __launch_bounds__(256) void k_lin64(const unsigned short* __restrict__ in,
                                               const unsigned short* __restrict__ WT,
                                               const float* __restrict__ bias,
                                               float* __restrict__ out) {
  int r0 = blockIdx.x * 64;
  int t = threadIdx.x, w = t >> 6, lane = t & 63;
  int lr = lane & 15, g = lane >> 4;
  const unsigned short* aP = in + (size_t)(r0 + w * 16 + lr) * 64 + g * 8;
  short8 af0 = *(const short8*)aP;
  short8 af1 = *(const short8*)(aP + 32);
  f32x4 acc[4];
#pragma unroll
  for (int ct = 0; ct < 4; ++ct) acc[ct] = f32x4{0.f, 0.f, 0.f, 0.f};
#pragma unroll
  for (int ct = 0; ct < 4; ++ct) {
    short8 b0 = *(const short8*)(WT + (size_t)(ct * 16 + lr) * 64 + g * 8);
    short8 b1 = *(const short8*)(WT + (size_t)(ct * 16 + lr) * 64 + 32 + g * 8);
    acc[ct] = __builtin_amdgcn_mfma_f32_16x16x32_bf16(af0, b0, acc[ct], 0, 0, 0);
    acc[ct] = __builtin_amdgcn_mfma_f32_16x16x32_bf16(af1, b1, acc[ct], 0, 0, 0);
  }
#pragma unroll
  for (int ct = 0; ct < 4; ++ct) {
    int o = ct * 16 + lr;
    float bv = bias[o];
#pragma unroll
    for (int reg = 0; reg < 4; ++reg)
      out[(size_t)(r0 + w * 16 + g * 4 + reg) * 64 + o] = acc[ct][reg] + bv;
  }
}

// ---------------- fused channel FFN (MFMA): relu(X@ff1+b1)@ff2+b2; X bf16 [R][64] -> fp32 ----------------
__global__ __launch_bounds__(256) void k_cffn(const unsigned short* __restrict__ in,
                                              const unsigned short* __restrict__ ff1T,
                                              const unsigned short* __restrict__ ff2T,
                                              const float* __restrict__ b1,
                                              const float* __restrict__ b2,
                                              float* __restrict__ out) {
  __shared__ unsigned short sH[4][16 * 128];
  int r0 = blockIdx.x * 64;
  int t = threadIdx.x, w = t >> 6, lane = t & 63;
  int lr = lane & 15, g = lane >> 4;
  unsigned short* myH = sH[w];
  const unsigned short* aP = in + (size_t)(r0 + w * 16 + lr) * 64 + g * 8;
  short8 af0 = *(const short8*)aP;
  short8 af1 = *(const short8*)(aP + 32);
  f32x4 acc1[8];
#pragma unroll
  for (int ct = 0; ct < 8; ++ct) acc1[ct] = f32x4{0.f, 0.f, 0.f, 0.f};
#pragma unroll
  for (int ct = 0; ct < 8; ++ct) {
    short8 b0 = *(const short8*)(ff1T + (size_t)(ct * 16 + lr) * 64 + g * 8);
    short8 bx = *(const short8*)(ff1T + (size_t)(ct * 16 + lr) * 64 + 32 + g * 8);
    acc1[ct] = __builtin_amdgcn_mfma_f32_16x16x32_bf16(af0, b0, acc1[ct], 0, 0, 0);
    acc1[ct] = __builtin_amdgcn_mfma_f32_16x16x32_bf16(af1, bx, acc1[ct], 0, 0, 0);
  }
#pragma unroll
  for (int ct = 0; ct < 8; ++ct) {
    int o = ct * 16 + lr;
    float bv = b1[o];
#pragma unroll
    for (int reg = 0; reg < 4; ++reg) {
      int m = g * 4 + reg;
      float h = fmaxf(acc1[ct][reg] + bv, 0.f);
      int bo = ((m * 128 + o) * 2) ^ ((m & 7) << 4);
      *(unsigned short*)((char*)myH + bo) = f2bf(h);
    }
  }
  __syncthreads();
  short8 ha[4];
#pragma unroll
  for (int ks = 0; ks < 4; ++ks) {
    int bo = ((lr * 128 + ks * 32 + g * 8) * 2) ^ ((lr & 7) << 4);
    ha[ks] = *(const short8*)((char*)myH + bo);
  }
  f32x4 acc2[4];
#pragma unroll
  for (int ct = 0; ct < 4; ++ct) acc2[ct] = f32x4{0.f, 0.f, 0.f, 0.f};
#pragma unroll
  for (int ct = 0; ct < 4; ++ct)
#pragma unroll
    for (int ks = 0; ks < 4; ++ks) {
      short8 b0 = *(const short8*)(ff2T + (size_t)(ct * 16 + lr) * 128 + ks * 32 + g * 8);
      acc2[ct] = __builtin_amdgcn_mfma_f32_16x16x32_bf16(ha[ks], b0, acc2[ct], 0, 0, 0);
    }
#pragma unroll
  for (int ct = 0; ct < 4; ++ct) {
    int o = ct * 16 + lr;
    float bv = b2[o];
#pragma unroll
    for (int reg = 0; reg < 4; ++reg)
      out[(size_t)(r0 + w * 16 + g * 4 + reg) * 64 + o] = acc2[ct][reg] + bv;
  }
}

// ---------------- fused LN1 -> FFN(64->8 gelu ->64) -> LN2, row-local; block = 64 rows ----------------
__global__ __launch_bounds__(256) void k_tffn(const float* __restrict__ A, const float* __restrict__ Bz,
                                              const float* __restrict__ l1w, const float* __restrict__ l1b,
                                              const float* __restrict__ l2w, const float* __restrict__ l2b,
                                              const float* __restrict__ ln1g, const float* __restrict__ ln1b,
                                              const float* __restrict__ ln2g, const float* __restrict__ ln2b,
                                              float* __restrict__ outp) {
  int r0 = blockIdx.x * 64;
  __shared__ float sSrc[64][65];
  __shared__ float sH[64][8];
  __shared__ float sW1[64][8];
  __shared__ float sW2[8][64];
  int t = threadIdx.x;
  for (int i = t; i < 512; i += 256) { ((float*)sW1)[i] = l1w[i]; ((float*)sW2)[i] = l2w[i]; }
  int c = t & 63, rg = t >> 6;
  float g1 = ln1g[c], be1 = ln1b[c];
  for (int it = 0; it < 16; ++it) {
    int r = it * 4 + rg;
    size_t idx = (size_t)(r0 + r) * 64 + c;
    float x = A[idx] + Bz[idx];
    float s = x, ss = x * x;
#pragma unroll
    for (int off = 32; off; off >>= 1) { s += __shfl_xor(s, off); ss += __shfl_xor(ss, off); }
    float mu = s * (1.f / 64.f);
    float var = ss * (1.f / 64.f) - mu * mu;
    sSrc[r][c] = (x - mu) * rsqrtf(var + EPSV) * g1 + be1;
  }
  __syncthreads();
#pragma unroll
  for (int p = 0; p < 2; ++p) {
    int idx = t + 256 * p;
    int row = idx >> 3, j = idx & 7;
    float acc = l1b[j];
    for (int cc = 0; cc < 64; ++cc) acc += sSrc[row][cc] * sW1[cc][j];
    acc = 0.5f * acc * (1.f + erff(acc * 0.70710678118654752440f));
    sH[row][j] = acc;
  }
  __syncthreads();
  float g2 = ln2g[c], be2 = ln2b[c];
  float l2bc = l2b[c];
  for (int it = 0; it < 16; ++it) {
    int r = it * 4 + rg;
    float o = l2bc;
#pragma unroll
    for (int j = 0; j < 8; ++j) o += sH[r][j] * sW2[j][c];
    float x = sSrc[r][c] + o;
    float s = x, ss = x * x;
#pragma unroll
    for (int off = 32; off; off >>= 1) { s += __shfl_xor(s, off); ss += __shfl_xor(ss, off); }
    float mu = s * (1.f / 64.f);
    float var = ss * (1.f / 64.f) - mu * mu;
    outp[(size_t)(r0 + r) * 64 + c] = (x - mu) * rsqrtf(var + EPSV) * g2 + be2;
  }
}

// ---------------- per-head MFMA attention: block = 128 q-rows, 8 waves = 8 heads; bf16 out ----------------
template <int NKV, int KVSHIFT>
__global__ __launch_bounds__(512) void k_attnH(const unsigned short* __restrict__ Qb,
                                               const unsigned short* __restrict__ Kb,
                                               const unsigned short* __restrict__ VTb,
                                               unsigned short* __restrict__ O) {
  constexpr int NCT = NKV / 16;
  constexpr int NKS = NKV / 32;
  int blk = blockIdx.x;
  const unsigned short* Qp = Qb + (size_t)blk * 128 * 64;
  unsigned short* Op = O + (size_t)blk * 128 * 64;
  const unsigned short* Kp = Kb + (size_t)(blk >> KVSHIFT) * NKV * 64;
  const unsigned short* VTp = VTb + (size_t)(blk >> KVSHIFT) * 64 * NKV;
  int t = threadIdx.x;
  int h = t >> 6, lane = t & 63, lr = lane & 15, g = lane >> 4;
  __shared__ unsigned short sP[8][16 * NKV];
  unsigned short* myP = sP[h];

  short8 kbf[NCT];
#pragma unroll
  for (int ct = 0; ct < NCT; ++ct)
    kbf[ct] = *(const short8*)(Kp + (size_t)(ct * 16 + lr) * 64 + h * 8);

  int vr = h * 8 + lr; if (vr > 63) vr = 63;
  short8 vbf[NKS];
#pragma unroll
  for (int ks = 0; ks < NKS; ++ks)
    vbf[ks] = *(const short8*)(VTp + (size_t)vr * NKV + ks * 32 + g * 8);

  for (int mt = 0; mt < 8; ++mt) {
    short8 qa = short8{0, 0, 0, 0, 0, 0, 0, 0};
    if (g == 0) qa = *(const short8*)(Qp + (size_t)(mt * 16 + lr) * 64 + h * 8);

    f32x4 sacc[NCT];
#pragma unroll
    for (int ct = 0; ct < NCT; ++ct) sacc[ct] = f32x4{0.f, 0.f, 0.f, 0.f};
#pragma unroll
    for (int ct = 0; ct < NCT; ++ct)
      sacc[ct] = __builtin_amdgcn_mfma_f32_16x16x32_bf16(qa, kbf[ct], sacc[ct], 0, 0, 0);

    float inv4[4];
#pragma unroll
    for (int reg = 0; reg < 4; ++reg) {
      float s = 0.f;
#pragma unroll
      for (int ct = 0; ct < NCT; ++ct) {
        float e = __expf(sacc[ct][reg] * SCL);
        sacc[ct][reg] = e;
        s += e;
      }
      s += __shfl_xor(s, 1); s += __shfl_xor(s, 2); s += __shfl_xor(s, 4); s += __shfl_xor(s, 8);
      inv4[reg] = 1.f / s;
    }

#pragma unroll
    for (int ct = 0; ct < NCT; ++ct)
#pragma unroll
      for (int reg = 0; reg < 4; ++reg) {
        int row = g * 4 + reg;
        int bo = ((row * NKV + ct * 16 + lr) * 2) ^ ((row & 7) << 4);
        *(unsigned short*)((char*)myP + bo) = f2bf(sacc[ct][reg]);
      }
    __syncthreads();

    f32x4 oacc = f32x4{0.f, 0.f, 0.f, 0.f};
#pragma unroll
    for (int ks = 0; ks < NKS; ++ks) {
      int bo = ((lr * NKV + ks * 32 + g * 8) * 2) ^ ((lr & 7) << 4);
      short8 pa = *(const short8*)((char*)myP + bo);
      oacc = __builtin_amdgcn_mfma_f32_16x16x32_bf16(pa, vbf[ks], oacc, 0, 0, 0);
    }
    if (lr < 8) {
#pragma unroll
      for (int reg = 0; reg < 4; ++reg) {
        int row = mt * 16 + g * 4 + reg;
        Op[(size_t)row * 64 + h * 8 + lr] = f2bf(oacc[reg] * inv4[reg]);
      }
    }
    __syncthreads();
  }
}

// ---------------- GroupNorm stats (fp32 inputs) ----------------
__global__ __launch_bounds__(256) void k_gn_part(const float* __restrict__ p0, const float* __restrict__ p1,
                                                 const float* __restrict__ p2, const float* __restrict__ p3,
                                                 const float* __restrict__ p4,
                                                 float* __restrict__ sumOut,
                                                 float* __restrict__ part) {
  int bg = blockIdx.y, blk = blockIdx.x, t = threadIdx.x;
  size_t start = (size_t)bg * ((size_t)CPG * NN) + (size_t)blk * 8192;
  const float4* q0 = (const float4*)(p0 + start);
  const float4* q1 = p1 ? (const float4*)(p1 + start) : nullptr;
  const float4* q2 = p2 ? (const float4*)(p2 + start) : nullptr;
  const float4* q3 = p3 ? (const float4*)(p3 + start) : nullptr;
  const float4* q4 = p4 ? (const float4*)(p4 + start) : nullptr;
  float4* so = sumOut ? (float4*)(sumOut + start) : nullptr;
  float s = 0.f, ss = 0.f;
  for (int i = t; i < 2048; i += 256) {
    float4 x = q0[i];
    if (q1) { float4 y4 = q1[i]; x.x += y4.x; x.y += y4.y; x.z += y4.z; x.w += y4.w; }
    if (q2) { float4 y4 = q2[i]; x.x += y4.x; x.y += y4.y; x.z += y4.z; x.w += y4.w; }
    if (q3) { float4 y4 = q3[i]; x.x += y4.x; x.y += y4.y; x.z += y4.z; x.w += y4.w; }
    if (q4) { float4 y4 = q4[i]; x.x += y4.x; x.y += y4.y; x.z += y4.z; x.w += y4.w; }
    if (so) so[i] = x;
    s += x.x + x.y + x.z + x.w;
    ss += x.x * x.x + x.y * x.y + x.z * x.z + x.w * x.w;
  }
  __shared__ float rs[256], rq[256];
  rs[t] = s; rq[t] = ss; __syncthreads();
  for (int off = 128; off; off >>= 1) { if (t < off) { rs[t] += rs[t + off]; rq[t] += rq[t + off]; } __syncthreads(); }
  if (t == 0) { part[(bg * 64 + blk) * 2] = rs[0]; part[(bg * 64 + blk) * 2 + 1] = rq[0]; }
}

// ---------------- GroupNorm stats: y(fp32) + 4 bf16 branch tensors -> fp32 sum + partials ----------------
__global__ __launch_bounds__(256) void k_gn_partB(const float* __restrict__ p0,
                                                  const unsigned short* __restrict__ q1,
                                                  const unsigned short* __restrict__ q2,
                                                  const unsigned short* __restrict__ q3,
                                                  const unsigned short* __restrict__ q4,
                                                  float* __restrict__ sumOut,
                                                  float* __restrict__ part) {
  int bg = blockIdx.y, blk = blockIdx.x, t = threadIdx.x;
  size_t start = (size_t)bg * ((size_t)CPG * NN) + (size_t)blk * 8192;
  const float4* f0 = (const float4*)(p0 + start);
  const ushort4* b1 = (const ushort4*)(q1 + start);
  const ushort4* b2 = (const ushort4*)(q2 + start);
  const ushort4* b3 = (const ushort4*)(q3 + start);
  const ushort4* b4 = (const ushort4*)(q4 + start);
  float4* so = (float4*)(sumOut + start);
  float s = 0.f, ss = 0.f;
  for (int i = t; i < 2048; i += 256) {
    float4 x = f0[i];
    ushort4 u;
    u = b1[i]; x.x += bf2f(u.x); x.y += bf2f(u.y); x.z += bf2f(u.z); x.w += bf2f(u.w);
    u = b2[i]; x.x += bf2f(u.x); x.y += bf2f(u.y); x.z += bf2f(u.z); x.w += bf2f(u.w);
    u = b3[i]; x.x += bf2f(u.x); x.y += bf2f(u.y); x.z += bf2f(u.z); x.w += bf2f(u.w);
    u = b4[i]; x.x += bf2f(u.x); x.y += bf2f(u.y); x.z += bf2f(u.z); x.w += bf2f(u.w);
    so[i] = x;
    s += x.x + x.y + x.z + x.w;
    ss += x.x * x.x + x.y * x.y + x.z * x.z + x.w * x.w;
  }
  __shared__ float rs[256], rq[256];
  rs[t] = s; rq[t] = ss; __syncthreads();
  for (int off = 128; off; off >>= 1) { if (t < off) { rs[t] += rs[t + off]; rq[t] += rq[t + off]; } __syncthreads(); }
  if (t == 0) { part[(bg * 64 + blk) * 2] = rs[0]; part[(bg * 64 + blk) * 2 + 1] = rq[0]; }
}

// out = GN(p0[+p1]) (+ q0) (+ q1) — reduces 64 partials per block
__global__ __launch_bounds__(256) void k_gn_apply(const float* __restrict__ p0, const float* __restrict__ p1,
                                                  const float* __restrict__ part, const float* __restrict__ g,
                                                  const float* __restrict__ be,
                                                  const float* __restrict__ q0, const float* __restrict__ q1,
                                                  float* __restrict__ out) {
  size_t i4 = (size_t)blockIdx.x * 256 + threadIdx.x;
  size_t i = i4 * 4;
  int chan = (int)(i >> 15) & 63;
  int bg = (int)(i >> 19);
  __shared__ float smu, srr;
  int t = threadIdx.x;
  if (t < 64) {
    float s = part[(bg * 64 + t) * 2], ss = part[(bg * 64 + t) * 2 + 1];
#pragma unroll
    for (int off = 32; off; off >>= 1) { s += __shfl_xor(s, off); ss += __shfl_xor(ss, off); }
    if (t == 0) {
      float inv = 1.f / (float)((size_t)CPG * NN);
      float mu = s * inv;
      float var = ss * inv - mu * mu;
      smu = mu; srr = rsqrtf(var + EPSV);
    }
  }
  __syncthreads();
  float mu = smu, rr = srr;
  float4 x = ((const float4*)p0)[i4];
  if (p1) { float4 y4 = ((const float4*)p1)[i4]; x.x += y4.x; x.y += y4.y; x.z += y4.z; x.w += y4.w; }
  float gc = g[chan], bc = be[chan];
  float4 v;
  v.x = (x.x - mu) * rr * gc + bc;
  v.y = (x.y - mu) * rr * gc + bc;
  v.z = (x.z - mu) * rr * gc + bc;
  v.w = (x.w - mu) * rr * gc + bc;
  if (q0) { float4 y4 = ((const float4*)q0)[i4]; v.x += y4.x; v.y += y4.y; v.z += y4.z; v.w += y4.w; }
  if (q1) { float4 y4 = ((const float4*)q1)[i4]; v.x += y4.x; v.y += y4.y; v.z += y4.z; v.w += y4.w; }
  ((float4*)out)[i4] = v;
}

extern "C" void kernel_launch(void* const* d_in, const int* in_sizes, int n_in,
                              void* d_out, int out_size, void* d_ws, size_t ws_size,
                              hipStream_t stream) {
  (void)in_sizes; (void)n_in; (void)out_size; (void)ws_size;
  const float* y     = (const float*)d_in[0];
  const float* a1    = (const float*)d_in[1];
  const float* a2    = (const float*)d_in[2];
  const float* nv1   = (const float*)d_in[3];
  const float* nv2   = (const float*)d_in[4];
  const float* gcn_w = (const float*)d_in[5];
  const float* gcn_b = (const float*)d_in[6];
  const float* s_wq  = (const float*)d_in[7];
  const float* s_wk  = (const float*)d_in[8];
  const float* s_wv  = (const float*)d_in[9];
  const float* s_pk  = (const float*)d_in[10];
  const float* s_pv  = (const float*)d_in[11];
  const float* s_wo  = (const float*)d_in[12];
  const float* s_bo  = (const float*)d_in[13];
  const float* t_wq  = (const float*)d_in[14];
  const float* t_wk  = (const float*)d_in[15];
  const float* t_wv  = (const float*)d_in[16];
  const float* t_bq  = (const float*)d_in[17];
  const float* t_bk  = (const float*)d_in[18];
  const float* t_bv  = (const float*)d_in[19];
  const float* t_wo  = (const float*)d_in[20];
  const float* t_bo  = (const float*)d_in[21];
  const float* t_l1w = (const float*)d_in[22];
  const float* t_l1b = (const float*)d_in[23];
  const float* t_l2w = (const float*)d_in[24];
  const float* t_l2b = (const float*)d_in[25];
  const float* ln1g  = (const float*)d_in[26];
  const float* ln1b  = (const float*)d_in[27];
  const float* ln2g  = (const float*)d_in[28];
  const float* ln2b  = (const float*)d_in[29];
  const float* gnlg  = (const float*)d_in[30];
  const float* gnlb  = (const float*)d_in[31];
  const float* gnsg  = (const float*)d_in[32];
  const float* gnsb  = (const float*)d_in[33];
  const float* gntg  = (const float*)d_in[34];
  const float* gntb  = (const float*)d_in[35];
  const float* ff1w  = (const float*)d_in[36];
  const float* ff1b  = (const float*)d_in[37];
  const float* ff2w  = (const float*)d_in[38];
  const float* ff2b  = (const float*)d_in[39];
  const float* gn2g  = (const float*)d_in[40];
  const float* gn2b  = (const float*)d_in[41];

  float* ws = (float*)d_ws;
  float* adp   = ws;
  float* part  = ws + 65536;
  unsigned short* a1_bf   = (unsigned short*)(ws + 131072);
  unsigned short* a2_bf   = (unsigned short*)(ws + 163840);
  unsigned short* adp_bf  = (unsigned short*)(ws + 196608);
  unsigned short* gcnw_bf = (unsigned short*)(ws + 229376);
  unsigned short* xs_bf   = (unsigned short*)(ws + 262144);   // ends 2359296
  unsigned short* swoT = (unsigned short*)(ws + 2359296);
  unsigned short* twoT = (unsigned short*)(ws + 2361344);
  unsigned short* ff1T = (unsigned short*)(ws + 2363392);
  unsigned short* ff2T = (unsigned short*)(ws + 2367488);
  unsigned short* kpb  = (unsigned short*)(ws + 131072);
  unsigned short* PkT  = (unsigned short*)(ws + 720896);
  unsigned short* PvT  = (unsigned short*)(ws + 729088);
  unsigned short* vptb = (unsigned short*)(ws + 1179648);
  const size_t SLOT = 4194304;
  float* G0 = ws + SLOT * 1;
  float* G1 = ws + SLOT * 2;
  float* G2 = ws + SLOT * 3;
  float* G3 = ws + SLOT * 4;
  float* G4 = ws + SLOT * 5;
  float* G5 = ws + SLOT * 6;
  float* G6 = ws + SLOT * 7;
  unsigned short* U1 = (unsigned short*)G3;
  unsigned short* U2 = (unsigned short*)G3 + 4194304;
  unsigned short* U3 = (unsigned short*)G4;
  unsigned short* U4 = (unsigned short*)G4 + 4194304;
  unsigned short* U5 = (unsigned short*)G5;
  unsigned short* U6 = (unsigned short*)G5 + 4194304;
  unsigned short* s0bf = (unsigned short*)G1;                 // 8MB
  unsigned short* Q1bf = (unsigned short*)G0;                 // 8MB
  unsigned short* Q3bf = (unsigned short*)G0 + 4194304;       // 8MB (G0 second half)
  unsigned short* Q2bf = (unsigned short*)G6;                 // 8MB
  unsigned short* xkT = (unsigned short*)G4;
  unsigned short* xvT = (unsigned short*)G5;
  float* out = (float*)d_out;

  const long BS = 2097152;

  // ---- adaptive adjacency + bf16 casts ----
  k_adp<<<256, 256, 0, stream>>>(nv1, nv2, adp);
  k_castW<<<736, 256, 0, stream>>>(a1, a2, gcn_w, s_wo, t_wo, ff1w, ff2w,
                                   a1_bf, a2_bf, gcnw_bf, swoT, twoT, ff1T, ff2T);
  k_cast<<<256, 256, 0, stream>>>(adp, adp_bf);

  // ---- xs (B,L,K,C) fp32 + bf16 ----
  k_tr<<<dim3(512, 8), 256, 0, stream>>>(y, G2, nullptr, xs_bf, BS, 128, 32768, 1, BS, 64, 1, 16384, 64, 128);

  // ---- AdaptiveGCN (all-bf16 branch tensors) ----
  k_mix0<<<1024, 64, 0, stream>>>(xs_bf, gcnw_bf, gcn_b, s0bf);
  k_mix6<<<dim3(1024, 3), 64, 0, stream>>>(xs_bf, gcnw_bf, U1, U2, U3, U4, U5, U6);
  k_adj2M<<<512, 256, 0, stream>>>(a1_bf, U2, U1, Q1bf);
  k_adj2M<<<512, 256, 0, stream>>>(a2_bf, U4, U3, Q2bf);
  k_adj2M<<<512, 256, 0, stream>>>(adp_bf, U6, U5, Q3bf);
  k_gn_partB<<<dim3(64, 8), 256, 0, stream>>>(y, s0bf, Q1bf, Q2bf, Q3bf, G3, part);
  k_gn_apply<<<4096, 256, 0, stream>>>(G3, nullptr, part, gnlg, gnlb, nullptr, nullptr, G0);

  // ---- Linformer spatial attention (G2 = xs) ----
  k_castP<<<dim3(16, 2), 256, 0, stream>>>(s_pk, s_pv, PkT, PvT);
  k_qkv_s<<<1024, 256, 0, stream>>>(G2, s_wq, s_wk, s_wv, (unsigned short*)G3, xkT, xvT);
  k_sprojM<<<dim3(256, 2), 256, 0, stream>>>(xkT, xvT, PkT, PvT, kpb, vptb);
  k_attnH<64, 1><<<512, 512, 0, stream>>>((unsigned short*)G3, kpb, vptb, (unsigned short*)G6);
  k_lin64<<<1024, 256, 0, stream>>>((unsigned short*)G6, swoT, s_bo, G4);
  k_tr<<<dim3(512, 8), 256, 0, stream>>>(G4, G1, y, nullptr, BS, 64, 16384, 1, BS, 128, 1, 32768, 128, 64);
  k_gn_part<<<dim3(64, 8), 256, 0, stream>>>(G1, nullptr, nullptr, nullptr, nullptr, nullptr, part);
  k_gn_apply<<<4096, 256, 0, stream>>>(G1, nullptr, part, gnsg, gnsb, nullptr, nullptr, G1);

  // ---- temporal transformer layer ----
  k_tr<<<dim3(512, 8), 256, 0, stream>>>(y, G2, nullptr, nullptr, BS, 128, 32768, 1, BS, 8192, 1, 64, 64, 128);
  k_qkv_t<<<1024, 256, 0, stream>>>(G2, t_wq, t_wk, t_wv, t_bq, t_bk, t_bv,
                                    (unsigned short*)G3, (unsigned short*)G4, (unsigned short*)G5);
  k_attnH<128, 0><<<512, 512, 0, stream>>>((unsigned short*)G3, (unsigned short*)G4, (unsigned short*)G5,
                                           (unsigned short*)G6);
  k_lin64<<<1024, 256, 0, stream>>>((unsigned short*)G6, twoT, t_bo, G3);
  k_tffn<<<1024, 256, 0, stream>>>(G2, G3, t_l1w, t_l1b, t_l2w, t_l2b,
                                   ln1g, ln1b, ln2g, ln2b, G6);
  k_tr<<<dim3(512, 8), 256, 0, stream>>>(G6, G2, y, nullptr, BS, 8192, 64, 1, BS, 128, 1, 32768, 128, 64);
  k_gn_part<<<dim3(64, 8), 256, 0, stream>>>(G2, nullptr, nullptr, nullptr, nullptr, nullptr, part);
  k_gn_apply<<<4096, 256, 0, stream>>>(G2, nullptr, part, gntg, gntb, G0, G1, G3);

  // ---- fuse + channel FFN + final GroupNorm ----
  k_tr<<<dim3(512, 8), 256, 0, stream>>>(G3, nullptr, nullptr, (unsigned short*)G4,
                                         BS, 128, 32768, 1, BS, 8192, 1, 64, 64, 128);
  k_cffn<<<1024, 256, 0, stream>>>((unsigned short*)G4, ff1T, ff2T, ff1b, ff2b, G5);
  k_tr<<<dim3(512, 8), 256, 0, stream>>>(G5, out, G3, nullptr, BS, 8192, 64, 1, BS, 128, 1, 32768, 128, 64);
  k_gn_part<<<dim3(64, 8), 256, 0, stream>>>(out, nullptr, nullptr, nullptr, nullptr, nullptr, part);
  k_gn_apply<<<4096, 256, 0, stream>>>(out, nullptr, part, gn2g, gn2b, nullptr, nullptr, out);
}

// Round 18
// 387.337 us; speedup vs baseline: 1.6760x; 1.0875x over previous
//
#include <hip/hip_runtime.h>
#include <math.h>

constexpr int CC = 64, KK = 256, LL = 128;
constexpr int NN = KK * LL;          // 32768
constexpr int PR = 64;               // Linformer projection
constexpr int CPG = 16;              // channels per group (C / 4)
constexpr float EPSV = 1e-5f;
constexpr float SCL = 0.35355339059327373f;  // 1/sqrt(8)

typedef __attribute__((ext_vector_type(8))) short short8;      // 8 bf16 (4 VGPR)
typedef __attribute__((ext_vector_type(4))) float f32x4;       // MFMA 16x16 acc

__device__ __forceinline__ unsigned short f2bf(float x) {
  union { float f; unsigned int u; } v; v.f = x;
  unsigned int r = (v.u + 0x7FFFu + ((v.u >> 16) & 1u)) >> 16;
  return (unsigned short)r;
}
__device__ __forceinline__ float bf2f(unsigned short x) {
  union { unsigned int u; float f; } v; v.u = ((unsigned int)x) << 16;
  return v.f;
}

// ---------------- adaptive adjacency: softmax(relu(nv1@nv2), axis=1) -> bf16 ----------------
__global__ __launch_bounds__(256) void k_adp(const float* __restrict__ nv1,
                                             const float* __restrict__ nv2,
                                             unsigned short* __restrict__ adp_bf) {
  int w = blockIdx.x, v = threadIdx.x;
  float s = 0.f;
  for (int d = 0; d < 10; ++d) s += nv1[w * 10 + d] * nv2[d * KK + v];
  s = fmaxf(s, 0.f);
  __shared__ float red[256];
  red[v] = s; __syncthreads();
  for (int off = 128; off; off >>= 1) { if (v < off) red[v] = fmaxf(red[v], red[v + off]); __syncthreads(); }
  float m = red[0]; __syncthreads();
  float e = expf(s - m);
  red[v] = e; __syncthreads();
  for (int off = 128; off; off >>= 1) { if (v < off) red[v] += red[v + off]; __syncthreads(); }
  adp_bf[w * KK + v] = f2bf(e / red[0]);
}

// ---------------- fused cast: a1, a2, gcn_w plain; 10 weight matrices transposed; grid 832 ----------------
__global__ __launch_bounds__(256) void k_castW(const float* __restrict__ s0, const float* __restrict__ s1,
                                               const float* __restrict__ s2,
                                               const float* __restrict__ swo, const float* __restrict__ two,
                                               const float* __restrict__ f1, const float* __restrict__ f2,
                                               const float* __restrict__ swq, const float* __restrict__ swk,
                                               const float* __restrict__ swv,
                                               const float* __restrict__ twq, const float* __restrict__ twk,
                                               const float* __restrict__ twv,
                                               unsigned short* __restrict__ d0, unsigned short* __restrict__ d1,
                                               unsigned short* __restrict__ d2,
                                               unsigned short* __restrict__ swoT, unsigned short* __restrict__ twoT,
                                               unsigned short* __restrict__ ff1T, unsigned short* __restrict__ ff2T,
                                               unsigned short* __restrict__ swqT, unsigned short* __restrict__ swkT,
                                               unsigned short* __restrict__ swvT,
                                               unsigned short* __restrict__ twqT, unsigned short* __restrict__ twkT,
                                               unsigned short* __restrict__ twvT) {
  int i = blockIdx.x * 256 + threadIdx.x;
  if (i < 65536) d0[i] = f2bf(s0[i]);
  else if (i < 131072) d1[i - 65536] = f2bf(s1[i - 65536]);
  else if (i < 159744) d2[i - 131072] = f2bf(s2[i - 131072]);
  else if (i >= 163840) {
    int j = i - 163840;
    if (j < 4096) { int r = j >> 6, c = j & 63; swoT[c * 64 + r] = f2bf(swo[j]); }
    else if (j < 8192) { int q = j - 4096; int r = q >> 6, c = q & 63; twoT[c * 64 + r] = f2bf(two[q]); }
    else if (j < 16384) { int q = j - 8192; int r = q >> 7, c = q & 127; ff1T[c * 64 + r] = f2bf(f1[q]); }
    else if (j < 24576) { int q = j - 16384; int r = q >> 6, c = q & 63; ff2T[c * 128 + r] = f2bf(f2[q]); }
    else if (j < 28672) { int q = j - 24576; int r = q >> 6, c = q & 63; swqT[c * 64 + r] = f2bf(swq[q]); }
    else if (j < 32768) { int q = j - 28672; int r = q >> 6, c = q & 63; swkT[c * 64 + r] = f2bf(swk[q]); }
    else if (j < 36864) { int q = j - 32768; int r = q >> 6, c = q & 63; swvT[c * 64 + r] = f2bf(swv[q]); }
    else if (j < 40960) { int q = j - 36864; int r = q >> 6, c = q & 63; twqT[c * 64 + r] = f2bf(twq[q]); }
    else if (j < 45056) { int q = j - 40960; int r = q >> 6, c = q & 63; twkT[c * 64 + r] = f2bf(twk[q]); }
    else if (j < 49152) { int q = j - 45056; int r = q >> 6, c = q & 63; twvT[c * 64 + r] = f2bf(twv[q]); }
  }
}

// ---------------- transpose-cast P (256 x 64) -> PT bf16 (64 x 256); grid (16, 2) ----------------
__global__ __launch_bounds__(256) void k_castP(const float* __restrict__ P0, const float* __restrict__ P1,
                                               unsigned short* __restrict__ T0, unsigned short* __restrict__ T1) {
  const float* P = blockIdx.y ? P1 : P0;
  unsigned short* T = blockIdx.y ? T1 : T0;
  int tv = blockIdx.x >> 1, tc = blockIdx.x & 1;
  int n0 = tv * 32, c0 = tc * 32;
  __shared__ float s[32][33];
  int tx = threadIdx.x & 31, ty = threadIdx.x >> 5;
#pragma unroll
  for (int j = 0; j < 4; ++j)
    s[ty + j * 8][tx] = P[(size_t)(n0 + ty + j * 8) * 64 + c0 + tx];
  __syncthreads();
#pragma unroll
  for (int j = 0; j < 4; ++j)
    T[(size_t)(c0 + ty + j * 8) * 256 + n0 + tx] = f2bf(s[tx][ty + j * 8]);
}

// ---------------- s0 term (bf16 out) ----------------
__global__ __launch_bounds__(64) void k_mix0(const unsigned short* __restrict__ Xbf,
                                             const unsigned short* __restrict__ Wbf,
                                             const float* __restrict__ bias,
                                             unsigned short* __restrict__ s0) {
  int pb = blockIdx.x;
  int lh = pb & 1;
  int k = (pb >> 1) & 255;
  int b = pb >> 9;
  int lane = threadIdx.x;
  int lr = lane & 15, g = lane >> 4;
  short8 af[4][2], bfv[4][2];
#pragma unroll
  for (int ot = 0; ot < 4; ++ot)
#pragma unroll
    for (int kc = 0; kc < 2; ++kc)
      af[ot][kc] = *(const short8*)(Wbf + (size_t)(ot * 16 + lr) * 448 + kc * 32 + g * 8);
#pragma unroll
  for (int ct = 0; ct < 4; ++ct)
#pragma unroll
    for (int kc = 0; kc < 2; ++kc)
      bfv[ct][kc] = *(const short8*)(Xbf + ((size_t)(b * 128 + lh * 64 + ct * 16 + lr) * 256 + k) * 64 + kc * 32 + g * 8);
  f32x4 acc[4][4];
#pragma unroll
  for (int ot = 0; ot < 4; ++ot)
#pragma unroll
    for (int ct = 0; ct < 4; ++ct) acc[ot][ct] = f32x4{0.f, 0.f, 0.f, 0.f};
#pragma unroll
  for (int kc = 0; kc < 2; ++kc)
#pragma unroll
    for (int ot = 0; ot < 4; ++ot)
#pragma unroll
      for (int ct = 0; ct < 4; ++ct)
        acc[ot][ct] = __builtin_amdgcn_mfma_f32_16x16x32_bf16(af[ot][kc], bfv[ct][kc], acc[ot][ct], 0, 0, 0);
#pragma unroll
  for (int ot = 0; ot < 4; ++ot)
#pragma unroll
    for (int ct = 0; ct < 4; ++ct) {
#pragma unroll
      for (int reg = 0; reg < 4; ++reg) {
        int o = ot * 16 + g * 4 + reg;
        s0[(size_t)(b * 64 + o) * NN + (size_t)k * 128 + lh * 64 + ct * 16 + lr] = f2bf(acc[ot][ct][reg] + bias[o]);
      }
    }
}

// ---------------- U terms ----------------
__global__ __launch_bounds__(64) void k_mix6(const unsigned short* __restrict__ Xbf,
                                             const unsigned short* __restrict__ Wbf,
                                             unsigned short* __restrict__ U1, unsigned short* __restrict__ U2,
                                             unsigned short* __restrict__ U3, unsigned short* __restrict__ U4,
                                             unsigned short* __restrict__ U5, unsigned short* __restrict__ U6) {
  unsigned short* Us[6] = {U1, U2, U3, U4, U5, U6};
  int pb = blockIdx.x;
  int sy = blockIdx.y;
  int b = pb >> 9;
  int rem = pb & 511;
  int l = rem >> 2;
  int kq = (rem & 3) * 64;
  size_t posbase = ((size_t)(b * 128 + l)) * 256 + kq;
  int lane = threadIdx.x;
  int lr = lane & 15, g = lane >> 4;

  short8 af[4][2];
#pragma unroll
  for (int rt = 0; rt < 4; ++rt)
#pragma unroll
    for (int kc = 0; kc < 2; ++kc)
      af[rt][kc] = *(const short8*)(Xbf + (posbase + rt * 16 + lr) * 64 + kc * 32 + g * 8);

  for (int si = 0; si < 2; ++si) {
    int s = sy * 2 + 1 + si;
    short8 bfv[4][2];
#pragma unroll
    for (int ct = 0; ct < 4; ++ct)
#pragma unroll
      for (int kc = 0; kc < 2; ++kc)
        bfv[ct][kc] = *(const short8*)(Wbf + (size_t)(ct * 16 + lr) * 448 + s * 64 + kc * 32 + g * 8);
    f32x4 acc[4][4];
#pragma unroll
    for (int rt = 0; rt < 4; ++rt)
#pragma unroll
      for (int ct = 0; ct < 4; ++ct) acc[rt][ct] = f32x4{0.f, 0.f, 0.f, 0.f};
#pragma unroll
    for (int kc = 0; kc < 2; ++kc)
#pragma unroll
      for (int rt = 0; rt < 4; ++rt)
#pragma unroll
        for (int ct = 0; ct < 4; ++ct)
          acc[rt][ct] = __builtin_amdgcn_mfma_f32_16x16x32_bf16(af[rt][kc], bfv[ct][kc], acc[rt][ct], 0, 0, 0);
    unsigned short* dst = Us[s - 1];
#pragma unroll
    for (int rt = 0; rt < 4; ++rt)
#pragma unroll
      for (int ct = 0; ct < 4; ++ct) {
        int o = ct * 16 + lr;
        int k = kq + rt * 16 + g * 4;
        ushort4 pk;
        pk.x = f2bf(acc[rt][ct][0]); pk.y = f2bf(acc[rt][ct][1]);
        pk.z = f2bf(acc[rt][ct][2]); pk.w = f2bf(acc[rt][ct][3]);
        *(ushort4*)&dst[((size_t)(b * 64 + o) * 128 + l) * 256 + k] = pk;
      }
  }
}

// ---------------- fused 2-hop (bf16 out) ----------------
__global__ __launch_bounds__(256) void k_adj2M(const unsigned short* __restrict__ Abf,
                                               const unsigned short* __restrict__ Ueven,
                                               const unsigned short* __restrict__ Uodd,
                                               unsigned short* __restrict__ out) {
  __shared__ unsigned short sH[32 * 256];
  int lq = blockIdx.x & 3, bc = blockIdx.x >> 2;
  int tid = threadIdx.x, wid = tid >> 6, lane = tid & 63;
  int lr = lane & 15, g = lane >> 4;
  int wbase = wid * 64;
  const unsigned short* aP = Abf + (size_t)(wbase + lr) * 256 + g * 8;
  const unsigned short* bP = Ueven + ((size_t)bc * 128 + lq * 32 + lr) * 256 + g * 8;

  f32x4 acc[4][2];
#pragma unroll
  for (int i = 0; i < 4; ++i)
#pragma unroll
    for (int j = 0; j < 2; ++j) acc[i][j] = f32x4{0.f, 0.f, 0.f, 0.f};
  for (int k0 = 0; k0 < 256; k0 += 32) {
    short8 af[4], bfv[2];
#pragma unroll
    for (int i = 0; i < 4; ++i) af[i] = *(const short8*)(aP + (size_t)i * 16 * 256 + k0);
#pragma unroll
    for (int i = 0; i < 2; ++i) bfv[i] = *(const short8*)(bP + (size_t)i * 16 * 256 + k0);
#pragma unroll
    for (int rm = 0; rm < 4; ++rm)
#pragma unroll
      for (int cn = 0; cn < 2; ++cn)
        acc[rm][cn] = __builtin_amdgcn_mfma_f32_16x16x32_bf16(af[rm], bfv[cn], acc[rm][cn], 0, 0, 0);
  }
  {
    const unsigned short* aT = Uodd + (size_t)bc * NN + (size_t)(lq * 32) * 256;
#pragma unroll
    for (int rm = 0; rm < 4; ++rm)
#pragma unroll
      for (int cn = 0; cn < 2; ++cn) {
        int l = cn * 16 + lr;
        int v = wbase + rm * 16 + g * 4;
        ushort4 av = *(const ushort4*)&aT[(size_t)l * 256 + v];
        ushort4 pk;
        pk.x = f2bf(acc[rm][cn][0] + bf2f(av.x));
        pk.y = f2bf(acc[rm][cn][1] + bf2f(av.y));
        pk.z = f2bf(acc[rm][cn][2] + bf2f(av.z));
        pk.w = f2bf(acc[rm][cn][3] + bf2f(av.w));
        int bo = ((l * 256 + v) * 2) ^ ((l & 7) << 4);
        *(ushort4*)((char*)sH + bo) = pk;
      }
  }
  __syncthreads();

  f32x4 c2[4][2];
#pragma unroll
  for (int i = 0; i < 4; ++i)
#pragma unroll
    for (int j = 0; j < 2; ++j) c2[i][j] = f32x4{0.f, 0.f, 0.f, 0.f};
  for (int k0 = 0; k0 < 256; k0 += 32) {
    short8 af[4], bfv[2];
#pragma unroll
    for (int i = 0; i < 4; ++i) af[i] = *(const short8*)(aP + (size_t)i * 16 * 256 + k0);
#pragma unroll
    for (int cn = 0; cn < 2; ++cn) {
      int l = cn * 16 + lr;
      int bo = ((l * 256 + k0 + g * 8) * 2) ^ ((l & 7) << 4);
      bfv[cn] = *(const short8*)((char*)sH + bo);
    }
#pragma unroll
    for (int rm = 0; rm < 4; ++rm)
#pragma unroll
      for (int cn = 0; cn < 2; ++cn)
        c2[rm][cn] = __builtin_amdgcn_mfma_f32_16x16x32_bf16(af[rm], bfv[cn], c2[rm][cn], 0, 0, 0);
  }
  unsigned short* dst = out + (size_t)bc * NN + lq * 32;
#pragma unroll
  for (int rm = 0; rm < 4; ++rm)
#pragma unroll
    for (int cn = 0; cn < 2; ++cn) {
      int col = cn * 16 + lr;
      int row = wbase + rm * 16 + g * 4;
#pragma unroll
      for (int j = 0; j < 4; ++j)
        dst[(size_t)(row + j) * 128 + col] = f2bf(c2[rm][cn][j]);
    }
}

// ---------------- generic (c,l)-plane transpose; optional dst/add/bf16 ----------------
__global__ __launch_bounds__(256) void k_tr(const float* __restrict__ src, float* __restrict__ dst,
                                            const float* __restrict__ add,
                                            unsigned short* __restrict__ dstBf,
                                            long sb, long sk, long sc, long sl,
                                            long db, long dk, long dc, long dl, int nC, int nL) {
  int outer = blockIdx.x;
  int b = outer >> 8, k = outer & 255;
  int tilesL = nL >> 5;
  int tC = blockIdx.y / tilesL, tL = blockIdx.y % tilesL;
  int c0 = tC << 5, l0 = tL << 5;
  __shared__ float s[32][33];
  int tx = threadIdx.x & 31, ty = threadIdx.x >> 5;
  const float* sp = src + (long)b * sb + (long)k * sk;
#pragma unroll
  for (int j = 0; j < 4; ++j) {
    int cc = c0 + ty + j * 8;
    s[ty + j * 8][tx] = sp[(long)cc * sc + (long)(l0 + tx) * sl];
  }
  __syncthreads();
  long dbase = (long)b * db + (long)k * dk;
#pragma unroll
  for (int j = 0; j < 4; ++j) {
    int ll = l0 + ty + j * 8;
    long off = dbase + (long)(c0 + tx) * dc + (long)ll * dl;
    float val = s[tx][ty + j * 8];
    if (add) val += add[off];
    if (dst) dst[off] = val;
    if (dstBf) dstBf[off] = f2bf(val);
  }
}

// ---------------- spatial QKV (MFMA, bf16 in/out): Q RM; K^T,V^T [bl][c][n] ----------------
__global__ __launch_bounds__(256) void k_qkvs_M(const unsigned short* __restrict__ Xbf,
                                                const unsigned short* __restrict__ wqT,
                                                const unsigned short* __restrict__ wkT,
                                                const unsigned short* __restrict__ wvT,
                                                unsigned short* __restrict__ qb,
                                                unsigned short* __restrict__ xkT,
                                                unsigned short* __restrict__ xvT) {
  int r0 = blockIdx.x * 64;
  int t = threadIdx.x, w = t >> 6, lane = t & 63;
  int lr = lane & 15, g = lane >> 4;
  const unsigned short* aP = Xbf + (size_t)(r0 + w * 16 + lr) * 64 + g * 8;
  short8 ax0 = *(const short8*)aP;
  short8 ax1 = *(const short8*)(aP + 32);
  // Q (RM)
  {
    f32x4 acc[4];
#pragma unroll
    for (int ct = 0; ct < 4; ++ct) acc[ct] = f32x4{0.f, 0.f, 0.f, 0.f};
#pragma unroll
    for (int ct = 0; ct < 4; ++ct) {
      short8 b0 = *(const short8*)(wqT + (size_t)(ct * 16 + lr) * 64 + g * 8);
      short8 b1 = *(const short8*)(wqT + (size_t)(ct * 16 + lr) * 64 + 32 + g * 8);
      acc[ct] = __builtin_amdgcn_mfma_f32_16x16x32_bf16(ax0, b0, acc[ct], 0, 0, 0);
      acc[ct] = __builtin_amdgcn_mfma_f32_16x16x32_bf16(ax1, b1, acc[ct], 0, 0, 0);
    }
#pragma unroll
    for (int ct = 0; ct < 4; ++ct)
#pragma unroll
      for (int reg = 0; reg < 4; ++reg)
        qb[(size_t)(r0 + w * 16 + g * 4 + reg) * 64 + ct * 16 + lr] = f2bf(acc[ct][reg]);
  }
  // K^T, V^T (operand-swapped)
  short8 bx0[4], bx1[4];
#pragma unroll
  for (int ct = 0; ct < 4; ++ct) {
    const unsigned short* bP = Xbf + (size_t)(r0 + ct * 16 + lr) * 64 + g * 8;
    bx0[ct] = *(const short8*)bP;
    bx1[ct] = *(const short8*)(bP + 32);
  }
  int bl = r0 >> 8, nb = r0 & 255;
#pragma unroll
  for (int which = 0; which < 2; ++which) {
    const unsigned short* WT = which ? wvT : wkT;
    unsigned short* dstb = which ? xvT : xkT;
    short8 aw0 = *(const short8*)(WT + (size_t)(w * 16 + lr) * 64 + g * 8);
    short8 aw1 = *(const short8*)(WT + (size_t)(w * 16 + lr) * 64 + 32 + g * 8);
    f32x4 acc[4];
#pragma unroll
    for (int ct = 0; ct < 4; ++ct) {
      acc[ct] = f32x4{0.f, 0.f, 0.f, 0.f};
      acc[ct] = __builtin_amdgcn_mfma_f32_16x16x32_bf16(aw0, bx0[ct], acc[ct], 0, 0, 0);
      acc[ct] = __builtin_amdgcn_mfma_f32_16x16x32_bf16(aw1, bx1[ct], acc[ct], 0, 0, 0);
    }
#pragma unroll
    for (int ct = 0; ct < 4; ++ct)
#pragma unroll
      for (int reg = 0; reg < 4; ++reg) {
        int o = w * 16 + g * 4 + reg;
        dstb[(size_t)bl * 16384 + (size_t)o * 256 + nb + ct * 16 + lr] = f2bf(acc[ct][reg]);
      }
  }
}

// ---------------- temporal QKV (MFMA, bf16 in/out): Q,K RM + bias; V^T [bk][c][l] + bias ----------------
__global__ __launch_bounds__(256) void k_qkvt_M(const unsigned short* __restrict__ Xbf,
                                                const unsigned short* __restrict__ wqT,
                                                const unsigned short* __restrict__ wkT,
                                                const unsigned short* __restrict__ wvT,
                                                const float* __restrict__ bq, const float* __restrict__ bk_,
                                                const float* __restrict__ bv,
                                                unsigned short* __restrict__ qb,
                                                unsigned short* __restrict__ kb,
                                                unsigned short* __restrict__ vt) {
  int r0 = blockIdx.x * 64;
  int t = threadIdx.x, w = t >> 6, lane = t & 63;
  int lr = lane & 15, g = lane >> 4;
  const unsigned short* aP = Xbf + (size_t)(r0 + w * 16 + lr) * 64 + g * 8;
  short8 ax0 = *(const short8*)aP;
  short8 ax1 = *(const short8*)(aP + 32);
#pragma unroll
  for (int which = 0; which < 2; ++which) {
    const unsigned short* WT = which ? wkT : wqT;
    const float* bias = which ? bk_ : bq;
    unsigned short* dstb = which ? kb : qb;
    f32x4 acc[4];
#pragma unroll
    for (int ct = 0; ct < 4; ++ct) {
      acc[ct] = f32x4{0.f, 0.f, 0.f, 0.f};
      short8 b0 = *(const short8*)(WT + (size_t)(ct * 16 + lr) * 64 + g * 8);
      short8 b1 = *(const short8*)(WT + (size_t)(ct * 16 + lr) * 64 + 32 + g * 8);
      acc[ct] = __builtin_amdgcn_mfma_f32_16x16x32_bf16(ax0, b0, acc[ct], 0, 0, 0);
      acc[ct] = __builtin_amdgcn_mfma_f32_16x16x32_bf16(ax1, b1, acc[ct], 0, 0, 0);
    }
#pragma unroll
    for (int ct = 0; ct < 4; ++ct) {
      float bvv = bias[ct * 16 + lr];
#pragma unroll
      for (int reg = 0; reg < 4; ++reg)
        dstb[(size_t)(r0 + w * 16 + g * 4 + reg) * 64 + ct * 16 + lr] = f2bf(acc[ct][reg] + bvv);
    }
  }
  // V^T (operand-swapped)
  short8 bx0[4], bx1[4];
#pragma unroll
  for (int ct = 0; ct < 4; ++ct) {
    const unsigned short* bP = Xbf + (size_t)(r0 + ct * 16 + lr) * 64 + g * 8;
    bx0[ct] = *(const short8*)bP;
    bx1[ct] = *(const short8*)(bP + 32);
  }
  int bkk = r0 >> 7, lbase = r0 & 127;
  short8 aw0 = *(const short8*)(wvT + (size_t)(w * 16 + lr) * 64 + g * 8);
  short8 aw1 = *(const short8*)(wvT + (size_t)(w * 16 + lr) * 64 + 32 + g * 8);
  f32x4 acc[4];
#pragma unroll
  for (int ct = 0; ct < 4; ++ct) {
    acc[ct] = f32x4{0.f, 0.f, 0.f, 0.f};
    acc[ct] = __builtin_amdgcn_mfma_f32_16x16x32_bf16(aw0, bx0[ct], acc[ct], 0, 0, 0);
    acc[ct] = __builtin_amdgcn_mfma_f32_16x16x32_bf16(aw1, bx1[ct], acc[ct], 0, 0, 0);
  }
#pragma unroll
  for (int ct = 0; ct < 4; ++ct)
#pragma unroll
    for (int reg = 0; reg < 4; ++reg) {
      int o = w * 16 + g * 4 + reg;
      vt[(size_t)bkk * 8192 + (size_t)o * 128 + lbase + ct * 16 + lr] = f2bf(acc[ct][reg] + bv[o]);
    }
}

// ---------------- MFMA sproj ----------------
__global__ __launch_bounds__(256) void k_sprojM(const unsigned short* __restrict__ XkT,
                                                const unsigned short* __restrict__ XvT,
                                                const unsigned short* __restrict__ PkT,
                                                const unsigned short* __restrict__ PvT,
                                                unsigned short* __restrict__ kpb,
                                                unsigned short* __restrict__ vptb) {
  int bl = blockIdx.x;
  int which = blockIdx.y;
  int t = threadIdx.x, w = t >> 6, lane = t & 63;
  int lr = lane & 15, g = lane >> 4;
  const unsigned short* Abase = which ? PvT : XkT + (size_t)bl * 16384;
  const unsigned short* Bbase = which ? XvT + (size_t)bl * 16384 : PkT;
  const unsigned short* aP = Abase + (size_t)(w * 16 + lr) * 256 + g * 8;
  f32x4 acc[4];
#pragma unroll
  for (int ct = 0; ct < 4; ++ct) acc[ct] = f32x4{0.f, 0.f, 0.f, 0.f};
  for (int k0 = 0; k0 < 256; k0 += 32) {
    short8 af = *(const short8*)(aP + k0);
#pragma unroll
    for (int ct = 0; ct < 4; ++ct) {
      short8 bf = *(const short8*)(Bbase + (size_t)(ct * 16 + lr) * 256 + k0 + g * 8);
      acc[ct] = __builtin_amdgcn_mfma_f32_16x16x32_bf16(af, bf, acc[ct], 0, 0, 0);
    }
  }
  if (!which) {
    unsigned short* dst = kpb + (size_t)bl * 4096;
#pragma unroll
    for (int ct = 0; ct < 4; ++ct) {
      int p = ct * 16 + lr;
      int c0 = w * 16 + g * 4;
      ushort4 pk;
      pk.x = f2bf(acc[ct][0]); pk.y = f2bf(acc[ct][1]);
      pk.z = f2bf(acc[ct][2]); pk.w = f2bf(acc[ct][3]);
      *(ushort4*)&dst[(size_t)p * 64 + c0] = pk;
    }
  } else {
    unsigned short* dst = vptb + (size_t)bl * 4096;
#pragma unroll
    for (int ct = 0; ct < 4; ++ct) {
      int c = ct * 16 + lr;
      int p0 = w * 16 + g * 4;
      ushort4 pk;
      pk.x = f2bf(acc[ct][0]); pk.y = f2bf(acc[ct][1]);
      pk.z = f2bf(acc[ct][2]); pk.w = f2bf(acc[ct][3]);
      *(ushort4*)&dst[(size_t)c * 64 + p0] = pk;
    }
  }
}

// ---------------- MFMA 64x64 projection: bf16 in @ W^T + bias -> fp32 ----------------
__global__ __launch_bounds__(256) void k_lin64(const unsigned short* __restrict__ in,
                                               const unsigned short* __restrict__ WT,
                                               const float* __restrict__ bias,
                                               float* __restrict__ out) {
  int r0 = blockIdx.x * 64;
  int t = threadIdx.x, w = t >> 6, lane = t & 63;
  int lr = lane & 15, g = lane >> 4;
  const unsigned short* aP = in + (size_t)(r0 + w * 16 + lr) * 64 + g * 8;
  short8 af0 = *(const short8*)aP;
  short8 af1 = *(const short8*)(aP + 32);
  f32x4 acc[4];
#pragma unroll
  for (int ct = 0; ct < 4; ++ct) acc[ct] = f32x4{0.f, 0.f, 0.f, 0.f};
#pragma unroll
  for (int ct = 0; ct < 4; ++ct) {
    short8 b0 = *(const short8*)(WT + (size_t)(ct * 16 + lr) * 64 + g * 8);
    short8 b1 = *(const short8*)(WT + (size_t)(ct * 16 + lr) * 64 + 32 + g * 8);
    acc[ct] = __builtin_amdgcn_mfma_f32_16x16x32_bf16(af0, b0, acc[ct], 0, 0, 0);
    acc[ct] = __builtin_amdgcn_mfma_f32_16x16x32_bf16(af1, b1, acc[ct], 0, 0, 0);
  }
#pragma unroll
  for (int ct = 0; ct < 4; ++ct) {
    int o = ct * 16 + lr;
    float bv = bias[o];
#pragma unroll
    for (int reg = 0; reg < 4; ++reg)
      out[(size_t)(r0 + w * 16 + g * 4 + reg) * 64 + o] = acc[ct][reg] + bv;
  }
}

// ---------------- fused channel FFN (MFMA) ----------------
__global__ __launch_bounds__(256) void k_cffn(const unsigned short* __restrict__ in,
                                              const unsigned short* __restrict__ ff1T,
                                              const unsigned short* __restrict__ ff2T,
                                              const float* __restrict__ b1,
                                              const float* __restrict__ b2,
                                              float* __restrict__ out) {
  __shared__ unsigned short sH[4][16 * 128];
  int r0 = blockIdx.x * 64;
  int t = threadIdx.x, w = t >> 6, lane = t & 63;
  int lr = lane & 15, g = lane >> 4;
  unsigned short* myH = sH[w];
  const unsigned short* aP = in + (size_t)(r0 + w * 16 + lr) * 64 + g * 8;
  short8 af0 = *(const short8*)aP;
  short8 af1 = *(const short8*)(aP + 32);
  f32x4 acc1[8];
#pragma unroll
  for (int ct = 0; ct < 8; ++ct) acc1[ct] = f32x4{0.f, 0.f, 0.f, 0.f};
#pragma unroll
  for (int ct = 0; ct < 8; ++ct) {
    short8 b0 = *(const short8*)(ff1T + (size_t)(ct * 16 + lr) * 64 + g * 8);
    short8 bx = *(const short8*)(ff1T + (size_t)(ct * 16 + lr) * 64 + 32 + g * 8);
    acc1[ct] = __builtin_amdgcn_mfma_f32_16x16x32_bf16(af0, b0, acc1[ct], 0, 0, 0);
    acc1[ct] = __builtin_amdgcn_mfma_f32_16x16x32_bf16(af1, bx, acc1[ct], 0, 0, 0);
  }
#pragma unroll
  for (int ct = 0; ct < 8; ++ct) {
    int o = ct * 16 + lr;
    float bv = b1[o];
#pragma unroll
    for (int reg = 0; reg < 4; ++reg) {
      int m = g * 4 + reg;
      float h = fmaxf(acc1[ct][reg] + bv, 0.f);
      int bo = ((m * 128 + o) * 2) ^ ((m & 7) << 4);
      *(unsigned short*)((char*)myH + bo) = f2bf(h);
    }
  }
  __syncthreads();
  short8 ha[4];
#pragma unroll
  for (int ks = 0; ks < 4; ++ks) {
    int bo = ((lr * 128 + ks * 32 + g * 8) * 2) ^ ((lr & 7) << 4);
    ha[ks] = *(const short8*)((char*)myH + bo);
  }
  f32x4 acc2[4];
#pragma unroll
  for (int ct = 0; ct < 4; ++ct) acc2[ct] = f32x4{0.f, 0.f, 0.f, 0.f};
#pragma unroll
  for (int ct = 0; ct < 4; ++ct)
#pragma unroll
    for (int ks = 0; ks < 4; ++ks) {
      short8 b0 = *(const short8*)(ff2T + (size_t)(ct * 16 + lr) * 128 + ks * 32 + g * 8);
      acc2[ct] = __builtin_amdgcn_mfma_f32_16x16x32_bf16(ha[ks], b0, acc2[ct], 0, 0, 0);
    }
#pragma unroll
  for (int ct = 0; ct < 4; ++ct) {
    int o = ct * 16 + lr;
    float bv = b2[o];
#pragma unroll
    for (int reg = 0; reg < 4; ++reg)
      out[(size_t)(r0 + w * 16 + g * 4 + reg) * 64 + o] = acc2[ct][reg] + bv;
  }
}

// ---------------- fused LN1 -> FFN(64->8 gelu ->64) -> LN2 ----------------
__global__ __launch_bounds__(256) void k_tffn(const float* __restrict__ A, const float* __restrict__ Bz,
                                              const float* __restrict__ l1w, const float* __restrict__ l1b,
                                              const float* __restrict__ l2w, const float* __restrict__ l2b,
                                              const float* __restrict__ ln1g, const float* __restrict__ ln1b,
                                              const float* __restrict__ ln2g, const float* __restrict__ ln2b,
                                              float* __restrict__ outp) {
  int r0 = blockIdx.x * 64;
  __shared__ float sSrc[64][65];
  __shared__ float sH[64][8];
  __shared__ float sW1[64][8];
  __shared__ float sW2[8][64];
  int t = threadIdx.x;
  for (int i = t; i < 512; i += 256) { ((float*)sW1)[i] = l1w[i]; ((float*)sW2)[i] = l2w[i]; }
  int c = t & 63, rg = t >> 6;
  float g1 = ln1g[c], be1 = ln1b[c];
  for (int it = 0; it < 16; ++it) {
    int r = it * 4 + rg;
    size_t idx = (size_t)(r0 + r) * 64 + c;
    float x = A[idx] + Bz[idx];
    float s = x, ss = x * x;
#pragma unroll
    for (int off = 32; off; off >>= 1) { s += __shfl_xor(s, off); ss += __shfl_xor(ss, off); }
    float mu = s * (1.f / 64.f);
    float var = ss * (1.f / 64.f) - mu * mu;
    sSrc[r][c] = (x - mu) * rsqrtf(var + EPSV) * g1 + be1;
  }
  __syncthreads();
#pragma unroll
  for (int p = 0; p < 2; ++p) {
    int idx = t + 256 * p;
    int row = idx >> 3, j = idx & 7;
    float acc = l1b[j];
    for (int cc = 0; cc < 64; ++cc) acc += sSrc[row][cc] * sW1[cc][j];
    acc = 0.5f * acc * (1.f + erff(acc * 0.70710678118654752440f));
    sH[row][j] = acc;
  }
  __syncthreads();
  float g2 = ln2g[c], be2 = ln2b[c];
  float l2bc = l2b[c];
  for (int it = 0; it < 16; ++it) {
    int r = it * 4 + rg;
    float o = l2bc;
#pragma unroll
    for (int j = 0; j < 8; ++j) o += sH[r][j] * sW2[j][c];
    float x = sSrc[r][c] + o;
    float s = x, ss = x * x;
#pragma unroll
    for (int off = 32; off; off >>= 1) { s += __shfl_xor(s, off); ss += __shfl_xor(ss, off); }
    float mu = s * (1.f / 64.f);
    float var = ss * (1.f / 64.f) - mu * mu;
    outp[(size_t)(r0 + r) * 64 + c] = (x - mu) * rsqrtf(var + EPSV) * g2 + be2;
  }
}

// ---------------- per-head MFMA attention; bf16 out ----------------
template <int NKV, int KVSHIFT>
__global__ __launch_bounds__(512) void k_attnH(const unsigned short* __restrict__ Qb,
                                               const unsigned short* __restrict__ Kb,
                                               const unsigned short* __restrict__ VTb,
                                               unsigned short* __restrict__ O) {
  constexpr int NCT = NKV / 16;
  constexpr int NKS = NKV / 32;
  int blk = blockIdx.x;
  const unsigned short* Qp = Qb + (size_t)blk * 128 * 64;
  unsigned short* Op = O + (size_t)blk * 128 * 64;
  const unsigned short* Kp = Kb + (size_t)(blk >> KVSHIFT) * NKV * 64;
  const unsigned short* VTp = VTb + (size_t)(blk >> KVSHIFT) * 64 * NKV;
  int t = threadIdx.x;
  int h = t >> 6, lane = t & 63, lr = lane & 15, g = lane >> 4;
  __shared__ unsigned short sP[8][16 * NKV];
  unsigned short* myP = sP[h];

  short8 kbf[NCT];
#pragma unroll
  for (int ct = 0; ct < NCT; ++ct)
    kbf[ct] = *(const short8*)(Kp + (size_t)(ct * 16 + lr) * 64 + h * 8);

  int vr = h * 8 + lr; if (vr > 63) vr = 63;
  short8 vbf[NKS];
#pragma unroll
  for (int ks = 0; ks < NKS; ++ks)
    vbf[ks] = *(const short8*)(VTp + (size_t)vr * NKV + ks * 32 + g * 8);

  for (int mt = 0; mt < 8; ++mt) {
    short8 qa = short8{0, 0, 0, 0, 0, 0, 0, 0};
    if (g == 0) qa = *(const short8*)(Qp + (size_t)(mt * 16 + lr) * 64 + h * 8);

    f32x4 sacc[NCT];
#pragma unroll
    for (int ct = 0; ct < NCT; ++ct) sacc[ct] = f32x4{0.f, 0.f, 0.f, 0.f};
#pragma unroll
    for (int ct = 0; ct < NCT; ++ct)
      sacc[ct] = __builtin_amdgcn_mfma_f32_16x16x32_bf16(qa, kbf[ct], sacc[ct], 0, 0, 0);

    float inv4[4];
#pragma unroll
    for (int reg = 0; reg < 4; ++reg) {
      float s = 0.f;
#pragma unroll
      for (int ct = 0; ct < NCT; ++ct) {
        float e = __expf(sacc[ct][reg] * SCL);
        sacc[ct][reg] = e;
        s += e;
      }
      s += __shfl_xor(s, 1); s += __shfl_xor(s, 2); s += __shfl_xor(s, 4); s += __shfl_xor(s, 8);
      inv4[reg] = 1.f / s;
    }

#pragma unroll
    for (int ct = 0; ct < NCT; ++ct)
#pragma unroll
      for (int reg = 0; reg < 4; ++reg) {
        int row = g * 4 + reg;
        int bo = ((row * NKV + ct * 16 + lr) * 2) ^ ((row & 7) << 4);
        *(unsigned short*)((char*)myP + bo) = f2bf(sacc[ct][reg]);
      }
    __syncthreads();

    f32x4 oacc = f32x4{0.f, 0.f, 0.f, 0.f};
#pragma unroll
    for (int ks = 0; ks < NKS; ++ks) {
      int bo = ((lr * NKV + ks * 32 + g * 8) * 2) ^ ((lr & 7) << 4);
      short8 pa = *(const short8*)((char*)myP + bo);
      oacc = __builtin_amdgcn_mfma_f32_16x16x32_bf16(pa, vbf[ks], oacc, 0, 0, 0);
    }
    if (lr < 8) {
#pragma unroll
      for (int reg = 0; reg < 4; ++reg) {
        int row = mt * 16 + g * 4 + reg;
        Op[(size_t)row * 64 + h * 8 + lr] = f2bf(oacc[reg] * inv4[reg]);
      }
    }
    __syncthreads();
  }
}

// ---------------- GroupNorm stats (fp32 inputs, optional sum write-back) ----------------
__global__ __launch_bounds__(256) void k_gn_part(const float* __restrict__ p0, const float* __restrict__ p1,
                                                 const float* __restrict__ p2, const float* __restrict__ p3,
                                                 const float* __restrict__ p4,
                                                 float* __restrict__ sumOut,
                                                 float* __restrict__ part) {
  int bg = blockIdx.y, blk = blockIdx.x, t = threadIdx.x;
  size_t start = (size_t)bg * ((size_t)CPG * NN) + (size_t)blk * 8192;
  const float4* q0 = (const float4*)(p0 + start);
  const float4* q1 = p1 ? (const float4*)(p1 + start) : nullptr;
  const float4* q2 = p2 ? (const float4*)(p2 + start) : nullptr;
  const float4* q3 = p3 ? (const float4*)(p3 + start) : nullptr;
  const float4* q4 = p4 ? (const float4*)(p4 + start) : nullptr;
  float4* so = sumOut ? (float4*)(sumOut + start) : nullptr;
  float s = 0.f, ss = 0.f;
  for (int i = t; i < 2048; i += 256) {
    float4 x = q0[i];
    if (q1) { float4 y4 = q1[i]; x.x += y4.x; x.y += y4.y; x.z += y4.z; x.w += y4.w; }
    if (q2) { float4 y4 = q2[i]; x.x += y4.x; x.y += y4.y; x.z += y4.z; x.w += y4.w; }
    if (q3) { float4 y4 = q3[i]; x.x += y4.x; x.y += y4.y; x.z += y4.z; x.w += y4.w; }
    if (q4) { float4 y4 = q4[i]; x.x += y4.x; x.y += y4.y; x.z += y4.z; x.w += y4.w; }
    if (so) so[i] = x;
    s += x.x + x.y + x.z + x.w;
    ss += x.x * x.x + x.y * x.y + x.z * x.z + x.w * x.w;
  }
  __shared__ float rs[256], rq[256];
  rs[t] = s; rq[t] = ss; __syncthreads();
  for (int off = 128; off; off >>= 1) { if (t < off) { rs[t] += rs[t + off]; rq[t] += rq[t + off]; } __syncthreads(); }
  if (t == 0) { part[(bg * 64 + blk) * 2] = rs[0]; part[(bg * 64 + blk) * 2 + 1] = rq[0]; }
}

// ---------------- GroupNorm stats: y(fp32) + 4 bf16 branch tensors -> fp32 sum + partials ----------------
__global__ __launch_bounds__(256) void k_gn_partB(const float* __restrict__ p0,
                                                  const unsigned short* __restrict__ q1,
                                                  const unsigned short* __restrict__ q2,
                                                  const unsigned short* __restrict__ q3,
                                                  const unsigned short* __restrict__ q4,
                                                  float* __restrict__ sumOut,
                                                  float* __restrict__ part) {
  int bg = blockIdx.y, blk = blockIdx.x, t = threadIdx.x;
  size_t start = (size_t)bg * ((size_t)CPG * NN) + (size_t)blk * 8192;
  const float4* f0 = (const float4*)(p0 + start);
  const ushort4* b1 = (const ushort4*)(q1 + start);
  const ushort4* b2 = (const ushort4*)(q2 + start);
  const ushort4* b3 = (const ushort4*)(q3 + start);
  const ushort4* b4 = (const ushort4*)(q4 + start);
  float4* so = (float4*)(sumOut + start);
  float s = 0.f, ss = 0.f;
  for (int i = t; i < 2048; i += 256) {
    float4 x = f0[i];
    ushort4 u;
    u = b1[i]; x.x += bf2f(u.x); x.y += bf2f(u.y); x.z += bf2f(u.z); x.w += bf2f(u.w);
    u = b2[i]; x.x += bf2f(u.x); x.y += bf2f(u.y); x.z += bf2f(u.z); x.w += bf2f(u.w);
    u = b3[i]; x.x += bf2f(u.x); x.y += bf2f(u.y); x.z += bf2f(u.z); x.w += bf2f(u.w);
    u = b4[i]; x.x += bf2f(u.x); x.y += bf2f(u.y); x.z += bf2f(u.z); x.w += bf2f(u.w);
    so[i] = x;
    s += x.x + x.y + x.z + x.w;
    ss += x.x * x.x + x.y * x.y + x.z * x.z + x.w * x.w;
  }
  __shared__ float rs[256], rq[256];
  rs[t] = s; rq[t] = ss; __syncthreads();
  for (int off = 128; off; off >>= 1) { if (t < off) { rs[t] += rs[t + off]; rq[t] += rq[t + off]; } __syncthreads(); }
  if (t == 0) { part[(bg * 64 + blk) * 2] = rs[0]; part[(bg * 64 + blk) * 2 + 1] = rq[0]; }
}

// out = GN(p0[+p1]) (+ q0) (+ q1) — reduces 64 partials per block
__global__ __launch_bounds__(256) void k_gn_apply(const float* __restrict__ p0, const float* __restrict__ p1,
                                                  const float* __restrict__ part, const float* __restrict__ g,
                                                  const float* __restrict__ be,
                                                  const float* __restrict__ q0, const float* __restrict__ q1,
                                                  float* __restrict__ out) {
  size_t i4 = (size_t)blockIdx.x * 256 + threadIdx.x;
  size_t i = i4 * 4;
  int chan = (int)(i >> 15) & 63;
  int bg = (int)(i >> 19);
  __shared__ float smu, srr;
  int t = threadIdx.x;
  if (t < 64) {
    float s = part[(bg * 64 + t) * 2], ss = part[(bg * 64 + t) * 2 + 1];
#pragma unroll
    for (int off = 32; off; off >>= 1) { s += __shfl_xor(s, off); ss += __shfl_xor(ss, off); }
    if (t == 0) {
      float inv = 1.f / (float)((size_t)CPG * NN);
      float mu = s * inv;
      float var = ss * inv - mu * mu;
      smu = mu; srr = rsqrtf(var + EPSV);
    }
  }
  __syncthreads();
  float mu = smu, rr = srr;
  float4 x = ((const float4*)p0)[i4];
  if (p1) { float4 y4 = ((const float4*)p1)[i4]; x.x += y4.x; x.y += y4.y; x.z += y4.z; x.w += y4.w; }
  float gc = g[chan], bc = be[chan];
  float4 v;
  v.x = (x.x - mu) * rr * gc + bc;
  v.y = (x.y - mu) * rr * gc + bc;
  v.z = (x.z - mu) * rr * gc + bc;
  v.w = (x.w - mu) * rr * gc + bc;
  if (q0) { float4 y4 = ((const float4*)q0)[i4]; v.x += y4.x; v.y += y4.y; v.z += y4.z; v.w += y4.w; }
  if (q1) { float4 y4 = ((const float4*)q1)[i4]; v.x += y4.x; v.y += y4.y; v.z += y4.z; v.w += y4.w; }
  ((float4*)out)[i4] = v;
}

extern "C" void kernel_launch(void* const* d_in, const int* in_sizes, int n_in,
                              void* d_out, int out_size, void* d_ws, size_t ws_size,
                              hipStream_t stream) {
  (void)in_sizes; (void)n_in; (void)out_size; (void)ws_size;
  const float* y     = (const float*)d_in[0];
  const float* a1    = (const float*)d_in[1];
  const float* a2    = (const float*)d_in[2];
  const float* nv1   = (const float*)d_in[3];
  const float* nv2   = (const float*)d_in[4];
  const float* gcn_w = (const float*)d_in[5];
  const float* gcn_b = (const float*)d_in[6];
  const float* s_wq  = (const float*)d_in[7];
  const float* s_wk  = (const float*)d_in[8];
  const float* s_wv  = (const float*)d_in[9];
  const float* s_pk  = (const float*)d_in[10];
  const float* s_pv  = (const float*)d_in[11];
  const float* s_wo  = (const float*)d_in[12];
  const float* s_bo  = (const float*)d_in[13];
  const float* t_wq  = (const float*)d_in[14];
  const float* t_wk  = (const float*)d_in[15];
  const float* t_wv  = (const float*)d_in[16];
  const float* t_bq  = (const float*)d_in[17];
  const float* t_bk  = (const float*)d_in[18];
  const float* t_bv  = (const float*)d_in[19];
  const float* t_wo  = (const float*)d_in[20];
  const float* t_bo  = (const float*)d_in[21];
  const float* t_l1w = (const float*)d_in[22];
  const float* t_l1b = (const float*)d_in[23];
  const float* t_l2w = (const float*)d_in[24];
  const float* t_l2b = (const float*)d_in[25];
  const float* ln1g  = (const float*)d_in[26];
  const float* ln1b  = (const float*)d_in[27];
  const float* ln2g  = (const float*)d_in[28];
  const float* ln2b  = (const float*)d_in[29];
  const float* gnlg  = (const float*)d_in[30];
  const float* gnlb  = (const float*)d_in[31];
  const float* gnsg  = (const float*)d_in[32];
  const float* gnsb  = (const float*)d_in[33];
  const float* gntg  = (const float*)d_in[34];
  const float* gntb  = (const float*)d_in[35];
  const float* ff1w  = (const float*)d_in[36];
  const float* ff1b  = (const float*)d_in[37];
  const float* ff2w  = (const float*)d_in[38];
  const float* ff2b  = (const float*)d_in[39];
  const float* gn2g  = (const float*)d_in[40];
  const float* gn2b  = (const float*)d_in[41];

  float* ws = (float*)d_ws;
  float* part  = ws + 65536;
  unsigned short* a1_bf   = (unsigned short*)(ws + 131072);
  unsigned short* a2_bf   = (unsigned short*)(ws + 163840);
  unsigned short* adp_bf  = (unsigned short*)(ws + 196608);
  unsigned short* gcnw_bf = (unsigned short*)(ws + 229376);
  unsigned short* xs_bf   = (unsigned short*)(ws + 262144);   // ends 2359296 floats
  unsigned short* swoT = (unsigned short*)(ws + 2359296);
  unsigned short* twoT = (unsigned short*)(ws + 2361344);
  unsigned short* ff1T = (unsigned short*)(ws + 2363392);
  unsigned short* ff2T = (unsigned short*)(ws + 2367488);
  unsigned short* swqT = (unsigned short*)(ws + 2371584);
  unsigned short* swkT = (unsigned short*)(ws + 2373632);
  unsigned short* swvT = (unsigned short*)(ws + 2375680);
  unsigned short* twqT = (unsigned short*)(ws + 2377728);
  unsigned short* twkT = (unsigned short*)(ws + 2379776);
  unsigned short* twvT = (unsigned short*)(ws + 2381824);
  unsigned short* kpb  = (unsigned short*)(ws + 131072);
  unsigned short* PkT  = (unsigned short*)(ws + 720896);
  unsigned short* PvT  = (unsigned short*)(ws + 729088);
  unsigned short* vptb = (unsigned short*)(ws + 1179648);
  const size_t SLOT = 4194304;
  float* G0 = ws + SLOT * 1;
  float* G1 = ws + SLOT * 2;
  float* G2 = ws + SLOT * 3;
  float* G3 = ws + SLOT * 4;
  float* G4 = ws + SLOT * 5;
  float* G5 = ws + SLOT * 6;
  float* G6 = ws + SLOT * 7;
  unsigned short* U1 = (unsigned short*)G3;
  unsigned short* U2 = (unsigned short*)G3 + 4194304;
  unsigned short* U3 = (unsigned short*)G4;
  unsigned short* U4 = (unsigned short*)G4 + 4194304;
  unsigned short* U5 = (unsigned short*)G5;
  unsigned short* U6 = (unsigned short*)G5 + 4194304;
  unsigned short* s0bf = (unsigned short*)G1;
  unsigned short* Q1bf = (unsigned short*)G0;
  unsigned short* Q3bf = (unsigned short*)G0 + 4194304;
  unsigned short* Q2bf = (unsigned short*)G6;
  unsigned short* xkT = (unsigned short*)G4;
  unsigned short* xvT = (unsigned short*)G5;
  unsigned short* xt_bf = (unsigned short*)G6;
  float* out = (float*)d_out;

  const long BS = 2097152;

  // ---- setup casts ----
  k_adp<<<256, 256, 0, stream>>>(nv1, nv2, adp_bf);
  k_castW<<<832, 256, 0, stream>>>(a1, a2, gcn_w, s_wo, t_wo, ff1w, ff2w,
                                   s_wq, s_wk, s_wv, t_wq, t_wk, t_wv,
                                   a1_bf, a2_bf, gcnw_bf, swoT, twoT, ff1T, ff2T,
                                   swqT, swkT, swvT, twqT, twkT, twvT);

  // ---- xs bf16 (B,L,K,C) ----
  k_tr<<<dim3(512, 8), 256, 0, stream>>>(y, nullptr, nullptr, xs_bf, BS, 128, 32768, 1, BS, 64, 1, 16384, 64, 128);

  // ---- AdaptiveGCN (all-bf16 branch tensors) ----
  k_mix0<<<1024, 64, 0, stream>>>(xs_bf, gcnw_bf, gcn_b, s0bf);
  k_mix6<<<dim3(1024, 3), 64, 0, stream>>>(xs_bf, gcnw_bf, U1, U2, U3, U4, U5, U6);
  k_adj2M<<<512, 256, 0, stream>>>(a1_bf, U2, U1, Q1bf);
  k_adj2M<<<512, 256, 0, stream>>>(a2_bf, U4, U3, Q2bf);
  k_adj2M<<<512, 256, 0, stream>>>(adp_bf, U6, U5, Q3bf);
  k_gn_partB<<<dim3(64, 8), 256, 0, stream>>>(y, s0bf, Q1bf, Q2bf, Q3bf, G3, part);
  k_gn_apply<<<4096, 256, 0, stream>>>(G3, nullptr, part, gnlg, gnlb, nullptr, nullptr, G0);

  // ---- Linformer spatial attention (xs_bf input) ----
  k_castP<<<dim3(16, 2), 256, 0, stream>>>(s_pk, s_pv, PkT, PvT);
  k_qkvs_M<<<1024, 256, 0, stream>>>(xs_bf, swqT, swkT, swvT, (unsigned short*)G3, xkT, xvT);
  k_sprojM<<<dim3(256, 2), 256, 0, stream>>>(xkT, xvT, PkT, PvT, kpb, vptb);
  k_attnH<64, 1><<<512, 512, 0, stream>>>((unsigned short*)G3, kpb, vptb, (unsigned short*)G6);
  k_lin64<<<1024, 256, 0, stream>>>((unsigned short*)G6, swoT, s_bo, G4);
  k_tr<<<dim3(512, 8), 256, 0, stream>>>(G4, G1, y, nullptr, BS, 64, 16384, 1, BS, 128, 1, 32768, 128, 64);
  k_gn_part<<<dim3(64, 8), 256, 0, stream>>>(G1, nullptr, nullptr, nullptr, nullptr, nullptr, part);
  k_gn_apply<<<4096, 256, 0, stream>>>(G1, nullptr, part, gnsg, gnsb, nullptr, nullptr, G1);

  // ---- temporal transformer layer ----
  k_tr<<<dim3(512, 8), 256, 0, stream>>>(y, G2, nullptr, xt_bf, BS, 128, 32768, 1, BS, 8192, 1, 64, 64, 128);
  k_qkvt_M<<<1024, 256, 0, stream>>>(xt_bf, twqT, twkT, twvT, t_bq, t_bk, t_bv,
                                     (unsigned short*)G3, (unsigned short*)G4, (unsigned short*)G5);
  k_attnH<128, 0><<<512, 512, 0, stream>>>((unsigned short*)G3, (unsigned short*)G4, (unsigned short*)G5,
                                           (unsigned short*)G6);
  k_lin64<<<1024, 256, 0, stream>>>((unsigned short*)G6, twoT, t_bo, G3);
  k_tffn<<<1024, 256, 0, stream>>>(G2, G3, t_l1w, t_l1b, t_l2w, t_l2b,
                                   ln1g, ln1b, ln2g, ln2b, G6);
  k_tr<<<dim3(512, 8), 256, 0, stream>>>(G6, G2, y, nullptr, BS, 8192, 64, 1, BS, 128, 1, 32768, 128, 64);
  k_gn_part<<<dim3(64, 8), 256, 0, stream>>>(G2, nullptr, nullptr, nullptr, nullptr, nullptr, part);
  k_gn_apply<<<4096, 256, 0, stream>>>(G2, nullptr, part, gntg, gntb, G0, G1, G3);

  // ---- fuse + channel FFN + final GroupNorm ----
  k_tr<<<dim3(512, 8), 256, 0, stream>>>(G3, nullptr, nullptr, (unsigned short*)G4,
                                         BS, 128, 32768, 1, BS, 8192, 1, 64, 64, 128);
  k_cffn<<<1024, 256, 0, stream>>>((unsigned short*)G4, ff1T, ff2T, ff1b, ff2b, G5);
  k_tr<<<dim3(512, 8), 256, 0, stream>>>(G5, out, G3, nullptr, BS, 8192, 64, 1, BS, 128, 1, 32768, 128, 64);
  k_gn_part<<<dim3(64, 8), 256, 0, stream>>>(out, nullptr, nullptr, nullptr, nullptr, nullptr, part);
  k_gn_apply<<<4096, 256, 0, stream>>>(out, nullptr, part, gn2g, gn2b, nullptr, nullptr, out);
}

// Round 19
// 366.291 us; speedup vs baseline: 1.7723x; 1.0575x over previous
//
#include <hip/hip_runtime.h>
#include <math.h>

constexpr int CC = 64, KK = 256, LL = 128;
constexpr int NN = KK * LL;          // 32768
constexpr int PR = 64;               // Linformer projection
constexpr int CPG = 16;              // channels per group (C / 4)
constexpr float EPSV = 1e-5f;
constexpr float SCL = 0.35355339059327373f;  // 1/sqrt(8)

typedef __attribute__((ext_vector_type(8))) short short8;      // 8 bf16 (4 VGPR)
typedef __attribute__((ext_vector_type(4))) float f32x4;       // MFMA 16x16 acc

__device__ __forceinline__ unsigned short f2bf(float x) {
  union { float f; unsigned int u; } v; v.f = x;
  unsigned int r = (v.u + 0x7FFFu + ((v.u >> 16) & 1u)) >> 16;
  return (unsigned short)r;
}
__device__ __forceinline__ float bf2f(unsigned short x) {
  union { unsigned int u; float f; } v; v.u = ((unsigned int)x) << 16;
  return v.f;
}

// ---------------- adaptive adjacency: softmax(relu(nv1@nv2), axis=1) -> bf16 ----------------
__global__ __launch_bounds__(256) void k_adp(const float* __restrict__ nv1,
                                             const float* __restrict__ nv2,
                                             unsigned short* __restrict__ adp_bf) {
  int w = blockIdx.x, v = threadIdx.x;
  float s = 0.f;
  for (int d = 0; d < 10; ++d) s += nv1[w * 10 + d] * nv2[d * KK + v];
  s = fmaxf(s, 0.f);
  __shared__ float red[256];
  red[v] = s; __syncthreads();
  for (int off = 128; off; off >>= 1) { if (v < off) red[v] = fmaxf(red[v], red[v + off]); __syncthreads(); }
  float m = red[0]; __syncthreads();
  float e = expf(s - m);
  red[v] = e; __syncthreads();
  for (int off = 128; off; off >>= 1) { if (v < off) red[v] += red[v + off]; __syncthreads(); }
  adp_bf[w * KK + v] = f2bf(e / red[0]);
}

// ---------------- fused cast: a1,a2,gcn_w plain; 10 weights transposed; s_pk/s_pv transposed; grid 960 ----------------
__global__ __launch_bounds__(256) void k_castW(const float* __restrict__ s0, const float* __restrict__ s1,
                                               const float* __restrict__ s2,
                                               const float* __restrict__ swo, const float* __restrict__ two,
                                               const float* __restrict__ f1, const float* __restrict__ f2,
                                               const float* __restrict__ swq, const float* __restrict__ swk,
                                               const float* __restrict__ swv,
                                               const float* __restrict__ twq, const float* __restrict__ twk,
                                               const float* __restrict__ twv,
                                               const float* __restrict__ pk, const float* __restrict__ pv,
                                               unsigned short* __restrict__ d0, unsigned short* __restrict__ d1,
                                               unsigned short* __restrict__ d2,
                                               unsigned short* __restrict__ swoT, unsigned short* __restrict__ twoT,
                                               unsigned short* __restrict__ ff1T, unsigned short* __restrict__ ff2T,
                                               unsigned short* __restrict__ swqT, unsigned short* __restrict__ swkT,
                                               unsigned short* __restrict__ swvT,
                                               unsigned short* __restrict__ twqT, unsigned short* __restrict__ twkT,
                                               unsigned short* __restrict__ twvT,
                                               unsigned short* __restrict__ PkT, unsigned short* __restrict__ PvT) {
  int i = blockIdx.x * 256 + threadIdx.x;
  if (i < 65536) d0[i] = f2bf(s0[i]);
  else if (i < 131072) d1[i - 65536] = f2bf(s1[i - 65536]);
  else if (i < 159744) d2[i - 131072] = f2bf(s2[i - 131072]);
  else if (i >= 163840) {
    int j = i - 163840;
    if (j < 4096) { int r = j >> 6, c = j & 63; swoT[c * 64 + r] = f2bf(swo[j]); }
    else if (j < 8192) { int q = j - 4096; int r = q >> 6, c = q & 63; twoT[c * 64 + r] = f2bf(two[q]); }
    else if (j < 16384) { int q = j - 8192; int r = q >> 7, c = q & 127; ff1T[c * 64 + r] = f2bf(f1[q]); }
    else if (j < 24576) { int q = j - 16384; int r = q >> 6, c = q & 63; ff2T[c * 128 + r] = f2bf(f2[q]); }
    else if (j < 28672) { int q = j - 24576; int r = q >> 6, c = q & 63; swqT[c * 64 + r] = f2bf(swq[q]); }
    else if (j < 32768) { int q = j - 28672; int r = q >> 6, c = q & 63; swkT[c * 64 + r] = f2bf(swk[q]); }
    else if (j < 36864) { int q = j - 32768; int r = q >> 6, c = q & 63; swvT[c * 64 + r] = f2bf(swv[q]); }
    else if (j < 40960) { int q = j - 36864; int r = q >> 6, c = q & 63; twqT[c * 64 + r] = f2bf(twq[q]); }
    else if (j < 45056) { int q = j - 40960; int r = q >> 6, c = q & 63; twkT[c * 64 + r] = f2bf(twk[q]); }
    else if (j < 49152) { int q = j - 45056; int r = q >> 6, c = q & 63; twvT[c * 64 + r] = f2bf(twv[q]); }
    else if (j < 65536) { int q = j - 49152; int n = q >> 6, c = q & 63; PkT[c * 256 + n] = f2bf(pk[q]); }
    else if (j < 81920) { int q = j - 65536; int n = q >> 6, c = q & 63; PvT[c * 256 + n] = f2bf(pv[q]); }
  }
}

// ---------------- s0 term (bf16 out) ----------------
__global__ __launch_bounds__(64) void k_mix0(const unsigned short* __restrict__ Xbf,
                                             const unsigned short* __restrict__ Wbf,
                                             const float* __restrict__ bias,
                                             unsigned short* __restrict__ s0) {
  int pb = blockIdx.x;
  int lh = pb & 1;
  int k = (pb >> 1) & 255;
  int b = pb >> 9;
  int lane = threadIdx.x;
  int lr = lane & 15, g = lane >> 4;
  short8 af[4][2], bfv[4][2];
#pragma unroll
  for (int ot = 0; ot < 4; ++ot)
#pragma unroll
    for (int kc = 0; kc < 2; ++kc)
      af[ot][kc] = *(const short8*)(Wbf + (size_t)(ot * 16 + lr) * 448 + kc * 32 + g * 8);
#pragma unroll
  for (int ct = 0; ct < 4; ++ct)
#pragma unroll
    for (int kc = 0; kc < 2; ++kc)
      bfv[ct][kc] = *(const short8*)(Xbf + ((size_t)(b * 128 + lh * 64 + ct * 16 + lr) * 256 + k) * 64 + kc * 32 + g * 8);
  f32x4 acc[4][4];
#pragma unroll
  for (int ot = 0; ot < 4; ++ot)
#pragma unroll
    for (int ct = 0; ct < 4; ++ct) acc[ot][ct] = f32x4{0.f, 0.f, 0.f, 0.f};
#pragma unroll
  for (int kc = 0; kc < 2; ++kc)
#pragma unroll
    for (int ot = 0; ot < 4; ++ot)
#pragma unroll
      for (int ct = 0; ct < 4; ++ct)
        acc[ot][ct] = __builtin_amdgcn_mfma_f32_16x16x32_bf16(af[ot][kc], bfv[ct][kc], acc[ot][ct], 0, 0, 0);
#pragma unroll
  for (int ot = 0; ot < 4; ++ot)
#pragma unroll
    for (int ct = 0; ct < 4; ++ct) {
#pragma unroll
      for (int reg = 0; reg < 4; ++reg) {
        int o = ot * 16 + g * 4 + reg;
        s0[(size_t)(b * 64 + o) * NN + (size_t)k * 128 + lh * 64 + ct * 16 + lr] = f2bf(acc[ot][ct][reg] + bias[o]);
      }
    }
}

// ---------------- U terms ----------------
__global__ __launch_bounds__(64) void k_mix6(const unsigned short* __restrict__ Xbf,
                                             const unsigned short* __restrict__ Wbf,
                                             unsigned short* __restrict__ U1, unsigned short* __restrict__ U2,
                                             unsigned short* __restrict__ U3, unsigned short* __restrict__ U4,
                                             unsigned short* __restrict__ U5, unsigned short* __restrict__ U6) {
  unsigned short* Us[6] = {U1, U2, U3, U4, U5, U6};
  int pb = blockIdx.x;
  int sy = blockIdx.y;
  int b = pb >> 9;
  int rem = pb & 511;
  int l = rem >> 2;
  int kq = (rem & 3) * 64;
  size_t posbase = ((size_t)(b * 128 + l)) * 256 + kq;
  int lane = threadIdx.x;
  int lr = lane & 15, g = lane >> 4;

  short8 af[4][2];
#pragma unroll
  for (int rt = 0; rt < 4; ++rt)
#pragma unroll
    for (int kc = 0; kc < 2; ++kc)
      af[rt][kc] = *(const short8*)(Xbf + (posbase + rt * 16 + lr) * 64 + kc * 32 + g * 8);

  for (int si = 0; si < 2; ++si) {
    int s = sy * 2 + 1 + si;
    short8 bfv[4][2];
#pragma unroll
    for (int ct = 0; ct < 4; ++ct)
#pragma unroll
      for (int kc = 0; kc < 2; ++kc)
        bfv[ct][kc] = *(const short8*)(Wbf + (size_t)(ct * 16 + lr) * 448 + s * 64 + kc * 32 + g * 8);
    f32x4 acc[4][4];
#pragma unroll
    for (int rt = 0; rt < 4; ++rt)
#pragma unroll
      for (int ct = 0; ct < 4; ++ct) acc[rt][ct] = f32x4{0.f, 0.f, 0.f, 0.f};
#pragma unroll
    for (int kc = 0; kc < 2; ++kc)
#pragma unroll
      for (int rt = 0; rt < 4; ++rt)
#pragma unroll
        for (int ct = 0; ct < 4; ++ct)
          acc[rt][ct] = __builtin_amdgcn_mfma_f32_16x16x32_bf16(af[rt][kc], bfv[ct][kc], acc[rt][ct], 0, 0, 0);
    unsigned short* dst = Us[s - 1];
#pragma unroll
    for (int rt = 0; rt < 4; ++rt)
#pragma unroll
      for (int ct = 0; ct < 4; ++ct) {
        int o = ct * 16 + lr;
        int k = kq + rt * 16 + g * 4;
        ushort4 pk;
        pk.x = f2bf(acc[rt][ct][0]); pk.y = f2bf(acc[rt][ct][1]);
        pk.z = f2bf(acc[rt][ct][2]); pk.w = f2bf(acc[rt][ct][3]);
        *(ushort4*)&dst[((size_t)(b * 64 + o) * 128 + l) * 256 + k] = pk;
      }
  }
}

// ---------------- fused 2-hop (bf16 out) ----------------
__global__ __launch_bounds__(256) void k_adj2M(const unsigned short* __restrict__ Abf,
                                               const unsigned short* __restrict__ Ueven,
                                               const unsigned short* __restrict__ Uodd,
                                               unsigned short* __restrict__ out) {
  __shared__ unsigned short sH[32 * 256];
  int lq = blockIdx.x & 3, bc = blockIdx.x >> 2;
  int tid = threadIdx.x, wid = tid >> 6, lane = tid & 63;
  int lr = lane & 15, g = lane >> 4;
  int wbase = wid * 64;
  const unsigned short* aP = Abf + (size_t)(wbase + lr) * 256 + g * 8;
  const unsigned short* bP = Ueven + ((size_t)bc * 128 + lq * 32 + lr) * 256 + g * 8;

  f32x4 acc[4][2];
#pragma unroll
  for (int i = 0; i < 4; ++i)
#pragma unroll
    for (int j = 0; j < 2; ++j) acc[i][j] = f32x4{0.f, 0.f, 0.f, 0.f};
  for (int k0 = 0; k0 < 256; k0 += 32) {
    short8 af[4], bfv[2];
#pragma unroll
    for (int i = 0; i < 4; ++i) af[i] = *(const short8*)(aP + (size_t)i * 16 * 256 + k0);
#pragma unroll
    for (int i = 0; i < 2; ++i) bfv[i] = *(const short8*)(bP + (size_t)i * 16 * 256 + k0);
#pragma unroll
    for (int rm = 0; rm < 4; ++rm)
#pragma unroll
      for (int cn = 0; cn < 2; ++cn)
        acc[rm][cn] = __builtin_amdgcn_mfma_f32_16x16x32_bf16(af[rm], bfv[cn], acc[rm][cn], 0, 0, 0);
  }
  {
    const unsigned short* aT = Uodd + (size_t)bc * NN + (size_t)(lq * 32) * 256;
#pragma unroll
    for (int rm = 0; rm < 4; ++rm)
#pragma unroll
      for (int cn = 0; cn < 2; ++cn) {
        int l = cn * 16 + lr;
        int v = wbase + rm * 16 + g * 4;
        ushort4 av = *(const ushort4*)&aT[(size_t)l * 256 + v];
        ushort4 pk;
        pk.x = f2bf(acc[rm][cn][0] + bf2f(av.x));
        pk.y = f2bf(acc[rm][cn][1] + bf2f(av.y));
        pk.z = f2bf(acc[rm][cn][2] + bf2f(av.z));
        pk.w = f2bf(acc[rm][cn][3] + bf2f(av.w));
        int bo = ((l * 256 + v) * 2) ^ ((l & 7) << 4);
        *(ushort4*)((char*)sH + bo) = pk;
      }
  }
  __syncthreads();

  f32x4 c2[4][2];
#pragma unroll
  for (int i = 0; i < 4; ++i)
#pragma unroll
    for (int j = 0; j < 2; ++j) c2[i][j] = f32x4{0.f, 0.f, 0.f, 0.f};
  for (int k0 = 0; k0 < 256; k0 += 32) {
    short8 af[4], bfv[2];
#pragma unroll
    for (int i = 0; i < 4; ++i) af[i] = *(const short8*)(aP + (size_t)i * 16 * 256 + k0);
#pragma unroll
    for (int cn = 0; cn < 2; ++cn) {
      int l = cn * 16 + lr;
      int bo = ((l * 256 + k0 + g * 8) * 2) ^ ((l & 7) << 4);
      bfv[cn] = *(const short8*)((char*)sH + bo);
    }
#pragma unroll
    for (int rm = 0; rm < 4; ++rm)
#pragma unroll
      for (int cn = 0; cn < 2; ++cn)
        c2[rm][cn] = __builtin_amdgcn_mfma_f32_16x16x32_bf16(af[rm], bfv[cn], c2[rm][cn], 0, 0, 0);
  }
  unsigned short* dst = out + (size_t)bc * NN + lq * 32;
#pragma unroll
  for (int rm = 0; rm < 4; ++rm)
#pragma unroll
    for (int cn = 0; cn < 2; ++cn) {
      int col = cn * 16 + lr;
      int row = wbase + rm * 16 + g * 4;
#pragma unroll
      for (int j = 0; j < 4; ++j)
        dst[(size_t)(row + j) * 128 + col] = f2bf(c2[rm][cn][j]);
    }
}

// ---------------- generic (c,l)-plane transpose; optional dst/add/bf16 ----------------
__global__ __launch_bounds__(256) void k_tr(const float* __restrict__ src, float* __restrict__ dst,
                                            const float* __restrict__ add,
                                            unsigned short* __restrict__ dstBf,
                                            long sb, long sk, long sc, long sl,
                                            long db, long dk, long dc, long dl, int nC, int nL) {
  int outer = blockIdx.x;
  int b = outer >> 8, k = outer & 255;
  int tilesL = nL >> 5;
  int tC = blockIdx.y / tilesL, tL = blockIdx.y % tilesL;
  int c0 = tC << 5, l0 = tL << 5;
  __shared__ float s[32][33];
  int tx = threadIdx.x & 31, ty = threadIdx.x >> 5;
  const float* sp = src + (long)b * sb + (long)k * sk;
#pragma unroll
  for (int j = 0; j < 4; ++j) {
    int cc = c0 + ty + j * 8;
    s[ty + j * 8][tx] = sp[(long)cc * sc + (long)(l0 + tx) * sl];
  }
  __syncthreads();
  long dbase = (long)b * db + (long)k * dk;
#pragma unroll
  for (int j = 0; j < 4; ++j) {
    int ll = l0 + ty + j * 8;
    long off = dbase + (long)(c0 + tx) * dc + (long)ll * dl;
    float val = s[tx][ty + j * 8];
    if (add) val += add[off];
    if (dst) dst[off] = val;
    if (dstBf) dstBf[off] = f2bf(val);
  }
}

// ---------------- spatial QKV (MFMA, bf16 in/out): Q RM; K^T,V^T [bl][c][n] ----------------
__global__ __launch_bounds__(256) void k_qkvs_M(const unsigned short* __restrict__ Xbf,
                                                const unsigned short* __restrict__ wqT,
                                                const unsigned short* __restrict__ wkT,
                                                const unsigned short* __restrict__ wvT,
                                                unsigned short* __restrict__ qb,
                                                unsigned short* __restrict__ xkT,
                                                unsigned short* __restrict__ xvT) {
  int r0 = blockIdx.x * 64;
  int t = threadIdx.x, w = t >> 6, lane = t & 63;
  int lr = lane & 15, g = lane >> 4;
  const unsigned short* aP = Xbf + (size_t)(r0 + w * 16 + lr) * 64 + g * 8;
  short8 ax0 = *(const short8*)aP;
  short8 ax1 = *(const short8*)(aP + 32);
  {
    f32x4 acc[4];
#pragma unroll
    for (int ct = 0; ct < 4; ++ct) acc[ct] = f32x4{0.f, 0.f, 0.f, 0.f};
#pragma unroll
    for (int ct = 0; ct < 4; ++ct) {
      short8 b0 = *(const short8*)(wqT + (size_t)(ct * 16 + lr) * 64 + g * 8);
      short8 b1 = *(const short8*)(wqT + (size_t)(ct * 16 + lr) * 64 + 32 + g * 8);
      acc[ct] = __builtin_amdgcn_mfma_f32_16x16x32_bf16(ax0, b0, acc[ct], 0, 0, 0);
      acc[ct] = __builtin_amdgcn_mfma_f32_16x16x32_bf16(ax1, b1, acc[ct], 0, 0, 0);
    }
#pragma unroll
    for (int ct = 0; ct < 4; ++ct)
#pragma unroll
      for (int reg = 0; reg < 4; ++reg)
        qb[(size_t)(r0 + w * 16 + g * 4 + reg) * 64 + ct * 16 + lr] = f2bf(acc[ct][reg]);
  }
  short8 bx0[4], bx1[4];
#pragma unroll
  for (int ct = 0; ct < 4; ++ct) {
    const unsigned short* bP = Xbf + (size_t)(r0 + ct * 16 + lr) * 64 + g * 8;
    bx0[ct] = *(const short8*)bP;
    bx1[ct] = *(const short8*)(bP + 32);
  }
  int bl = r0 >> 8, nb = r0 & 255;
#pragma unroll
  for (int which = 0; which < 2; ++which) {
    const unsigned short* WT = which ? wvT : wkT;
    unsigned short* dstb = which ? xvT : xkT;
    short8 aw0 = *(const short8*)(WT + (size_t)(w * 16 + lr) * 64 + g * 8);
    short8 aw1 = *(const short8*)(WT + (size_t)(w * 16 + lr) * 64 + 32 + g * 8);
    f32x4 acc[4];
#pragma unroll
    for (int ct = 0; ct < 4; ++ct) {
      acc[ct] = f32x4{0.f, 0.f, 0.f, 0.f};
      acc[ct] = __builtin_amdgcn_mfma_f32_16x16x32_bf16(aw0, bx0[ct], acc[ct], 0, 0, 0);
      acc[ct] = __builtin_amdgcn_mfma_f32_16x16x32_bf16(aw1, bx1[ct], acc[ct], 0, 0, 0);
    }
#pragma unroll
    for (int ct = 0; ct < 4; ++ct)
#pragma unroll
      for (int reg = 0; reg < 4; ++reg) {
        int o = w * 16 + g * 4 + reg;
        dstb[(size_t)bl * 16384 + (size_t)o * 256 + nb + ct * 16 + lr] = f2bf(acc[ct][reg]);
      }
  }
}

// ---------------- temporal QKV (MFMA, bf16 in/out) ----------------
__global__ __launch_bounds__(256) void k_qkvt_M(const unsigned short* __restrict__ Xbf,
                                                const unsigned short* __restrict__ wqT,
                                                const unsigned short* __restrict__ wkT,
                                                const unsigned short* __restrict__ wvT,
                                                const float* __restrict__ bq, const float* __restrict__ bk_,
                                                const float* __restrict__ bv,
                                                unsigned short* __restrict__ qb,
                                                unsigned short* __restrict__ kb,
                                                unsigned short* __restrict__ vt) {
  int r0 = blockIdx.x * 64;
  int t = threadIdx.x, w = t >> 6, lane = t & 63;
  int lr = lane & 15, g = lane >> 4;
  const unsigned short* aP = Xbf + (size_t)(r0 + w * 16 + lr) * 64 + g * 8;
  short8 ax0 = *(const short8*)aP;
  short8 ax1 = *(const short8*)(aP + 32);
#pragma unroll
  for (int which = 0; which < 2; ++which) {
    const unsigned short* WT = which ? wkT : wqT;
    const float* bias = which ? bk_ : bq;
    unsigned short* dstb = which ? kb : qb;
    f32x4 acc[4];
#pragma unroll
    for (int ct = 0; ct < 4; ++ct) {
      acc[ct] = f32x4{0.f, 0.f, 0.f, 0.f};
      short8 b0 = *(const short8*)(WT + (size_t)(ct * 16 + lr) * 64 + g * 8);
      short8 b1 = *(const short8*)(WT + (size_t)(ct * 16 + lr) * 64 + 32 + g * 8);
      acc[ct] = __builtin_amdgcn_mfma_f32_16x16x32_bf16(ax0, b0, acc[ct], 0, 0, 0);
      acc[ct] = __builtin_amdgcn_mfma_f32_16x16x32_bf16(ax1, b1, acc[ct], 0, 0, 0);
    }
#pragma unroll
    for (int ct = 0; ct < 4; ++ct) {
      float bvv = bias[ct * 16 + lr];
#pragma unroll
      for (int reg = 0; reg < 4; ++reg)
        dstb[(size_t)(r0 + w * 16 + g * 4 + reg) * 64 + ct * 16 + lr] = f2bf(acc[ct][reg] + bvv);
    }
  }
  short8 bx0[4], bx1[4];
#pragma unroll
  for (int ct = 0; ct < 4; ++ct) {
    const unsigned short* bP = Xbf + (size_t)(r0 + ct * 16 + lr) * 64 + g * 8;
    bx0[ct] = *(const short8*)bP;
    bx1[ct] = *(const short8*)(bP + 32);
  }
  int bkk = r0 >> 7, lbase = r0 & 127;
  short8 aw0 = *(const short8*)(wvT + (size_t)(w * 16 + lr) * 64 + g * 8);
  short8 aw1 = *(const short8*)(wvT + (size_t)(w * 16 + lr) * 64 + 32 + g * 8);
  f32x4 acc[4];
#pragma unroll
  for (int ct = 0; ct < 4; ++ct) {
    acc[ct] = f32x4{0.f, 0.f, 0.f, 0.f};
    acc[ct] = __builtin_amdgcn_mfma_f32_16x16x32_bf16(aw0, bx0[ct], acc[ct], 0, 0, 0);
    acc[ct] = __builtin_amdgcn_mfma_f32_16x16x32_bf16(aw1, bx1[ct], acc[ct], 0, 0, 0);
  }
#pragma unroll
  for (int ct = 0; ct < 4; ++ct)
#pragma unroll
    for (int reg = 0; reg < 4; ++reg) {
      int o = w * 16 + g * 4 + reg;
      vt[(size_t)bkk * 8192 + (size_t)o * 128 + lbase + ct * 16 + lr] = f2bf(acc[ct][reg] + bv[o]);
    }
}

// ---------------- MFMA sproj ----------------
__global__ __launch_bounds__(256) void k_sprojM(const unsigned short* __restrict__ XkT,
                                                const unsigned short* __restrict__ XvT,
                                                const unsigned short* __restrict__ PkT,
                                                const unsigned short* __restrict__ PvT,
                                                unsigned short* __restrict__ kpb,
                                                unsigned short* __restrict__ vptb) {
  int bl = blockIdx.x;
  int which = blockIdx.y;
  int t = threadIdx.x, w = t >> 6, lane = t & 63;
  int lr = lane & 15, g = lane >> 4;
  const unsigned short* Abase = which ? PvT : XkT + (size_t)bl * 16384;
  const unsigned short* Bbase = which ? XvT + (size_t)bl * 16384 : PkT;
  const unsigned short* aP = Abase + (size_t)(w * 16 + lr) * 256 + g * 8;
  f32x4 acc[4];
#pragma unroll
  for (int ct = 0; ct < 4; ++ct) acc[ct] = f32x4{0.f, 0.f, 0.f, 0.f};
  for (int k0 = 0; k0 < 256; k0 += 32) {
    short8 af = *(const short8*)(aP + k0);
#pragma unroll
    for (int ct = 0; ct < 4; ++ct) {
      short8 bf = *(const short8*)(Bbase + (size_t)(ct * 16 + lr) * 256 + k0 + g * 8);
      acc[ct] = __builtin_amdgcn_mfma_f32_16x16x32_bf16(af, bf, acc[ct], 0, 0, 0);
    }
  }
  if (!which) {
    unsigned short* dst = kpb + (size_t)bl * 4096;
#pragma unroll
    for (int ct = 0; ct < 4; ++ct) {
      int p = ct * 16 + lr;
      int c0 = w * 16 + g * 4;
      ushort4 pk;
      pk.x = f2bf(acc[ct][0]); pk.y = f2bf(acc[ct][1]);
      pk.z = f2bf(acc[ct][2]); pk.w = f2bf(acc[ct][3]);
      *(ushort4*)&dst[(size_t)p * 64 + c0] = pk;
    }
  } else {
    unsigned short* dst = vptb + (size_t)bl * 4096;
#pragma unroll
    for (int ct = 0; ct < 4; ++ct) {
      int c = ct * 16 + lr;
      int p0 = w * 16 + g * 4;
      ushort4 pk;
      pk.x = f2bf(acc[ct][0]); pk.y = f2bf(acc[ct][1]);
      pk.z = f2bf(acc[ct][2]); pk.w = f2bf(acc[ct][3]);
      *(ushort4*)&dst[(size_t)c * 64 + p0] = pk;
    }
  }
}

// ---------------- MFMA 64x64 projection: bf16 in @ W^T + bias -> fp32 ----------------
__global__ __launch_bounds__(256) void k_lin64(const unsigned short* __restrict__ in,
                                               const unsigned short* __restrict__ WT,
                                               const float* __restrict__ bias,
                                               float* __restrict__ out) {
  int r0 = blockIdx.x * 64;
  int t = threadIdx.x, w = t >> 6, lane = t & 63;
  int lr = lane & 15, g = lane >> 4;
  const unsigned short* aP = in + (size_t)(r0 + w * 16 + lr) * 64 + g * 8;
  short8 af0 = *(const short8*)aP;
  short8 af1 = *(const short8*)(aP + 32);
  f32x4 acc[4];
#pragma unroll
  for (int ct = 0; ct < 4; ++ct) acc[ct] = f32x4{0.f, 0.f, 0.f, 0.f};
#pragma unroll
  for (int ct = 0; ct < 4; ++ct) {
    short8 b0 = *(const short8*)(WT + (size_t)(ct * 16 + lr) * 64 + g * 8);
    short8 b1 = *(const short8*)(WT + (size_t)(ct * 16 + lr) * 64 + 32 + g * 8);
    acc[ct] = __builtin_amdgcn_mfma_f32_16x16x32_bf16(af0, b0, acc[ct], 0, 0, 0);
    acc[ct] = __builtin_amdgcn_mfma_f32_16x16x32_bf16(af1, b1, acc[ct], 0, 0, 0);
  }
#pragma unroll
  for (int ct = 0; ct < 4; ++ct) {
    int o = ct * 16 + lr;
    float bv = bias[o];
#pragma unroll
    for (int reg = 0; reg < 4; ++reg)
      out[(size_t)(r0 + w * 16 + g * 4 + reg) * 64 + o] = acc[ct][reg] + bv;
  }
}

// ---------------- fused channel FFN (MFMA) ----------------
__global__ __launch_bounds__(256) void k_cffn(const unsigned short* __restrict__ in,
                                              const unsigned short* __restrict__ ff1T,
                                              const unsigned short* __restrict__ ff2T,
                                              const float* __restrict__ b1,
                                              const float* __restrict__ b2,
                                              float* __restrict__ out) {
  __shared__ unsigned short sH[4][16 * 128];
  int r0 = blockIdx.x * 64;
  int t = threadIdx.x, w = t >> 6, lane = t & 63;
  int lr = lane & 15, g = lane >> 4;
  unsigned short* myH = sH[w];
  const unsigned short* aP = in + (size_t)(r0 + w * 16 + lr) * 64 + g * 8;
  short8 af0 = *(const short8*)aP;
  short8 af1 = *(const short8*)(aP + 32);
  f32x4 acc1[8];
#pragma unroll
  for (int ct = 0; ct < 8; ++ct) acc1[ct] = f32x4{0.f, 0.f, 0.f, 0.f};
#pragma unroll
  for (int ct = 0; ct < 8; ++ct) {
    short8 b0 = *(const short8*)(ff1T + (size_t)(ct * 16 + lr) * 64 + g * 8);
    short8 bx = *(const short8*)(ff1T + (size_t)(ct * 16 + lr) * 64 + 32 + g * 8);
    acc1[ct] = __builtin_amdgcn_mfma_f32_16x16x32_bf16(af0, b0, acc1[ct], 0, 0, 0);
    acc1[ct] = __builtin_amdgcn_mfma_f32_16x16x32_bf16(af1, bx, acc1[ct], 0, 0, 0);
  }
#pragma unroll
  for (int ct = 0; ct < 8; ++ct) {
    int o = ct * 16 + lr;
    float bv = b1[o];
#pragma unroll
    for (int reg = 0; reg < 4; ++reg) {
      int m = g * 4 + reg;
      float h = fmaxf(acc1[ct][reg] + bv, 0.f);
      int bo = ((m * 128 + o) * 2) ^ ((m & 7) << 4);
      *(unsigned short*)((char*)myH + bo) = f2bf(h);
    }
  }
  __syncthreads();
  short8 ha[4];
#pragma unroll
  for (int ks = 0; ks < 4; ++ks) {
    int bo = ((lr * 128 + ks * 32 + g * 8) * 2) ^ ((lr & 7) << 4);
    ha[ks] = *(const short8*)((char*)myH + bo);
  }
  f32x4 acc2[4];
#pragma unroll
  for (int ct = 0; ct < 4; ++ct) acc2[ct] = f32x4{0.f, 0.f, 0.f, 0.f};
#pragma unroll
  for (int ct = 0; ct < 4; ++ct)
#pragma unroll
    for (int ks = 0; ks < 4; ++ks) {
      short8 b0 = *(const short8*)(ff2T + (size_t)(ct * 16 + lr) * 128 + ks * 32 + g * 8);
      acc2[ct] = __builtin_amdgcn_mfma_f32_16x16x32_bf16(ha[ks], b0, acc2[ct], 0, 0, 0);
    }
#pragma unroll
  for (int ct = 0; ct < 4; ++ct) {
    int o = ct * 16 + lr;
    float bv = b2[o];
#pragma unroll
    for (int reg = 0; reg < 4; ++reg)
      out[(size_t)(r0 + w * 16 + g * 4 + reg) * 64 + o] = acc2[ct][reg] + bv;
  }
}

// ---------------- fused LN1 -> FFN(64->8 gelu ->64) -> LN2 ----------------
__global__ __launch_bounds__(256) void k_tffn(const float* __restrict__ A, const float* __restrict__ Bz,
                                              const float* __restrict__ l1w, const float* __restrict__ l1b,
                                              const float* __restrict__ l2w, const float* __restrict__ l2b,
                                              const float* __restrict__ ln1g, const float* __restrict__ ln1b,
                                              const float* __restrict__ ln2g, const float* __restrict__ ln2b,
                                              float* __restrict__ outp) {
  int r0 = blockIdx.x * 64;
  __shared__ float sSrc[64][65];
  __shared__ float sH[64][8];
  __shared__ float sW1[64][8];
  __shared__ float sW2[8][64];
  int t = threadIdx.x;
  for (int i = t; i < 512; i += 256) { ((float*)sW1)[i] = l1w[i]; ((float*)sW2)[i] = l2w[i]; }
  int c = t & 63, rg = t >> 6;
  float g1 = ln1g[c], be1 = ln1b[c];
  for (int it = 0; it < 16; ++it) {
    int r = it * 4 + rg;
    size_t idx = (size_t)(r0 + r) * 64 + c;
    float x = A[idx] + Bz[idx];
    float s = x, ss = x * x;
#pragma unroll
    for (int off = 32; off; off >>= 1) { s += __shfl_xor(s, off); ss += __shfl_xor(ss, off); }
    float mu = s * (1.f / 64.f);
    float var = ss * (1.f / 64.f) - mu * mu;
    sSrc[r][c] = (x - mu) * rsqrtf(var + EPSV) * g1 + be1;
  }
  __syncthreads();
#pragma unroll
  for (int p = 0; p < 2; ++p) {
    int idx = t + 256 * p;
    int row = idx >> 3, j = idx & 7;
    float acc = l1b[j];
    for (int cc = 0; cc < 64; ++cc) acc += sSrc[row][cc] * sW1[cc][j];
    acc = 0.5f * acc * (1.f + erff(acc * 0.70710678118654752440f));
    sH[row][j] = acc;
  }
  __syncthreads();
  float g2 = ln2g[c], be2 = ln2b[c];
  float l2bc = l2b[c];
  for (int it = 0; it < 16; ++it) {
    int r = it * 4 + rg;
    float o = l2bc;
#pragma unroll
    for (int j = 0; j < 8; ++j) o += sH[r][j] * sW2[j][c];
    float x = sSrc[r][c] + o;
    float s = x, ss = x * x;
#pragma unroll
    for (int off = 32; off; off >>= 1) { s += __shfl_xor(s, off); ss += __shfl_xor(ss, off); }
    float mu = s * (1.f / 64.f);
    float var = ss * (1.f / 64.f) - mu * mu;
    outp[(size_t)(r0 + r) * 64 + c] = (x - mu) * rsqrtf(var + EPSV) * g2 + be2;
  }
}

// ---------------- per-head MFMA attention; bf16 out ----------------
template <int NKV, int KVSHIFT>
__global__ __launch_bounds__(512) void k_attnH(const unsigned short* __restrict__ Qb,
                                               const unsigned short* __restrict__ Kb,
                                               const unsigned short* __restrict__ VTb,
                                               unsigned short* __restrict__ O) {
  constexpr int NCT = NKV / 16;
  constexpr int NKS = NKV / 32;
  int blk = blockIdx.x;
  const unsigned short* Qp = Qb + (size_t)blk * 128 * 64;
  unsigned short* Op = O + (size_t)blk * 128 * 64;
  const unsigned short* Kp = Kb + (size_t)(blk >> KVSHIFT) * NKV * 64;
  const unsigned short* VTp = VTb + (size_t)(blk >> KVSHIFT) * 64 * NKV;
  int t = threadIdx.x;
  int h = t >> 6, lane = t & 63, lr = lane & 15, g = lane >> 4;
  __shared__ unsigned short sP[8][16 * NKV];
  unsigned short* myP = sP[h];

  short8 kbf[NCT];
#pragma unroll
  for (int ct = 0; ct < NCT; ++ct)
    kbf[ct] = *(const short8*)(Kp + (size_t)(ct * 16 + lr) * 64 + h * 8);

  int vr = h * 8 + lr; if (vr > 63) vr = 63;
  short8 vbf[NKS];
#pragma unroll
  for (int ks = 0; ks < NKS; ++ks)
    vbf[ks] = *(const short8*)(VTp + (size_t)vr * NKV + ks * 32 + g * 8);

  for (int mt = 0; mt < 8; ++mt) {
    short8 qa = short8{0, 0, 0, 0, 0, 0, 0, 0};
    if (g == 0) qa = *(const short8*)(Qp + (size_t)(mt * 16 + lr) * 64 + h * 8);

    f32x4 sacc[NCT];
#pragma unroll
    for (int ct = 0; ct < NCT; ++ct) sacc[ct] = f32x4{0.f, 0.f, 0.f, 0.f};
#pragma unroll
    for (int ct = 0; ct < NCT; ++ct)
      sacc[ct] = __builtin_amdgcn_mfma_f32_16x16x32_bf16(qa, kbf[ct], sacc[ct], 0, 0, 0);

    float inv4[4];
#pragma unroll
    for (int reg = 0; reg < 4; ++reg) {
      float s = 0.f;
#pragma unroll
      for (int ct = 0; ct < NCT; ++ct) {
        float e = __expf(sacc[ct][reg] * SCL);
        sacc[ct][reg] = e;
        s += e;
      }
      s += __shfl_xor(s, 1); s += __shfl_xor(s, 2); s += __shfl_xor(s, 4); s += __shfl_xor(s, 8);
      inv4[reg] = 1.f / s;
    }

#pragma unroll
    for (int ct = 0; ct < NCT; ++ct)
#pragma unroll
      for (int reg = 0; reg < 4; ++reg) {
        int row = g * 4 + reg;
        int bo = ((row * NKV + ct * 16 + lr) * 2) ^ ((row & 7) << 4);
        *(unsigned short*)((char*)myP + bo) = f2bf(sacc[ct][reg]);
      }
    __syncthreads();

    f32x4 oacc = f32x4{0.f, 0.f, 0.f, 0.f};
#pragma unroll
    for (int ks = 0; ks < NKS; ++ks) {
      int bo = ((lr * NKV + ks * 32 + g * 8) * 2) ^ ((lr & 7) << 4);
      short8 pa = *(const short8*)((char*)myP + bo);
      oacc = __builtin_amdgcn_mfma_f32_16x16x32_bf16(pa, vbf[ks], oacc, 0, 0, 0);
    }
    if (lr < 8) {
#pragma unroll
      for (int reg = 0; reg < 4; ++reg) {
        int row = mt * 16 + g * 4 + reg;
        Op[(size_t)row * 64 + h * 8 + lr] = f2bf(oacc[reg] * inv4[reg]);
      }
    }
    __syncthreads();
  }
}

// ---------------- GroupNorm stats (fp32 inputs, optional sum write-back) ----------------
__global__ __launch_bounds__(256) void k_gn_part(const float* __restrict__ p0, const float* __restrict__ p1,
                                                 const float* __restrict__ p2, const float* __restrict__ p3,
                                                 const float* __restrict__ p4,
                                                 float* __restrict__ sumOut,
                                                 float* __restrict__ part) {
  int bg = blockIdx.y, blk = blockIdx.x, t = threadIdx.x;
  size_t start = (size_t)bg * ((size_t)CPG * NN) + (size_t)blk * 8192;
  const float4* q0 = (const float4*)(p0 + start);
  const float4* q1 = p1 ? (const float4*)(p1 + start) : nullptr;
  const float4* q2 = p2 ? (const float4*)(p2 + start) : nullptr;
  const float4* q3 = p3 ? (const float4*)(p3 + start) : nullptr;
  const float4* q4 = p4 ? (const float4*)(p4 + start) : nullptr;
  float4* so = sumOut ? (float4*)(sumOut + start) : nullptr;
  float s = 0.f, ss = 0.f;
  for (int i = t; i < 2048; i += 256) {
    float4 x = q0[i];
    if (q1) { float4 y4 = q1[i]; x.x += y4.x; x.y += y4.y; x.z += y4.z; x.w += y4.w; }
    if (q2) { float4 y4 = q2[i]; x.x += y4.x; x.y += y4.y; x.z += y4.z; x.w += y4.w; }
    if (q3) { float4 y4 = q3[i]; x.x += y4.x; x.y += y4.y; x.z += y4.z; x.w += y4.w; }
    if (q4) { float4 y4 = q4[i]; x.x += y4.x; x.y += y4.y; x.z += y4.z; x.w += y4.w; }
    if (so) so[i] = x;
    s += x.x + x.y + x.z + x.w;
    ss += x.x * x.x + x.y * x.y + x.z * x.z + x.w * x.w;
  }
  __shared__ float rs[256], rq[256];
  rs[t] = s; rq[t] = ss; __syncthreads();
  for (int off = 128; off; off >>= 1) { if (t < off) { rs[t] += rs[t + off]; rq[t] += rq[t + off]; } __syncthreads(); }
  if (t == 0) { part[(bg * 64 + blk) * 2] = rs[0]; part[(bg * 64 + blk) * 2 + 1] = rq[0]; }
}

// ---------------- GroupNorm stats: y(fp32) + 4 bf16 -> fp32 sum + partials ----------------
__global__ __launch_bounds__(256) void k_gn_partB(const float* __restrict__ p0,
                                                  const unsigned short* __restrict__ q1,
                                                  const unsigned short* __restrict__ q2,
                                                  const unsigned short* __restrict__ q3,
                                                  const unsigned short* __restrict__ q4,
                                                  float* __restrict__ sumOut,
                                                  float* __restrict__ part) {
  int bg = blockIdx.y, blk = blockIdx.x, t = threadIdx.x;
  size_t start = (size_t)bg * ((size_t)CPG * NN) + (size_t)blk * 8192;
  const float4* f0 = (const float4*)(p0 + start);
  const ushort4* b1 = (const ushort4*)(q1 + start);
  const ushort4* b2 = (const ushort4*)(q2 + start);
  const ushort4* b3 = (const ushort4*)(q3 + start);
  const ushort4* b4 = (const ushort4*)(q4 + start);
  float4* so = (float4*)(sumOut + start);
  float s = 0.f, ss = 0.f;
  for (int i = t; i < 2048; i += 256) {
    float4 x = f0[i];
    ushort4 u;
    u = b1[i]; x.x += bf2f(u.x); x.y += bf2f(u.y); x.z += bf2f(u.z); x.w += bf2f(u.w);
    u = b2[i]; x.x += bf2f(u.x); x.y += bf2f(u.y); x.z += bf2f(u.z); x.w += bf2f(u.w);
    u = b3[i]; x.x += bf2f(u.x); x.y += bf2f(u.y); x.z += bf2f(u.z); x.w += bf2f(u.w);
    u = b4[i]; x.x += bf2f(u.x); x.y += bf2f(u.y); x.z += bf2f(u.z); x.w += bf2f(u.w);
    so[i] = x;
    s += x.x + x.y + x.z + x.w;
    ss += x.x * x.x + x.y * x.y + x.z * x.z + x.w * x.w;
  }
  __shared__ float rs[256], rq[256];
  rs[t] = s; rq[t] = ss; __syncthreads();
  for (int off = 128; off; off >>= 1) { if (t < off) { rs[t] += rs[t + off]; rq[t] += rq[t + off]; } __syncthreads(); }
  if (t == 0) { part[(bg * 64 + blk) * 2] = rs[0]; part[(bg * 64 + blk) * 2 + 1] = rq[0]; }
}

// out = GN(p0[+p1]) (+ q0) (+ q1) — reduces 64 partials per block
__global__ __launch_bounds__(256) void k_gn_apply(const float* __restrict__ p0, const float* __restrict__ p1,
                                                  const float* __restrict__ part, const float* __restrict__ g,
                                                  const float* __restrict__ be,
                                                  const float* __restrict__ q0, const float* __restrict__ q1,
                                                  float* __restrict__ out) {
  size_t i4 = (size_t)blockIdx.x * 256 + threadIdx.x;
  size_t i = i4 * 4;
  int chan = (int)(i >> 15) & 63;
  int bg = (int)(i >> 19);
  __shared__ float smu, srr;
  int t = threadIdx.x;
  if (t < 64) {
    float s = part[(bg * 64 + t) * 2], ss = part[(bg * 64 + t) * 2 + 1];
#pragma unroll
    for (int off = 32; off; off >>= 1) { s += __shfl_xor(s, off); ss += __shfl_xor(ss, off); }
    if (t == 0) {
      float inv = 1.f / (float)((size_t)CPG * NN);
      float mu = s * inv;
      float var = ss * inv - mu * mu;
      smu = mu; srr = rsqrtf(var + EPSV);
    }
  }
  __syncthreads();
  float mu = smu, rr = srr;
  float4 x = ((const float4*)p0)[i4];
  if (p1) { float4 y4 = ((const float4*)p1)[i4]; x.x += y4.x; x.y += y4.y; x.z += y4.z; x.w += y4.w; }
  float gc = g[chan], bc = be[chan];
  float4 v;
  v.x = (x.x - mu) * rr * gc + bc;
  v.y = (x.y - mu) * rr * gc + bc;
  v.z = (x.z - mu) * rr * gc + bc;
  v.w = (x.w - mu) * rr * gc + bc;
  if (q0) { float4 y4 = ((const float4*)q0)[i4]; v.x += y4.x; v.y += y4.y; v.z += y4.z; v.w += y4.w; }
  if (q1) { float4 y4 = ((const float4*)q1)[i4]; v.x += y4.x; v.y += y4.y; v.z += y4.z; v.w += y4.w; }
  ((float4*)out)[i4] = v;
}

// out = GN_l(SL) + GN_s(SS) + GN_t(ST); three partial sets at part+0/+2048/+4096
__global__ __launch_bounds__(256) void k_gn_apply3(const float* __restrict__ SL, const float* __restrict__ SS,
                                                   const float* __restrict__ ST,
                                                   const float* __restrict__ part,
                                                   const float* __restrict__ gl, const float* __restrict__ bl_,
                                                   const float* __restrict__ gs, const float* __restrict__ bs_,
                                                   const float* __restrict__ gt, const float* __restrict__ bt_,
                                                   float* __restrict__ out) {
  size_t i4 = (size_t)blockIdx.x * 256 + threadIdx.x;
  size_t i = i4 * 4;
  int chan = (int)(i >> 15) & 63;
  int bg = (int)(i >> 19);
  __shared__ float smu[3], srr[3];
  int t = threadIdx.x;
  if (t < 192) {
    int which = t >> 6, tt = t & 63;
    const float* pp = part + which * 2048;
    float s = pp[(bg * 64 + tt) * 2], ss = pp[(bg * 64 + tt) * 2 + 1];
#pragma unroll
    for (int off = 32; off; off >>= 1) { s += __shfl_xor(s, off); ss += __shfl_xor(ss, off); }
    if (tt == 0) {
      float inv = 1.f / (float)((size_t)CPG * NN);
      float mu = s * inv;
      float var = ss * inv - mu * mu;
      smu[which] = mu; srr[which] = rsqrtf(var + EPSV);
    }
  }
  __syncthreads();
  float mL = smu[0], rL = srr[0];
  float mS = smu[1], rS = srr[1];
  float mT = smu[2], rT = srr[2];
  float gL = gl[chan] * rL, bL = bl_[chan] - mL * gl[chan] * rL;
  float gS = gs[chan] * rS, bS = bs_[chan] - mS * gs[chan] * rS;
  float gT = gt[chan] * rT, bT = bt_[chan] - mT * gt[chan] * rT;
  float4 xl = ((const float4*)SL)[i4];
  float4 xs = ((const float4*)SS)[i4];
  float4 xt = ((const float4*)ST)[i4];
  float4 v;
  v.x = xl.x * gL + bL + xs.x * gS + bS + xt.x * gT + bT;
  v.y = xl.y * gL + bL + xs.y * gS + bS + xt.y * gT + bT;
  v.z = xl.z * gL + bL + xs.z * gS + bS + xt.z * gT + bT;
  v.w = xl.w * gL + bL + xs.w * gS + bS + xt.w * gT + bT;
  ((float4*)out)[i4] = v;
}

extern "C" void kernel_launch(void* const* d_in, const int* in_sizes, int n_in,
                              void* d_out, int out_size, void* d_ws, size_t ws_size,
                              hipStream_t stream) {
  (void)in_sizes; (void)n_in; (void)out_size; (void)ws_size;
  const float* y     = (const float*)d_in[0];
  const float* a1    = (const float*)d_in[1];
  const float* a2    = (const float*)d_in[2];
  const float* nv1   = (const float*)d_in[3];
  const float* nv2   = (const float*)d_in[4];
  const float* gcn_w = (const float*)d_in[5];
  const float* gcn_b = (const float*)d_in[6];
  const float* s_wq  = (const float*)d_in[7];
  const float* s_wk  = (const float*)d_in[8];
  const float* s_wv  = (const float*)d_in[9];
  const float* s_pk  = (const float*)d_in[10];
  const float* s_pv  = (const float*)d_in[11];
  const float* s_wo  = (const float*)d_in[12];
  const float* s_bo  = (const float*)d_in[13];
  const float* t_wq  = (const float*)d_in[14];
  const float* t_wk  = (const float*)d_in[15];
  const float* t_wv  = (const float*)d_in[16];
  const float* t_bq  = (const float*)d_in[17];
  const float* t_bk  = (const float*)d_in[18];
  const float* t_bv  = (const float*)d_in[19];
  const float* t_wo  = (const float*)d_in[20];
  const float* t_bo  = (const float*)d_in[21];
  const float* t_l1w = (const float*)d_in[22];
  const float* t_l1b = (const float*)d_in[23];
  const float* t_l2w = (const float*)d_in[24];
  const float* t_l2b = (const float*)d_in[25];
  const float* ln1g  = (const float*)d_in[26];
  const float* ln1b  = (const float*)d_in[27];
  const float* ln2g  = (const float*)d_in[28];
  const float* ln2b  = (const float*)d_in[29];
  const float* gnlg  = (const float*)d_in[30];
  const float* gnlb  = (const float*)d_in[31];
  const float* gnsg  = (const float*)d_in[32];
  const float* gnsb  = (const float*)d_in[33];
  const float* gntg  = (const float*)d_in[34];
  const float* gntb  = (const float*)d_in[35];
  const float* ff1w  = (const float*)d_in[36];
  const float* ff1b  = (const float*)d_in[37];
  const float* ff2w  = (const float*)d_in[38];
  const float* ff2b  = (const float*)d_in[39];
  const float* gn2g  = (const float*)d_in[40];
  const float* gn2b  = (const float*)d_in[41];

  float* ws = (float*)d_ws;
  float* part  = ws + 65536;                                  // 3 x 1024 used at stride 2048
  unsigned short* a1_bf   = (unsigned short*)(ws + 131072);
  unsigned short* a2_bf   = (unsigned short*)(ws + 163840);
  unsigned short* adp_bf  = (unsigned short*)(ws + 196608);
  unsigned short* gcnw_bf = (unsigned short*)(ws + 229376);
  unsigned short* xs_bf   = (unsigned short*)(ws + 262144);   // floats [262144, 2359296)
  unsigned short* swoT = (unsigned short*)(ws + 2359296);
  unsigned short* twoT = (unsigned short*)(ws + 2361344);
  unsigned short* ff1T = (unsigned short*)(ws + 2363392);
  unsigned short* ff2T = (unsigned short*)(ws + 2367488);
  unsigned short* swqT = (unsigned short*)(ws + 2371584);
  unsigned short* swkT = (unsigned short*)(ws + 2373632);
  unsigned short* swvT = (unsigned short*)(ws + 2375680);
  unsigned short* twqT = (unsigned short*)(ws + 2377728);
  unsigned short* twkT = (unsigned short*)(ws + 2379776);
  unsigned short* twvT = (unsigned short*)(ws + 2381824);
  unsigned short* PkT  = (unsigned short*)(ws + 2383872);     // moved OUT of xs_bf range
  unsigned short* PvT  = (unsigned short*)(ws + 2392064);
  unsigned short* kpb  = (unsigned short*)(ws + 131072);      // written after xs_bf dead
  unsigned short* vptb = (unsigned short*)(ws + 1179648);
  const size_t SLOT = 4194304;
  float* G0 = ws + SLOT * 1;
  float* G1 = ws + SLOT * 2;
  float* G2 = ws + SLOT * 3;
  float* G3 = ws + SLOT * 4;
  float* G4 = ws + SLOT * 5;
  float* G5 = ws + SLOT * 6;
  float* G6 = ws + SLOT * 7;
  unsigned short* U1 = (unsigned short*)G3;
  unsigned short* U2 = (unsigned short*)G3 + 4194304;
  unsigned short* U3 = (unsigned short*)G4;
  unsigned short* U4 = (unsigned short*)G4 + 4194304;
  unsigned short* U5 = (unsigned short*)G5;
  unsigned short* U6 = (unsigned short*)G5 + 4194304;
  unsigned short* s0bf = (unsigned short*)G1;
  unsigned short* Q1bf = (unsigned short*)G0;
  unsigned short* Q3bf = (unsigned short*)G0 + 4194304;
  unsigned short* Q2bf = (unsigned short*)G6;
  unsigned short* qbuf = (unsigned short*)G0;                 // spatial & temporal Q (after partB)
  unsigned short* xkT = (unsigned short*)G4;
  unsigned short* xvT = (unsigned short*)G5;
  unsigned short* kbuf = (unsigned short*)G4;                 // temporal K
  unsigned short* vtbuf = (unsigned short*)G5;                // temporal V^T
  unsigned short* xt_bf = (unsigned short*)G6;
  float* out = (float*)d_out;

  const long BS = 2097152;

  // ---- setup casts (PkT/PvT now outside xs_bf range) ----
  k_adp<<<256, 256, 0, stream>>>(nv1, nv2, adp_bf);
  k_castW<<<960, 256, 0, stream>>>(a1, a2, gcn_w, s_wo, t_wo, ff1w, ff2w,
                                   s_wq, s_wk, s_wv, t_wq, t_wk, t_wv, s_pk, s_pv,
                                   a1_bf, a2_bf, gcnw_bf, swoT, twoT, ff1T, ff2T,
                                   swqT, swkT, swvT, twqT, twkT, twvT, PkT, PvT);

  // ---- xs bf16 (B,L,K,C) ----
  k_tr<<<dim3(512, 8), 256, 0, stream>>>(y, nullptr, nullptr, xs_bf, BS, 128, 32768, 1, BS, 64, 1, 16384, 64, 128);

  // ---- AdaptiveGCN: sum -> G3 (raw, GN deferred), partials -> part+0 ----
  k_mix0<<<1024, 64, 0, stream>>>(xs_bf, gcnw_bf, gcn_b, s0bf);
  k_mix6<<<dim3(1024, 3), 64, 0, stream>>>(xs_bf, gcnw_bf, U1, U2, U3, U4, U5, U6);
  k_adj2M<<<512, 256, 0, stream>>>(a1_bf, U2, U1, Q1bf);
  k_adj2M<<<512, 256, 0, stream>>>(a2_bf, U4, U3, Q2bf);
  k_adj2M<<<512, 256, 0, stream>>>(adp_bf, U6, U5, Q3bf);
  k_gn_partB<<<dim3(64, 8), 256, 0, stream>>>(y, s0bf, Q1bf, Q2bf, Q3bf, G3, part);

  // ---- Linformer spatial attention (Q in G0; GCN sum lives in G3) ----
  k_qkvs_M<<<1024, 256, 0, stream>>>(xs_bf, swqT, swkT, swvT, qbuf, xkT, xvT);
  k_sprojM<<<dim3(256, 2), 256, 0, stream>>>(xkT, xvT, PkT, PvT, kpb, vptb);
  k_attnH<64, 1><<<512, 512, 0, stream>>>(qbuf, kpb, vptb, (unsigned short*)G6);
  k_lin64<<<1024, 256, 0, stream>>>((unsigned short*)G6, swoT, s_bo, G4);
  k_tr<<<dim3(512, 8), 256, 0, stream>>>(G4, G1, y, nullptr, BS, 64, 16384, 1, BS, 128, 1, 32768, 128, 64);
  k_gn_part<<<dim3(64, 8), 256, 0, stream>>>(G1, nullptr, nullptr, nullptr, nullptr, nullptr, part + 2048);

  // ---- temporal transformer layer (sum -> G2, partials -> part+4096) ----
  k_tr<<<dim3(512, 8), 256, 0, stream>>>(y, G2, nullptr, xt_bf, BS, 128, 32768, 1, BS, 8192, 1, 64, 64, 128);
  k_qkvt_M<<<1024, 256, 0, stream>>>(xt_bf, twqT, twkT, twvT, t_bq, t_bk, t_bv, qbuf, kbuf, vtbuf);
  k_attnH<128, 0><<<512, 512, 0, stream>>>(qbuf, kbuf, vtbuf, (unsigned short*)G6);
  k_lin64<<<1024, 256, 0, stream>>>((unsigned short*)G6, twoT, t_bo, G4);
  k_tffn<<<1024, 256, 0, stream>>>(G2, G4, t_l1w, t_l1b, t_l2w, t_l2b,
                                   ln1g, ln1b, ln2g, ln2b, G6);
  k_tr<<<dim3(512, 8), 256, 0, stream>>>(G6, G2, y, nullptr, BS, 8192, 64, 1, BS, 128, 1, 32768, 128, 64);
  k_gn_part<<<dim3(64, 8), 256, 0, stream>>>(G2, nullptr, nullptr, nullptr, nullptr, nullptr, part + 4096);

  // ---- fused triple-GN: y_in2 = GN_l(G3) + GN_s(G1) + GN_t(G2) -> G3 (in-place safe) ----
  k_gn_apply3<<<4096, 256, 0, stream>>>(G3, G1, G2, part, gnlg, gnlb, gnsg, gnsb, gntg, gntb, G3);

  // ---- fuse + channel FFN + final GroupNorm ----
  k_tr<<<dim3(512, 8), 256, 0, stream>>>(G3, nullptr, nullptr, (unsigned short*)G4,
                                         BS, 128, 32768, 1, BS, 8192, 1, 64, 64, 128);
  k_cffn<<<1024, 256, 0, stream>>>((unsigned short*)G4, ff1T, ff2T, ff1b, ff2b, G5);
  k_tr<<<dim3(512, 8), 256, 0, stream>>>(G5, out, G3, nullptr, BS, 8192, 64, 1, BS, 128, 1, 32768, 128, 64);
  k_gn_part<<<dim3(64, 8), 256, 0, stream>>>(out, nullptr, nullptr, nullptr, nullptr, nullptr, part);
  k_gn_apply<<<4096, 256, 0, stream>>>(out, nullptr, part, gn2g, gn2b, nullptr, nullptr, out);
}